// Round 1
// baseline (58066.547 us; speedup 1.0000x reference)
//
#include <hip/hip_runtime.h>
#include <hip/hip_bf16.h>

#define BB 2
#define TT 1023
#define CC 1024
#define HH 16
#define HSZ 64
#define LL 6
#define FFD 4096
#define VV 50258
#define MM (BB*TT)   // 2046

// ---------------------------------------------------------------------------
// Embedding: out[r, c] = wte[ids[r], c] + wpe[r % T, c]
// ---------------------------------------------------------------------------
__global__ __launch_bounds__(256) void embed_kernel(
    const int* __restrict__ ids, const float* __restrict__ wte,
    const float* __restrict__ wpe, float* __restrict__ out)
{
    int r = blockIdx.x;           // 0..M-1
    int t = r % TT;
    long id = ids[r];
    const float* src = wte + id * (long)CC;
    const float* pos = wpe + (long)t * CC;
    float* dst = out + (long)r * CC;
    for (int c = threadIdx.x; c < CC; c += 256)
        dst[c] = src[c] + pos[c];
}

// ---------------------------------------------------------------------------
// Generic tiled fp32 GEMM.  C = act(A @ B(^T) + bias)
// A: [M,K] row-major. B: if !BT [K,N], if BT [N,K]. C: [M,N].
// Batched over grid.z with strides sB (B) and sC (C); A shared across batch.
// ---------------------------------------------------------------------------
#define GBM 64
#define GBN 64
#define GBK 16

template<bool BT, bool RELU>
__global__ __launch_bounds__(256) void gemm_kernel(
    const float* __restrict__ A, const float* __restrict__ B,
    const float* __restrict__ bias, float* __restrict__ Cm,
    int M, int N, int K, long sB, long sC)
{
    B  += (long)blockIdx.z * sB;
    Cm += (long)blockIdx.z * sC;

    __shared__ float As[GBK][GBM + 4];
    __shared__ float Bs[GBK][GBN + 4];

    const int tx = threadIdx.x, ty = threadIdx.y;      // 16 x 16
    const int tid = ty * 16 + tx;
    const int m0 = blockIdx.y * GBM, n0 = blockIdx.x * GBN;

    float acc[4][4] = {};

    for (int k0 = 0; k0 < K; k0 += GBK) {
        // A tile: 64 rows x 16 k  (1024 elems, 4 per thread)
        #pragma unroll
        for (int l = 0; l < 4; ++l) {
            int idx = tid + l * 256;
            int kk = idx & 15, mm = idx >> 4;
            int gm = m0 + mm;
            As[kk][mm] = (gm < M) ? A[(long)gm * K + k0 + kk] : 0.f;
        }
        // B tile: 16 k x 64 n
        #pragma unroll
        for (int l = 0; l < 4; ++l) {
            int idx = tid + l * 256;
            if (!BT) {
                int nn = idx & 63, kk = idx >> 6;
                int gn = n0 + nn;
                Bs[kk][nn] = (gn < N) ? B[(long)(k0 + kk) * N + gn] : 0.f;
            } else {
                int kk = idx & 15, nn = idx >> 4;
                int gn = n0 + nn;
                Bs[kk][nn] = (gn < N) ? B[(long)gn * K + k0 + kk] : 0.f;
            }
        }
        __syncthreads();

        #pragma unroll
        for (int kk = 0; kk < GBK; ++kk) {
            float a[4], b[4];
            #pragma unroll
            for (int i = 0; i < 4; ++i) a[i] = As[kk][ty * 4 + i];
            #pragma unroll
            for (int j = 0; j < 4; ++j) b[j] = Bs[kk][tx * 4 + j];
            #pragma unroll
            for (int i = 0; i < 4; ++i)
                #pragma unroll
                for (int j = 0; j < 4; ++j)
                    acc[i][j] += a[i] * b[j];
        }
        __syncthreads();
    }

    #pragma unroll
    for (int i = 0; i < 4; ++i) {
        int gm = m0 + ty * 4 + i;
        if (gm >= M) continue;
        #pragma unroll
        for (int j = 0; j < 4; ++j) {
            int gn = n0 + tx * 4 + j;
            if (gn >= N) continue;
            float v = acc[i][j];
            if (bias) v += bias[gn];
            if (RELU) v = fmaxf(v, 0.f);
            Cm[(long)gm * N + gn] = v;
        }
    }
}

// ---------------------------------------------------------------------------
// Flash attention, one wave (64 lanes) per (b, h, t) query row.
// q,k,v layout: [H, M, HS]  (rows of batch b occupy b*T .. b*T+T-1)
// out written directly into concat layout: [M, C] at column h*HS.
// scale = 1/sqrt(C) = 1/32  (reference scales by sqrt(n_embed)!)
// ---------------------------------------------------------------------------
__global__ __launch_bounds__(64) void attn_kernel(
    const float* __restrict__ q, const float* __restrict__ k,
    const float* __restrict__ v, float* __restrict__ out, int causal)
{
    const int t = blockIdx.x, h = blockIdx.y, b = blockIdx.z;
    const int lane = threadIdx.x;
    const float scale = 1.0f / 32.0f;

    const long head_base = ((long)h * MM + (long)b * TT) * HSZ;
    const float qd = q[head_base + (long)t * HSZ + lane];
    const float* kb = k + head_base;
    const float* vb = v + head_base;

    const int smax = causal ? (t + 1) : TT;

    float m = -3.0e38f, l = 0.f, acc = 0.f;
    for (int s = 0; s < smax; ++s) {
        float prod = qd * kb[(long)s * HSZ + lane];
        #pragma unroll
        for (int off = 32; off > 0; off >>= 1)
            prod += __shfl_xor(prod, off);
        float score = prod * scale;
        float mn = fmaxf(m, score);
        float corr = __expf(m - mn);
        float p = __expf(score - mn);
        l = l * corr + p;
        acc = acc * corr + p * vb[(long)s * HSZ + lane];
        m = mn;
    }
    out[((long)b * TT + t) * CC + h * HSZ + lane] = acc / l;
}

// ---------------------------------------------------------------------------
// LayerNorm with optional fused residual: out = (res? res : 0) + g*xhat + b
// one block per row
// ---------------------------------------------------------------------------
__global__ __launch_bounds__(256) void ln_kernel(
    const float* __restrict__ in, const float* __restrict__ res,
    const float* __restrict__ g, const float* __restrict__ b,
    float* __restrict__ out)
{
    const int r = blockIdx.x;
    const float* row = in + (long)r * CC;
    __shared__ float red[256];

    float s = 0.f;
    for (int c = threadIdx.x; c < CC; c += 256) s += row[c];
    red[threadIdx.x] = s;
    __syncthreads();
    for (int o = 128; o > 0; o >>= 1) {
        if (threadIdx.x < o) red[threadIdx.x] += red[threadIdx.x + o];
        __syncthreads();
    }
    const float mean = red[0] / CC;
    __syncthreads();

    float s2 = 0.f;
    for (int c = threadIdx.x; c < CC; c += 256) {
        float d = row[c] - mean;
        s2 += d * d;
    }
    red[threadIdx.x] = s2;
    __syncthreads();
    for (int o = 128; o > 0; o >>= 1) {
        if (threadIdx.x < o) red[threadIdx.x] += red[threadIdx.x + o];
        __syncthreads();
    }
    const float rstd = rsqrtf(red[0] / CC + 1e-5f);

    for (int c = threadIdx.x; c < CC; c += 256) {
        float vv = g[c] * (row[c] - mean) * rstd + b[c];
        if (res) vv += res[(long)r * CC + c];
        out[(long)r * CC + c] = vv;
    }
}

// ---------------------------------------------------------------------------
extern "C" void kernel_launch(void* const* d_in, const int* in_sizes, int n_in,
                              void* d_out, int out_size, void* d_ws, size_t ws_size,
                              hipStream_t stream)
{
    const int*   x      = (const int*)  d_in[0];
    const int*   y      = (const int*)  d_in[1];
    const float* wte    = (const float*)d_in[2];
    const float* wpe_x  = (const float*)d_in[3];
    const float* wpe_y  = (const float*)d_in[4];
    const float* eWq    = (const float*)d_in[5];
    const float* eWk    = (const float*)d_in[6];
    const float* eWv    = (const float*)d_in[7];
    const float* epw    = (const float*)d_in[8];
    const float* epb    = (const float*)d_in[9];
    const float* eln1g  = (const float*)d_in[10];
    const float* eln1b  = (const float*)d_in[11];
    const float* eln2g  = (const float*)d_in[12];
    const float* eln2b  = (const float*)d_in[13];
    const float* ew1    = (const float*)d_in[14];
    const float* eb1    = (const float*)d_in[15];
    const float* ew2    = (const float*)d_in[16];
    const float* eb2    = (const float*)d_in[17];
    const float* dsWq   = (const float*)d_in[18];
    const float* dsWk   = (const float*)d_in[19];
    const float* dsWv   = (const float*)d_in[20];
    const float* dspw   = (const float*)d_in[21];
    const float* dspb   = (const float*)d_in[22];
    const float* dcWq   = (const float*)d_in[23];
    const float* dcWk   = (const float*)d_in[24];
    const float* dcWv   = (const float*)d_in[25];
    const float* dcpw   = (const float*)d_in[26];
    const float* dcpb   = (const float*)d_in[27];
    const float* dln1g  = (const float*)d_in[28];
    const float* dln1b  = (const float*)d_in[29];
    const float* dln2g  = (const float*)d_in[30];
    const float* dln2b  = (const float*)d_in[31];
    const float* dln3g  = (const float*)d_in[32];
    const float* dln3b  = (const float*)d_in[33];
    const float* dw1    = (const float*)d_in[34];
    const float* db1    = (const float*)d_in[35];
    const float* dw2    = (const float*)d_in[36];
    const float* db2    = (const float*)d_in[37];
    const float* lnfg   = (const float*)d_in[38];
    const float* lnfb   = (const float*)d_in[39];
    const float* lm_b   = (const float*)d_in[40];

    float* out = (float*)d_out;

    // workspace carve-up (fp32)
    const size_t MC = (size_t)MM * CC;        // 2,095,104 floats
    float* ws  = (float*)d_ws;
    float* enc = ws;            // [M, C]
    float* dec = enc + MC;      // [M, C]
    float* t0  = dec + MC;      // [M, C]  block outputs pre-residual
    float* qb  = t0  + MC;      // [H, M, HS]
    float* kb  = qb  + MC;      // [H, M, HS]
    float* vb  = kb  + MC;      // [H, M, HS]
    float* a0  = vb  + MC;      // [M, C]  attn concat
    float* ff  = a0  + MC;      // [M, FF]

    const dim3 gblk(16, 16);

    auto gemm = [&](const float* A, const float* Bm, const float* bias, float* Cm,
                    int M_, int N_, int K_, int batch, long sB, long sC,
                    bool bt, bool relu) {
        dim3 grid((N_ + GBN - 1) / GBN, (M_ + GBM - 1) / GBM, batch);
        if (bt) {
            if (relu) gemm_kernel<true,  true ><<<grid, gblk, 0, stream>>>(A, Bm, bias, Cm, M_, N_, K_, sB, sC);
            else      gemm_kernel<true,  false><<<grid, gblk, 0, stream>>>(A, Bm, bias, Cm, M_, N_, K_, sB, sC);
        } else {
            if (relu) gemm_kernel<false, true ><<<grid, gblk, 0, stream>>>(A, Bm, bias, Cm, M_, N_, K_, sB, sC);
            else      gemm_kernel<false, false><<<grid, gblk, 0, stream>>>(A, Bm, bias, Cm, M_, N_, K_, sB, sC);
        }
    };

    // one attention block: q from xq, k/v from xkv, writes concat to a0,
    // then proj into t0
    auto mha = [&](const float* xq, const float* xkv,
                   const float* Wq, const float* Wk, const float* Wv,
                   const float* pw, const float* pb, int causal) {
        const long sW = (long)CC * HSZ;   // per-head weight stride
        const long sO = (long)MM * HSZ;   // per-head output stride
        gemm(xq,  Wq, nullptr, qb, MM, HSZ, CC, HH, sW, sO, false, false);
        gemm(xkv, Wk, nullptr, kb, MM, HSZ, CC, HH, sW, sO, false, false);
        gemm(xkv, Wv, nullptr, vb, MM, HSZ, CC, HH, sW, sO, false, false);
        attn_kernel<<<dim3(TT, HH, BB), 64, 0, stream>>>(qb, kb, vb, a0, causal);
        gemm(a0, pw, pb, t0, MM, CC, CC, 1, 0, 0, false, false);
    };

    auto ffn = [&](const float* xin, const float* w1, const float* b1,
                   const float* w2, const float* b2) {
        gemm(xin, w1, b1, ff, MM, FFD, CC, 1, 0, 0, false, true);
        gemm(ff,  w2, b2, t0, MM, CC, FFD, 1, 0, 0, false, false);
    };

    // ---- encoder ----
    embed_kernel<<<MM, 256, 0, stream>>>(x, wte, wpe_x, enc);
    for (int i = 0; i < LL; ++i) {
        const long wOff = (long)i * HH * CC * HSZ;
        const long pOff = (long)i * CC * CC;
        const long cOff = (long)i * CC;
        mha(enc, enc, eWq + wOff, eWk + wOff, eWv + wOff, epw + pOff, epb + cOff, 0);
        ln_kernel<<<MM, 256, 0, stream>>>(t0, enc, eln1g + cOff, eln1b + cOff, enc);
        ffn(enc, ew1 + (long)i * CC * FFD, eb1 + (long)i * FFD,
                 ew2 + (long)i * FFD * CC, eb2 + cOff);
        ln_kernel<<<MM, 256, 0, stream>>>(t0, enc, eln2g + cOff, eln2b + cOff, enc);
    }

    // ---- decoder ----
    embed_kernel<<<MM, 256, 0, stream>>>(y, wte, wpe_y, dec);
    for (int i = 0; i < LL; ++i) {
        const long wOff = (long)i * HH * CC * HSZ;
        const long pOff = (long)i * CC * CC;
        const long cOff = (long)i * CC;
        // masked self-attn
        mha(dec, dec, dsWq + wOff, dsWk + wOff, dsWv + wOff, dspw + pOff, dspb + cOff, 1);
        ln_kernel<<<MM, 256, 0, stream>>>(t0, dec, dln1g + cOff, dln1b + cOff, dec);
        // cross-attn (k/v from final encoder output)
        mha(dec, enc, dcWq + wOff, dcWk + wOff, dcWv + wOff, dcpw + pOff, dcpb + cOff, 0);
        ln_kernel<<<MM, 256, 0, stream>>>(t0, dec, dln2g + cOff, dln2b + cOff, dec);
        // ffn
        ffn(dec, dw1 + (long)i * CC * FFD, db1 + (long)i * FFD,
                 dw2 + (long)i * FFD * CC, db2 + cOff);
        ln_kernel<<<MM, 256, 0, stream>>>(t0, dec, dln3g + cOff, dln3b + cOff, dec);
    }

    // ---- final LN + logits (tied embedding, B^T GEMM) ----
    ln_kernel<<<MM, 256, 0, stream>>>(dec, nullptr, lnfg, lnfb, t0);
    gemm(t0, wte, lm_b, out, MM, VV, CC, 1, 0, 0, true, false);
}

// Round 2
// 43400.629 us; speedup vs baseline: 1.3379x; 1.3379x over previous
//
#include <hip/hip_runtime.h>
#include <hip/hip_bf16.h>

#define BB 2
#define TT 1023
#define CC 1024
#define HH 16
#define HSZ 64
#define LL 6
#define FFD 4096
#define VV 50258
#define MM (BB*TT)   // 2046

typedef __attribute__((ext_vector_type(4))) float  f32x4;
typedef __attribute__((ext_vector_type(8))) short  s16x8;
typedef __attribute__((ext_vector_type(4))) short  s16x4;

__device__ __forceinline__ short f2b(float x) {
    __hip_bfloat16 h = __float2bfloat16(x);
    short s;
    __builtin_memcpy(&s, &h, 2);
    return s;
}

// ---------------------------------------------------------------------------
// Embedding: out[r, c] = wte[ids[r], c] + wpe[r % T, c]   (float4 vectorized)
// ---------------------------------------------------------------------------
__global__ __launch_bounds__(256) void embed_kernel(
    const int* __restrict__ ids, const float* __restrict__ wte,
    const float* __restrict__ wpe, float* __restrict__ out)
{
    int r = blockIdx.x;
    int t = r % TT;
    long id = ids[r];
    int c = threadIdx.x * 4;
    float4 a = *(const float4*)(wte + id * (long)CC + c);
    float4 p = *(const float4*)(wpe + (long)t * CC + c);
    float4 o; o.x = a.x + p.x; o.y = a.y + p.y; o.z = a.z + p.z; o.w = a.w + p.w;
    *(float4*)(out + (long)r * CC + c) = o;
}

// ---------------------------------------------------------------------------
// Transpose + fp32->bf16 convert: in [R][S] fp32 -> out [S][R] bf16.
// block (32,8), 32x32 LDS tile, grid (S/32, R/32, Z). R,S multiples of 32.
// ---------------------------------------------------------------------------
__global__ __launch_bounds__(256) void tcvt_kernel(
    const float* __restrict__ in, __hip_bfloat16* __restrict__ out,
    int R, int S, long inZ, long outZ)
{
    in  += (long)blockIdx.z * inZ;
    out += (long)blockIdx.z * outZ;
    __shared__ float tile[32][33];
    int s0 = blockIdx.x * 32, r0 = blockIdx.y * 32;
    int tx = threadIdx.x, ty = threadIdx.y;
    #pragma unroll
    for (int i = 0; i < 4; ++i)
        tile[ty + i * 8][tx] = in[(long)(r0 + ty + i * 8) * S + s0 + tx];
    __syncthreads();
    #pragma unroll
    for (int i = 0; i < 4; ++i)
        out[(long)(s0 + ty + i * 8) * R + r0 + tx] =
            __float2bfloat16(tile[tx][ty + i * 8]);
}

// ---------------------------------------------------------------------------
// bf16 MFMA GEMM.  C[M,N] = act(A[M,K](fp32) @ B + bias),  B is [N][K]
// (bf16 if BF16B else fp32), converted/staged to LDS as bf16.
// 128x128x32 tile, 256 threads = 4 waves (2x2), each wave 64x64 (4x4 frags
// of 16x16), mfma_f32_16x16x32_bf16, fp32 accumulate. ldc = output stride.
// ---------------------------------------------------------------------------
template<bool BF16B, bool RELU>
__global__ __launch_bounds__(256) void mgemm_kernel(
    const float* __restrict__ A, const void* __restrict__ Bv,
    const float* __restrict__ bias, float* __restrict__ Cm,
    int M, int N, int K, int ldc)
{
    __shared__ short As[128][40];   // padded: 80B row stride, 16B-aligned frags
    __shared__ short Bs[128][40];   // [n][k]

    const int tid  = threadIdx.x;
    const int lane = tid & 63, w = tid >> 6;
    const int wr = w >> 1, wc = w & 1;
    const int lr = lane & 15, kg = lane >> 4;
    const int m0 = blockIdx.y * 128, n0 = blockIdx.x * 128;

    const int ar = tid >> 3, ac = (tid & 7) * 4;   // A stage: 4 passes of 32 rows
    const int br = tid >> 2, bc = (tid & 3) * 8;   // B stage: 2 passes of 64 rows

    f32x4 acc[4][4];
    #pragma unroll
    for (int i = 0; i < 4; ++i)
        #pragma unroll
        for (int j = 0; j < 4; ++j)
            acc[i][j] = (f32x4){0.f, 0.f, 0.f, 0.f};

    for (int k0 = 0; k0 < K; k0 += 32) {
        // ---- A tile: 128 rows x 32 k (fp32 -> bf16) ----
        #pragma unroll
        for (int p = 0; p < 4; ++p) {
            int row = ar + p * 32;
            int gm = m0 + row;
            float4 f = {0.f, 0.f, 0.f, 0.f};
            if (gm < M) f = *(const float4*)(A + (long)gm * K + k0 + ac);
            s16x4 h; h[0] = f2b(f.x); h[1] = f2b(f.y); h[2] = f2b(f.z); h[3] = f2b(f.w);
            *(s16x4*)&As[row][ac] = h;
        }
        // ---- B tile: 128 n x 32 k ----
        #pragma unroll
        for (int p = 0; p < 2; ++p) {
            int n = br + p * 64;
            int gn = n0 + n;
            s16x8 h = (s16x8){0,0,0,0,0,0,0,0};
            if (gn < N) {
                if (BF16B) {
                    const __hip_bfloat16* Bp = (const __hip_bfloat16*)Bv;
                    h = *(const s16x8*)(Bp + (long)gn * K + k0 + bc);
                } else {
                    const float* Bp = (const float*)Bv;
                    float4 f0 = *(const float4*)(Bp + (long)gn * K + k0 + bc);
                    float4 f1 = *(const float4*)(Bp + (long)gn * K + k0 + bc + 4);
                    h[0] = f2b(f0.x); h[1] = f2b(f0.y); h[2] = f2b(f0.z); h[3] = f2b(f0.w);
                    h[4] = f2b(f1.x); h[5] = f2b(f1.y); h[6] = f2b(f1.z); h[7] = f2b(f1.w);
                }
            }
            *(s16x8*)&Bs[n][bc] = h;
        }
        __syncthreads();

        // ---- fragments + MFMA ----
        s16x8 af[4], bf[4];
        #pragma unroll
        for (int i = 0; i < 4; ++i)
            af[i] = *(const s16x8*)&As[wr * 64 + i * 16 + lr][kg * 8];
        #pragma unroll
        for (int j = 0; j < 4; ++j)
            bf[j] = *(const s16x8*)&Bs[wc * 64 + j * 16 + lr][kg * 8];
        #pragma unroll
        for (int i = 0; i < 4; ++i)
            #pragma unroll
            for (int j = 0; j < 4; ++j)
                acc[i][j] = __builtin_amdgcn_mfma_f32_16x16x32_bf16(
                    af[i], bf[j], acc[i][j], 0, 0, 0);
        __syncthreads();
    }

    // ---- epilogue: C/D layout col=lane&15, row=(lane>>4)*4+reg ----
    #pragma unroll
    for (int j = 0; j < 4; ++j) {
        int gcol = n0 + wc * 64 + j * 16 + lr;
        if (gcol >= N) continue;
        float bv = bias ? bias[gcol] : 0.f;
        #pragma unroll
        for (int i = 0; i < 4; ++i) {
            int grow0 = m0 + wr * 64 + i * 16 + kg * 4;
            #pragma unroll
            for (int q = 0; q < 4; ++q) {
                int gr = grow0 + q;
                if (gr >= M) continue;
                float v = acc[i][j][q] + bv;
                if (RELU) v = fmaxf(v, 0.f);
                Cm[(long)gr * ldc + gcol] = v;
            }
        }
    }
}

// ---------------------------------------------------------------------------
// Flash attention, one wave per (b, h, t) query row.
// qkv layout: [M, 3072]: q at col h*64, k at 1024+h*64, v at 2048+h*64.
// out: [M, C] at column h*64.  scale = 1/sqrt(C) = 1/32 (reference quirk).
// ---------------------------------------------------------------------------
__global__ __launch_bounds__(64) void attn_kernel(
    const float* __restrict__ qkv, float* __restrict__ out, int causal)
{
    const int t = blockIdx.x, h = blockIdx.y, b = blockIdx.z;
    const int lane = threadIdx.x;
    const float scale = 1.0f / 32.0f;

    const long rowq = (long)(b * TT + t) * 3072;
    const float qd = qkv[rowq + h * HSZ + lane];
    const float* kb = qkv + (long)b * TT * 3072 + CC + h * HSZ;        // k cols
    const float* vb = kb + CC;                                          // v cols

    const int smax = causal ? (t + 1) : TT;

    float m = -3.0e38f, l = 0.f, acc = 0.f;
    for (int s = 0; s < smax; ++s) {
        float prod = qd * kb[(long)s * 3072 + lane];
        #pragma unroll
        for (int off = 32; off > 0; off >>= 1)
            prod += __shfl_xor(prod, off);
        float score = prod * scale;
        float mn = fmaxf(m, score);
        float corr = __expf(m - mn);
        float p = __expf(score - mn);
        l = l * corr + p;
        acc = acc * corr + p * vb[(long)s * 3072 + lane];
        m = mn;
    }
    out[((long)b * TT + t) * CC + h * HSZ + lane] = acc / l;
}

// ---------------------------------------------------------------------------
// LayerNorm (+optional residual): out = res + g*norm(in) + b.  Row = 1024.
// 256 threads, each owns one float4; two-pass on registers.
// ---------------------------------------------------------------------------
__global__ __launch_bounds__(256) void ln_kernel(
    const float* __restrict__ in, const float* __restrict__ res,
    const float* __restrict__ g, const float* __restrict__ b,
    float* __restrict__ out)
{
    const int r = blockIdx.x, tid = threadIdx.x;
    __shared__ float sm[4];

    float4 xv = *(const float4*)(in + (long)r * CC + tid * 4);
    float s = xv.x + xv.y + xv.z + xv.w;
    #pragma unroll
    for (int o = 32; o > 0; o >>= 1) s += __shfl_xor(s, o);
    if ((tid & 63) == 0) sm[tid >> 6] = s;
    __syncthreads();
    const float mean = (sm[0] + sm[1] + sm[2] + sm[3]) * (1.0f / CC);
    __syncthreads();

    float4 d; d.x = xv.x - mean; d.y = xv.y - mean; d.z = xv.z - mean; d.w = xv.w - mean;
    float s2 = d.x * d.x + d.y * d.y + d.z * d.z + d.w * d.w;
    #pragma unroll
    for (int o = 32; o > 0; o >>= 1) s2 += __shfl_xor(s2, o);
    if ((tid & 63) == 0) sm[tid >> 6] = s2;
    __syncthreads();
    const float rstd = rsqrtf((sm[0] + sm[1] + sm[2] + sm[3]) * (1.0f / CC) + 1e-5f);

    float4 gv = *(const float4*)(g + tid * 4);
    float4 bv = *(const float4*)(b + tid * 4);
    float4 o;
    o.x = gv.x * d.x * rstd + bv.x; o.y = gv.y * d.y * rstd + bv.y;
    o.z = gv.z * d.z * rstd + bv.z; o.w = gv.w * d.w * rstd + bv.w;
    if (res) {
        float4 rv = *(const float4*)(res + (long)r * CC + tid * 4);
        o.x += rv.x; o.y += rv.y; o.z += rv.z; o.w += rv.w;
    }
    *(float4*)(out + (long)r * CC + tid * 4) = o;
}

// ---------------------------------------------------------------------------
extern "C" void kernel_launch(void* const* d_in, const int* in_sizes, int n_in,
                              void* d_out, int out_size, void* d_ws, size_t ws_size,
                              hipStream_t stream)
{
    const int*   x      = (const int*)  d_in[0];
    const int*   y      = (const int*)  d_in[1];
    const float* wte    = (const float*)d_in[2];
    const float* wpe_x  = (const float*)d_in[3];
    const float* wpe_y  = (const float*)d_in[4];
    const float* eWq    = (const float*)d_in[5];
    const float* eWk    = (const float*)d_in[6];
    const float* eWv    = (const float*)d_in[7];
    const float* epw    = (const float*)d_in[8];
    const float* epb    = (const float*)d_in[9];
    const float* eln1g  = (const float*)d_in[10];
    const float* eln1b  = (const float*)d_in[11];
    const float* eln2g  = (const float*)d_in[12];
    const float* eln2b  = (const float*)d_in[13];
    const float* ew1    = (const float*)d_in[14];
    const float* eb1    = (const float*)d_in[15];
    const float* ew2    = (const float*)d_in[16];
    const float* eb2    = (const float*)d_in[17];
    const float* dsWq   = (const float*)d_in[18];
    const float* dsWk   = (const float*)d_in[19];
    const float* dsWv   = (const float*)d_in[20];
    const float* dspw   = (const float*)d_in[21];
    const float* dspb   = (const float*)d_in[22];
    const float* dcWq   = (const float*)d_in[23];
    const float* dcWk   = (const float*)d_in[24];
    const float* dcWv   = (const float*)d_in[25];
    const float* dcpw   = (const float*)d_in[26];
    const float* dcpb   = (const float*)d_in[27];
    const float* dln1g  = (const float*)d_in[28];
    const float* dln1b  = (const float*)d_in[29];
    const float* dln2g  = (const float*)d_in[30];
    const float* dln2b  = (const float*)d_in[31];
    const float* dln3g  = (const float*)d_in[32];
    const float* dln3b  = (const float*)d_in[33];
    const float* dw1    = (const float*)d_in[34];
    const float* db1    = (const float*)d_in[35];
    const float* dw2    = (const float*)d_in[36];
    const float* db2    = (const float*)d_in[37];
    const float* lnfg   = (const float*)d_in[38];
    const float* lnfb   = (const float*)d_in[39];
    const float* lm_b   = (const float*)d_in[40];

    float* out = (float*)d_out;

    // workspace carve-up
    const size_t MC = (size_t)MM * CC;
    float* ws  = (float*)d_ws;
    float* enc = ws;                       // [M, C]
    float* dec = enc + MC;                 // [M, C]
    float* t0  = dec + MC;                 // [M, C]
    float* a0  = t0  + MC;                 // [M, C]
    float* qkv = a0  + MC;                 // [M, 3072]
    float* ff  = qkv + (size_t)MM * 3072;  // [M, FF]
    __hip_bfloat16* wb = (__hip_bfloat16*)(ff + (size_t)MM * FFD);  // 4M bf16 max

    const int GM = (MM + 127) / 128;   // 16

    auto gemm_b = [&](const float* A, const __hip_bfloat16* B, const float* bias,
                      float* Cm, int N_, int K_, int ldc, bool relu) {
        dim3 grid((N_ + 127) / 128, GM);
        if (relu) mgemm_kernel<true,  true ><<<grid, 256, 0, stream>>>(A, B, bias, Cm, MM, N_, K_, ldc);
        else      mgemm_kernel<true,  false><<<grid, 256, 0, stream>>>(A, B, bias, Cm, MM, N_, K_, ldc);
    };

    // convert Wq/Wk/Wv [H][C][HS] -> wb[which*1024 + h*64 + d][c]
    auto cvt_qkv = [&](const float* Wq, const float* Wk, const float* Wv) {
        dim3 g(HSZ / 32, CC / 32, HH);
        dim3 blk(32, 8);
        tcvt_kernel<<<g, blk, 0, stream>>>(Wq, wb,                 CC, HSZ, (long)CC * HSZ, (long)HSZ * CC);
        tcvt_kernel<<<g, blk, 0, stream>>>(Wk, wb + 1024 * 1024,   CC, HSZ, (long)CC * HSZ, (long)HSZ * CC);
        tcvt_kernel<<<g, blk, 0, stream>>>(Wv, wb + 2 * 1024 * 1024, CC, HSZ, (long)CC * HSZ, (long)HSZ * CC);
    };
    // convert [R][S] fp32 -> wb [S][R] bf16
    auto cvt_nt = [&](const float* W, int R, int S) {
        dim3 g(S / 32, R / 32, 1);
        dim3 blk(32, 8);
        tcvt_kernel<<<g, blk, 0, stream>>>(W, wb, R, S, 0, 0);
    };

    auto proj_ln = [&](const float* pw, const float* pb,
                       const float* lg, const float* lb, float* resbuf) {
        cvt_nt(pw, CC, CC);
        gemm_b(a0, wb, pb, t0, CC, CC, CC, false);
        ln_kernel<<<MM, 256, 0, stream>>>(t0, resbuf, lg, lb, resbuf);
    };

    auto ffn = [&](float* xbuf, const float* w1, const float* b1,
                   const float* w2, const float* b2,
                   const float* lg, const float* lb) {
        cvt_nt(w1, CC, FFD);
        gemm_b(xbuf, wb, b1, ff, FFD, CC, FFD, true);
        cvt_nt(w2, FFD, CC);
        gemm_b(ff, wb, b2, t0, CC, FFD, CC, false);
        ln_kernel<<<MM, 256, 0, stream>>>(t0, xbuf, lg, lb, xbuf);
    };

    // ---- encoder ----
    embed_kernel<<<MM, 256, 0, stream>>>(x, wte, wpe_x, enc);
    for (int i = 0; i < LL; ++i) {
        const long wOff = (long)i * HH * CC * HSZ;
        const long pOff = (long)i * CC * CC;
        const long cOff = (long)i * CC;
        cvt_qkv(eWq + wOff, eWk + wOff, eWv + wOff);
        gemm_b(enc, wb, nullptr, qkv, 3072, CC, 3072, false);
        attn_kernel<<<dim3(TT, HH, BB), 64, 0, stream>>>(qkv, a0, 0);
        proj_ln(epw + pOff, epb + cOff, eln1g + cOff, eln1b + cOff, enc);
        ffn(enc, ew1 + (long)i * CC * FFD, eb1 + (long)i * FFD,
                 ew2 + (long)i * FFD * CC, eb2 + cOff, eln2g + cOff, eln2b + cOff);
    }

    // ---- decoder ----
    embed_kernel<<<MM, 256, 0, stream>>>(y, wte, wpe_y, dec);
    for (int i = 0; i < LL; ++i) {
        const long wOff = (long)i * HH * CC * HSZ;
        const long pOff = (long)i * CC * CC;
        const long cOff = (long)i * CC;
        // masked self-attn
        cvt_qkv(dsWq + wOff, dsWk + wOff, dsWv + wOff);
        gemm_b(dec, wb, nullptr, qkv, 3072, CC, 3072, false);
        attn_kernel<<<dim3(TT, HH, BB), 64, 0, stream>>>(qkv, a0, 1);
        proj_ln(dspw + pOff, dspb + cOff, dln1g + cOff, dln1b + cOff, dec);
        // cross-attn: q from dec, k/v from enc
        cvt_qkv(dcWq + wOff, dcWk + wOff, dcWv + wOff);
        gemm_b(dec, wb, nullptr, qkv, CC, CC, 3072, false);                    // q -> cols 0..1023
        gemm_b(enc, wb + 1024 * 1024, nullptr, qkv + CC, 2048, CC, 3072, false); // k,v -> cols 1024..3071
        attn_kernel<<<dim3(TT, HH, BB), 64, 0, stream>>>(qkv, a0, 0);
        proj_ln(dcpw + pOff, dcpb + cOff, dln2g + cOff, dln2b + cOff, dec);
        // ffn
        ffn(dec, dw1 + (long)i * CC * FFD, db1 + (long)i * FFD,
                 dw2 + (long)i * FFD * CC, db2 + cOff, dln3g + cOff, dln3b + cOff);
    }

    // ---- final LN + logits (tied embedding: wte is [V][K] = [N][K] fp32) ----
    ln_kernel<<<MM, 256, 0, stream>>>(dec, nullptr, lnfg, lnfb, t0);
    {
        dim3 grid((VV + 127) / 128, GM);
        mgemm_kernel<false, false><<<grid, 256, 0, stream>>>(t0, wte, lm_b, out, MM, VV, CC, VV);
    }
}

// Round 3
// 9334.722 us; speedup vs baseline: 6.2205x; 4.6494x over previous
//
#include <hip/hip_runtime.h>
#include <hip/hip_bf16.h>

#define BB 2
#define TT 1023
#define CC 1024
#define HH 16
#define HSZ 64
#define LL 6
#define FFD 4096
#define VV 50258
#define MM (BB*TT)   // 2046

typedef __attribute__((ext_vector_type(4))) float  f32x4;
typedef __attribute__((ext_vector_type(8))) short  s16x8;
typedef __attribute__((ext_vector_type(4))) short  s16x4;

__device__ __forceinline__ short f2b(float x) {
    __hip_bfloat16 h = __float2bfloat16(x);
    short s;
    __builtin_memcpy(&s, &h, 2);
    return s;
}

// ---------------------------------------------------------------------------
// Embedding: out[r, c] = wte[ids[r], c] + wpe[r % T, c]   (float4 vectorized)
// ---------------------------------------------------------------------------
__global__ __launch_bounds__(256) void embed_kernel(
    const int* __restrict__ ids, const float* __restrict__ wte,
    const float* __restrict__ wpe, float* __restrict__ out)
{
    int r = blockIdx.x;
    int t = r % TT;
    long id = ids[r];
    int c = threadIdx.x * 4;
    float4 a = *(const float4*)(wte + id * (long)CC + c);
    float4 p = *(const float4*)(wpe + (long)t * CC + c);
    float4 o; o.x = a.x + p.x; o.y = a.y + p.y; o.z = a.z + p.z; o.w = a.w + p.w;
    *(float4*)(out + (long)r * CC + c) = o;
}

// ---------------------------------------------------------------------------
// Transpose + fp32->bf16 convert: in [R][S] fp32 -> out [S][R] bf16.
// ---------------------------------------------------------------------------
__global__ __launch_bounds__(256) void tcvt_kernel(
    const float* __restrict__ in, __hip_bfloat16* __restrict__ out,
    int R, int S, long inZ, long outZ)
{
    in  += (long)blockIdx.z * inZ;
    out += (long)blockIdx.z * outZ;
    __shared__ float tile[32][33];
    int s0 = blockIdx.x * 32, r0 = blockIdx.y * 32;
    int tx = threadIdx.x, ty = threadIdx.y;
    #pragma unroll
    for (int i = 0; i < 4; ++i)
        tile[ty + i * 8][tx] = in[(long)(r0 + ty + i * 8) * S + s0 + tx];
    __syncthreads();
    #pragma unroll
    for (int i = 0; i < 4; ++i)
        out[(long)(s0 + ty + i * 8) * R + r0 + tx] =
            __float2bfloat16(tile[tx][ty + i * 8]);
}

// ---------------------------------------------------------------------------
// bf16 MFMA GEMM.  C[M,N] = act(A[M,K](fp32) @ B + bias),  B is [N][K]
// ---------------------------------------------------------------------------
template<bool BF16B, bool RELU>
__global__ __launch_bounds__(256) void mgemm_kernel(
    const float* __restrict__ A, const void* __restrict__ Bv,
    const float* __restrict__ bias, float* __restrict__ Cm,
    int M, int N, int K, int ldc)
{
    __shared__ short As[128][40];
    __shared__ short Bs[128][40];

    const int tid  = threadIdx.x;
    const int lane = tid & 63, w = tid >> 6;
    const int wr = w >> 1, wc = w & 1;
    const int lr = lane & 15, kg = lane >> 4;
    const int m0 = blockIdx.y * 128, n0 = blockIdx.x * 128;

    const int ar = tid >> 3, ac = (tid & 7) * 4;
    const int br = tid >> 2, bc = (tid & 3) * 8;

    f32x4 acc[4][4];
    #pragma unroll
    for (int i = 0; i < 4; ++i)
        #pragma unroll
        for (int j = 0; j < 4; ++j)
            acc[i][j] = (f32x4){0.f, 0.f, 0.f, 0.f};

    for (int k0 = 0; k0 < K; k0 += 32) {
        #pragma unroll
        for (int p = 0; p < 4; ++p) {
            int row = ar + p * 32;
            int gm = m0 + row;
            float4 f = {0.f, 0.f, 0.f, 0.f};
            if (gm < M) f = *(const float4*)(A + (long)gm * K + k0 + ac);
            s16x4 h; h[0] = f2b(f.x); h[1] = f2b(f.y); h[2] = f2b(f.z); h[3] = f2b(f.w);
            *(s16x4*)&As[row][ac] = h;
        }
        #pragma unroll
        for (int p = 0; p < 2; ++p) {
            int n = br + p * 64;
            int gn = n0 + n;
            s16x8 h = (s16x8){0,0,0,0,0,0,0,0};
            if (gn < N) {
                if (BF16B) {
                    const __hip_bfloat16* Bp = (const __hip_bfloat16*)Bv;
                    h = *(const s16x8*)(Bp + (long)gn * K + k0 + bc);
                } else {
                    const float* Bp = (const float*)Bv;
                    float4 f0 = *(const float4*)(Bp + (long)gn * K + k0 + bc);
                    float4 f1 = *(const float4*)(Bp + (long)gn * K + k0 + bc + 4);
                    h[0] = f2b(f0.x); h[1] = f2b(f0.y); h[2] = f2b(f0.z); h[3] = f2b(f0.w);
                    h[4] = f2b(f1.x); h[5] = f2b(f1.y); h[6] = f2b(f1.z); h[7] = f2b(f1.w);
                }
            }
            *(s16x8*)&Bs[n][bc] = h;
        }
        __syncthreads();

        s16x8 af[4], bf[4];
        #pragma unroll
        for (int i = 0; i < 4; ++i)
            af[i] = *(const s16x8*)&As[wr * 64 + i * 16 + lr][kg * 8];
        #pragma unroll
        for (int j = 0; j < 4; ++j)
            bf[j] = *(const s16x8*)&Bs[wc * 64 + j * 16 + lr][kg * 8];
        #pragma unroll
        for (int i = 0; i < 4; ++i)
            #pragma unroll
            for (int j = 0; j < 4; ++j)
                acc[i][j] = __builtin_amdgcn_mfma_f32_16x16x32_bf16(
                    af[i], bf[j], acc[i][j], 0, 0, 0);
        __syncthreads();
    }

    #pragma unroll
    for (int j = 0; j < 4; ++j) {
        int gcol = n0 + wc * 64 + j * 16 + lr;
        if (gcol >= N) continue;
        float bv = bias ? bias[gcol] : 0.f;
        #pragma unroll
        for (int i = 0; i < 4; ++i) {
            int grow0 = m0 + wr * 64 + i * 16 + kg * 4;
            #pragma unroll
            for (int q = 0; q < 4; ++q) {
                int gr = grow0 + q;
                if (gr >= M) continue;
                float v = acc[i][j][q] + bv;
                if (RELU) v = fmaxf(v, 0.f);
                Cm[(long)gr * ldc + gcol] = v;
            }
        }
    }
}

// ---------------------------------------------------------------------------
// MFMA flash attention. grid (16, H, B), block 256 (4 waves).
// Workgroup: 64 q-rows for head h, batch b; wave w owns q rows [w*16, w*16+16).
// qkv: [M, 3072]  (q | k | v each [*,1024], head h at col h*64)
// out: [M, C] at col h*64.  scale = 1/sqrt(C) = 1/32 (reference quirk).
// ---------------------------------------------------------------------------
template<bool CAUSAL>
__global__ __launch_bounds__(256) void fattn_kernel(
    const float* __restrict__ qkv, float* __restrict__ out)
{
    __shared__ short Ks[64][72];        // [s][d]
    __shared__ short Vt[64][72];        // [d][s]
    __shared__ short Ps[4][16][72];     // per-wave P tile [q][s]

    const int q0 = blockIdx.x * 64;
    const int h = blockIdx.y, b = blockIdx.z;
    const int tid = threadIdx.x;
    const int lane = tid & 63, w = tid >> 6;
    const int lr = lane & 15, lg = lane >> 4;

    const float scale = 1.0f / 32.0f;
    const long base = (long)b * TT * 3072;
    const float* Kg = qkv + base + 1024 + h * 64;
    const float* Vg = qkv + base + 2048 + h * 64;

    // Q fragments for this wave (A-operand: row=lane&15, k=(lane>>4)*8+e)
    s16x8 qf[2];
    {
        int qr = q0 + w * 16 + lr;
        #pragma unroll
        for (int kc = 0; kc < 2; ++kc) {
            s16x8 hv = (s16x8){0,0,0,0,0,0,0,0};
            if (qr < TT) {
                const float* p = qkv + base + (long)qr * 3072 + h * 64 + kc * 32 + lg * 8;
                float4 f0 = *(const float4*)p;
                float4 f1 = *(const float4*)(p + 4);
                hv[0]=f2b(f0.x); hv[1]=f2b(f0.y); hv[2]=f2b(f0.z); hv[3]=f2b(f0.w);
                hv[4]=f2b(f1.x); hv[5]=f2b(f1.y); hv[6]=f2b(f1.z); hv[7]=f2b(f1.w);
            }
            qf[kc] = hv;
        }
    }

    f32x4 acc[4];
    #pragma unroll
    for (int jd = 0; jd < 4; ++jd) acc[jd] = (f32x4){0.f, 0.f, 0.f, 0.f};
    float mrun[4] = {-3.0e38f, -3.0e38f, -3.0e38f, -3.0e38f};
    float lrun[4] = {0.f, 0.f, 0.f, 0.f};

    const int send = CAUSAL ? min(TT, q0 + 64) : TT;
    const int sr = tid >> 2;           // staging row 0..63
    const int dc = (tid & 3) * 16;     // staging col chunk

    for (int s0 = 0; s0 < send; s0 += 64) {
        __syncthreads();               // prev tile's MFMA reads done
        {
            int sg = s0 + sr;
            if (sg < TT) {
                const float* kp = Kg + (long)sg * 3072 + dc;
                const float* vp = Vg + (long)sg * 3072 + dc;
                #pragma unroll
                for (int e = 0; e < 4; ++e) {
                    float4 f = *(const float4*)(kp + e * 4);
                    s16x4 hk; hk[0]=f2b(f.x); hk[1]=f2b(f.y); hk[2]=f2b(f.z); hk[3]=f2b(f.w);
                    *(s16x4*)&Ks[sr][dc + e * 4] = hk;
                    float4 g = *(const float4*)(vp + e * 4);
                    Vt[dc + e*4 + 0][sr] = f2b(g.x);
                    Vt[dc + e*4 + 1][sr] = f2b(g.y);
                    Vt[dc + e*4 + 2][sr] = f2b(g.z);
                    Vt[dc + e*4 + 3][sr] = f2b(g.w);
                }
            } else {
                #pragma unroll
                for (int e = 0; e < 4; ++e) {
                    *(s16x4*)&Ks[sr][dc + e * 4] = (s16x4){0,0,0,0};
                    Vt[dc + e*4 + 0][sr] = 0;
                    Vt[dc + e*4 + 1][sr] = 0;
                    Vt[dc + e*4 + 2][sr] = 0;
                    Vt[dc + e*4 + 3][sr] = 0;
                }
            }
        }
        __syncthreads();

        // ---- S = Q K^T (fragment: col s = j*16+lr, row q = lg*4+r) ----
        f32x4 sf[4];
        #pragma unroll
        for (int j = 0; j < 4; ++j) {
            f32x4 z = (f32x4){0.f, 0.f, 0.f, 0.f};
            #pragma unroll
            for (int kc = 0; kc < 2; ++kc) {
                s16x8 kf = *(const s16x8*)&Ks[j * 16 + lr][kc * 32 + lg * 8];
                z = __builtin_amdgcn_mfma_f32_16x16x32_bf16(qf[kc], kf, z, 0, 0, 0);
            }
            sf[j] = z;
        }

        // ---- scale + mask + row max ----
        float mloc[4] = {-3.0e38f, -3.0e38f, -3.0e38f, -3.0e38f};
        #pragma unroll
        for (int j = 0; j < 4; ++j) {
            int sg = s0 + j * 16 + lr;
            #pragma unroll
            for (int r = 0; r < 4; ++r) {
                float sc = sf[j][r] * scale;
                int qg = q0 + w * 16 + lg * 4 + r;
                if ((CAUSAL && sg > qg) || sg >= TT) sc = -3.0e38f;
                sf[j][r] = sc;
                mloc[r] = fmaxf(mloc[r], sc);
            }
        }
        #pragma unroll
        for (int r = 0; r < 4; ++r)
            #pragma unroll
            for (int off = 1; off < 16; off <<= 1)
                mloc[r] = fmaxf(mloc[r], __shfl_xor(mloc[r], off));

        float corr[4], psum[4];
        #pragma unroll
        for (int r = 0; r < 4; ++r) {
            float mn = fmaxf(mrun[r], mloc[r]);
            corr[r] = __expf(mrun[r] - mn);
            mrun[r] = mn;
            psum[r] = 0.f;
        }

        // ---- P = exp(S - m): accumulate l, stage P to LDS ----
        #pragma unroll
        for (int j = 0; j < 4; ++j) {
            #pragma unroll
            for (int r = 0; r < 4; ++r) {
                float p = __expf(sf[j][r] - mrun[r]);
                psum[r] += p;
                Ps[w][lg * 4 + r][j * 16 + lr] = f2b(p);
            }
        }
        #pragma unroll
        for (int r = 0; r < 4; ++r) {
            #pragma unroll
            for (int off = 1; off < 16; off <<= 1)
                psum[r] += __shfl_xor(psum[r], off);
            lrun[r] = lrun[r] * corr[r] + psum[r];
            #pragma unroll
            for (int jd = 0; jd < 4; ++jd) acc[jd][r] *= corr[r];
        }

        // ---- O += P @ V ----
        #pragma unroll
        for (int kc = 0; kc < 2; ++kc) {
            s16x8 pa = *(const s16x8*)&Ps[w][lr][kc * 32 + lg * 8];
            #pragma unroll
            for (int jd = 0; jd < 4; ++jd) {
                s16x8 bv = *(const s16x8*)&Vt[jd * 16 + lr][kc * 32 + lg * 8];
                acc[jd] = __builtin_amdgcn_mfma_f32_16x16x32_bf16(pa, bv, acc[jd], 0, 0, 0);
            }
        }
    }

    // ---- O /= l, store ----
    #pragma unroll
    for (int r = 0; r < 4; ++r) {
        int qg = q0 + w * 16 + lg * 4 + r;
        if (qg >= TT) continue;
        float inv = 1.0f / lrun[r];
        #pragma unroll
        for (int jd = 0; jd < 4; ++jd)
            out[((long)b * TT + qg) * CC + h * 64 + jd * 16 + lr] = acc[jd][r] * inv;
    }
}

// ---------------------------------------------------------------------------
// LayerNorm (+optional residual): out = res + g*norm(in) + b.
// ---------------------------------------------------------------------------
__global__ __launch_bounds__(256) void ln_kernel(
    const float* __restrict__ in, const float* __restrict__ res,
    const float* __restrict__ g, const float* __restrict__ b,
    float* __restrict__ out)
{
    const int r = blockIdx.x, tid = threadIdx.x;
    __shared__ float sm[4];

    float4 xv = *(const float4*)(in + (long)r * CC + tid * 4);
    float s = xv.x + xv.y + xv.z + xv.w;
    #pragma unroll
    for (int o = 32; o > 0; o >>= 1) s += __shfl_xor(s, o);
    if ((tid & 63) == 0) sm[tid >> 6] = s;
    __syncthreads();
    const float mean = (sm[0] + sm[1] + sm[2] + sm[3]) * (1.0f / CC);
    __syncthreads();

    float4 d; d.x = xv.x - mean; d.y = xv.y - mean; d.z = xv.z - mean; d.w = xv.w - mean;
    float s2 = d.x * d.x + d.y * d.y + d.z * d.z + d.w * d.w;
    #pragma unroll
    for (int o = 32; o > 0; o >>= 1) s2 += __shfl_xor(s2, o);
    if ((tid & 63) == 0) sm[tid >> 6] = s2;
    __syncthreads();
    const float rstd = rsqrtf((sm[0] + sm[1] + sm[2] + sm[3]) * (1.0f / CC) + 1e-5f);

    float4 gv = *(const float4*)(g + tid * 4);
    float4 bv = *(const float4*)(b + tid * 4);
    float4 o;
    o.x = gv.x * d.x * rstd + bv.x; o.y = gv.y * d.y * rstd + bv.y;
    o.z = gv.z * d.z * rstd + bv.z; o.w = gv.w * d.w * rstd + bv.w;
    if (res) {
        float4 rv = *(const float4*)(res + (long)r * CC + tid * 4);
        o.x += rv.x; o.y += rv.y; o.z += rv.z; o.w += rv.w;
    }
    *(float4*)(out + (long)r * CC + tid * 4) = o;
}

// ---------------------------------------------------------------------------
extern "C" void kernel_launch(void* const* d_in, const int* in_sizes, int n_in,
                              void* d_out, int out_size, void* d_ws, size_t ws_size,
                              hipStream_t stream)
{
    const int*   x      = (const int*)  d_in[0];
    const int*   y      = (const int*)  d_in[1];
    const float* wte    = (const float*)d_in[2];
    const float* wpe_x  = (const float*)d_in[3];
    const float* wpe_y  = (const float*)d_in[4];
    const float* eWq    = (const float*)d_in[5];
    const float* eWk    = (const float*)d_in[6];
    const float* eWv    = (const float*)d_in[7];
    const float* epw    = (const float*)d_in[8];
    const float* epb    = (const float*)d_in[9];
    const float* eln1g  = (const float*)d_in[10];
    const float* eln1b  = (const float*)d_in[11];
    const float* eln2g  = (const float*)d_in[12];
    const float* eln2b  = (const float*)d_in[13];
    const float* ew1    = (const float*)d_in[14];
    const float* eb1    = (const float*)d_in[15];
    const float* ew2    = (const float*)d_in[16];
    const float* eb2    = (const float*)d_in[17];
    const float* dsWq   = (const float*)d_in[18];
    const float* dsWk   = (const float*)d_in[19];
    const float* dsWv   = (const float*)d_in[20];
    const float* dspw   = (const float*)d_in[21];
    const float* dspb   = (const float*)d_in[22];
    const float* dcWq   = (const float*)d_in[23];
    const float* dcWk   = (const float*)d_in[24];
    const float* dcWv   = (const float*)d_in[25];
    const float* dcpw   = (const float*)d_in[26];
    const float* dcpb   = (const float*)d_in[27];
    const float* dln1g  = (const float*)d_in[28];
    const float* dln1b  = (const float*)d_in[29];
    const float* dln2g  = (const float*)d_in[30];
    const float* dln2b  = (const float*)d_in[31];
    const float* dln3g  = (const float*)d_in[32];
    const float* dln3b  = (const float*)d_in[33];
    const float* dw1    = (const float*)d_in[34];
    const float* db1    = (const float*)d_in[35];
    const float* dw2    = (const float*)d_in[36];
    const float* db2    = (const float*)d_in[37];
    const float* lnfg   = (const float*)d_in[38];
    const float* lnfb   = (const float*)d_in[39];
    const float* lm_b   = (const float*)d_in[40];

    float* out = (float*)d_out;

    const size_t MC = (size_t)MM * CC;
    float* ws  = (float*)d_ws;
    float* enc = ws;                       // [M, C]
    float* dec = enc + MC;                 // [M, C]
    float* t0  = dec + MC;                 // [M, C]
    float* a0  = t0  + MC;                 // [M, C]
    float* qkv = a0  + MC;                 // [M, 3072]
    float* ff  = qkv + (size_t)MM * 3072;  // [M, FF]
    __hip_bfloat16* wb = (__hip_bfloat16*)(ff + (size_t)MM * FFD);

    const int GM = (MM + 127) / 128;   // 16
    const int QT = (TT + 63) / 64;     // 16 q-tiles

    auto gemm_b = [&](const float* A, const __hip_bfloat16* B, const float* bias,
                      float* Cm, int N_, int K_, int ldc, bool relu) {
        dim3 grid((N_ + 127) / 128, GM);
        if (relu) mgemm_kernel<true,  true ><<<grid, 256, 0, stream>>>(A, B, bias, Cm, MM, N_, K_, ldc);
        else      mgemm_kernel<true,  false><<<grid, 256, 0, stream>>>(A, B, bias, Cm, MM, N_, K_, ldc);
    };

    auto cvt_qkv = [&](const float* Wq, const float* Wk, const float* Wv) {
        dim3 g(HSZ / 32, CC / 32, HH);
        dim3 blk(32, 8);
        tcvt_kernel<<<g, blk, 0, stream>>>(Wq, wb,                   CC, HSZ, (long)CC * HSZ, (long)HSZ * CC);
        tcvt_kernel<<<g, blk, 0, stream>>>(Wk, wb + 1024 * 1024,     CC, HSZ, (long)CC * HSZ, (long)HSZ * CC);
        tcvt_kernel<<<g, blk, 0, stream>>>(Wv, wb + 2 * 1024 * 1024, CC, HSZ, (long)CC * HSZ, (long)HSZ * CC);
    };
    auto cvt_nt = [&](const float* W, int R, int S) {
        dim3 g(S / 32, R / 32, 1);
        dim3 blk(32, 8);
        tcvt_kernel<<<g, blk, 0, stream>>>(W, wb, R, S, 0, 0);
    };

    auto proj_ln = [&](const float* pw, const float* pb,
                       const float* lg, const float* lb, float* resbuf) {
        cvt_nt(pw, CC, CC);
        gemm_b(a0, wb, pb, t0, CC, CC, CC, false);
        ln_kernel<<<MM, 256, 0, stream>>>(t0, resbuf, lg, lb, resbuf);
    };

    auto ffn = [&](float* xbuf, const float* w1, const float* b1,
                   const float* w2, const float* b2,
                   const float* lg, const float* lb) {
        cvt_nt(w1, CC, FFD);
        gemm_b(xbuf, wb, b1, ff, FFD, CC, FFD, true);
        cvt_nt(w2, FFD, CC);
        gemm_b(ff, wb, b2, t0, CC, FFD, CC, false);
        ln_kernel<<<MM, 256, 0, stream>>>(t0, xbuf, lg, lb, xbuf);
    };

    // ---- encoder ----
    embed_kernel<<<MM, 256, 0, stream>>>(x, wte, wpe_x, enc);
    for (int i = 0; i < LL; ++i) {
        const long wOff = (long)i * HH * CC * HSZ;
        const long pOff = (long)i * CC * CC;
        const long cOff = (long)i * CC;
        cvt_qkv(eWq + wOff, eWk + wOff, eWv + wOff);
        gemm_b(enc, wb, nullptr, qkv, 3072, CC, 3072, false);
        fattn_kernel<false><<<dim3(QT, HH, BB), 256, 0, stream>>>(qkv, a0);
        proj_ln(epw + pOff, epb + cOff, eln1g + cOff, eln1b + cOff, enc);
        ffn(enc, ew1 + (long)i * CC * FFD, eb1 + (long)i * FFD,
                 ew2 + (long)i * FFD * CC, eb2 + cOff, eln2g + cOff, eln2b + cOff);
    }

    // ---- decoder ----
    embed_kernel<<<MM, 256, 0, stream>>>(y, wte, wpe_y, dec);
    for (int i = 0; i < LL; ++i) {
        const long wOff = (long)i * HH * CC * HSZ;
        const long pOff = (long)i * CC * CC;
        const long cOff = (long)i * CC;
        // masked self-attn
        cvt_qkv(dsWq + wOff, dsWk + wOff, dsWv + wOff);
        gemm_b(dec, wb, nullptr, qkv, 3072, CC, 3072, false);
        fattn_kernel<true><<<dim3(QT, HH, BB), 256, 0, stream>>>(qkv, a0);
        proj_ln(dspw + pOff, dspb + cOff, dln1g + cOff, dln1b + cOff, dec);
        // cross-attn: q from dec, k/v from enc
        cvt_qkv(dcWq + wOff, dcWk + wOff, dcWv + wOff);
        gemm_b(dec, wb, nullptr, qkv, CC, CC, 3072, false);
        gemm_b(enc, wb + 1024 * 1024, nullptr, qkv + CC, 2048, CC, 3072, false);
        fattn_kernel<false><<<dim3(QT, HH, BB), 256, 0, stream>>>(qkv, a0);
        proj_ln(dcpw + pOff, dcpb + cOff, dln2g + cOff, dln2b + cOff, dec);
        // ffn
        ffn(dec, dw1 + (long)i * CC * FFD, db1 + (long)i * FFD,
                 dw2 + (long)i * FFD * CC, db2 + cOff, dln3g + cOff, dln3b + cOff);
    }

    // ---- final LN + logits (tied embedding: wte is [V][K] fp32) ----
    ln_kernel<<<MM, 256, 0, stream>>>(dec, nullptr, lnfg, lnfb, t0);
    {
        dim3 grid((VV + 127) / 128, GM);
        mgemm_kernel<false, false><<<grid, 256, 0, stream>>>(t0, wte, lm_b, out, MM, VV, CC, VV);
    }
}

// Round 4
// 4879.999 us; speedup vs baseline: 11.8989x; 1.9129x over previous
//
#include <hip/hip_runtime.h>
#include <hip/hip_bf16.h>

#define BB 2
#define TT 1023
#define CC 1024
#define HH 16
#define HSZ 64
#define LL 6
#define FFD 4096
#define VV 50258
#define MM (BB*TT)   // 2046
#define MP 2048      // padded row count
#define VP 50304     // padded vocab (multiple of 128)

typedef __attribute__((ext_vector_type(4))) float  f32x4;
typedef __attribute__((ext_vector_type(8))) short  s16x8;
typedef __attribute__((ext_vector_type(4))) short  s16x4;

__device__ __forceinline__ short f2b(float x) {
    __hip_bfloat16 h = __float2bfloat16(x);
    short s;
    __builtin_memcpy(&s, &h, 2);
    return s;
}

__device__ __forceinline__ void gld16(const void* g, void* l) {
    __builtin_amdgcn_global_load_lds(
        (__attribute__((address_space(1))) const void*)g,
        (__attribute__((address_space(3))) void*)l, 16, 0, 0);
}

// ---------------------------------------------------------------------------
// Embedding: fp32 + bf16 mirror
// ---------------------------------------------------------------------------
__global__ __launch_bounds__(256) void embed_kernel(
    const int* __restrict__ ids, const float* __restrict__ wte,
    const float* __restrict__ wpe, float* __restrict__ out,
    __hip_bfloat16* __restrict__ outb)
{
    int r = blockIdx.x;
    int t = r % TT;
    long id = ids[r];
    int c = threadIdx.x * 4;
    float4 a = *(const float4*)(wte + id * (long)CC + c);
    float4 p = *(const float4*)(wpe + (long)t * CC + c);
    float4 o; o.x = a.x + p.x; o.y = a.y + p.y; o.z = a.z + p.z; o.w = a.w + p.w;
    *(float4*)(out + (long)r * CC + c) = o;
    s16x4 h; h[0] = f2b(o.x); h[1] = f2b(o.y); h[2] = f2b(o.z); h[3] = f2b(o.w);
    *(s16x4*)(outb + (long)r * CC + c) = h;
}

// ---------------------------------------------------------------------------
// Elementwise fp32 -> bf16
// ---------------------------------------------------------------------------
__global__ __launch_bounds__(256) void cvtb_kernel(
    const float* __restrict__ in, __hip_bfloat16* __restrict__ out, long n)
{
    long i = ((long)blockIdx.x * 256 + threadIdx.x) * 8;
    if (i >= n) return;
    float4 f0 = *(const float4*)(in + i);
    float4 f1 = *(const float4*)(in + i + 4);
    s16x8 h;
    h[0]=f2b(f0.x); h[1]=f2b(f0.y); h[2]=f2b(f0.z); h[3]=f2b(f0.w);
    h[4]=f2b(f1.x); h[5]=f2b(f1.y); h[6]=f2b(f1.z); h[7]=f2b(f1.w);
    *(s16x8*)(out + i) = h;
}

// ---------------------------------------------------------------------------
// Transpose + fp32->bf16 convert: in [R][S] fp32 -> out [S][R] bf16.
// ---------------------------------------------------------------------------
__global__ __launch_bounds__(256) void tcvt_kernel(
    const float* __restrict__ in, __hip_bfloat16* __restrict__ out,
    int R, int S, long inZ, long outZ)
{
    in  += (long)blockIdx.z * inZ;
    out += (long)blockIdx.z * outZ;
    __shared__ float tile[32][33];
    int s0 = blockIdx.x * 32, r0 = blockIdx.y * 32;
    int tx = threadIdx.x, ty = threadIdx.y;
    #pragma unroll
    for (int i = 0; i < 4; ++i)
        tile[ty + i * 8][tx] = in[(long)(r0 + ty + i * 8) * S + s0 + tx];
    __syncthreads();
    #pragma unroll
    for (int i = 0; i < 4; ++i)
        out[(long)(s0 + ty + i * 8) * R + r0 + tx] =
            __float2bfloat16(tile[tx][ty + i * 8]);
}

// ---------------------------------------------------------------------------
// m97-style bf16 MFMA GEMM.  C = act(A @ B^T + bias).
// A [>=ceil(M,128)][K] bf16, B [>=ceil(N,128)][K] bf16, K % 32 == 0.
// 128x128x32 tile, 4 waves (2x2), global_load_lds staging, linear LDS.
// 1-D grid with bijective XCD swizzle, m-tile-inner ordering (B-tile L2 reuse).
// WMODE: 0 = fp32 out, 1 = fp32 + bf16, 2 = bf16 only.
// ---------------------------------------------------------------------------
template<int WMODE, bool RELU>
__global__ __launch_bounds__(256) void mgemm2_kernel(
    const __hip_bfloat16* __restrict__ A, const __hip_bfloat16* __restrict__ B,
    const float* __restrict__ bias, float* __restrict__ Cm,
    __hip_bfloat16* __restrict__ Cb,
    int M, int N, int K, int ldc, int GM)
{
    __shared__ short AsL[128 * 32];
    __shared__ short BsL[128 * 32];

    // bijective XCD swizzle (m204) + m-fastest decode
    const int nwg = gridDim.x;
    const int bid = blockIdx.x;
    const int q = nwg >> 3, r = nwg & 7;
    const int xcd = bid & 7, lid = bid >> 3;
    const int swz = (xcd < r) ? xcd * (q + 1) + lid
                              : r * (q + 1) + (xcd - r) * q + lid;
    const int m0 = (swz % GM) * 128;
    const int n0 = (swz / GM) * 128;

    const int tid  = threadIdx.x;
    const int lane = tid & 63, w = tid >> 6;
    const int wr = w >> 1, wc = w & 1;
    const int lr = lane & 15, kg = lane >> 4;

    const __hip_bfloat16* Abase = A + (long)m0 * K;
    const __hip_bfloat16* Bbase = B + (long)n0 * K;

    f32x4 acc[4][4];
    #pragma unroll
    for (int i = 0; i < 4; ++i)
        #pragma unroll
        for (int j = 0; j < 4; ++j)
            acc[i][j] = (f32x4){0.f, 0.f, 0.f, 0.f};

    // staging geometry: tile 128x32 bf16 = 8KB = 8 chunks of 1KB; wave w
    // stages chunks 2w, 2w+1. lane's flat elem = chunk*512 + lane*8.
    const int c0flat = (w * 2) * 512 + lane * 8;

    for (int k0 = 0; k0 < K; k0 += 32) {
        #pragma unroll
        for (int c = 0; c < 2; ++c) {
            int flat = c0flat + c * 512;
            int row = flat >> 5, col = flat & 31;
            gld16(Abase + (long)row * K + k0 + col, &AsL[(w * 2 + c) * 512]);
        }
        #pragma unroll
        for (int c = 0; c < 2; ++c) {
            int flat = c0flat + c * 512;
            int row = flat >> 5, col = flat & 31;
            gld16(Bbase + (long)row * K + k0 + col, &BsL[(w * 2 + c) * 512]);
        }
        __syncthreads();   // vmcnt(0) drained by compiler before barrier

        s16x8 af[4], bf[4];
        #pragma unroll
        for (int i = 0; i < 4; ++i)
            af[i] = *(const s16x8*)&AsL[(wr * 64 + i * 16 + lr) * 32 + kg * 8];
        #pragma unroll
        for (int j = 0; j < 4; ++j)
            bf[j] = *(const s16x8*)&BsL[(wc * 64 + j * 16 + lr) * 32 + kg * 8];
        #pragma unroll
        for (int i = 0; i < 4; ++i)
            #pragma unroll
            for (int j = 0; j < 4; ++j)
                acc[i][j] = __builtin_amdgcn_mfma_f32_16x16x32_bf16(
                    af[i], bf[j], acc[i][j], 0, 0, 0);
        __syncthreads();   // all reads done before next overwrite
    }

    #pragma unroll
    for (int j = 0; j < 4; ++j) {
        int gcol = n0 + wc * 64 + j * 16 + lr;
        if (gcol >= N) continue;
        float bv = bias ? bias[gcol] : 0.f;
        #pragma unroll
        for (int i = 0; i < 4; ++i) {
            int grow0 = m0 + wr * 64 + i * 16 + kg * 4;
            #pragma unroll
            for (int qq = 0; qq < 4; ++qq) {
                int gr = grow0 + qq;
                if (gr >= M) continue;
                float v = acc[i][j][qq] + bv;
                if (RELU) v = fmaxf(v, 0.f);
                if (WMODE <= 1) Cm[(long)gr * ldc + gcol] = v;
                if (WMODE >= 1) Cb[(long)gr * ldc + gcol] = __float2bfloat16(v);
            }
        }
    }
}

// ---------------------------------------------------------------------------
// Fallback fp32-B GEMM (logits only, if ws too small for bf16 wte mirror).
// ---------------------------------------------------------------------------
__global__ __launch_bounds__(256) void mgemm_f32b_kernel(
    const float* __restrict__ A, const float* __restrict__ Bv,
    const float* __restrict__ bias, float* __restrict__ Cm,
    int M, int N, int K, int ldc)
{
    __shared__ short As[128][40];
    __shared__ short Bs[128][40];
    const int tid  = threadIdx.x;
    const int lane = tid & 63, w = tid >> 6;
    const int wr = w >> 1, wc = w & 1;
    const int lr = lane & 15, kg = lane >> 4;
    const int m0 = blockIdx.y * 128, n0 = blockIdx.x * 128;
    const int ar = tid >> 3, ac = (tid & 7) * 4;
    const int br = tid >> 2, bc = (tid & 3) * 8;

    f32x4 acc[4][4];
    #pragma unroll
    for (int i = 0; i < 4; ++i)
        #pragma unroll
        for (int j = 0; j < 4; ++j)
            acc[i][j] = (f32x4){0.f, 0.f, 0.f, 0.f};

    for (int k0 = 0; k0 < K; k0 += 32) {
        #pragma unroll
        for (int p = 0; p < 4; ++p) {
            int row = ar + p * 32, gm = m0 + row;
            float4 f = {0.f, 0.f, 0.f, 0.f};
            if (gm < M) f = *(const float4*)(A + (long)gm * K + k0 + ac);
            s16x4 h; h[0] = f2b(f.x); h[1] = f2b(f.y); h[2] = f2b(f.z); h[3] = f2b(f.w);
            *(s16x4*)&As[row][ac] = h;
        }
        #pragma unroll
        for (int p = 0; p < 2; ++p) {
            int n = br + p * 64, gn = n0 + n;
            s16x8 h = (s16x8){0,0,0,0,0,0,0,0};
            if (gn < N) {
                float4 f0 = *(const float4*)(Bv + (long)gn * K + k0 + bc);
                float4 f1 = *(const float4*)(Bv + (long)gn * K + k0 + bc + 4);
                h[0]=f2b(f0.x); h[1]=f2b(f0.y); h[2]=f2b(f0.z); h[3]=f2b(f0.w);
                h[4]=f2b(f1.x); h[5]=f2b(f1.y); h[6]=f2b(f1.z); h[7]=f2b(f1.w);
            }
            *(s16x8*)&Bs[n][bc] = h;
        }
        __syncthreads();
        s16x8 af[4], bf[4];
        #pragma unroll
        for (int i = 0; i < 4; ++i) af[i] = *(const s16x8*)&As[wr*64 + i*16 + lr][kg*8];
        #pragma unroll
        for (int j = 0; j < 4; ++j) bf[j] = *(const s16x8*)&Bs[wc*64 + j*16 + lr][kg*8];
        #pragma unroll
        for (int i = 0; i < 4; ++i)
            #pragma unroll
            for (int j = 0; j < 4; ++j)
                acc[i][j] = __builtin_amdgcn_mfma_f32_16x16x32_bf16(af[i], bf[j], acc[i][j], 0, 0, 0);
        __syncthreads();
    }
    #pragma unroll
    for (int j = 0; j < 4; ++j) {
        int gcol = n0 + wc * 64 + j * 16 + lr;
        if (gcol >= N) continue;
        float bv = bias ? bias[gcol] : 0.f;
        #pragma unroll
        for (int i = 0; i < 4; ++i) {
            int grow0 = m0 + wr * 64 + i * 16 + kg * 4;
            #pragma unroll
            for (int qq = 0; qq < 4; ++qq) {
                int gr = grow0 + qq;
                if (gr >= M) continue;
                Cm[(long)gr * ldc + gcol] = acc[i][j][qq] + bv;
            }
        }
    }
}

// ---------------------------------------------------------------------------
// MFMA flash attention (bf16 in / bf16 out). grid (16, H, B), 4 waves.
// qkvb: [M,3072] bf16 (q|k|v, head h at col h*64). outb: [M,C] bf16.
// scale = 1/sqrt(C) = 1/32 (reference quirk).
// ---------------------------------------------------------------------------
template<bool CAUSAL>
__global__ __launch_bounds__(256) void fattn_kernel(
    const __hip_bfloat16* __restrict__ qkvb, __hip_bfloat16* __restrict__ outb)
{
    __shared__ short Ks[64][72];
    __shared__ short Vt[64][72];
    __shared__ short Ps[4][16][72];

    const int q0 = blockIdx.x * 64;
    const int h = blockIdx.y, b = blockIdx.z;
    const int tid = threadIdx.x;
    const int lane = tid & 63, w = tid >> 6;
    const int lr = lane & 15, lg = lane >> 4;

    const float scale = 1.0f / 32.0f;
    const long base = (long)b * TT * 3072;
    const __hip_bfloat16* Kg = qkvb + base + 1024 + h * 64;
    const __hip_bfloat16* Vg = qkvb + base + 2048 + h * 64;

    s16x8 qf[2];
    {
        int qr = q0 + w * 16 + lr;
        #pragma unroll
        for (int kc = 0; kc < 2; ++kc) {
            s16x8 hv = (s16x8){0,0,0,0,0,0,0,0};
            if (qr < TT)
                hv = *(const s16x8*)(qkvb + base + (long)qr * 3072 + h * 64 + kc * 32 + lg * 8);
            qf[kc] = hv;
        }
    }

    f32x4 acc[4];
    #pragma unroll
    for (int jd = 0; jd < 4; ++jd) acc[jd] = (f32x4){0.f, 0.f, 0.f, 0.f};
    float mrun[4] = {-3.0e38f, -3.0e38f, -3.0e38f, -3.0e38f};
    float lrun[4] = {0.f, 0.f, 0.f, 0.f};

    const int send = CAUSAL ? min(TT, q0 + 64) : TT;
    const int sr = tid >> 2;
    const int dc = (tid & 3) * 16;

    for (int s0 = 0; s0 < send; s0 += 64) {
        __syncthreads();
        {
            int sg = s0 + sr;
            if (sg < TT) {
                s16x8 k0 = *(const s16x8*)(Kg + (long)sg * 3072 + dc);
                s16x8 k1 = *(const s16x8*)(Kg + (long)sg * 3072 + dc + 8);
                *(s16x8*)&Ks[sr][dc] = k0;
                *(s16x8*)&Ks[sr][dc + 8] = k1;
                s16x8 v0 = *(const s16x8*)(Vg + (long)sg * 3072 + dc);
                s16x8 v1 = *(const s16x8*)(Vg + (long)sg * 3072 + dc + 8);
                #pragma unroll
                for (int e = 0; e < 8; ++e) Vt[dc + e][sr] = v0[e];
                #pragma unroll
                for (int e = 0; e < 8; ++e) Vt[dc + 8 + e][sr] = v1[e];
            } else {
                *(s16x8*)&Ks[sr][dc] = (s16x8){0,0,0,0,0,0,0,0};
                *(s16x8*)&Ks[sr][dc + 8] = (s16x8){0,0,0,0,0,0,0,0};
                #pragma unroll
                for (int e = 0; e < 16; ++e) Vt[dc + e][sr] = 0;
            }
        }
        __syncthreads();

        f32x4 sf[4];
        #pragma unroll
        for (int j = 0; j < 4; ++j) {
            f32x4 z = (f32x4){0.f, 0.f, 0.f, 0.f};
            #pragma unroll
            for (int kc = 0; kc < 2; ++kc) {
                s16x8 kf = *(const s16x8*)&Ks[j * 16 + lr][kc * 32 + lg * 8];
                z = __builtin_amdgcn_mfma_f32_16x16x32_bf16(qf[kc], kf, z, 0, 0, 0);
            }
            sf[j] = z;
        }

        float mloc[4] = {-3.0e38f, -3.0e38f, -3.0e38f, -3.0e38f};
        #pragma unroll
        for (int j = 0; j < 4; ++j) {
            int sg = s0 + j * 16 + lr;
            #pragma unroll
            for (int r = 0; r < 4; ++r) {
                float sc = sf[j][r] * scale;
                int qg = q0 + w * 16 + lg * 4 + r;
                if ((CAUSAL && sg > qg) || sg >= TT) sc = -3.0e38f;
                sf[j][r] = sc;
                mloc[r] = fmaxf(mloc[r], sc);
            }
        }
        #pragma unroll
        for (int r = 0; r < 4; ++r)
            #pragma unroll
            for (int off = 1; off < 16; off <<= 1)
                mloc[r] = fmaxf(mloc[r], __shfl_xor(mloc[r], off));

        float corr[4], psum[4];
        #pragma unroll
        for (int r = 0; r < 4; ++r) {
            float mn = fmaxf(mrun[r], mloc[r]);
            corr[r] = __expf(mrun[r] - mn);
            mrun[r] = mn;
            psum[r] = 0.f;
        }

        #pragma unroll
        for (int j = 0; j < 4; ++j) {
            #pragma unroll
            for (int r = 0; r < 4; ++r) {
                float p = __expf(sf[j][r] - mrun[r]);
                psum[r] += p;
                Ps[w][lg * 4 + r][j * 16 + lr] = f2b(p);
            }
        }
        #pragma unroll
        for (int r = 0; r < 4; ++r) {
            #pragma unroll
            for (int off = 1; off < 16; off <<= 1)
                psum[r] += __shfl_xor(psum[r], off);
            lrun[r] = lrun[r] * corr[r] + psum[r];
            #pragma unroll
            for (int jd = 0; jd < 4; ++jd) acc[jd][r] *= corr[r];
        }

        #pragma unroll
        for (int kc = 0; kc < 2; ++kc) {
            s16x8 pa = *(const s16x8*)&Ps[w][lr][kc * 32 + lg * 8];
            #pragma unroll
            for (int jd = 0; jd < 4; ++jd) {
                s16x8 bv = *(const s16x8*)&Vt[jd * 16 + lr][kc * 32 + lg * 8];
                acc[jd] = __builtin_amdgcn_mfma_f32_16x16x32_bf16(pa, bv, acc[jd], 0, 0, 0);
            }
        }
    }

    #pragma unroll
    for (int r = 0; r < 4; ++r) {
        int qg = q0 + w * 16 + lg * 4 + r;
        if (qg >= TT) continue;
        float inv = 1.0f / lrun[r];
        #pragma unroll
        for (int jd = 0; jd < 4; ++jd)
            outb[((long)b * TT + qg) * CC + h * 64 + jd * 16 + lr] =
                __float2bfloat16(acc[jd][r] * inv);
    }
}

// ---------------------------------------------------------------------------
// LayerNorm (+optional residual), fp32 out + optional bf16 mirror.
// ---------------------------------------------------------------------------
__global__ __launch_bounds__(256) void ln_kernel(
    const float* __restrict__ in, const float* __restrict__ res,
    const float* __restrict__ g, const float* __restrict__ b,
    float* __restrict__ out, __hip_bfloat16* __restrict__ outb)
{
    const int r = blockIdx.x, tid = threadIdx.x;
    __shared__ float sm[4];

    float4 xv = *(const float4*)(in + (long)r * CC + tid * 4);
    float s = xv.x + xv.y + xv.z + xv.w;
    #pragma unroll
    for (int o = 32; o > 0; o >>= 1) s += __shfl_xor(s, o);
    if ((tid & 63) == 0) sm[tid >> 6] = s;
    __syncthreads();
    const float mean = (sm[0] + sm[1] + sm[2] + sm[3]) * (1.0f / CC);
    __syncthreads();

    float4 d; d.x = xv.x - mean; d.y = xv.y - mean; d.z = xv.z - mean; d.w = xv.w - mean;
    float s2 = d.x * d.x + d.y * d.y + d.z * d.z + d.w * d.w;
    #pragma unroll
    for (int o = 32; o > 0; o >>= 1) s2 += __shfl_xor(s2, o);
    if ((tid & 63) == 0) sm[tid >> 6] = s2;
    __syncthreads();
    const float rstd = rsqrtf((sm[0] + sm[1] + sm[2] + sm[3]) * (1.0f / CC) + 1e-5f);

    float4 gv = *(const float4*)(g + tid * 4);
    float4 bv = *(const float4*)(b + tid * 4);
    float4 o;
    o.x = gv.x * d.x * rstd + bv.x; o.y = gv.y * d.y * rstd + bv.y;
    o.z = gv.z * d.z * rstd + bv.z; o.w = gv.w * d.w * rstd + bv.w;
    if (res) {
        float4 rv = *(const float4*)(res + (long)r * CC + tid * 4);
        o.x += rv.x; o.y += rv.y; o.z += rv.z; o.w += rv.w;
    }
    *(float4*)(out + (long)r * CC + tid * 4) = o;
    if (outb) {
        s16x4 h; h[0] = f2b(o.x); h[1] = f2b(o.y); h[2] = f2b(o.z); h[3] = f2b(o.w);
        *(s16x4*)(outb + (long)r * CC + tid * 4) = h;
    }
}

// ---------------------------------------------------------------------------
extern "C" void kernel_launch(void* const* d_in, const int* in_sizes, int n_in,
                              void* d_out, int out_size, void* d_ws, size_t ws_size,
                              hipStream_t stream)
{
    const int*   x      = (const int*)  d_in[0];
    const int*   y      = (const int*)  d_in[1];
    const float* wte    = (const float*)d_in[2];
    const float* wpe_x  = (const float*)d_in[3];
    const float* wpe_y  = (const float*)d_in[4];
    const float* eWq    = (const float*)d_in[5];
    const float* eWk    = (const float*)d_in[6];
    const float* eWv    = (const float*)d_in[7];
    const float* epw    = (const float*)d_in[8];
    const float* epb    = (const float*)d_in[9];
    const float* eln1g  = (const float*)d_in[10];
    const float* eln1b  = (const float*)d_in[11];
    const float* eln2g  = (const float*)d_in[12];
    const float* eln2b  = (const float*)d_in[13];
    const float* ew1    = (const float*)d_in[14];
    const float* eb1    = (const float*)d_in[15];
    const float* ew2    = (const float*)d_in[16];
    const float* eb2    = (const float*)d_in[17];
    const float* dsWq   = (const float*)d_in[18];
    const float* dsWk   = (const float*)d_in[19];
    const float* dsWv   = (const float*)d_in[20];
    const float* dspw   = (const float*)d_in[21];
    const float* dspb   = (const float*)d_in[22];
    const float* dcWq   = (const float*)d_in[23];
    const float* dcWk   = (const float*)d_in[24];
    const float* dcWv   = (const float*)d_in[25];
    const float* dcpw   = (const float*)d_in[26];
    const float* dcpb   = (const float*)d_in[27];
    const float* dln1g  = (const float*)d_in[28];
    const float* dln1b  = (const float*)d_in[29];
    const float* dln2g  = (const float*)d_in[30];
    const float* dln2b  = (const float*)d_in[31];
    const float* dln3g  = (const float*)d_in[32];
    const float* dln3b  = (const float*)d_in[33];
    const float* dw1    = (const float*)d_in[34];
    const float* db1    = (const float*)d_in[35];
    const float* dw2    = (const float*)d_in[36];
    const float* db2    = (const float*)d_in[37];
    const float* lnfg   = (const float*)d_in[38];
    const float* lnfb   = (const float*)d_in[39];
    const float* lm_b   = (const float*)d_in[40];

    float* out = (float*)d_out;

    // ---- workspace carve-up ----
    const size_t MCp = (size_t)MP * CC;
    float* ws  = (float*)d_ws;
    float* enc = ws;                 // fp32 [MP][C]
    float* dec = enc + MCp;
    float* t0  = dec + MCp;
    __hip_bfloat16* encb = (__hip_bfloat16*)(t0 + MCp);  // bf16 [MP][C]
    __hip_bfloat16* decb = encb + MCp;
    __hip_bfloat16* t0b  = decb + MCp;
    __hip_bfloat16* a0b  = t0b + MCp;
    __hip_bfloat16* qkvb = a0b + MCp;                    // [MP][3072]
    __hip_bfloat16* ffb  = qkvb + (size_t)MP * 3072;     // [MP][FFD]
    __hip_bfloat16* wb   = ffb + (size_t)MP * FFD;       // [FFD][C] max
    __hip_bfloat16* wteb = wb + (size_t)FFD * CC;        // [VP][C]
    const size_t need = (size_t)((char*)(wteb + (size_t)VP * CC) - (char*)d_ws);
    const bool useWteb = (ws_size >= need);

    const int GM = MP / 128;           // 16 m-tiles
    const int QT = (TT + 63) / 64;     // 16 q-tiles

    // WMODE dispatch helper
    auto gemm = [&](const __hip_bfloat16* A, const __hip_bfloat16* B,
                    const float* bias, float* Cm, __hip_bfloat16* Cb,
                    int N_, int K_, int ldc, int wmode, bool relu) {
        int nwg = GM * (N_ + 127) / 128;
        if (wmode == 0) {
            if (relu) mgemm2_kernel<0, true ><<<nwg, 256, 0, stream>>>(A, B, bias, Cm, Cb, MM, N_, K_, ldc, GM);
            else      mgemm2_kernel<0, false><<<nwg, 256, 0, stream>>>(A, B, bias, Cm, Cb, MM, N_, K_, ldc, GM);
        } else if (wmode == 1) {
            if (relu) mgemm2_kernel<1, true ><<<nwg, 256, 0, stream>>>(A, B, bias, Cm, Cb, MM, N_, K_, ldc, GM);
            else      mgemm2_kernel<1, false><<<nwg, 256, 0, stream>>>(A, B, bias, Cm, Cb, MM, N_, K_, ldc, GM);
        } else {
            if (relu) mgemm2_kernel<2, true ><<<nwg, 256, 0, stream>>>(A, B, bias, Cm, Cb, MM, N_, K_, ldc, GM);
            else      mgemm2_kernel<2, false><<<nwg, 256, 0, stream>>>(A, B, bias, Cm, Cb, MM, N_, K_, ldc, GM);
        }
    };

    auto cvt_qkv = [&](const float* Wq, const float* Wk, const float* Wv) {
        dim3 g(HSZ / 32, CC / 32, HH);
        dim3 blk(32, 8);
        tcvt_kernel<<<g, blk, 0, stream>>>(Wq, wb,                   CC, HSZ, (long)CC * HSZ, (long)HSZ * CC);
        tcvt_kernel<<<g, blk, 0, stream>>>(Wk, wb + 1024 * 1024,     CC, HSZ, (long)CC * HSZ, (long)HSZ * CC);
        tcvt_kernel<<<g, blk, 0, stream>>>(Wv, wb + 2 * 1024 * 1024, CC, HSZ, (long)CC * HSZ, (long)HSZ * CC);
    };
    auto cvt_nt = [&](const float* W, int R, int S) {
        dim3 g(S / 32, R / 32, 1);
        dim3 blk(32, 8);
        tcvt_kernel<<<g, blk, 0, stream>>>(W, wb, R, S, 0, 0);
    };

    auto proj_ln = [&](const float* pw, const float* pb,
                       const float* lg, const float* lb,
                       float* resf, __hip_bfloat16* resb) {
        cvt_nt(pw, CC, CC);
        gemm(a0b, wb, pb, t0, nullptr, CC, CC, CC, 0, false);
        ln_kernel<<<MM, 256, 0, stream>>>(t0, resf, lg, lb, resf, resb);
    };

    auto ffn = [&](float* xf, __hip_bfloat16* xb,
                   const float* w1, const float* b1,
                   const float* w2, const float* b2,
                   const float* lg, const float* lb) {
        cvt_nt(w1, CC, FFD);
        gemm(xb, wb, b1, nullptr, ffb, FFD, CC, FFD, 2, true);
        cvt_nt(w2, FFD, CC);
        gemm(ffb, wb, b2, t0, nullptr, CC, FFD, CC, 0, false);
        ln_kernel<<<MM, 256, 0, stream>>>(t0, xf, lg, lb, xf, xb);
    };

    // ---- bf16 wte mirror (for logits GEMM) ----
    if (useWteb) {
        long n = (long)VV * CC;
        cvtb_kernel<<<(int)((n / 8 + 255) / 256), 256, 0, stream>>>(wte, wteb, n);
    }

    // ---- encoder ----
    embed_kernel<<<MM, 256, 0, stream>>>(x, wte, wpe_x, enc, encb);
    for (int i = 0; i < LL; ++i) {
        const long wOff = (long)i * HH * CC * HSZ;
        const long pOff = (long)i * CC * CC;
        const long cOff = (long)i * CC;
        cvt_qkv(eWq + wOff, eWk + wOff, eWv + wOff);
        gemm(encb, wb, nullptr, nullptr, qkvb, 3072, CC, 3072, 2, false);
        fattn_kernel<false><<<dim3(QT, HH, BB), 256, 0, stream>>>(qkvb, a0b);
        proj_ln(epw + pOff, epb + cOff, eln1g + cOff, eln1b + cOff, enc, encb);
        ffn(enc, encb, ew1 + (long)i * CC * FFD, eb1 + (long)i * FFD,
            ew2 + (long)i * FFD * CC, eb2 + cOff, eln2g + cOff, eln2b + cOff);
    }

    // ---- decoder ----
    embed_kernel<<<MM, 256, 0, stream>>>(y, wte, wpe_y, dec, decb);
    for (int i = 0; i < LL; ++i) {
        const long wOff = (long)i * HH * CC * HSZ;
        const long pOff = (long)i * CC * CC;
        const long cOff = (long)i * CC;
        // masked self-attn
        cvt_qkv(dsWq + wOff, dsWk + wOff, dsWv + wOff);
        gemm(decb, wb, nullptr, nullptr, qkvb, 3072, CC, 3072, 2, false);
        fattn_kernel<true><<<dim3(QT, HH, BB), 256, 0, stream>>>(qkvb, a0b);
        proj_ln(dspw + pOff, dspb + cOff, dln1g + cOff, dln1b + cOff, dec, decb);
        // cross-attn: q from dec, k/v from enc
        cvt_qkv(dcWq + wOff, dcWk + wOff, dcWv + wOff);
        gemm(decb, wb, nullptr, nullptr, qkvb, CC, CC, 3072, 2, false);
        gemm(encb, wb + 1024 * 1024, nullptr, nullptr, qkvb + CC, 2048, CC, 3072, 2, false);
        fattn_kernel<false><<<dim3(QT, HH, BB), 256, 0, stream>>>(qkvb, a0b);
        proj_ln(dcpw + pOff, dcpb + cOff, dln2g + cOff, dln2b + cOff, dec, decb);
        // ffn
        ffn(dec, decb, dw1 + (long)i * CC * FFD, db1 + (long)i * FFD,
            dw2 + (long)i * FFD * CC, db2 + cOff, dln3g + cOff, dln3b + cOff);
    }

    // ---- final LN + logits ----
    ln_kernel<<<MM, 256, 0, stream>>>(dec, nullptr, lnfg, lnfb, t0, t0b);
    if (useWteb) {
        gemm(t0b, wteb, lm_b, out, nullptr, VV, CC, VV, 0, false);
    } else {
        dim3 grid((VV + 127) / 128, GM);
        mgemm_f32b_kernel<<<grid, 256, 0, stream>>>(t0, wte, lm_b, out, MM, VV, CC, VV);
    }
}

// Round 5
// 4618.279 us; speedup vs baseline: 12.5732x; 1.0567x over previous
//
#include <hip/hip_runtime.h>
#include <hip/hip_bf16.h>

#define BB 2
#define TT 1023
#define CC 1024
#define HH 16
#define HSZ 64
#define LL 6
#define FFD 4096
#define VV 50258
#define MM (BB*TT)   // 2046
#define MP 2048      // padded row count
#define VP 50304     // padded vocab (multiple of 128)

typedef __attribute__((ext_vector_type(4))) float  f32x4;
typedef __attribute__((ext_vector_type(8))) short  s16x8;
typedef __attribute__((ext_vector_type(4))) short  s16x4;

__device__ __forceinline__ short f2b(float x) {
    __hip_bfloat16 h = __float2bfloat16(x);
    short s;
    __builtin_memcpy(&s, &h, 2);
    return s;
}

__device__ __forceinline__ void gld16(const void* g, void* l) {
    __builtin_amdgcn_global_load_lds(
        (__attribute__((address_space(1))) const void*)g,
        (__attribute__((address_space(3))) void*)l, 16, 0, 0);
}

// ---------------------------------------------------------------------------
// Embedding: fp32 + bf16 mirror
// ---------------------------------------------------------------------------
__global__ __launch_bounds__(256) void embed_kernel(
    const int* __restrict__ ids, const float* __restrict__ wte,
    const float* __restrict__ wpe, float* __restrict__ out,
    __hip_bfloat16* __restrict__ outb)
{
    int r = blockIdx.x;
    int t = r % TT;
    long id = ids[r];
    int c = threadIdx.x * 4;
    float4 a = *(const float4*)(wte + id * (long)CC + c);
    float4 p = *(const float4*)(wpe + (long)t * CC + c);
    float4 o; o.x = a.x + p.x; o.y = a.y + p.y; o.z = a.z + p.z; o.w = a.w + p.w;
    *(float4*)(out + (long)r * CC + c) = o;
    s16x4 h; h[0] = f2b(o.x); h[1] = f2b(o.y); h[2] = f2b(o.z); h[3] = f2b(o.w);
    *(s16x4*)(outb + (long)r * CC + c) = h;
}

// ---------------------------------------------------------------------------
// Elementwise fp32 -> bf16
// ---------------------------------------------------------------------------
__global__ __launch_bounds__(256) void cvtb_kernel(
    const float* __restrict__ in, __hip_bfloat16* __restrict__ out, long n)
{
    long i = ((long)blockIdx.x * 256 + threadIdx.x) * 8;
    if (i >= n) return;
    float4 f0 = *(const float4*)(in + i);
    float4 f1 = *(const float4*)(in + i + 4);
    s16x8 h;
    h[0]=f2b(f0.x); h[1]=f2b(f0.y); h[2]=f2b(f0.z); h[3]=f2b(f0.w);
    h[4]=f2b(f1.x); h[5]=f2b(f1.y); h[6]=f2b(f1.z); h[7]=f2b(f1.w);
    *(s16x8*)(out + i) = h;
}

// ---------------------------------------------------------------------------
// Transpose + fp32->bf16: in [R][S] fp32 -> out [S][R] bf16, batched over z.
// out offset = (z/zdiv)*outZa + (z%zdiv)*outZb ; in offset = z*inZ.
// ---------------------------------------------------------------------------
__global__ __launch_bounds__(256) void tcvt_kernel(
    const float* __restrict__ in, __hip_bfloat16* __restrict__ out,
    int R, int S, long inZ, long outZa, long outZb, int zdiv)
{
    int z = blockIdx.z;
    in  += (long)z * inZ;
    out += (long)(z / zdiv) * outZa + (long)(z % zdiv) * outZb;
    __shared__ float tile[32][33];
    int s0 = blockIdx.x * 32, r0 = blockIdx.y * 32;
    int tx = threadIdx.x, ty = threadIdx.y;
    #pragma unroll
    for (int i = 0; i < 4; ++i)
        tile[ty + i * 8][tx] = in[(long)(r0 + ty + i * 8) * S + s0 + tx];
    __syncthreads();
    #pragma unroll
    for (int i = 0; i < 4; ++i)
        out[(long)(s0 + ty + i * 8) * R + r0 + tx] =
            __float2bfloat16(tile[tx][ty + i * 8]);
}

// ---------------------------------------------------------------------------
// bf16 MFMA GEMM, BK=64, coalesced LDS-staged epilogue.
// C = act(A @ B^T + bias). A [pad(M,128)][K] bf16, B [pad(N,128)][K] bf16,
// K % 64 == 0. 128x128 tile, 4 waves, global_load_lds staging.
// WMODE: 0 = fp32 out (float2-coalesced), 2 = bf16 out (b128-coalesced,
// requires N % 8 == 0 and ldc % 8 == 0).
// ---------------------------------------------------------------------------
template<int WMODE, bool RELU>
__global__ __launch_bounds__(256) void mgemm2_kernel(
    const __hip_bfloat16* __restrict__ A, const __hip_bfloat16* __restrict__ B,
    const float* __restrict__ bias, float* __restrict__ Cm,
    __hip_bfloat16* __restrict__ Cb,
    int M, int N, int K, int ldc, int GM)
{
    __shared__ short LDSBUF[2][128 * 64];   // 32 KB: A tile | B tile
    short* AsL = LDSBUF[0];
    short* BsL = LDSBUF[1];

    // bijective XCD swizzle + m-fastest decode
    const int nwg = gridDim.x;
    const int bid = blockIdx.x;
    const int q = nwg >> 3, r = nwg & 7;
    const int xcd = bid & 7, lid = bid >> 3;
    const int swz = (xcd < r) ? xcd * (q + 1) + lid
                              : r * (q + 1) + (xcd - r) * q + lid;
    const int m0 = (swz % GM) * 128;
    const int n0 = (swz / GM) * 128;

    const int tid  = threadIdx.x;
    const int lane = tid & 63, w = tid >> 6;
    const int wr = w >> 1, wc = w & 1;
    const int lr = lane & 15, kg = lane >> 4;

    const __hip_bfloat16* Abase = A + (long)m0 * K;
    const __hip_bfloat16* Bbase = B + (long)n0 * K;

    f32x4 acc[4][4];
    #pragma unroll
    for (int i = 0; i < 4; ++i)
        #pragma unroll
        for (int j = 0; j < 4; ++j)
            acc[i][j] = (f32x4){0.f, 0.f, 0.f, 0.f};

    // staging: tile 128x64 bf16 = 16 KB = 16 chunks of 1 KB; wave w stages
    // chunks 4w..4w+3 of each operand. lane's src elem = chunk*512 + lane*8.
    const int c0flat = w * 4 * 512 + lane * 8;

    for (int k0 = 0; k0 < K; k0 += 64) {
        #pragma unroll
        for (int c = 0; c < 4; ++c) {
            int flat = c0flat + c * 512;
            int row = flat >> 6, col = flat & 63;
            gld16(Abase + (long)row * K + k0 + col, &AsL[(w * 4 + c) * 512]);
        }
        #pragma unroll
        for (int c = 0; c < 4; ++c) {
            int flat = c0flat + c * 512;
            int row = flat >> 6, col = flat & 63;
            gld16(Bbase + (long)row * K + k0 + col, &BsL[(w * 4 + c) * 512]);
        }
        __syncthreads();

        #pragma unroll
        for (int kk = 0; kk < 2; ++kk) {
            s16x8 af[4], bf[4];
            #pragma unroll
            for (int i = 0; i < 4; ++i)
                af[i] = *(const s16x8*)&AsL[(wr * 64 + i * 16 + lr) * 64 + kk * 32 + kg * 8];
            #pragma unroll
            for (int j = 0; j < 4; ++j)
                bf[j] = *(const s16x8*)&BsL[(wc * 64 + j * 16 + lr) * 64 + kk * 32 + kg * 8];
            #pragma unroll
            for (int i = 0; i < 4; ++i)
                #pragma unroll
                for (int j = 0; j < 4; ++j)
                    acc[i][j] = __builtin_amdgcn_mfma_f32_16x16x32_bf16(
                        af[i], bf[j], acc[i][j], 0, 0, 0);
        }
        __syncthreads();
    }

    // ---- epilogue: stage C tile through LDS for coalesced stores ----
    if (WMODE == 0) {
        float* LF = (float*)&LDSBUF[0][0];     // [128][64] fp32 = 32 KB
        #pragma unroll
        for (int h = 0; h < 2; ++h) {
            if (wc == h) {
                #pragma unroll
                for (int j = 0; j < 4; ++j) {
                    int gcol = n0 + h * 64 + j * 16 + lr;
                    float bv = (bias && gcol < N) ? bias[gcol] : 0.f;
                    #pragma unroll
                    for (int i = 0; i < 4; ++i) {
                        int row0 = wr * 64 + i * 16 + kg * 4;
                        #pragma unroll
                        for (int qq = 0; qq < 4; ++qq) {
                            float v = acc[i][j][qq] + bv;
                            if (RELU) v = fmaxf(v, 0.f);
                            LF[(row0 + qq) * 64 + j * 16 + lr] = v;
                        }
                    }
                }
            }
            __syncthreads();
            #pragma unroll
            for (int i = 0; i < 16; ++i) {
                int F = i * 256 + tid;               // float2 index
                int row = F >> 5, col = (F & 31) * 2;
                int gr = m0 + row, gc = n0 + h * 64 + col;
                if (gr < M && gc < N)
                    *(float2*)(Cm + (long)gr * ldc + gc) = *(const float2*)&LF[row * 64 + col];
            }
            __syncthreads();
        }
    } else {
        short* LS = (short*)&LDSBUF[0][0];     // [128][128] bf16 = 32 KB
        #pragma unroll
        for (int j = 0; j < 4; ++j) {
            int gcol = n0 + wc * 64 + j * 16 + lr;
            float bv = (bias && gcol < N) ? bias[gcol] : 0.f;
            #pragma unroll
            for (int i = 0; i < 4; ++i) {
                int row0 = wr * 64 + i * 16 + kg * 4;
                #pragma unroll
                for (int qq = 0; qq < 4; ++qq) {
                    float v = acc[i][j][qq] + bv;
                    if (RELU) v = fmaxf(v, 0.f);
                    LS[(row0 + qq) * 128 + wc * 64 + j * 16 + lr] = f2b(v);
                }
            }
        }
        __syncthreads();
        #pragma unroll
        for (int i = 0; i < 8; ++i) {
            int F = i * 256 + tid;                   // s16x8 index
            int row = F >> 4, col = (F & 15) * 8;
            int gr = m0 + row, gc = n0 + col;
            if (gr < M && gc < N)
                *(s16x8*)((short*)Cb + (long)gr * ldc + gc) = *(const s16x8*)&LS[row * 128 + col];
        }
    }
}

// ---------------------------------------------------------------------------
// Fallback fp32-B GEMM (logits only, if ws too small for bf16 wte mirror).
// ---------------------------------------------------------------------------
__global__ __launch_bounds__(256) void mgemm_f32b_kernel(
    const float* __restrict__ A, const float* __restrict__ Bv,
    const float* __restrict__ bias, float* __restrict__ Cm,
    int M, int N, int K, int ldc)
{
    __shared__ short As[128][40];
    __shared__ short Bs[128][40];
    const int tid  = threadIdx.x;
    const int lane = tid & 63, w = tid >> 6;
    const int wr = w >> 1, wc = w & 1;
    const int lr = lane & 15, kg = lane >> 4;
    const int m0 = blockIdx.y * 128, n0 = blockIdx.x * 128;
    const int ar = tid >> 3, ac = (tid & 7) * 4;
    const int br = tid >> 2, bc = (tid & 3) * 8;

    f32x4 acc[4][4];
    #pragma unroll
    for (int i = 0; i < 4; ++i)
        #pragma unroll
        for (int j = 0; j < 4; ++j)
            acc[i][j] = (f32x4){0.f, 0.f, 0.f, 0.f};

    for (int k0 = 0; k0 < K; k0 += 32) {
        #pragma unroll
        for (int p = 0; p < 4; ++p) {
            int row = ar + p * 32, gm = m0 + row;
            float4 f = {0.f, 0.f, 0.f, 0.f};
            if (gm < M) f = *(const float4*)(A + (long)gm * K + k0 + ac);
            s16x4 h; h[0] = f2b(f.x); h[1] = f2b(f.y); h[2] = f2b(f.z); h[3] = f2b(f.w);
            *(s16x4*)&As[row][ac] = h;
        }
        #pragma unroll
        for (int p = 0; p < 2; ++p) {
            int n = br + p * 64, gn = n0 + n;
            s16x8 h = (s16x8){0,0,0,0,0,0,0,0};
            if (gn < N) {
                float4 f0 = *(const float4*)(Bv + (long)gn * K + k0 + bc);
                float4 f1 = *(const float4*)(Bv + (long)gn * K + k0 + bc + 4);
                h[0]=f2b(f0.x); h[1]=f2b(f0.y); h[2]=f2b(f0.z); h[3]=f2b(f0.w);
                h[4]=f2b(f1.x); h[5]=f2b(f1.y); h[6]=f2b(f1.z); h[7]=f2b(f1.w);
            }
            *(s16x8*)&Bs[n][bc] = h;
        }
        __syncthreads();
        s16x8 af[4], bf[4];
        #pragma unroll
        for (int i = 0; i < 4; ++i) af[i] = *(const s16x8*)&As[wr*64 + i*16 + lr][kg*8];
        #pragma unroll
        for (int j = 0; j < 4; ++j) bf[j] = *(const s16x8*)&Bs[wc*64 + j*16 + lr][kg*8];
        #pragma unroll
        for (int i = 0; i < 4; ++i)
            #pragma unroll
            for (int j = 0; j < 4; ++j)
                acc[i][j] = __builtin_amdgcn_mfma_f32_16x16x32_bf16(af[i], bf[j], acc[i][j], 0, 0, 0);
        __syncthreads();
    }
    #pragma unroll
    for (int j = 0; j < 4; ++j) {
        int gcol = n0 + wc * 64 + j * 16 + lr;
        if (gcol >= N) continue;
        float bv = bias ? bias[gcol] : 0.f;
        #pragma unroll
        for (int i = 0; i < 4; ++i) {
            int grow0 = m0 + wr * 64 + i * 16 + kg * 4;
            #pragma unroll
            for (int qq = 0; qq < 4; ++qq) {
                int gr = grow0 + qq;
                if (gr >= M) continue;
                Cm[(long)gr * ldc + gcol] = acc[i][j][qq] + bv;
            }
        }
    }
}

// ---------------------------------------------------------------------------
// MFMA flash attention (bf16 in / bf16 out). grid (16, H, B), 4 waves.
// qkvb: [M,3072] bf16 (q|k|v, head h at col h*64). outb: [M,C] bf16.
// scale = 1/sqrt(C) = 1/32 (reference quirk).
// ---------------------------------------------------------------------------
template<bool CAUSAL>
__global__ __launch_bounds__(256) void fattn_kernel(
    const __hip_bfloat16* __restrict__ qkvb, __hip_bfloat16* __restrict__ outb)
{
    __shared__ short Ks[64][72];
    __shared__ short Vt[64][72];
    __shared__ short Ps[4][16][72];

    const int q0 = blockIdx.x * 64;
    const int h = blockIdx.y, b = blockIdx.z;
    const int tid = threadIdx.x;
    const int lane = tid & 63, w = tid >> 6;
    const int lr = lane & 15, lg = lane >> 4;

    const float scale = 1.0f / 32.0f;
    const long base = (long)b * TT * 3072;
    const __hip_bfloat16* Kg = qkvb + base + 1024 + h * 64;
    const __hip_bfloat16* Vg = qkvb + base + 2048 + h * 64;

    s16x8 qf[2];
    {
        int qr = q0 + w * 16 + lr;
        #pragma unroll
        for (int kc = 0; kc < 2; ++kc) {
            s16x8 hv = (s16x8){0,0,0,0,0,0,0,0};
            if (qr < TT)
                hv = *(const s16x8*)(qkvb + base + (long)qr * 3072 + h * 64 + kc * 32 + lg * 8);
            qf[kc] = hv;
        }
    }

    f32x4 acc[4];
    #pragma unroll
    for (int jd = 0; jd < 4; ++jd) acc[jd] = (f32x4){0.f, 0.f, 0.f, 0.f};
    float mrun[4] = {-3.0e38f, -3.0e38f, -3.0e38f, -3.0e38f};
    float lrun[4] = {0.f, 0.f, 0.f, 0.f};

    const int send = CAUSAL ? min(TT, q0 + 64) : TT;
    const int sr2 = (tid >> 3) * 2;        // rows sr2, sr2+1
    const int dcc = (tid & 7) * 8;         // col chunk

    for (int s0 = 0; s0 < send; s0 += 64) {
        __syncthreads();
        {
            s16x8 v8[2];
            #pragma unroll
            for (int rr = 0; rr < 2; ++rr) {
                int sg = s0 + sr2 + rr;
                if (sg < TT) {
                    *(s16x8*)&Ks[sr2 + rr][dcc] = *(const s16x8*)(Kg + (long)sg * 3072 + dcc);
                    v8[rr] = *(const s16x8*)(Vg + (long)sg * 3072 + dcc);
                } else {
                    *(s16x8*)&Ks[sr2 + rr][dcc] = (s16x8){0,0,0,0,0,0,0,0};
                    v8[rr] = (s16x8){0,0,0,0,0,0,0,0};
                }
            }
            #pragma unroll
            for (int e = 0; e < 8; ++e) {
                unsigned pack = (unsigned)(unsigned short)v8[0][e]
                              | ((unsigned)(unsigned short)v8[1][e] << 16);
                *(unsigned*)&Vt[dcc + e][sr2] = pack;
            }
        }
        __syncthreads();

        f32x4 sf[4];
        #pragma unroll
        for (int j = 0; j < 4; ++j) {
            f32x4 z = (f32x4){0.f, 0.f, 0.f, 0.f};
            #pragma unroll
            for (int kc = 0; kc < 2; ++kc) {
                s16x8 kf = *(const s16x8*)&Ks[j * 16 + lr][kc * 32 + lg * 8];
                z = __builtin_amdgcn_mfma_f32_16x16x32_bf16(qf[kc], kf, z, 0, 0, 0);
            }
            sf[j] = z;
        }

        float mloc[4] = {-3.0e38f, -3.0e38f, -3.0e38f, -3.0e38f};
        #pragma unroll
        for (int j = 0; j < 4; ++j) {
            int sg = s0 + j * 16 + lr;
            #pragma unroll
            for (int r = 0; r < 4; ++r) {
                float sc = sf[j][r] * scale;
                int qg = q0 + w * 16 + lg * 4 + r;
                if ((CAUSAL && sg > qg) || sg >= TT) sc = -3.0e38f;
                sf[j][r] = sc;
                mloc[r] = fmaxf(mloc[r], sc);
            }
        }
        #pragma unroll
        for (int r = 0; r < 4; ++r)
            #pragma unroll
            for (int off = 1; off < 16; off <<= 1)
                mloc[r] = fmaxf(mloc[r], __shfl_xor(mloc[r], off));

        float corr[4], psum[4];
        #pragma unroll
        for (int r = 0; r < 4; ++r) {
            float mn = fmaxf(mrun[r], mloc[r]);
            corr[r] = __expf(mrun[r] - mn);
            mrun[r] = mn;
            psum[r] = 0.f;
        }

        #pragma unroll
        for (int j = 0; j < 4; ++j) {
            #pragma unroll
            for (int r = 0; r < 4; ++r) {
                float p = __expf(sf[j][r] - mrun[r]);
                psum[r] += p;
                Ps[w][lg * 4 + r][j * 16 + lr] = f2b(p);
            }
        }
        #pragma unroll
        for (int r = 0; r < 4; ++r) {
            #pragma unroll
            for (int off = 1; off < 16; off <<= 1)
                psum[r] += __shfl_xor(psum[r], off);
            lrun[r] = lrun[r] * corr[r] + psum[r];
            #pragma unroll
            for (int jd = 0; jd < 4; ++jd) acc[jd][r] *= corr[r];
        }

        #pragma unroll
        for (int kc = 0; kc < 2; ++kc) {
            s16x8 pa = *(const s16x8*)&Ps[w][lr][kc * 32 + lg * 8];
            #pragma unroll
            for (int jd = 0; jd < 4; ++jd) {
                s16x8 bv = *(const s16x8*)&Vt[jd * 16 + lr][kc * 32 + lg * 8];
                acc[jd] = __builtin_amdgcn_mfma_f32_16x16x32_bf16(pa, bv, acc[jd], 0, 0, 0);
            }
        }
    }

    #pragma unroll
    for (int r = 0; r < 4; ++r) {
        int qg = q0 + w * 16 + lg * 4 + r;
        if (qg >= TT) continue;
        float inv = 1.0f / lrun[r];
        #pragma unroll
        for (int jd = 0; jd < 4; ++jd)
            outb[((long)b * TT + qg) * CC + h * 64 + jd * 16 + lr] =
                __float2bfloat16(acc[jd][r] * inv);
    }
}

// ---------------------------------------------------------------------------
// LayerNorm (+optional residual), fp32 out + optional bf16 mirror.
// ---------------------------------------------------------------------------
__global__ __launch_bounds__(256) void ln_kernel(
    const float* __restrict__ in, const float* __restrict__ res,
    const float* __restrict__ g, const float* __restrict__ b,
    float* __restrict__ out, __hip_bfloat16* __restrict__ outb)
{
    const int r = blockIdx.x, tid = threadIdx.x;
    __shared__ float sm[4];

    float4 xv = *(const float4*)(in + (long)r * CC + tid * 4);
    float s = xv.x + xv.y + xv.z + xv.w;
    #pragma unroll
    for (int o = 32; o > 0; o >>= 1) s += __shfl_xor(s, o);
    if ((tid & 63) == 0) sm[tid >> 6] = s;
    __syncthreads();
    const float mean = (sm[0] + sm[1] + sm[2] + sm[3]) * (1.0f / CC);
    __syncthreads();

    float4 d; d.x = xv.x - mean; d.y = xv.y - mean; d.z = xv.z - mean; d.w = xv.w - mean;
    float s2 = d.x * d.x + d.y * d.y + d.z * d.z + d.w * d.w;
    #pragma unroll
    for (int o = 32; o > 0; o >>= 1) s2 += __shfl_xor(s2, o);
    if ((tid & 63) == 0) sm[tid >> 6] = s2;
    __syncthreads();
    const float rstd = rsqrtf((sm[0] + sm[1] + sm[2] + sm[3]) * (1.0f / CC) + 1e-5f);

    float4 gv = *(const float4*)(g + tid * 4);
    float4 bv = *(const float4*)(b + tid * 4);
    float4 o;
    o.x = gv.x * d.x * rstd + bv.x; o.y = gv.y * d.y * rstd + bv.y;
    o.z = gv.z * d.z * rstd + bv.z; o.w = gv.w * d.w * rstd + bv.w;
    if (res) {
        float4 rv = *(const float4*)(res + (long)r * CC + tid * 4);
        o.x += rv.x; o.y += rv.y; o.z += rv.z; o.w += rv.w;
    }
    *(float4*)(out + (long)r * CC + tid * 4) = o;
    if (outb) {
        s16x4 h; h[0] = f2b(o.x); h[1] = f2b(o.y); h[2] = f2b(o.z); h[3] = f2b(o.w);
        *(s16x4*)(outb + (long)r * CC + tid * 4) = h;
    }
}

// ---------------------------------------------------------------------------
extern "C" void kernel_launch(void* const* d_in, const int* in_sizes, int n_in,
                              void* d_out, int out_size, void* d_ws, size_t ws_size,
                              hipStream_t stream)
{
    const int*   x      = (const int*)  d_in[0];
    const int*   y      = (const int*)  d_in[1];
    const float* wte    = (const float*)d_in[2];
    const float* wpe_x  = (const float*)d_in[3];
    const float* wpe_y  = (const float*)d_in[4];
    const float* eWq    = (const float*)d_in[5];
    const float* eWk    = (const float*)d_in[6];
    const float* eWv    = (const float*)d_in[7];
    const float* epw    = (const float*)d_in[8];
    const float* epb    = (const float*)d_in[9];
    const float* eln1g  = (const float*)d_in[10];
    const float* eln1b  = (const float*)d_in[11];
    const float* eln2g  = (const float*)d_in[12];
    const float* eln2b  = (const float*)d_in[13];
    const float* ew1    = (const float*)d_in[14];
    const float* eb1    = (const float*)d_in[15];
    const float* ew2    = (const float*)d_in[16];
    const float* eb2    = (const float*)d_in[17];
    const float* dsWq   = (const float*)d_in[18];
    const float* dsWk   = (const float*)d_in[19];
    const float* dsWv   = (const float*)d_in[20];
    const float* dspw   = (const float*)d_in[21];
    const float* dspb   = (const float*)d_in[22];
    const float* dcWq   = (const float*)d_in[23];
    const float* dcWk   = (const float*)d_in[24];
    const float* dcWv   = (const float*)d_in[25];
    const float* dcpw   = (const float*)d_in[26];
    const float* dcpb   = (const float*)d_in[27];
    const float* dln1g  = (const float*)d_in[28];
    const float* dln1b  = (const float*)d_in[29];
    const float* dln2g  = (const float*)d_in[30];
    const float* dln2b  = (const float*)d_in[31];
    const float* dln3g  = (const float*)d_in[32];
    const float* dln3b  = (const float*)d_in[33];
    const float* dw1    = (const float*)d_in[34];
    const float* db1    = (const float*)d_in[35];
    const float* dw2    = (const float*)d_in[36];
    const float* db2    = (const float*)d_in[37];
    const float* lnfg   = (const float*)d_in[38];
    const float* lnfb   = (const float*)d_in[39];
    const float* lm_b   = (const float*)d_in[40];

    float* out = (float*)d_out;

    // ---- workspace carve-up ----
    const size_t MCp = (size_t)MP * CC;
    float* enc = (float*)d_ws;
    float* dec = enc + MCp;
    float* t0  = dec + MCp;
    __hip_bfloat16* encb = (__hip_bfloat16*)(t0 + MCp);
    __hip_bfloat16* decb = encb + MCp;
    __hip_bfloat16* t0b  = decb + MCp;
    __hip_bfloat16* a0b  = t0b + MCp;
    __hip_bfloat16* qkvb = a0b + MCp;                    // [MP][3072]
    __hip_bfloat16* ffb  = qkvb + (size_t)MP * 3072;     // [MP][FFD]
    __hip_bfloat16* wteb = ffb + (size_t)MP * FFD;       // [VP][C]
    // big-mode weight blocks
    __hip_bfloat16* eQKVw = wteb + (size_t)VP * CC;      // [L][3072][C]
    __hip_bfloat16* ePWw  = eQKVw + (size_t)LL * 3072 * CC;
    __hip_bfloat16* eW1w  = ePWw  + (size_t)LL * CC * CC;     // [L][FFD][C]
    __hip_bfloat16* eW2w  = eW1w  + (size_t)LL * FFD * CC;    // [L][C][FFD]
    __hip_bfloat16* sQKVw = eW2w  + (size_t)LL * CC * FFD;
    __hip_bfloat16* sPWw  = sQKVw + (size_t)LL * 3072 * CC;
    __hip_bfloat16* cQKVw = sPWw  + (size_t)LL * CC * CC;
    __hip_bfloat16* cPWw  = cQKVw + (size_t)LL * 3072 * CC;
    __hip_bfloat16* dW1w  = cPWw  + (size_t)LL * CC * CC;
    __hip_bfloat16* dW2w  = dW1w  + (size_t)LL * FFD * CC;
    __hip_bfloat16* bigEnd = dW2w + (size_t)LL * CC * FFD;
    // small-mode: per-use conversion buffer where eQKVw starts
    __hip_bfloat16* wb = eQKVw;
    const size_t needBig   = (size_t)((char*)bigEnd - (char*)d_ws);
    const size_t needSmall = (size_t)((char*)(wb + (size_t)FFD * CC) - (char*)d_ws);
    const size_t needWteb  = (size_t)((char*)eQKVw - (char*)d_ws);
    const bool big     = (ws_size >= needBig);
    const bool useWteb = (ws_size >= needWteb) &&
                         (big || ws_size >= needSmall);

    const int GM = MP / 128;           // 16 m-tiles
    const int QT = (TT + 63) / 64;     // 16 q-tiles
    const dim3 tblk(32, 8);

    auto gemm = [&](const __hip_bfloat16* A, const __hip_bfloat16* B,
                    const float* bias, float* Cm, __hip_bfloat16* Cb,
                    int N_, int K_, int ldc, int wmode, bool relu) {
        int nwg = GM * ((N_ + 127) / 128);
        if (wmode == 0) {
            if (relu) mgemm2_kernel<0, true ><<<nwg, 256, 0, stream>>>(A, B, bias, Cm, Cb, MM, N_, K_, ldc, GM);
            else      mgemm2_kernel<0, false><<<nwg, 256, 0, stream>>>(A, B, bias, Cm, Cb, MM, N_, K_, ldc, GM);
        } else {
            if (relu) mgemm2_kernel<2, true ><<<nwg, 256, 0, stream>>>(A, B, bias, Cm, Cb, MM, N_, K_, ldc, GM);
            else      mgemm2_kernel<2, false><<<nwg, 256, 0, stream>>>(A, B, bias, Cm, Cb, MM, N_, K_, ldc, GM);
        }
    };

    if (useWteb) {
        long n = (long)VV * CC;
        cvtb_kernel<<<(int)((n / 8 + 255) / 256), 256, 0, stream>>>(wte, wteb, n);
    }

    if (big) {
        // ---- all weight conversions up-front ----
        const long sWH = (long)CC * HSZ;            // per-(l,h) input stride
        const long oA = (long)3072 * CC;            // per-layer qkv out stride
        const long oB = (long)HSZ * CC;             // per-head out stride
        dim3 gq(HSZ / 32, CC / 32, LL * HH);
        tcvt_kernel<<<gq, tblk, 0, stream>>>(eWq, eQKVw,             CC, HSZ, sWH, oA, oB, HH);
        tcvt_kernel<<<gq, tblk, 0, stream>>>(eWk, eQKVw + CC * CC,   CC, HSZ, sWH, oA, oB, HH);
        tcvt_kernel<<<gq, tblk, 0, stream>>>(eWv, eQKVw + 2*CC*CC,   CC, HSZ, sWH, oA, oB, HH);
        tcvt_kernel<<<gq, tblk, 0, stream>>>(dsWq, sQKVw,            CC, HSZ, sWH, oA, oB, HH);
        tcvt_kernel<<<gq, tblk, 0, stream>>>(dsWk, sQKVw + CC * CC,  CC, HSZ, sWH, oA, oB, HH);
        tcvt_kernel<<<gq, tblk, 0, stream>>>(dsWv, sQKVw + 2*CC*CC,  CC, HSZ, sWH, oA, oB, HH);
        tcvt_kernel<<<gq, tblk, 0, stream>>>(dcWq, cQKVw,            CC, HSZ, sWH, oA, oB, HH);
        tcvt_kernel<<<gq, tblk, 0, stream>>>(dcWk, cQKVw + CC * CC,  CC, HSZ, sWH, oA, oB, HH);
        tcvt_kernel<<<gq, tblk, 0, stream>>>(dcWv, cQKVw + 2*CC*CC,  CC, HSZ, sWH, oA, oB, HH);
        dim3 gp(CC / 32, CC / 32, LL);
        tcvt_kernel<<<gp, tblk, 0, stream>>>(epw,  ePWw, CC, CC, (long)CC*CC, (long)CC*CC, 0, 1);
        tcvt_kernel<<<gp, tblk, 0, stream>>>(dspw, sPWw, CC, CC, (long)CC*CC, (long)CC*CC, 0, 1);
        tcvt_kernel<<<gp, tblk, 0, stream>>>(dcpw, cPWw, CC, CC, (long)CC*CC, (long)CC*CC, 0, 1);
        dim3 g1(FFD / 32, CC / 32, LL);
        tcvt_kernel<<<g1, tblk, 0, stream>>>(ew1, eW1w, CC, FFD, (long)CC*FFD, (long)FFD*CC, 0, 1);
        tcvt_kernel<<<g1, tblk, 0, stream>>>(dw1, dW1w, CC, FFD, (long)CC*FFD, (long)FFD*CC, 0, 1);
        dim3 g2(CC / 32, FFD / 32, LL);
        tcvt_kernel<<<g2, tblk, 0, stream>>>(ew2, eW2w, FFD, CC, (long)FFD*CC, (long)CC*FFD, 0, 1);
        tcvt_kernel<<<g2, tblk, 0, stream>>>(dw2, dW2w, FFD, CC, (long)FFD*CC, (long)CC*FFD, 0, 1);
    }

    // small-mode per-use converters
    auto cvt_qkv = [&](const float* Wq, const float* Wk, const float* Wv) {
        dim3 g(HSZ / 32, CC / 32, HH);
        tcvt_kernel<<<g, tblk, 0, stream>>>(Wq, wb,             CC, HSZ, (long)CC*HSZ, (long)HSZ*CC, 0, 1);
        tcvt_kernel<<<g, tblk, 0, stream>>>(Wk, wb + CC*CC,     CC, HSZ, (long)CC*HSZ, (long)HSZ*CC, 0, 1);
        tcvt_kernel<<<g, tblk, 0, stream>>>(Wv, wb + 2*CC*CC,   CC, HSZ, (long)CC*HSZ, (long)HSZ*CC, 0, 1);
    };
    auto cvt_nt = [&](const float* W, int R, int S) {
        dim3 g(S / 32, R / 32, 1);
        tcvt_kernel<<<g, tblk, 0, stream>>>(W, wb, R, S, 0, 0, 0, 1);
    };

    // ---- encoder ----
    embed_kernel<<<MM, 256, 0, stream>>>(x, wte, wpe_x, enc, encb);
    for (int i = 0; i < LL; ++i) {
        const long cOff = (long)i * CC;
        const __hip_bfloat16 *Wqkv, *Wp, *W1, *W2;
        if (big) {
            Wqkv = eQKVw + (size_t)i * 3072 * CC;
            Wp   = ePWw  + (size_t)i * CC * CC;
            W1   = eW1w  + (size_t)i * FFD * CC;
            W2   = eW2w  + (size_t)i * CC * FFD;
        }
        if (!big) cvt_qkv(eWq + (long)i*HH*CC*HSZ, eWk + (long)i*HH*CC*HSZ, eWv + (long)i*HH*CC*HSZ), Wqkv = wb;
        gemm(encb, Wqkv, nullptr, nullptr, qkvb, 3072, CC, 3072, 2, false);
        fattn_kernel<false><<<dim3(QT, HH, BB), 256, 0, stream>>>(qkvb, a0b);
        if (!big) cvt_nt(epw + (long)i*CC*CC, CC, CC), Wp = wb;
        gemm(a0b, Wp, epb + cOff, t0, nullptr, CC, CC, CC, 0, false);
        ln_kernel<<<MM, 256, 0, stream>>>(t0, enc, eln1g + cOff, eln1b + cOff, enc, encb);
        if (!big) cvt_nt(ew1 + (long)i*CC*FFD, CC, FFD), W1 = wb;
        gemm(encb, W1, eb1 + (long)i*FFD, nullptr, ffb, FFD, CC, FFD, 2, true);
        if (!big) cvt_nt(ew2 + (long)i*FFD*CC, FFD, CC), W2 = wb;
        gemm(ffb, W2, eb2 + cOff, t0, nullptr, CC, FFD, CC, 0, false);
        ln_kernel<<<MM, 256, 0, stream>>>(t0, enc, eln2g + cOff, eln2b + cOff, enc, encb);
    }

    // ---- decoder ----
    embed_kernel<<<MM, 256, 0, stream>>>(y, wte, wpe_y, dec, decb);
    for (int i = 0; i < LL; ++i) {
        const long cOff = (long)i * CC;
        const __hip_bfloat16 *Ws, *Wsp, *Wc, *Wcp, *W1, *W2;
        if (big) {
            Ws  = sQKVw + (size_t)i * 3072 * CC;
            Wsp = sPWw  + (size_t)i * CC * CC;
            Wc  = cQKVw + (size_t)i * 3072 * CC;
            Wcp = cPWw  + (size_t)i * CC * CC;
            W1  = dW1w  + (size_t)i * FFD * CC;
            W2  = dW2w  + (size_t)i * CC * FFD;
        }
        // masked self-attn
        if (!big) cvt_qkv(dsWq + (long)i*HH*CC*HSZ, dsWk + (long)i*HH*CC*HSZ, dsWv + (long)i*HH*CC*HSZ), Ws = wb;
        gemm(decb, Ws, nullptr, nullptr, qkvb, 3072, CC, 3072, 2, false);
        fattn_kernel<true><<<dim3(QT, HH, BB), 256, 0, stream>>>(qkvb, a0b);
        if (!big) cvt_nt(dspw + (long)i*CC*CC, CC, CC), Wsp = wb;
        gemm(a0b, Wsp, dspb + cOff, t0, nullptr, CC, CC, CC, 0, false);
        ln_kernel<<<MM, 256, 0, stream>>>(t0, dec, dln1g + cOff, dln1b + cOff, dec, decb);
        // cross-attn: q from dec, k/v from enc
        if (!big) cvt_qkv(dcWq + (long)i*HH*CC*HSZ, dcWk + (long)i*HH*CC*HSZ, dcWv + (long)i*HH*CC*HSZ), Wc = wb;
        gemm(decb, Wc, nullptr, nullptr, qkvb, CC, CC, 3072, 2, false);
        gemm(encb, Wc + (size_t)CC * CC, nullptr, nullptr, qkvb + CC, 2048, CC, 3072, 2, false);
        fattn_kernel<false><<<dim3(QT, HH, BB), 256, 0, stream>>>(qkvb, a0b);
        if (!big) cvt_nt(dcpw + (long)i*CC*CC, CC, CC), Wcp = wb;
        gemm(a0b, Wcp, dcpb + cOff, t0, nullptr, CC, CC, CC, 0, false);
        ln_kernel<<<MM, 256, 0, stream>>>(t0, dec, dln2g + cOff, dln2b + cOff, dec, decb);
        // ffn
        if (!big) cvt_nt(dw1 + (long)i*CC*FFD, CC, FFD), W1 = wb;
        gemm(decb, W1, db1 + (long)i*FFD, nullptr, ffb, FFD, CC, FFD, 2, true);
        if (!big) cvt_nt(dw2 + (long)i*FFD*CC, FFD, CC), W2 = wb;
        gemm(ffb, W2, db2 + cOff, t0, nullptr, CC, FFD, CC, 0, false);
        ln_kernel<<<MM, 256, 0, stream>>>(t0, dec, dln3g + cOff, dln3b + cOff, dec, decb);
    }

    // ---- final LN + logits ----
    ln_kernel<<<MM, 256, 0, stream>>>(dec, nullptr, lnfg, lnfb, t0, t0b);
    if (useWteb) {
        gemm(t0b, wteb, lm_b, out, nullptr, VV, CC, VV, 0, false);
    } else {
        dim3 grid((VV + 127) / 128, GM);
        mgemm_f32b_kernel<<<grid, 256, 0, stream>>>(t0, wte, lm_b, out, MM, VV, CC, VV);
    }
}

// Round 6
// 4480.064 us; speedup vs baseline: 12.9611x; 1.0309x over previous
//
#include <hip/hip_runtime.h>
#include <hip/hip_bf16.h>

#define BB 2
#define TT 1023
#define CC 1024
#define HH 16
#define HSZ 64
#define LL 6
#define FFD 4096
#define VV 50258
#define MM (BB*TT)   // 2046
#define MP 2048      // padded row count
#define VP 50304     // padded vocab (multiple of 128)

typedef __attribute__((ext_vector_type(4))) float  f32x4;
typedef __attribute__((ext_vector_type(8))) short  s16x8;
typedef __attribute__((ext_vector_type(4))) short  s16x4;

__device__ __forceinline__ short f2b(float x) {
    __hip_bfloat16 h = __float2bfloat16(x);
    short s;
    __builtin_memcpy(&s, &h, 2);
    return s;
}

__device__ __forceinline__ void gld16(const void* g, void* l) {
    __builtin_amdgcn_global_load_lds(
        (__attribute__((address_space(1))) const void*)g,
        (__attribute__((address_space(3))) void*)l, 16, 0, 0);
}

// ---------------------------------------------------------------------------
// Embedding: fp32 + bf16 mirror
// ---------------------------------------------------------------------------
__global__ __launch_bounds__(256) void embed_kernel(
    const int* __restrict__ ids, const float* __restrict__ wte,
    const float* __restrict__ wpe, float* __restrict__ out,
    __hip_bfloat16* __restrict__ outb)
{
    int r = blockIdx.x;
    int t = r % TT;
    long id = ids[r];
    int c = threadIdx.x * 4;
    float4 a = *(const float4*)(wte + id * (long)CC + c);
    float4 p = *(const float4*)(wpe + (long)t * CC + c);
    float4 o; o.x = a.x + p.x; o.y = a.y + p.y; o.z = a.z + p.z; o.w = a.w + p.w;
    *(float4*)(out + (long)r * CC + c) = o;
    s16x4 h; h[0] = f2b(o.x); h[1] = f2b(o.y); h[2] = f2b(o.z); h[3] = f2b(o.w);
    *(s16x4*)(outb + (long)r * CC + c) = h;
}

// ---------------------------------------------------------------------------
// Elementwise fp32 -> bf16
// ---------------------------------------------------------------------------
__global__ __launch_bounds__(256) void cvtb_kernel(
    const float* __restrict__ in, __hip_bfloat16* __restrict__ out, long n)
{
    long i = ((long)blockIdx.x * 256 + threadIdx.x) * 8;
    if (i >= n) return;
    float4 f0 = *(const float4*)(in + i);
    float4 f1 = *(const float4*)(in + i + 4);
    s16x8 h;
    h[0]=f2b(f0.x); h[1]=f2b(f0.y); h[2]=f2b(f0.z); h[3]=f2b(f0.w);
    h[4]=f2b(f1.x); h[5]=f2b(f1.y); h[6]=f2b(f1.z); h[7]=f2b(f1.w);
    *(s16x8*)(out + i) = h;
}

// ---------------------------------------------------------------------------
// Transpose + fp32->bf16: in [R][S] fp32 -> out [S][R] bf16, batched over z.
// out offset = (z/zdiv)*outZa + (z%zdiv)*outZb ; in offset = z*inZ.
// ---------------------------------------------------------------------------
__global__ __launch_bounds__(256) void tcvt_kernel(
    const float* __restrict__ in, __hip_bfloat16* __restrict__ out,
    int R, int S, long inZ, long outZa, long outZb, int zdiv)
{
    int z = blockIdx.z;
    in  += (long)z * inZ;
    out += (long)(z / zdiv) * outZa + (long)(z % zdiv) * outZb;
    __shared__ float tile[32][33];
    int s0 = blockIdx.x * 32, r0 = blockIdx.y * 32;
    int tx = threadIdx.x, ty = threadIdx.y;
    #pragma unroll
    for (int i = 0; i < 4; ++i)
        tile[ty + i * 8][tx] = in[(long)(r0 + ty + i * 8) * S + s0 + tx];
    __syncthreads();
    #pragma unroll
    for (int i = 0; i < 4; ++i)
        out[(long)(s0 + ty + i * 8) * R + r0 + tx] =
            __float2bfloat16(tile[tx][ty + i * 8]);
}

// ---------------------------------------------------------------------------
// bf16 MFMA GEMM, BK=64 with split-K LDS layout [2][128][32] (64B row
// stride -> 2-way bank aliasing = free, m97 structure). C = act(A@B^T+bias).
// A [pad(M,128)][K] bf16, B [pad(N,128)][K] bf16, K % 64 == 0.
// 128x128 tile, 4 waves, global_load_lds staging, coalesced LDS epilogue.
// WMODE: 0 = fp32 out (float2-coalesced), 2 = bf16 out (b128-coalesced).
// ---------------------------------------------------------------------------
template<int WMODE, bool RELU>
__global__ __launch_bounds__(256) void mgemm2_kernel(
    const __hip_bfloat16* __restrict__ A, const __hip_bfloat16* __restrict__ B,
    const float* __restrict__ bias, float* __restrict__ Cm,
    __hip_bfloat16* __restrict__ Cb,
    int M, int N, int K, int ldc, int GM)
{
    __shared__ short LDSBUF[2][2 * 128 * 32];   // 32 KB: A | B, each [2][128][32]
    short* AsL = LDSBUF[0];
    short* BsL = LDSBUF[1];

    // bijective XCD swizzle + m-fastest decode
    const int nwg = gridDim.x;
    const int bid = blockIdx.x;
    const int q = nwg >> 3, r = nwg & 7;
    const int xcd = bid & 7, lid = bid >> 3;
    const int swz = (xcd < r) ? xcd * (q + 1) + lid
                              : r * (q + 1) + (xcd - r) * q + lid;
    const int m0 = (swz % GM) * 128;
    const int n0 = (swz / GM) * 128;

    const int tid  = threadIdx.x;
    const int lane = tid & 63, w = tid >> 6;
    const int wr = w >> 1, wc = w & 1;
    const int lr = lane & 15, kg = lane >> 4;

    const __hip_bfloat16* Abase = A + (long)m0 * K;
    const __hip_bfloat16* Bbase = B + (long)n0 * K;

    f32x4 acc[4][4];
    #pragma unroll
    for (int i = 0; i < 4; ++i)
        #pragma unroll
        for (int j = 0; j < 4; ++j)
            acc[i][j] = (f32x4){0.f, 0.f, 0.f, 0.f};

    // staging: 16 chunks of 512 elems (1 KB); chunk cc -> K-half cc>>3,
    // rows (cc&7)*16 + (lane>>2), global col (cc>>3)*32 + (lane&3)*8.
    // LDS dest stays linear (wave-uniform base + lane*16B); the per-lane
    // GLOBAL address carries the layout permutation.
    const int srow = lane >> 2;
    const int scol = (lane & 3) * 8;

    for (int k0 = 0; k0 < K; k0 += 64) {
        #pragma unroll
        for (int c = 0; c < 4; ++c) {
            int cc = w * 4 + c;
            int row = (cc & 7) * 16 + srow;
            int gc  = (cc >> 3) * 32 + scol;
            gld16(Abase + (long)row * K + k0 + gc, &AsL[cc * 512]);
        }
        #pragma unroll
        for (int c = 0; c < 4; ++c) {
            int cc = w * 4 + c;
            int row = (cc & 7) * 16 + srow;
            int gc  = (cc >> 3) * 32 + scol;
            gld16(Bbase + (long)row * K + k0 + gc, &BsL[cc * 512]);
        }
        __syncthreads();

        #pragma unroll
        for (int kk = 0; kk < 2; ++kk) {
            s16x8 af[4], bf[4];
            #pragma unroll
            for (int i = 0; i < 4; ++i)
                af[i] = *(const s16x8*)&AsL[kk * 4096 + (wr * 64 + i * 16 + lr) * 32 + kg * 8];
            #pragma unroll
            for (int j = 0; j < 4; ++j)
                bf[j] = *(const s16x8*)&BsL[kk * 4096 + (wc * 64 + j * 16 + lr) * 32 + kg * 8];
            #pragma unroll
            for (int i = 0; i < 4; ++i)
                #pragma unroll
                for (int j = 0; j < 4; ++j)
                    acc[i][j] = __builtin_amdgcn_mfma_f32_16x16x32_bf16(
                        af[i], bf[j], acc[i][j], 0, 0, 0);
        }
        __syncthreads();
    }

    // ---- epilogue: stage C tile through LDS for coalesced stores ----
    if (WMODE == 0) {
        float* LF = (float*)&LDSBUF[0][0];     // [128][64] fp32 = 32 KB
        #pragma unroll
        for (int h = 0; h < 2; ++h) {
            if (wc == h) {
                #pragma unroll
                for (int j = 0; j < 4; ++j) {
                    int gcol = n0 + h * 64 + j * 16 + lr;
                    float bv = (bias && gcol < N) ? bias[gcol] : 0.f;
                    #pragma unroll
                    for (int i = 0; i < 4; ++i) {
                        int row0 = wr * 64 + i * 16 + kg * 4;
                        #pragma unroll
                        for (int qq = 0; qq < 4; ++qq) {
                            float v = acc[i][j][qq] + bv;
                            if (RELU) v = fmaxf(v, 0.f);
                            LF[(row0 + qq) * 64 + j * 16 + lr] = v;
                        }
                    }
                }
            }
            __syncthreads();
            #pragma unroll
            for (int i = 0; i < 16; ++i) {
                int F = i * 256 + tid;               // float2 index
                int row = F >> 5, col = (F & 31) * 2;
                int gr = m0 + row, gc = n0 + h * 64 + col;
                if (gr < M && gc < N)
                    *(float2*)(Cm + (long)gr * ldc + gc) = *(const float2*)&LF[row * 64 + col];
            }
            __syncthreads();
        }
    } else {
        short* LS = (short*)&LDSBUF[0][0];     // [128][128] bf16 = 32 KB
        #pragma unroll
        for (int j = 0; j < 4; ++j) {
            int gcol = n0 + wc * 64 + j * 16 + lr;
            float bv = (bias && gcol < N) ? bias[gcol] : 0.f;
            #pragma unroll
            for (int i = 0; i < 4; ++i) {
                int row0 = wr * 64 + i * 16 + kg * 4;
                #pragma unroll
                for (int qq = 0; qq < 4; ++qq) {
                    float v = acc[i][j][qq] + bv;
                    if (RELU) v = fmaxf(v, 0.f);
                    LS[(row0 + qq) * 128 + wc * 64 + j * 16 + lr] = f2b(v);
                }
            }
        }
        __syncthreads();
        #pragma unroll
        for (int i = 0; i < 8; ++i) {
            int F = i * 256 + tid;                   // s16x8 index
            int row = F >> 4, col = (F & 15) * 8;
            int gr = m0 + row, gc = n0 + col;
            if (gr < M && gc < N)
                *(s16x8*)((short*)Cb + (long)gr * ldc + gc) = *(const s16x8*)&LS[row * 128 + col];
        }
    }
}

// ---------------------------------------------------------------------------
// Fallback fp32-B GEMM (logits only, if ws too small for bf16 wte mirror).
// ---------------------------------------------------------------------------
__global__ __launch_bounds__(256) void mgemm_f32b_kernel(
    const float* __restrict__ A, const float* __restrict__ Bv,
    const float* __restrict__ bias, float* __restrict__ Cm,
    int M, int N, int K, int ldc)
{
    __shared__ short As[128][40];
    __shared__ short Bs[128][40];
    const int tid  = threadIdx.x;
    const int lane = tid & 63, w = tid >> 6;
    const int wr = w >> 1, wc = w & 1;
    const int lr = lane & 15, kg = lane >> 4;
    const int m0 = blockIdx.y * 128, n0 = blockIdx.x * 128;
    const int ar = tid >> 3, ac = (tid & 7) * 4;
    const int br = tid >> 2, bc = (tid & 3) * 8;

    f32x4 acc[4][4];
    #pragma unroll
    for (int i = 0; i < 4; ++i)
        #pragma unroll
        for (int j = 0; j < 4; ++j)
            acc[i][j] = (f32x4){0.f, 0.f, 0.f, 0.f};

    for (int k0 = 0; k0 < K; k0 += 32) {
        #pragma unroll
        for (int p = 0; p < 4; ++p) {
            int row = ar + p * 32, gm = m0 + row;
            float4 f = {0.f, 0.f, 0.f, 0.f};
            if (gm < M) f = *(const float4*)(A + (long)gm * K + k0 + ac);
            s16x4 h; h[0] = f2b(f.x); h[1] = f2b(f.y); h[2] = f2b(f.z); h[3] = f2b(f.w);
            *(s16x4*)&As[row][ac] = h;
        }
        #pragma unroll
        for (int p = 0; p < 2; ++p) {
            int n = br + p * 64, gn = n0 + n;
            s16x8 h = (s16x8){0,0,0,0,0,0,0,0};
            if (gn < N) {
                float4 f0 = *(const float4*)(Bv + (long)gn * K + k0 + bc);
                float4 f1 = *(const float4*)(Bv + (long)gn * K + k0 + bc + 4);
                h[0]=f2b(f0.x); h[1]=f2b(f0.y); h[2]=f2b(f0.z); h[3]=f2b(f0.w);
                h[4]=f2b(f1.x); h[5]=f2b(f1.y); h[6]=f2b(f1.z); h[7]=f2b(f1.w);
            }
            *(s16x8*)&Bs[n][bc] = h;
        }
        __syncthreads();
        s16x8 af[4], bf[4];
        #pragma unroll
        for (int i = 0; i < 4; ++i) af[i] = *(const s16x8*)&As[wr*64 + i*16 + lr][kg*8];
        #pragma unroll
        for (int j = 0; j < 4; ++j) bf[j] = *(const s16x8*)&Bs[wc*64 + j*16 + lr][kg*8];
        #pragma unroll
        for (int i = 0; i < 4; ++i)
            #pragma unroll
            for (int j = 0; j < 4; ++j)
                acc[i][j] = __builtin_amdgcn_mfma_f32_16x16x32_bf16(af[i], bf[j], acc[i][j], 0, 0, 0);
        __syncthreads();
    }
    #pragma unroll
    for (int j = 0; j < 4; ++j) {
        int gcol = n0 + wc * 64 + j * 16 + lr;
        if (gcol >= N) continue;
        float bv = bias ? bias[gcol] : 0.f;
        #pragma unroll
        for (int i = 0; i < 4; ++i) {
            int grow0 = m0 + wr * 64 + i * 16 + kg * 4;
            #pragma unroll
            for (int qq = 0; qq < 4; ++qq) {
                int gr = grow0 + qq;
                if (gr >= M) continue;
                Cm[(long)gr * ldc + gcol] = acc[i][j][qq] + bv;
            }
        }
    }
}

// ---------------------------------------------------------------------------
// MFMA flash attention (bf16 in / bf16 out). grid (16, H, B), 4 waves.
// qkvb: [M,3072] bf16 (q|k|v, head h at col h*64). outb: [M,C] bf16.
// scale = 1/sqrt(C) = 1/32 (reference quirk).
// ---------------------------------------------------------------------------
template<bool CAUSAL>
__global__ __launch_bounds__(256) void fattn_kernel(
    const __hip_bfloat16* __restrict__ qkvb, __hip_bfloat16* __restrict__ outb)
{
    __shared__ short Ks[64][72];
    __shared__ short Vt[64][72];
    __shared__ short Ps[4][16][72];

    const int q0 = blockIdx.x * 64;
    const int h = blockIdx.y, b = blockIdx.z;
    const int tid = threadIdx.x;
    const int lane = tid & 63, w = tid >> 6;
    const int lr = lane & 15, lg = lane >> 4;

    const float scale = 1.0f / 32.0f;
    const long base = (long)b * TT * 3072;
    const __hip_bfloat16* Kg = qkvb + base + 1024 + h * 64;
    const __hip_bfloat16* Vg = qkvb + base + 2048 + h * 64;

    s16x8 qf[2];
    {
        int qr = q0 + w * 16 + lr;
        #pragma unroll
        for (int kc = 0; kc < 2; ++kc) {
            s16x8 hv = (s16x8){0,0,0,0,0,0,0,0};
            if (qr < TT)
                hv = *(const s16x8*)(qkvb + base + (long)qr * 3072 + h * 64 + kc * 32 + lg * 8);
            qf[kc] = hv;
        }
    }

    f32x4 acc[4];
    #pragma unroll
    for (int jd = 0; jd < 4; ++jd) acc[jd] = (f32x4){0.f, 0.f, 0.f, 0.f};
    float mrun[4] = {-3.0e38f, -3.0e38f, -3.0e38f, -3.0e38f};
    float lrun[4] = {0.f, 0.f, 0.f, 0.f};

    const int send = CAUSAL ? min(TT, q0 + 64) : TT;
    const int sr2 = (tid >> 3) * 2;        // rows sr2, sr2+1
    const int dcc = (tid & 7) * 8;         // col chunk

    for (int s0 = 0; s0 < send; s0 += 64) {
        __syncthreads();
        {
            s16x8 v8[2];
            #pragma unroll
            for (int rr = 0; rr < 2; ++rr) {
                int sg = s0 + sr2 + rr;
                if (sg < TT) {
                    *(s16x8*)&Ks[sr2 + rr][dcc] = *(const s16x8*)(Kg + (long)sg * 3072 + dcc);
                    v8[rr] = *(const s16x8*)(Vg + (long)sg * 3072 + dcc);
                } else {
                    *(s16x8*)&Ks[sr2 + rr][dcc] = (s16x8){0,0,0,0,0,0,0,0};
                    v8[rr] = (s16x8){0,0,0,0,0,0,0,0};
                }
            }
            #pragma unroll
            for (int e = 0; e < 8; ++e) {
                unsigned pack = (unsigned)(unsigned short)v8[0][e]
                              | ((unsigned)(unsigned short)v8[1][e] << 16);
                *(unsigned*)&Vt[dcc + e][sr2] = pack;
            }
        }
        __syncthreads();

        f32x4 sf[4];
        #pragma unroll
        for (int j = 0; j < 4; ++j) {
            f32x4 z = (f32x4){0.f, 0.f, 0.f, 0.f};
            #pragma unroll
            for (int kc = 0; kc < 2; ++kc) {
                s16x8 kf = *(const s16x8*)&Ks[j * 16 + lr][kc * 32 + lg * 8];
                z = __builtin_amdgcn_mfma_f32_16x16x32_bf16(qf[kc], kf, z, 0, 0, 0);
            }
            sf[j] = z;
        }

        float mloc[4] = {-3.0e38f, -3.0e38f, -3.0e38f, -3.0e38f};
        #pragma unroll
        for (int j = 0; j < 4; ++j) {
            int sg = s0 + j * 16 + lr;
            #pragma unroll
            for (int r = 0; r < 4; ++r) {
                float sc = sf[j][r] * scale;
                int qg = q0 + w * 16 + lg * 4 + r;
                if ((CAUSAL && sg > qg) || sg >= TT) sc = -3.0e38f;
                sf[j][r] = sc;
                mloc[r] = fmaxf(mloc[r], sc);
            }
        }
        #pragma unroll
        for (int r = 0; r < 4; ++r)
            #pragma unroll
            for (int off = 1; off < 16; off <<= 1)
                mloc[r] = fmaxf(mloc[r], __shfl_xor(mloc[r], off));

        float corr[4], psum[4];
        #pragma unroll
        for (int r = 0; r < 4; ++r) {
            float mn = fmaxf(mrun[r], mloc[r]);
            corr[r] = __expf(mrun[r] - mn);
            mrun[r] = mn;
            psum[r] = 0.f;
        }

        #pragma unroll
        for (int j = 0; j < 4; ++j) {
            #pragma unroll
            for (int r = 0; r < 4; ++r) {
                float p = __expf(sf[j][r] - mrun[r]);
                psum[r] += p;
                Ps[w][lg * 4 + r][j * 16 + lr] = f2b(p);
            }
        }
        #pragma unroll
        for (int r = 0; r < 4; ++r) {
            #pragma unroll
            for (int off = 1; off < 16; off <<= 1)
                psum[r] += __shfl_xor(psum[r], off);
            lrun[r] = lrun[r] * corr[r] + psum[r];
            #pragma unroll
            for (int jd = 0; jd < 4; ++jd) acc[jd][r] *= corr[r];
        }

        #pragma unroll
        for (int kc = 0; kc < 2; ++kc) {
            s16x8 pa = *(const s16x8*)&Ps[w][lr][kc * 32 + lg * 8];
            #pragma unroll
            for (int jd = 0; jd < 4; ++jd) {
                s16x8 bv = *(const s16x8*)&Vt[jd * 16 + lr][kc * 32 + lg * 8];
                acc[jd] = __builtin_amdgcn_mfma_f32_16x16x32_bf16(pa, bv, acc[jd], 0, 0, 0);
            }
        }
    }

    #pragma unroll
    for (int r = 0; r < 4; ++r) {
        int qg = q0 + w * 16 + lg * 4 + r;
        if (qg >= TT) continue;
        float inv = 1.0f / lrun[r];
        #pragma unroll
        for (int jd = 0; jd < 4; ++jd)
            outb[((long)b * TT + qg) * CC + h * 64 + jd * 16 + lr] =
                __float2bfloat16(acc[jd][r] * inv);
    }
}

// ---------------------------------------------------------------------------
// LayerNorm (+optional residual), fp32 out + optional bf16 mirror.
// ---------------------------------------------------------------------------
__global__ __launch_bounds__(256) void ln_kernel(
    const float* __restrict__ in, const float* __restrict__ res,
    const float* __restrict__ g, const float* __restrict__ b,
    float* __restrict__ out, __hip_bfloat16* __restrict__ outb)
{
    const int r = blockIdx.x, tid = threadIdx.x;
    __shared__ float sm[4];

    float4 xv = *(const float4*)(in + (long)r * CC + tid * 4);
    float s = xv.x + xv.y + xv.z + xv.w;
    #pragma unroll
    for (int o = 32; o > 0; o >>= 1) s += __shfl_xor(s, o);
    if ((tid & 63) == 0) sm[tid >> 6] = s;
    __syncthreads();
    const float mean = (sm[0] + sm[1] + sm[2] + sm[3]) * (1.0f / CC);
    __syncthreads();

    float4 d; d.x = xv.x - mean; d.y = xv.y - mean; d.z = xv.z - mean; d.w = xv.w - mean;
    float s2 = d.x * d.x + d.y * d.y + d.z * d.z + d.w * d.w;
    #pragma unroll
    for (int o = 32; o > 0; o >>= 1) s2 += __shfl_xor(s2, o);
    if ((tid & 63) == 0) sm[tid >> 6] = s2;
    __syncthreads();
    const float rstd = rsqrtf((sm[0] + sm[1] + sm[2] + sm[3]) * (1.0f / CC) + 1e-5f);

    float4 gv = *(const float4*)(g + tid * 4);
    float4 bv = *(const float4*)(b + tid * 4);
    float4 o;
    o.x = gv.x * d.x * rstd + bv.x; o.y = gv.y * d.y * rstd + bv.y;
    o.z = gv.z * d.z * rstd + bv.z; o.w = gv.w * d.w * rstd + bv.w;
    if (res) {
        float4 rv = *(const float4*)(res + (long)r * CC + tid * 4);
        o.x += rv.x; o.y += rv.y; o.z += rv.z; o.w += rv.w;
    }
    *(float4*)(out + (long)r * CC + tid * 4) = o;
    if (outb) {
        s16x4 h; h[0] = f2b(o.x); h[1] = f2b(o.y); h[2] = f2b(o.z); h[3] = f2b(o.w);
        *(s16x4*)(outb + (long)r * CC + tid * 4) = h;
    }
}

// ---------------------------------------------------------------------------
extern "C" void kernel_launch(void* const* d_in, const int* in_sizes, int n_in,
                              void* d_out, int out_size, void* d_ws, size_t ws_size,
                              hipStream_t stream)
{
    const int*   x      = (const int*)  d_in[0];
    const int*   y      = (const int*)  d_in[1];
    const float* wte    = (const float*)d_in[2];
    const float* wpe_x  = (const float*)d_in[3];
    const float* wpe_y  = (const float*)d_in[4];
    const float* eWq    = (const float*)d_in[5];
    const float* eWk    = (const float*)d_in[6];
    const float* eWv    = (const float*)d_in[7];
    const float* epw    = (const float*)d_in[8];
    const float* epb    = (const float*)d_in[9];
    const float* eln1g  = (const float*)d_in[10];
    const float* eln1b  = (const float*)d_in[11];
    const float* eln2g  = (const float*)d_in[12];
    const float* eln2b  = (const float*)d_in[13];
    const float* ew1    = (const float*)d_in[14];
    const float* eb1    = (const float*)d_in[15];
    const float* ew2    = (const float*)d_in[16];
    const float* eb2    = (const float*)d_in[17];
    const float* dsWq   = (const float*)d_in[18];
    const float* dsWk   = (const float*)d_in[19];
    const float* dsWv   = (const float*)d_in[20];
    const float* dspw   = (const float*)d_in[21];
    const float* dspb   = (const float*)d_in[22];
    const float* dcWq   = (const float*)d_in[23];
    const float* dcWk   = (const float*)d_in[24];
    const float* dcWv   = (const float*)d_in[25];
    const float* dcpw   = (const float*)d_in[26];
    const float* dcpb   = (const float*)d_in[27];
    const float* dln1g  = (const float*)d_in[28];
    const float* dln1b  = (const float*)d_in[29];
    const float* dln2g  = (const float*)d_in[30];
    const float* dln2b  = (const float*)d_in[31];
    const float* dln3g  = (const float*)d_in[32];
    const float* dln3b  = (const float*)d_in[33];
    const float* dw1    = (const float*)d_in[34];
    const float* db1    = (const float*)d_in[35];
    const float* dw2    = (const float*)d_in[36];
    const float* db2    = (const float*)d_in[37];
    const float* lnfg   = (const float*)d_in[38];
    const float* lnfb   = (const float*)d_in[39];
    const float* lm_b   = (const float*)d_in[40];

    float* out = (float*)d_out;

    // ---- workspace carve-up ----
    const size_t MCp = (size_t)MP * CC;
    float* enc = (float*)d_ws;
    float* dec = enc + MCp;
    float* t0  = dec + MCp;
    __hip_bfloat16* encb = (__hip_bfloat16*)(t0 + MCp);
    __hip_bfloat16* decb = encb + MCp;
    __hip_bfloat16* t0b  = decb + MCp;
    __hip_bfloat16* a0b  = t0b + MCp;
    __hip_bfloat16* qkvb = a0b + MCp;                    // [MP][3072]
    __hip_bfloat16* ffb  = qkvb + (size_t)MP * 3072;     // [MP][FFD]
    __hip_bfloat16* wteb = ffb + (size_t)MP * FFD;       // [VP][C]
    // big-mode weight blocks
    __hip_bfloat16* eQKVw = wteb + (size_t)VP * CC;      // [L][3072][C]
    __hip_bfloat16* ePWw  = eQKVw + (size_t)LL * 3072 * CC;
    __hip_bfloat16* eW1w  = ePWw  + (size_t)LL * CC * CC;     // [L][FFD][C]
    __hip_bfloat16* eW2w  = eW1w  + (size_t)LL * FFD * CC;    // [L][C][FFD]
    __hip_bfloat16* sQKVw = eW2w  + (size_t)LL * CC * FFD;
    __hip_bfloat16* sPWw  = sQKVw + (size_t)LL * 3072 * CC;
    __hip_bfloat16* cQKVw = sPWw  + (size_t)LL * CC * CC;
    __hip_bfloat16* cPWw  = cQKVw + (size_t)LL * 3072 * CC;
    __hip_bfloat16* dW1w  = cPWw  + (size_t)LL * CC * CC;
    __hip_bfloat16* dW2w  = dW1w  + (size_t)LL * FFD * CC;
    __hip_bfloat16* bigEnd = dW2w + (size_t)LL * CC * FFD;
    // small-mode: per-use conversion buffer where eQKVw starts
    __hip_bfloat16* wb = eQKVw;
    const size_t needBig   = (size_t)((char*)bigEnd - (char*)d_ws);
    const size_t needSmall = (size_t)((char*)(wb + (size_t)FFD * CC) - (char*)d_ws);
    const size_t needWteb  = (size_t)((char*)eQKVw - (char*)d_ws);
    const bool big     = (ws_size >= needBig);
    const bool useWteb = (ws_size >= needWteb) &&
                         (big || ws_size >= needSmall);

    const int GM = MP / 128;           // 16 m-tiles
    const int QT = (TT + 63) / 64;     // 16 q-tiles
    const dim3 tblk(32, 8);

    auto gemm = [&](const __hip_bfloat16* A, const __hip_bfloat16* B,
                    const float* bias, float* Cm, __hip_bfloat16* Cb,
                    int N_, int K_, int ldc, int wmode, bool relu) {
        int nwg = GM * ((N_ + 127) / 128);
        if (wmode == 0) {
            if (relu) mgemm2_kernel<0, true ><<<nwg, 256, 0, stream>>>(A, B, bias, Cm, Cb, MM, N_, K_, ldc, GM);
            else      mgemm2_kernel<0, false><<<nwg, 256, 0, stream>>>(A, B, bias, Cm, Cb, MM, N_, K_, ldc, GM);
        } else {
            if (relu) mgemm2_kernel<2, true ><<<nwg, 256, 0, stream>>>(A, B, bias, Cm, Cb, MM, N_, K_, ldc, GM);
            else      mgemm2_kernel<2, false><<<nwg, 256, 0, stream>>>(A, B, bias, Cm, Cb, MM, N_, K_, ldc, GM);
        }
    };

    if (useWteb) {
        long n = (long)VV * CC;
        cvtb_kernel<<<(int)((n / 8 + 255) / 256), 256, 0, stream>>>(wte, wteb, n);
    }

    if (big) {
        // ---- all weight conversions up-front ----
        const long sWH = (long)CC * HSZ;            // per-(l,h) input stride
        const long oA = (long)3072 * CC;            // per-layer qkv out stride
        const long oB = (long)HSZ * CC;             // per-head out stride
        dim3 gq(HSZ / 32, CC / 32, LL * HH);
        tcvt_kernel<<<gq, tblk, 0, stream>>>(eWq, eQKVw,             CC, HSZ, sWH, oA, oB, HH);
        tcvt_kernel<<<gq, tblk, 0, stream>>>(eWk, eQKVw + CC * CC,   CC, HSZ, sWH, oA, oB, HH);
        tcvt_kernel<<<gq, tblk, 0, stream>>>(eWv, eQKVw + 2*CC*CC,   CC, HSZ, sWH, oA, oB, HH);
        tcvt_kernel<<<gq, tblk, 0, stream>>>(dsWq, sQKVw,            CC, HSZ, sWH, oA, oB, HH);
        tcvt_kernel<<<gq, tblk, 0, stream>>>(dsWk, sQKVw + CC * CC,  CC, HSZ, sWH, oA, oB, HH);
        tcvt_kernel<<<gq, tblk, 0, stream>>>(dsWv, sQKVw + 2*CC*CC,  CC, HSZ, sWH, oA, oB, HH);
        tcvt_kernel<<<gq, tblk, 0, stream>>>(dcWq, cQKVw,            CC, HSZ, sWH, oA, oB, HH);
        tcvt_kernel<<<gq, tblk, 0, stream>>>(dcWk, cQKVw + CC * CC,  CC, HSZ, sWH, oA, oB, HH);
        tcvt_kernel<<<gq, tblk, 0, stream>>>(dcWv, cQKVw + 2*CC*CC,  CC, HSZ, sWH, oA, oB, HH);
        dim3 gp(CC / 32, CC / 32, LL);
        tcvt_kernel<<<gp, tblk, 0, stream>>>(epw,  ePWw, CC, CC, (long)CC*CC, (long)CC*CC, 0, 1);
        tcvt_kernel<<<gp, tblk, 0, stream>>>(dspw, sPWw, CC, CC, (long)CC*CC, (long)CC*CC, 0, 1);
        tcvt_kernel<<<gp, tblk, 0, stream>>>(dcpw, cPWw, CC, CC, (long)CC*CC, (long)CC*CC, 0, 1);
        dim3 g1(FFD / 32, CC / 32, LL);
        tcvt_kernel<<<g1, tblk, 0, stream>>>(ew1, eW1w, CC, FFD, (long)CC*FFD, (long)FFD*CC, 0, 1);
        tcvt_kernel<<<g1, tblk, 0, stream>>>(dw1, dW1w, CC, FFD, (long)CC*FFD, (long)FFD*CC, 0, 1);
        dim3 g2(CC / 32, FFD / 32, LL);
        tcvt_kernel<<<g2, tblk, 0, stream>>>(ew2, eW2w, FFD, CC, (long)FFD*CC, (long)CC*FFD, 0, 1);
        tcvt_kernel<<<g2, tblk, 0, stream>>>(dw2, dW2w, FFD, CC, (long)FFD*CC, (long)CC*FFD, 0, 1);
    }

    // small-mode per-use converters
    auto cvt_qkv = [&](const float* Wq, const float* Wk, const float* Wv) {
        dim3 g(HSZ / 32, CC / 32, HH);
        tcvt_kernel<<<g, tblk, 0, stream>>>(Wq, wb,             CC, HSZ, (long)CC*HSZ, (long)HSZ*CC, 0, 1);
        tcvt_kernel<<<g, tblk, 0, stream>>>(Wk, wb + CC*CC,     CC, HSZ, (long)CC*HSZ, (long)HSZ*CC, 0, 1);
        tcvt_kernel<<<g, tblk, 0, stream>>>(Wv, wb + 2*CC*CC,   CC, HSZ, (long)CC*HSZ, (long)HSZ*CC, 0, 1);
    };
    auto cvt_nt = [&](const float* W, int R, int S) {
        dim3 g(S / 32, R / 32, 1);
        tcvt_kernel<<<g, tblk, 0, stream>>>(W, wb, R, S, 0, 0, 0, 1);
    };

    // ---- encoder ----
    embed_kernel<<<MM, 256, 0, stream>>>(x, wte, wpe_x, enc, encb);
    for (int i = 0; i < LL; ++i) {
        const long cOff = (long)i * CC;
        const __hip_bfloat16 *Wqkv, *Wp, *W1, *W2;
        if (big) {
            Wqkv = eQKVw + (size_t)i * 3072 * CC;
            Wp   = ePWw  + (size_t)i * CC * CC;
            W1   = eW1w  + (size_t)i * FFD * CC;
            W2   = eW2w  + (size_t)i * CC * FFD;
        }
        if (!big) cvt_qkv(eWq + (long)i*HH*CC*HSZ, eWk + (long)i*HH*CC*HSZ, eWv + (long)i*HH*CC*HSZ), Wqkv = wb;
        gemm(encb, Wqkv, nullptr, nullptr, qkvb, 3072, CC, 3072, 2, false);
        fattn_kernel<false><<<dim3(QT, HH, BB), 256, 0, stream>>>(qkvb, a0b);
        if (!big) cvt_nt(epw + (long)i*CC*CC, CC, CC), Wp = wb;
        gemm(a0b, Wp, epb + cOff, t0, nullptr, CC, CC, CC, 0, false);
        ln_kernel<<<MM, 256, 0, stream>>>(t0, enc, eln1g + cOff, eln1b + cOff, enc, encb);
        if (!big) cvt_nt(ew1 + (long)i*CC*FFD, CC, FFD), W1 = wb;
        gemm(encb, W1, eb1 + (long)i*FFD, nullptr, ffb, FFD, CC, FFD, 2, true);
        if (!big) cvt_nt(ew2 + (long)i*FFD*CC, FFD, CC), W2 = wb;
        gemm(ffb, W2, eb2 + cOff, t0, nullptr, CC, FFD, CC, 0, false);
        ln_kernel<<<MM, 256, 0, stream>>>(t0, enc, eln2g + cOff, eln2b + cOff, enc, encb);
    }

    // ---- decoder ----
    embed_kernel<<<MM, 256, 0, stream>>>(y, wte, wpe_y, dec, decb);
    for (int i = 0; i < LL; ++i) {
        const long cOff = (long)i * CC;
        const __hip_bfloat16 *Ws, *Wsp, *Wc, *Wcp, *W1, *W2;
        if (big) {
            Ws  = sQKVw + (size_t)i * 3072 * CC;
            Wsp = sPWw  + (size_t)i * CC * CC;
            Wc  = cQKVw + (size_t)i * 3072 * CC;
            Wcp = cPWw  + (size_t)i * CC * CC;
            W1  = dW1w  + (size_t)i * FFD * CC;
            W2  = dW2w  + (size_t)i * CC * FFD;
        }
        // masked self-attn
        if (!big) cvt_qkv(dsWq + (long)i*HH*CC*HSZ, dsWk + (long)i*HH*CC*HSZ, dsWv + (long)i*HH*CC*HSZ), Ws = wb;
        gemm(decb, Ws, nullptr, nullptr, qkvb, 3072, CC, 3072, 2, false);
        fattn_kernel<true><<<dim3(QT, HH, BB), 256, 0, stream>>>(qkvb, a0b);
        if (!big) cvt_nt(dspw + (long)i*CC*CC, CC, CC), Wsp = wb;
        gemm(a0b, Wsp, dspb + cOff, t0, nullptr, CC, CC, CC, 0, false);
        ln_kernel<<<MM, 256, 0, stream>>>(t0, dec, dln1g + cOff, dln1b + cOff, dec, decb);
        // cross-attn: q from dec, k/v from enc
        if (!big) cvt_qkv(dcWq + (long)i*HH*CC*HSZ, dcWk + (long)i*HH*CC*HSZ, dcWv + (long)i*HH*CC*HSZ), Wc = wb;
        gemm(decb, Wc, nullptr, nullptr, qkvb, CC, CC, 3072, 2, false);
        gemm(encb, Wc + (size_t)CC * CC, nullptr, nullptr, qkvb + CC, 2048, CC, 3072, 2, false);
        fattn_kernel<false><<<dim3(QT, HH, BB), 256, 0, stream>>>(qkvb, a0b);
        if (!big) cvt_nt(dcpw + (long)i*CC*CC, CC, CC), Wcp = wb;
        gemm(a0b, Wcp, dcpb + cOff, t0, nullptr, CC, CC, CC, 0, false);
        ln_kernel<<<MM, 256, 0, stream>>>(t0, dec, dln2g + cOff, dln2b + cOff, dec, decb);
        // ffn
        if (!big) cvt_nt(dw1 + (long)i*CC*FFD, CC, FFD), W1 = wb;
        gemm(decb, W1, db1 + (long)i*FFD, nullptr, ffb, FFD, CC, FFD, 2, true);
        if (!big) cvt_nt(dw2 + (long)i*FFD*CC, FFD, CC), W2 = wb;
        gemm(ffb, W2, db2 + cOff, t0, nullptr, CC, FFD, CC, 0, false);
        ln_kernel<<<MM, 256, 0, stream>>>(t0, dec, dln3g + cOff, dln3b + cOff, dec, decb);
    }

    // ---- final LN + logits ----
    ln_kernel<<<MM, 256, 0, stream>>>(dec, nullptr, lnfg, lnfb, t0, t0b);
    if (useWteb) {
        gemm(t0b, wteb, lm_b, out, nullptr, VV, CC, VV, 0, false);
    } else {
        dim3 grid((VV + 127) / 128, GM);
        mgemm_f32b_kernel<<<grid, 256, 0, stream>>>(t0, wte, lm_b, out, MM, VV, CC, VV);
    }
}

// Round 7
// 3911.293 us; speedup vs baseline: 14.8459x; 1.1454x over previous
//
#include <hip/hip_runtime.h>
#include <hip/hip_bf16.h>

#define BB 2
#define TT 1023
#define CC 1024
#define HH 16
#define HSZ 64
#define LL 6
#define FFD 4096
#define VV 50258
#define MM (BB*TT)   // 2046
#define MP 2048      // padded row count
#define VP 50304     // padded vocab (multiple of 128)

typedef __attribute__((ext_vector_type(4))) float  f32x4;
typedef __attribute__((ext_vector_type(8))) short  s16x8;
typedef __attribute__((ext_vector_type(4))) short  s16x4;

#define SCHED0   __builtin_amdgcn_sched_barrier(0)
#define SBAR     __builtin_amdgcn_s_barrier()
#define VMCNT4   asm volatile("s_waitcnt vmcnt(4)" ::: "memory")
#define VMCNT0   asm volatile("s_waitcnt vmcnt(0)" ::: "memory")
#define LGKMCNT0 asm volatile("s_waitcnt lgkmcnt(0)" ::: "memory")

__device__ __forceinline__ short f2b(float x) {
    __hip_bfloat16 h = __float2bfloat16(x);
    short s;
    __builtin_memcpy(&s, &h, 2);
    return s;
}

__device__ __forceinline__ void gld16(const void* g, void* l) {
    __builtin_amdgcn_global_load_lds(
        (__attribute__((address_space(1))) const void*)g,
        (__attribute__((address_space(3))) void*)l, 16, 0, 0);
}

// ---------------------------------------------------------------------------
// Embedding: fp32 + bf16 mirror
// ---------------------------------------------------------------------------
__global__ __launch_bounds__(256) void embed_kernel(
    const int* __restrict__ ids, const float* __restrict__ wte,
    const float* __restrict__ wpe, float* __restrict__ out,
    __hip_bfloat16* __restrict__ outb)
{
    int r = blockIdx.x;
    int t = r % TT;
    long id = ids[r];
    int c = threadIdx.x * 4;
    float4 a = *(const float4*)(wte + id * (long)CC + c);
    float4 p = *(const float4*)(wpe + (long)t * CC + c);
    float4 o; o.x = a.x + p.x; o.y = a.y + p.y; o.z = a.z + p.z; o.w = a.w + p.w;
    *(float4*)(out + (long)r * CC + c) = o;
    s16x4 h; h[0] = f2b(o.x); h[1] = f2b(o.y); h[2] = f2b(o.z); h[3] = f2b(o.w);
    *(s16x4*)(outb + (long)r * CC + c) = h;
}

// ---------------------------------------------------------------------------
// Elementwise fp32 -> bf16
// ---------------------------------------------------------------------------
__global__ __launch_bounds__(256) void cvtb_kernel(
    const float* __restrict__ in, __hip_bfloat16* __restrict__ out, long n)
{
    long i = ((long)blockIdx.x * 256 + threadIdx.x) * 8;
    if (i >= n) return;
    float4 f0 = *(const float4*)(in + i);
    float4 f1 = *(const float4*)(in + i + 4);
    s16x8 h;
    h[0]=f2b(f0.x); h[1]=f2b(f0.y); h[2]=f2b(f0.z); h[3]=f2b(f0.w);
    h[4]=f2b(f1.x); h[5]=f2b(f1.y); h[6]=f2b(f1.z); h[7]=f2b(f1.w);
    *(s16x8*)(out + i) = h;
}

// ---------------------------------------------------------------------------
// Transpose + fp32->bf16: in [R][S] fp32 -> out [S][R] bf16, batched over z.
// out offset = (z/zdiv)*outZa + (z%zdiv)*outZb ; in offset = z*inZ.
// ---------------------------------------------------------------------------
__global__ __launch_bounds__(256) void tcvt_kernel(
    const float* __restrict__ in, __hip_bfloat16* __restrict__ out,
    int R, int S, long inZ, long outZa, long outZb, int zdiv)
{
    int z = blockIdx.z;
    in  += (long)z * inZ;
    out += (long)(z / zdiv) * outZa + (long)(z % zdiv) * outZb;
    __shared__ float tile[32][33];
    int s0 = blockIdx.x * 32, r0 = blockIdx.y * 32;
    int tx = threadIdx.x, ty = threadIdx.y;
    #pragma unroll
    for (int i = 0; i < 4; ++i)
        tile[ty + i * 8][tx] = in[(long)(r0 + ty + i * 8) * S + s0 + tx];
    __syncthreads();
    #pragma unroll
    for (int i = 0; i < 4; ++i)
        out[(long)(s0 + ty + i * 8) * R + r0 + tx] =
            __float2bfloat16(tile[tx][ty + i * 8]);
}

// ---------------------------------------------------------------------------
// bf16 MFMA GEMM, T3+T4 pipelined: BK=32 double-buffered LDS (32 KB total),
// counted s_waitcnt vmcnt(4) (never 0 in loop) + raw s_barrier so prefetch
// global_load_lds stay in flight across barriers. T5 setprio around MFMA.
// C = act(A @ B^T + bias). A [pad(M,128)][K] bf16, B [pad(N,128)][K] bf16,
// K % 32 == 0. 128x128 tile, 4 waves (2x2).
// WMODE: 0 = fp32 out (float2-coalesced), 2 = bf16 out (b128-coalesced).
// ---------------------------------------------------------------------------
template<int WMODE, bool RELU>
__global__ __launch_bounds__(256) void mgemm2_kernel(
    const __hip_bfloat16* __restrict__ A, const __hip_bfloat16* __restrict__ B,
    const float* __restrict__ bias, float* __restrict__ Cm,
    __hip_bfloat16* __restrict__ Cb,
    int M, int N, int K, int ldc, int GM)
{
    __shared__ short LDS[2][2][4096];   // [dbuf][A/B][128*32] = 32 KB

    // bijective XCD swizzle + m-fastest decode
    const int nwg = gridDim.x;
    const int bid = blockIdx.x;
    const int q = nwg >> 3, r = nwg & 7;
    const int xcd = bid & 7, lid = bid >> 3;
    const int swz = (xcd < r) ? xcd * (q + 1) + lid
                              : r * (q + 1) + (xcd - r) * q + lid;
    const int m0 = (swz % GM) * 128;
    const int n0 = (swz / GM) * 128;

    const int tid  = threadIdx.x;
    const int lane = tid & 63, w = tid >> 6;
    const int wr = w >> 1, wc = w & 1;
    const int lr = lane & 15, kg = lane >> 4;

    const __hip_bfloat16* Abase = A + (long)m0 * K;
    const __hip_bfloat16* Bbase = B + (long)n0 * K;

    f32x4 acc[4][4];
    #pragma unroll
    for (int i = 0; i < 4; ++i)
        #pragma unroll
        for (int j = 0; j < 4; ++j)
            acc[i][j] = (f32x4){0.f, 0.f, 0.f, 0.f};

    // staging geometry: tile 128x32 bf16 = 8 chunks of 512 elems (1 KB).
    // chunk cc covers rows cc*16..cc*16+15; thread handles chunks {w, 4+w}.
    // lane's elem within chunk: row cc*16 + (lane>>2), col (lane&3)*8 —
    // linear LDS offset cc*512 + lane*8 (matches gld16 base+lane*16B).
    const int srow = lane >> 2;
    const int scol = (lane & 3) * 8;

    auto stage = [&](int db, long kofs) {
        short* Ad = &LDS[db][0][0];
        short* Bd = &LDS[db][1][0];
        #pragma unroll
        for (int p = 0; p < 2; ++p) {
            int cc = p * 4 + w;
            long ro = (long)(cc * 16 + srow) * K + kofs + scol;
            gld16(Abase + ro, Ad + cc * 512);
            gld16(Bbase + ro, Bd + cc * 512);
        }
    };
    auto compute = [&](int db) {
        const short* Ar = &LDS[db][0][0];
        const short* Br = &LDS[db][1][0];
        s16x8 af[4], bf[4];
        #pragma unroll
        for (int i = 0; i < 4; ++i)
            af[i] = *(const s16x8*)&Ar[(wr * 64 + i * 16 + lr) * 32 + kg * 8];
        #pragma unroll
        for (int j = 0; j < 4; ++j)
            bf[j] = *(const s16x8*)&Br[(wc * 64 + j * 16 + lr) * 32 + kg * 8];
        __builtin_amdgcn_s_setprio(1);
        #pragma unroll
        for (int i = 0; i < 4; ++i)
            #pragma unroll
            for (int j = 0; j < 4; ++j)
                acc[i][j] = __builtin_amdgcn_mfma_f32_16x16x32_bf16(
                    af[i], bf[j], acc[i][j], 0, 0, 0);
        __builtin_amdgcn_s_setprio(0);
    };

    const int nt = K >> 5;
    int cur = 0;
    stage(0, 0);
    for (int t = 0; t < nt - 1; ++t) {
        stage(cur ^ 1, (long)(t + 1) << 5);      // prefetch next K-step
        SCHED0; VMCNT4; SCHED0; SBAR; SCHED0;    // prev stage landed, all waves
        compute(cur);
        SCHED0; LGKMCNT0; SCHED0; SBAR; SCHED0;  // reads done before overwrite
        cur ^= 1;
    }
    SCHED0; VMCNT0; SCHED0; SBAR; SCHED0;
    compute(cur);
    SCHED0; LGKMCNT0; SCHED0; SBAR; SCHED0;      // LDS free for epilogue

    // ---- epilogue: stage C tile through LDS for coalesced stores ----
    if (WMODE == 0) {
        float* LF = (float*)&LDS[0][0][0];     // [128][64] fp32 = 32 KB
        #pragma unroll
        for (int h = 0; h < 2; ++h) {
            if (wc == h) {
                #pragma unroll
                for (int j = 0; j < 4; ++j) {
                    int gcol = n0 + h * 64 + j * 16 + lr;
                    float bv = (bias && gcol < N) ? bias[gcol] : 0.f;
                    #pragma unroll
                    for (int i = 0; i < 4; ++i) {
                        int row0 = wr * 64 + i * 16 + kg * 4;
                        #pragma unroll
                        for (int qq = 0; qq < 4; ++qq) {
                            float v = acc[i][j][qq] + bv;
                            if (RELU) v = fmaxf(v, 0.f);
                            LF[(row0 + qq) * 64 + j * 16 + lr] = v;
                        }
                    }
                }
            }
            __syncthreads();
            #pragma unroll
            for (int i = 0; i < 16; ++i) {
                int F = i * 256 + tid;               // float2 index
                int row = F >> 5, col = (F & 31) * 2;
                int gr = m0 + row, gc = n0 + h * 64 + col;
                if (gr < M && gc < N)
                    *(float2*)(Cm + (long)gr * ldc + gc) = *(const float2*)&LF[row * 64 + col];
            }
            __syncthreads();
        }
    } else {
        short* LS = (short*)&LDS[0][0][0];     // [128][128] bf16 = 32 KB
        #pragma unroll
        for (int j = 0; j < 4; ++j) {
            int gcol = n0 + wc * 64 + j * 16 + lr;
            float bv = (bias && gcol < N) ? bias[gcol] : 0.f;
            #pragma unroll
            for (int i = 0; i < 4; ++i) {
                int row0 = wr * 64 + i * 16 + kg * 4;
                #pragma unroll
                for (int qq = 0; qq < 4; ++qq) {
                    float v = acc[i][j][qq] + bv;
                    if (RELU) v = fmaxf(v, 0.f);
                    LS[(row0 + qq) * 128 + wc * 64 + j * 16 + lr] = f2b(v);
                }
            }
        }
        __syncthreads();
        #pragma unroll
        for (int i = 0; i < 8; ++i) {
            int F = i * 256 + tid;                   // s16x8 index
            int row = F >> 4, col = (F & 15) * 8;
            int gr = m0 + row, gc = n0 + col;
            if (gr < M && gc < N)
                *(s16x8*)((short*)Cb + (long)gr * ldc + gc) = *(const s16x8*)&LS[row * 128 + col];
        }
    }
}

// ---------------------------------------------------------------------------
// Fallback fp32-B GEMM (logits only, if ws too small for bf16 wte mirror).
// ---------------------------------------------------------------------------
__global__ __launch_bounds__(256) void mgemm_f32b_kernel(
    const float* __restrict__ A, const float* __restrict__ Bv,
    const float* __restrict__ bias, float* __restrict__ Cm,
    int M, int N, int K, int ldc)
{
    __shared__ short As[128][40];
    __shared__ short Bs[128][40];
    const int tid  = threadIdx.x;
    const int lane = tid & 63, w = tid >> 6;
    const int wr = w >> 1, wc = w & 1;
    const int lr = lane & 15, kg = lane >> 4;
    const int m0 = blockIdx.y * 128, n0 = blockIdx.x * 128;
    const int ar = tid >> 3, ac = (tid & 7) * 4;
    const int br = tid >> 2, bc = (tid & 3) * 8;

    f32x4 acc[4][4];
    #pragma unroll
    for (int i = 0; i < 4; ++i)
        #pragma unroll
        for (int j = 0; j < 4; ++j)
            acc[i][j] = (f32x4){0.f, 0.f, 0.f, 0.f};

    for (int k0 = 0; k0 < K; k0 += 32) {
        #pragma unroll
        for (int p = 0; p < 4; ++p) {
            int row = ar + p * 32, gm = m0 + row;
            float4 f = {0.f, 0.f, 0.f, 0.f};
            if (gm < M) f = *(const float4*)(A + (long)gm * K + k0 + ac);
            s16x4 h; h[0] = f2b(f.x); h[1] = f2b(f.y); h[2] = f2b(f.z); h[3] = f2b(f.w);
            *(s16x4*)&As[row][ac] = h;
        }
        #pragma unroll
        for (int p = 0; p < 2; ++p) {
            int n = br + p * 64, gn = n0 + n;
            s16x8 h = (s16x8){0,0,0,0,0,0,0,0};
            if (gn < N) {
                float4 f0 = *(const float4*)(Bv + (long)gn * K + k0 + bc);
                float4 f1 = *(const float4*)(Bv + (long)gn * K + k0 + bc + 4);
                h[0]=f2b(f0.x); h[1]=f2b(f0.y); h[2]=f2b(f0.z); h[3]=f2b(f0.w);
                h[4]=f2b(f1.x); h[5]=f2b(f1.y); h[6]=f2b(f1.z); h[7]=f2b(f1.w);
            }
            *(s16x8*)&Bs[n][bc] = h;
        }
        __syncthreads();
        s16x8 af[4], bf[4];
        #pragma unroll
        for (int i = 0; i < 4; ++i) af[i] = *(const s16x8*)&As[wr*64 + i*16 + lr][kg*8];
        #pragma unroll
        for (int j = 0; j < 4; ++j) bf[j] = *(const s16x8*)&Bs[wc*64 + j*16 + lr][kg*8];
        #pragma unroll
        for (int i = 0; i < 4; ++i)
            #pragma unroll
            for (int j = 0; j < 4; ++j)
                acc[i][j] = __builtin_amdgcn_mfma_f32_16x16x32_bf16(af[i], bf[j], acc[i][j], 0, 0, 0);
        __syncthreads();
    }
    #pragma unroll
    for (int j = 0; j < 4; ++j) {
        int gcol = n0 + wc * 64 + j * 16 + lr;
        if (gcol >= N) continue;
        float bv = bias ? bias[gcol] : 0.f;
        #pragma unroll
        for (int i = 0; i < 4; ++i) {
            int grow0 = m0 + wr * 64 + i * 16 + kg * 4;
            #pragma unroll
            for (int qq = 0; qq < 4; ++qq) {
                int gr = grow0 + qq;
                if (gr >= M) continue;
                Cm[(long)gr * ldc + gcol] = acc[i][j][qq] + bv;
            }
        }
    }
}

// ---------------------------------------------------------------------------
// MFMA flash attention (bf16 in / bf16 out). grid (16, H, B), 4 waves.
// T14 async-split: K/V prefetched to REGISTERS one tile ahead; raw s_barrier
// (not __syncthreads) so the reg-prefetch loads are NOT drained at barriers.
// qkvb: [M,3072] bf16 (q|k|v, head h at col h*64). outb: [M,C] bf16.
// scale = 1/sqrt(C) = 1/32 (reference quirk).
// ---------------------------------------------------------------------------
template<bool CAUSAL>
__global__ __launch_bounds__(256) void fattn_kernel(
    const __hip_bfloat16* __restrict__ qkvb, __hip_bfloat16* __restrict__ outb)
{
    __shared__ short Ks[64][72];
    __shared__ short Vt[64][72];
    __shared__ short Ps[4][16][72];

    const int q0 = blockIdx.x * 64;
    const int h = blockIdx.y, b = blockIdx.z;
    const int tid = threadIdx.x;
    const int lane = tid & 63, w = tid >> 6;
    const int lr = lane & 15, lg = lane >> 4;

    const float scale = 1.0f / 32.0f;
    const long base = (long)b * TT * 3072;
    const __hip_bfloat16* Kg = qkvb + base + 1024 + h * 64;
    const __hip_bfloat16* Vg = qkvb + base + 2048 + h * 64;

    s16x8 qf[2];
    {
        int qr = q0 + w * 16 + lr;
        #pragma unroll
        for (int kc = 0; kc < 2; ++kc) {
            s16x8 hv = (s16x8){0,0,0,0,0,0,0,0};
            if (qr < TT)
                hv = *(const s16x8*)(qkvb + base + (long)qr * 3072 + h * 64 + kc * 32 + lg * 8);
            qf[kc] = hv;
        }
    }

    f32x4 acc[4];
    #pragma unroll
    for (int jd = 0; jd < 4; ++jd) acc[jd] = (f32x4){0.f, 0.f, 0.f, 0.f};
    float mrun[4] = {-3.0e38f, -3.0e38f, -3.0e38f, -3.0e38f};
    float lrun[4] = {0.f, 0.f, 0.f, 0.f};

    const int send = CAUSAL ? min(TT, q0 + 64) : TT;
    const int nt = (send + 63) >> 6;
    const int sr2 = (tid >> 3) * 2;        // rows sr2, sr2+1
    const int dcc = (tid & 7) * 8;         // col chunk

    s16x8 kreg[2], vreg[2];
    auto loadkv = [&](int t) {
        int sbase = t * 64;
        #pragma unroll
        for (int rr = 0; rr < 2; ++rr) {
            int sg = sbase + sr2 + rr;
            if (sg < TT) {
                kreg[rr] = *(const s16x8*)(Kg + (long)sg * 3072 + dcc);
                vreg[rr] = *(const s16x8*)(Vg + (long)sg * 3072 + dcc);
            } else {
                kreg[rr] = (s16x8){0,0,0,0,0,0,0,0};
                vreg[rr] = (s16x8){0,0,0,0,0,0,0,0};
            }
        }
    };

    loadkv(0);
    for (int ti = 0; ti < nt; ++ti) {
        const int s0 = ti * 64;
        SCHED0; SBAR; SCHED0;          // prev tile's LDS reads done (all waves)
        // write prefetched regs -> LDS (compiler waits vmcnt only on these regs)
        *(s16x8*)&Ks[sr2][dcc]     = kreg[0];
        *(s16x8*)&Ks[sr2 + 1][dcc] = kreg[1];
        #pragma unroll
        for (int e = 0; e < 8; ++e) {
            unsigned pack = (unsigned)(unsigned short)vreg[0][e]
                          | ((unsigned)(unsigned short)vreg[1][e] << 16);
            *(unsigned*)&Vt[dcc + e][sr2] = pack;
        }
        if (ti + 1 < nt) loadkv(ti + 1);   // issue next tile's loads early
        SCHED0; LGKMCNT0; SCHED0; SBAR; SCHED0;   // LDS writes visible

        f32x4 sf[4];
        __builtin_amdgcn_s_setprio(1);
        #pragma unroll
        for (int j = 0; j < 4; ++j) {
            f32x4 z = (f32x4){0.f, 0.f, 0.f, 0.f};
            #pragma unroll
            for (int kc = 0; kc < 2; ++kc) {
                s16x8 kf = *(const s16x8*)&Ks[j * 16 + lr][kc * 32 + lg * 8];
                z = __builtin_amdgcn_mfma_f32_16x16x32_bf16(qf[kc], kf, z, 0, 0, 0);
            }
            sf[j] = z;
        }
        __builtin_amdgcn_s_setprio(0);

        float mloc[4] = {-3.0e38f, -3.0e38f, -3.0e38f, -3.0e38f};
        #pragma unroll
        for (int j = 0; j < 4; ++j) {
            int sg = s0 + j * 16 + lr;
            #pragma unroll
            for (int r = 0; r < 4; ++r) {
                float sc = sf[j][r] * scale;
                int qg = q0 + w * 16 + lg * 4 + r;
                if ((CAUSAL && sg > qg) || sg >= TT) sc = -3.0e38f;
                sf[j][r] = sc;
                mloc[r] = fmaxf(mloc[r], sc);
            }
        }
        #pragma unroll
        for (int r = 0; r < 4; ++r)
            #pragma unroll
            for (int off = 1; off < 16; off <<= 1)
                mloc[r] = fmaxf(mloc[r], __shfl_xor(mloc[r], off));

        float corr[4], psum[4];
        #pragma unroll
        for (int r = 0; r < 4; ++r) {
            float mn = fmaxf(mrun[r], mloc[r]);
            corr[r] = __expf(mrun[r] - mn);
            mrun[r] = mn;
            psum[r] = 0.f;
        }

        #pragma unroll
        for (int j = 0; j < 4; ++j) {
            #pragma unroll
            for (int r = 0; r < 4; ++r) {
                float p = __expf(sf[j][r] - mrun[r]);
                psum[r] += p;
                Ps[w][lg * 4 + r][j * 16 + lr] = f2b(p);
            }
        }
        #pragma unroll
        for (int r = 0; r < 4; ++r) {
            #pragma unroll
            for (int off = 1; off < 16; off <<= 1)
                psum[r] += __shfl_xor(psum[r], off);
            lrun[r] = lrun[r] * corr[r] + psum[r];
            #pragma unroll
            for (int jd = 0; jd < 4; ++jd) acc[jd][r] *= corr[r];
        }

        __builtin_amdgcn_s_setprio(1);
        #pragma unroll
        for (int kc = 0; kc < 2; ++kc) {
            s16x8 pa = *(const s16x8*)&Ps[w][lr][kc * 32 + lg * 8];
            #pragma unroll
            for (int jd = 0; jd < 4; ++jd) {
                s16x8 bv = *(const s16x8*)&Vt[jd * 16 + lr][kc * 32 + lg * 8];
                acc[jd] = __builtin_amdgcn_mfma_f32_16x16x32_bf16(pa, bv, acc[jd], 0, 0, 0);
            }
        }
        __builtin_amdgcn_s_setprio(0);
        SCHED0; LGKMCNT0; SCHED0;      // my LDS reads complete before next write
    }

    #pragma unroll
    for (int r = 0; r < 4; ++r) {
        int qg = q0 + w * 16 + lg * 4 + r;
        if (qg >= TT) continue;
        float inv = 1.0f / lrun[r];
        #pragma unroll
        for (int jd = 0; jd < 4; ++jd)
            outb[((long)b * TT + qg) * CC + h * 64 + jd * 16 + lr] =
                __float2bfloat16(acc[jd][r] * inv);
    }
}

// ---------------------------------------------------------------------------
// LayerNorm (+optional residual), fp32 out + optional bf16 mirror.
// ---------------------------------------------------------------------------
__global__ __launch_bounds__(256) void ln_kernel(
    const float* __restrict__ in, const float* __restrict__ res,
    const float* __restrict__ g, const float* __restrict__ b,
    float* __restrict__ out, __hip_bfloat16* __restrict__ outb)
{
    const int r = blockIdx.x, tid = threadIdx.x;
    __shared__ float sm[4];

    float4 xv = *(const float4*)(in + (long)r * CC + tid * 4);
    float s = xv.x + xv.y + xv.z + xv.w;
    #pragma unroll
    for (int o = 32; o > 0; o >>= 1) s += __shfl_xor(s, o);
    if ((tid & 63) == 0) sm[tid >> 6] = s;
    __syncthreads();
    const float mean = (sm[0] + sm[1] + sm[2] + sm[3]) * (1.0f / CC);
    __syncthreads();

    float4 d; d.x = xv.x - mean; d.y = xv.y - mean; d.z = xv.z - mean; d.w = xv.w - mean;
    float s2 = d.x * d.x + d.y * d.y + d.z * d.z + d.w * d.w;
    #pragma unroll
    for (int o = 32; o > 0; o >>= 1) s2 += __shfl_xor(s2, o);
    if ((tid & 63) == 0) sm[tid >> 6] = s2;
    __syncthreads();
    const float rstd = rsqrtf((sm[0] + sm[1] + sm[2] + sm[3]) * (1.0f / CC) + 1e-5f);

    float4 gv = *(const float4*)(g + tid * 4);
    float4 bv = *(const float4*)(b + tid * 4);
    float4 o;
    o.x = gv.x * d.x * rstd + bv.x; o.y = gv.y * d.y * rstd + bv.y;
    o.z = gv.z * d.z * rstd + bv.z; o.w = gv.w * d.w * rstd + bv.w;
    if (res) {
        float4 rv = *(const float4*)(res + (long)r * CC + tid * 4);
        o.x += rv.x; o.y += rv.y; o.z += rv.z; o.w += rv.w;
    }
    *(float4*)(out + (long)r * CC + tid * 4) = o;
    if (outb) {
        s16x4 h; h[0] = f2b(o.x); h[1] = f2b(o.y); h[2] = f2b(o.z); h[3] = f2b(o.w);
        *(s16x4*)(outb + (long)r * CC + tid * 4) = h;
    }
}

// ---------------------------------------------------------------------------
extern "C" void kernel_launch(void* const* d_in, const int* in_sizes, int n_in,
                              void* d_out, int out_size, void* d_ws, size_t ws_size,
                              hipStream_t stream)
{
    const int*   x      = (const int*)  d_in[0];
    const int*   y      = (const int*)  d_in[1];
    const float* wte    = (const float*)d_in[2];
    const float* wpe_x  = (const float*)d_in[3];
    const float* wpe_y  = (const float*)d_in[4];
    const float* eWq    = (const float*)d_in[5];
    const float* eWk    = (const float*)d_in[6];
    const float* eWv    = (const float*)d_in[7];
    const float* epw    = (const float*)d_in[8];
    const float* epb    = (const float*)d_in[9];
    const float* eln1g  = (const float*)d_in[10];
    const float* eln1b  = (const float*)d_in[11];
    const float* eln2g  = (const float*)d_in[12];
    const float* eln2b  = (const float*)d_in[13];
    const float* ew1    = (const float*)d_in[14];
    const float* eb1    = (const float*)d_in[15];
    const float* ew2    = (const float*)d_in[16];
    const float* eb2    = (const float*)d_in[17];
    const float* dsWq   = (const float*)d_in[18];
    const float* dsWk   = (const float*)d_in[19];
    const float* dsWv   = (const float*)d_in[20];
    const float* dspw   = (const float*)d_in[21];
    const float* dspb   = (const float*)d_in[22];
    const float* dcWq   = (const float*)d_in[23];
    const float* dcWk   = (const float*)d_in[24];
    const float* dcWv   = (const float*)d_in[25];
    const float* dcpw   = (const float*)d_in[26];
    const float* dcpb   = (const float*)d_in[27];
    const float* dln1g  = (const float*)d_in[28];
    const float* dln1b  = (const float*)d_in[29];
    const float* dln2g  = (const float*)d_in[30];
    const float* dln2b  = (const float*)d_in[31];
    const float* dln3g  = (const float*)d_in[32];
    const float* dln3b  = (const float*)d_in[33];
    const float* dw1    = (const float*)d_in[34];
    const float* db1    = (const float*)d_in[35];
    const float* dw2    = (const float*)d_in[36];
    const float* db2    = (const float*)d_in[37];
    const float* lnfg   = (const float*)d_in[38];
    const float* lnfb   = (const float*)d_in[39];
    const float* lm_b   = (const float*)d_in[40];

    float* out = (float*)d_out;

    // ---- workspace carve-up ----
    const size_t MCp = (size_t)MP * CC;
    float* enc = (float*)d_ws;
    float* dec = enc + MCp;
    float* t0  = dec + MCp;
    __hip_bfloat16* encb = (__hip_bfloat16*)(t0 + MCp);
    __hip_bfloat16* decb = encb + MCp;
    __hip_bfloat16* t0b  = decb + MCp;
    __hip_bfloat16* a0b  = t0b + MCp;
    __hip_bfloat16* qkvb = a0b + MCp;                    // [MP][3072]
    __hip_bfloat16* ffb  = qkvb + (size_t)MP * 3072;     // [MP][FFD]
    __hip_bfloat16* wteb = ffb + (size_t)MP * FFD;       // [VP][C]
    // big-mode weight blocks
    __hip_bfloat16* eQKVw = wteb + (size_t)VP * CC;      // [L][3072][C]
    __hip_bfloat16* ePWw  = eQKVw + (size_t)LL * 3072 * CC;
    __hip_bfloat16* eW1w  = ePWw  + (size_t)LL * CC * CC;     // [L][FFD][C]
    __hip_bfloat16* eW2w  = eW1w  + (size_t)LL * FFD * CC;    // [L][C][FFD]
    __hip_bfloat16* sQKVw = eW2w  + (size_t)LL * CC * FFD;
    __hip_bfloat16* sPWw  = sQKVw + (size_t)LL * 3072 * CC;
    __hip_bfloat16* cQKVw = sPWw  + (size_t)LL * CC * CC;
    __hip_bfloat16* cPWw  = cQKVw + (size_t)LL * 3072 * CC;
    __hip_bfloat16* dW1w  = cPWw  + (size_t)LL * CC * CC;
    __hip_bfloat16* dW2w  = dW1w  + (size_t)LL * FFD * CC;
    __hip_bfloat16* bigEnd = dW2w + (size_t)LL * CC * FFD;
    // small-mode: per-use conversion buffer where eQKVw starts
    __hip_bfloat16* wb = eQKVw;
    const size_t needBig   = (size_t)((char*)bigEnd - (char*)d_ws);
    const size_t needSmall = (size_t)((char*)(wb + (size_t)FFD * CC) - (char*)d_ws);
    const size_t needWteb  = (size_t)((char*)eQKVw - (char*)d_ws);
    const bool big     = (ws_size >= needBig);
    const bool useWteb = (ws_size >= needWteb) &&
                         (big || ws_size >= needSmall);

    const int GM = MP / 128;           // 16 m-tiles
    const int QT = (TT + 63) / 64;     // 16 q-tiles
    const dim3 tblk(32, 8);

    auto gemm = [&](const __hip_bfloat16* A, const __hip_bfloat16* B,
                    const float* bias, float* Cm, __hip_bfloat16* Cb,
                    int N_, int K_, int ldc, int wmode, bool relu) {
        int nwg = GM * ((N_ + 127) / 128);
        if (wmode == 0) {
            if (relu) mgemm2_kernel<0, true ><<<nwg, 256, 0, stream>>>(A, B, bias, Cm, Cb, MM, N_, K_, ldc, GM);
            else      mgemm2_kernel<0, false><<<nwg, 256, 0, stream>>>(A, B, bias, Cm, Cb, MM, N_, K_, ldc, GM);
        } else {
            if (relu) mgemm2_kernel<2, true ><<<nwg, 256, 0, stream>>>(A, B, bias, Cm, Cb, MM, N_, K_, ldc, GM);
            else      mgemm2_kernel<2, false><<<nwg, 256, 0, stream>>>(A, B, bias, Cm, Cb, MM, N_, K_, ldc, GM);
        }
    };

    if (useWteb) {
        long n = (long)VV * CC;
        cvtb_kernel<<<(int)((n / 8 + 255) / 256), 256, 0, stream>>>(wte, wteb, n);
    }

    if (big) {
        // ---- all weight conversions up-front ----
        const long sWH = (long)CC * HSZ;            // per-(l,h) input stride
        const long oA = (long)3072 * CC;            // per-layer qkv out stride
        const long oB = (long)HSZ * CC;             // per-head out stride
        dim3 gq(HSZ / 32, CC / 32, LL * HH);
        tcvt_kernel<<<gq, tblk, 0, stream>>>(eWq, eQKVw,             CC, HSZ, sWH, oA, oB, HH);
        tcvt_kernel<<<gq, tblk, 0, stream>>>(eWk, eQKVw + CC * CC,   CC, HSZ, sWH, oA, oB, HH);
        tcvt_kernel<<<gq, tblk, 0, stream>>>(eWv, eQKVw + 2*CC*CC,   CC, HSZ, sWH, oA, oB, HH);
        tcvt_kernel<<<gq, tblk, 0, stream>>>(dsWq, sQKVw,            CC, HSZ, sWH, oA, oB, HH);
        tcvt_kernel<<<gq, tblk, 0, stream>>>(dsWk, sQKVw + CC * CC,  CC, HSZ, sWH, oA, oB, HH);
        tcvt_kernel<<<gq, tblk, 0, stream>>>(dsWv, sQKVw + 2*CC*CC,  CC, HSZ, sWH, oA, oB, HH);
        tcvt_kernel<<<gq, tblk, 0, stream>>>(dcWq, cQKVw,            CC, HSZ, sWH, oA, oB, HH);
        tcvt_kernel<<<gq, tblk, 0, stream>>>(dcWk, cQKVw + CC * CC,  CC, HSZ, sWH, oA, oB, HH);
        tcvt_kernel<<<gq, tblk, 0, stream>>>(dcWv, cQKVw + 2*CC*CC,  CC, HSZ, sWH, oA, oB, HH);
        dim3 gp(CC / 32, CC / 32, LL);
        tcvt_kernel<<<gp, tblk, 0, stream>>>(epw,  ePWw, CC, CC, (long)CC*CC, (long)CC*CC, 0, 1);
        tcvt_kernel<<<gp, tblk, 0, stream>>>(dspw, sPWw, CC, CC, (long)CC*CC, (long)CC*CC, 0, 1);
        tcvt_kernel<<<gp, tblk, 0, stream>>>(dcpw, cPWw, CC, CC, (long)CC*CC, (long)CC*CC, 0, 1);
        dim3 g1(FFD / 32, CC / 32, LL);
        tcvt_kernel<<<g1, tblk, 0, stream>>>(ew1, eW1w, CC, FFD, (long)CC*FFD, (long)FFD*CC, 0, 1);
        tcvt_kernel<<<g1, tblk, 0, stream>>>(dw1, dW1w, CC, FFD, (long)CC*FFD, (long)FFD*CC, 0, 1);
        dim3 g2(CC / 32, FFD / 32, LL);
        tcvt_kernel<<<g2, tblk, 0, stream>>>(ew2, eW2w, FFD, CC, (long)FFD*CC, (long)CC*FFD, 0, 1);
        tcvt_kernel<<<g2, tblk, 0, stream>>>(dw2, dW2w, FFD, CC, (long)FFD*CC, (long)CC*FFD, 0, 1);
    }

    // small-mode per-use converters
    auto cvt_qkv = [&](const float* Wq, const float* Wk, const float* Wv) {
        dim3 g(HSZ / 32, CC / 32, HH);
        tcvt_kernel<<<g, tblk, 0, stream>>>(Wq, wb,             CC, HSZ, (long)CC*HSZ, (long)HSZ*CC, 0, 1);
        tcvt_kernel<<<g, tblk, 0, stream>>>(Wk, wb + CC*CC,     CC, HSZ, (long)CC*HSZ, (long)HSZ*CC, 0, 1);
        tcvt_kernel<<<g, tblk, 0, stream>>>(Wv, wb + 2*CC*CC,   CC, HSZ, (long)CC*HSZ, (long)HSZ*CC, 0, 1);
    };
    auto cvt_nt = [&](const float* W, int R, int S) {
        dim3 g(S / 32, R / 32, 1);
        tcvt_kernel<<<g, tblk, 0, stream>>>(W, wb, R, S, 0, 0, 0, 1);
    };

    // ---- encoder ----
    embed_kernel<<<MM, 256, 0, stream>>>(x, wte, wpe_x, enc, encb);
    for (int i = 0; i < LL; ++i) {
        const long cOff = (long)i * CC;
        const __hip_bfloat16 *Wqkv, *Wp, *W1, *W2;
        if (big) {
            Wqkv = eQKVw + (size_t)i * 3072 * CC;
            Wp   = ePWw  + (size_t)i * CC * CC;
            W1   = eW1w  + (size_t)i * FFD * CC;
            W2   = eW2w  + (size_t)i * CC * FFD;
        }
        if (!big) cvt_qkv(eWq + (long)i*HH*CC*HSZ, eWk + (long)i*HH*CC*HSZ, eWv + (long)i*HH*CC*HSZ), Wqkv = wb;
        gemm(encb, Wqkv, nullptr, nullptr, qkvb, 3072, CC, 3072, 2, false);
        fattn_kernel<false><<<dim3(QT, HH, BB), 256, 0, stream>>>(qkvb, a0b);
        if (!big) cvt_nt(epw + (long)i*CC*CC, CC, CC), Wp = wb;
        gemm(a0b, Wp, epb + cOff, t0, nullptr, CC, CC, CC, 0, false);
        ln_kernel<<<MM, 256, 0, stream>>>(t0, enc, eln1g + cOff, eln1b + cOff, enc, encb);
        if (!big) cvt_nt(ew1 + (long)i*CC*FFD, CC, FFD), W1 = wb;
        gemm(encb, W1, eb1 + (long)i*FFD, nullptr, ffb, FFD, CC, FFD, 2, true);
        if (!big) cvt_nt(ew2 + (long)i*FFD*CC, FFD, CC), W2 = wb;
        gemm(ffb, W2, eb2 + cOff, t0, nullptr, CC, FFD, CC, 0, false);
        ln_kernel<<<MM, 256, 0, stream>>>(t0, enc, eln2g + cOff, eln2b + cOff, enc, encb);
    }

    // ---- decoder ----
    embed_kernel<<<MM, 256, 0, stream>>>(y, wte, wpe_y, dec, decb);
    for (int i = 0; i < LL; ++i) {
        const long cOff = (long)i * CC;
        const __hip_bfloat16 *Ws, *Wsp, *Wc, *Wcp, *W1, *W2;
        if (big) {
            Ws  = sQKVw + (size_t)i * 3072 * CC;
            Wsp = sPWw  + (size_t)i * CC * CC;
            Wc  = cQKVw + (size_t)i * 3072 * CC;
            Wcp = cPWw  + (size_t)i * CC * CC;
            W1  = dW1w  + (size_t)i * FFD * CC;
            W2  = dW2w  + (size_t)i * CC * FFD;
        }
        // masked self-attn
        if (!big) cvt_qkv(dsWq + (long)i*HH*CC*HSZ, dsWk + (long)i*HH*CC*HSZ, dsWv + (long)i*HH*CC*HSZ), Ws = wb;
        gemm(decb, Ws, nullptr, nullptr, qkvb, 3072, CC, 3072, 2, false);
        fattn_kernel<true><<<dim3(QT, HH, BB), 256, 0, stream>>>(qkvb, a0b);
        if (!big) cvt_nt(dspw + (long)i*CC*CC, CC, CC), Wsp = wb;
        gemm(a0b, Wsp, dspb + cOff, t0, nullptr, CC, CC, CC, 0, false);
        ln_kernel<<<MM, 256, 0, stream>>>(t0, dec, dln1g + cOff, dln1b + cOff, dec, decb);
        // cross-attn: q from dec, k/v from enc
        if (!big) cvt_qkv(dcWq + (long)i*HH*CC*HSZ, dcWk + (long)i*HH*CC*HSZ, dcWv + (long)i*HH*CC*HSZ), Wc = wb;
        gemm(decb, Wc, nullptr, nullptr, qkvb, CC, CC, 3072, 2, false);
        gemm(encb, Wc + (size_t)CC * CC, nullptr, nullptr, qkvb + CC, 2048, CC, 3072, 2, false);
        fattn_kernel<false><<<dim3(QT, HH, BB), 256, 0, stream>>>(qkvb, a0b);
        if (!big) cvt_nt(dcpw + (long)i*CC*CC, CC, CC), Wcp = wb;
        gemm(a0b, Wcp, dcpb + cOff, t0, nullptr, CC, CC, CC, 0, false);
        ln_kernel<<<MM, 256, 0, stream>>>(t0, dec, dln2g + cOff, dln2b + cOff, dec, decb);
        // ffn
        if (!big) cvt_nt(dw1 + (long)i*CC*FFD, CC, FFD), W1 = wb;
        gemm(decb, W1, db1 + (long)i*FFD, nullptr, ffb, FFD, CC, FFD, 2, true);
        if (!big) cvt_nt(dw2 + (long)i*FFD*CC, FFD, CC), W2 = wb;
        gemm(ffb, W2, db2 + cOff, t0, nullptr, CC, FFD, CC, 0, false);
        ln_kernel<<<MM, 256, 0, stream>>>(t0, dec, dln3g + cOff, dln3b + cOff, dec, decb);
    }

    // ---- final LN + logits ----
    ln_kernel<<<MM, 256, 0, stream>>>(dec, nullptr, lnfg, lnfb, t0, t0b);
    if (useWteb) {
        gemm(t0b, wteb, lm_b, out, nullptr, VV, CC, VV, 0, false);
    } else {
        dim3 grid((VV + 127) / 128, GM);
        mgemm_f32b_kernel<<<grid, 256, 0, stream>>>(t0, wte, lm_b, out, MM, VV, CC, VV);
    }
}

// Round 8
// 3512.992 us; speedup vs baseline: 16.5291x; 1.1134x over previous
//
#include <hip/hip_runtime.h>
#include <hip/hip_bf16.h>

#define BB 2
#define TT 1023
#define CC 1024
#define HH 16
#define HSZ 64
#define LL 6
#define FFD 4096
#define VV 50258
#define MM (BB*TT)   // 2046
#define MP 2048      // padded row count
#define VP 50304     // padded vocab (multiple of 128)

typedef __attribute__((ext_vector_type(4))) float  f32x4;
typedef __attribute__((ext_vector_type(8))) short  s16x8;
typedef __attribute__((ext_vector_type(4))) short  s16x4;

#define SCHED0   __builtin_amdgcn_sched_barrier(0)
#define SBAR     __builtin_amdgcn_s_barrier()
#define VMCNT8   asm volatile("s_waitcnt vmcnt(8)" ::: "memory")
#define VMCNT4   asm volatile("s_waitcnt vmcnt(4)" ::: "memory")
#define VMCNT0   asm volatile("s_waitcnt vmcnt(0)" ::: "memory")
#define LGKMCNT0 asm volatile("s_waitcnt lgkmcnt(0)" ::: "memory")

__device__ __forceinline__ short f2b(float x) {
    __hip_bfloat16 h = __float2bfloat16(x);
    short s;
    __builtin_memcpy(&s, &h, 2);
    return s;
}

__device__ __forceinline__ void gld16(const void* g, void* l) {
    __builtin_amdgcn_global_load_lds(
        (__attribute__((address_space(1))) const void*)g,
        (__attribute__((address_space(3))) void*)l, 16, 0, 0);
}

// ---------------------------------------------------------------------------
// Embedding: fp32 + bf16 mirror
// ---------------------------------------------------------------------------
__global__ __launch_bounds__(256) void embed_kernel(
    const int* __restrict__ ids, const float* __restrict__ wte,
    const float* __restrict__ wpe, float* __restrict__ out,
    __hip_bfloat16* __restrict__ outb)
{
    int r = blockIdx.x;
    int t = r % TT;
    long id = ids[r];
    int c = threadIdx.x * 4;
    float4 a = *(const float4*)(wte + id * (long)CC + c);
    float4 p = *(const float4*)(wpe + (long)t * CC + c);
    float4 o; o.x = a.x + p.x; o.y = a.y + p.y; o.z = a.z + p.z; o.w = a.w + p.w;
    *(float4*)(out + (long)r * CC + c) = o;
    s16x4 h; h[0] = f2b(o.x); h[1] = f2b(o.y); h[2] = f2b(o.z); h[3] = f2b(o.w);
    *(s16x4*)(outb + (long)r * CC + c) = h;
}

// ---------------------------------------------------------------------------
// Elementwise fp32 -> bf16
// ---------------------------------------------------------------------------
__global__ __launch_bounds__(256) void cvtb_kernel(
    const float* __restrict__ in, __hip_bfloat16* __restrict__ out, long n)
{
    long i = ((long)blockIdx.x * 256 + threadIdx.x) * 8;
    if (i >= n) return;
    float4 f0 = *(const float4*)(in + i);
    float4 f1 = *(const float4*)(in + i + 4);
    s16x8 h;
    h[0]=f2b(f0.x); h[1]=f2b(f0.y); h[2]=f2b(f0.z); h[3]=f2b(f0.w);
    h[4]=f2b(f1.x); h[5]=f2b(f1.y); h[6]=f2b(f1.z); h[7]=f2b(f1.w);
    *(s16x8*)(out + i) = h;
}

// ---------------------------------------------------------------------------
// Transpose + fp32->bf16: in [R][S] fp32 -> out [S][R] bf16, batched over z.
// out offset = (z/zdiv)*outZa + (z%zdiv)*outZb ; in offset = z*inZ.
// ---------------------------------------------------------------------------
__global__ __launch_bounds__(256) void tcvt_kernel(
    const float* __restrict__ in, __hip_bfloat16* __restrict__ out,
    int R, int S, long inZ, long outZa, long outZb, int zdiv)
{
    int z = blockIdx.z;
    in  += (long)z * inZ;
    out += (long)(z / zdiv) * outZa + (long)(z % zdiv) * outZb;
    __shared__ float tile[32][33];
    int s0 = blockIdx.x * 32, r0 = blockIdx.y * 32;
    int tx = threadIdx.x, ty = threadIdx.y;
    #pragma unroll
    for (int i = 0; i < 4; ++i)
        tile[ty + i * 8][tx] = in[(long)(r0 + ty + i * 8) * S + s0 + tx];
    __syncthreads();
    #pragma unroll
    for (int i = 0; i < 4; ++i)
        out[(long)(s0 + ty + i * 8) * R + r0 + tx] =
            __float2bfloat16(tile[tx][ty + i * 8]);
}

// ---------------------------------------------------------------------------
// bf16 MFMA GEMM, T3+T4 pipelined: BK=32, THREE LDS buffers (48 KB),
// 2-deep prefetch with counted s_waitcnt vmcnt(8) (never 0 in loop) + raw
// s_barrier -- prefetch global_load_lds stay in flight across 2 compute
// phases, covering HBM latency (~900cy). T5 setprio around MFMA.
// C = act(A @ B^T + bias). A [pad(M,128)][K] bf16, B [pad(N,128)][K] bf16,
// K % 32 == 0. 128x128 tile, 4 waves (2x2).
// WMODE: 0 = fp32 out (float2-coalesced), 2 = bf16 out (b128-coalesced).
// ---------------------------------------------------------------------------
template<int WMODE, bool RELU>
__global__ __launch_bounds__(256) void mgemm2_kernel(
    const __hip_bfloat16* __restrict__ A, const __hip_bfloat16* __restrict__ B,
    const float* __restrict__ bias, float* __restrict__ Cm,
    __hip_bfloat16* __restrict__ Cb,
    int M, int N, int K, int ldc, int GM)
{
    __shared__ short LDS[3][2][4096];   // [3buf][A/B][128*32] = 48 KB

    // bijective XCD swizzle + m-fastest decode
    const int nwg = gridDim.x;
    const int bid = blockIdx.x;
    const int q = nwg >> 3, r = nwg & 7;
    const int xcd = bid & 7, lid = bid >> 3;
    const int swz = (xcd < r) ? xcd * (q + 1) + lid
                              : r * (q + 1) + (xcd - r) * q + lid;
    const int m0 = (swz % GM) * 128;
    const int n0 = (swz / GM) * 128;

    const int tid  = threadIdx.x;
    const int lane = tid & 63, w = tid >> 6;
    const int wr = w >> 1, wc = w & 1;
    const int lr = lane & 15, kg = lane >> 4;

    const __hip_bfloat16* Abase = A + (long)m0 * K;
    const __hip_bfloat16* Bbase = B + (long)n0 * K;

    f32x4 acc[4][4];
    #pragma unroll
    for (int i = 0; i < 4; ++i)
        #pragma unroll
        for (int j = 0; j < 4; ++j)
            acc[i][j] = (f32x4){0.f, 0.f, 0.f, 0.f};

    // staging geometry: tile 128x32 bf16 = 8 chunks of 512 elems (1 KB).
    // thread handles chunks {w, 4+w} of each operand: 4 gld16 per stage.
    const int srow = lane >> 2;
    const int scol = (lane & 3) * 8;

    auto stage = [&](int db, long kofs) {
        short* Ad = &LDS[db][0][0];
        short* Bd = &LDS[db][1][0];
        #pragma unroll
        for (int p = 0; p < 2; ++p) {
            int cc = p * 4 + w;
            long ro = (long)(cc * 16 + srow) * K + kofs + scol;
            gld16(Abase + ro, Ad + cc * 512);
            gld16(Bbase + ro, Bd + cc * 512);
        }
    };
    auto compute = [&](int db) {
        const short* Ar = &LDS[db][0][0];
        const short* Br = &LDS[db][1][0];
        s16x8 af[4], bf[4];
        #pragma unroll
        for (int i = 0; i < 4; ++i)
            af[i] = *(const s16x8*)&Ar[(wr * 64 + i * 16 + lr) * 32 + kg * 8];
        #pragma unroll
        for (int j = 0; j < 4; ++j)
            bf[j] = *(const s16x8*)&Br[(wc * 64 + j * 16 + lr) * 32 + kg * 8];
        __builtin_amdgcn_s_setprio(1);
        #pragma unroll
        for (int i = 0; i < 4; ++i)
            #pragma unroll
            for (int j = 0; j < 4; ++j)
                acc[i][j] = __builtin_amdgcn_mfma_f32_16x16x32_bf16(
                    af[i], bf[j], acc[i][j], 0, 0, 0);
        __builtin_amdgcn_s_setprio(0);
    };

    const int nt = K >> 5;
    stage(0, 0);
    if (nt > 1) stage(1, 32);
    int db = 0;
    for (int t = 0; t < nt; ++t) {
        if (t + 2 < nt) {
            stage((db + 2) % 3, (long)(t + 2) << 5);   // keep 2 stages ahead
            SCHED0; VMCNT8; SCHED0;                    // wait stage t only
        } else if (t + 1 < nt) {
            SCHED0; VMCNT4; SCHED0;                    // drain: 1 stage left
        } else {
            SCHED0; VMCNT0; SCHED0;                    // drain: last stage
        }
        SBAR; SCHED0;                                  // stage t visible to all
        compute(db);
        SCHED0; LGKMCNT0; SCHED0; SBAR; SCHED0;        // reads done pre-overwrite
        db = (db + 1) % 3;
    }

    // ---- epilogue: stage C tile through LDS for coalesced stores ----
    if (WMODE == 0) {
        float* LF = (float*)&LDS[0][0][0];     // [128][64] fp32 = 32 KB
        #pragma unroll
        for (int h = 0; h < 2; ++h) {
            if (wc == h) {
                #pragma unroll
                for (int j = 0; j < 4; ++j) {
                    int gcol = n0 + h * 64 + j * 16 + lr;
                    float bv = (bias && gcol < N) ? bias[gcol] : 0.f;
                    #pragma unroll
                    for (int i = 0; i < 4; ++i) {
                        int row0 = wr * 64 + i * 16 + kg * 4;
                        #pragma unroll
                        for (int qq = 0; qq < 4; ++qq) {
                            float v = acc[i][j][qq] + bv;
                            if (RELU) v = fmaxf(v, 0.f);
                            LF[(row0 + qq) * 64 + j * 16 + lr] = v;
                        }
                    }
                }
            }
            __syncthreads();
            #pragma unroll
            for (int i = 0; i < 16; ++i) {
                int F = i * 256 + tid;               // float2 index
                int row = F >> 5, col = (F & 31) * 2;
                int gr = m0 + row, gc = n0 + h * 64 + col;
                if (gr < M && gc < N)
                    *(float2*)(Cm + (long)gr * ldc + gc) = *(const float2*)&LF[row * 64 + col];
            }
            __syncthreads();
        }
    } else {
        short* LS = (short*)&LDS[0][0][0];     // [128][128] bf16 = 32 KB
        #pragma unroll
        for (int j = 0; j < 4; ++j) {
            int gcol = n0 + wc * 64 + j * 16 + lr;
            float bv = (bias && gcol < N) ? bias[gcol] : 0.f;
            #pragma unroll
            for (int i = 0; i < 4; ++i) {
                int row0 = wr * 64 + i * 16 + kg * 4;
                #pragma unroll
                for (int qq = 0; qq < 4; ++qq) {
                    float v = acc[i][j][qq] + bv;
                    if (RELU) v = fmaxf(v, 0.f);
                    LS[(row0 + qq) * 128 + wc * 64 + j * 16 + lr] = f2b(v);
                }
            }
        }
        __syncthreads();
        #pragma unroll
        for (int i = 0; i < 8; ++i) {
            int F = i * 256 + tid;                   // s16x8 index
            int row = F >> 4, col = (F & 15) * 8;
            int gr = m0 + row, gc = n0 + col;
            if (gr < M && gc < N)
                *(s16x8*)((short*)Cb + (long)gr * ldc + gc) = *(const s16x8*)&LS[row * 128 + col];
        }
    }
}

// ---------------------------------------------------------------------------
// Fallback fp32-B GEMM (logits only, if ws too small for bf16 wte mirror).
// ---------------------------------------------------------------------------
__global__ __launch_bounds__(256) void mgemm_f32b_kernel(
    const float* __restrict__ A, const float* __restrict__ Bv,
    const float* __restrict__ bias, float* __restrict__ Cm,
    int M, int N, int K, int ldc)
{
    __shared__ short As[128][40];
    __shared__ short Bs[128][40];
    const int tid  = threadIdx.x;
    const int lane = tid & 63, w = tid >> 6;
    const int wr = w >> 1, wc = w & 1;
    const int lr = lane & 15, kg = lane >> 4;
    const int m0 = blockIdx.y * 128, n0 = blockIdx.x * 128;
    const int ar = tid >> 3, ac = (tid & 7) * 4;
    const int br = tid >> 2, bc = (tid & 3) * 8;

    f32x4 acc[4][4];
    #pragma unroll
    for (int i = 0; i < 4; ++i)
        #pragma unroll
        for (int j = 0; j < 4; ++j)
            acc[i][j] = (f32x4){0.f, 0.f, 0.f, 0.f};

    for (int k0 = 0; k0 < K; k0 += 32) {
        #pragma unroll
        for (int p = 0; p < 4; ++p) {
            int row = ar + p * 32, gm = m0 + row;
            float4 f = {0.f, 0.f, 0.f, 0.f};
            if (gm < M) f = *(const float4*)(A + (long)gm * K + k0 + ac);
            s16x4 h; h[0] = f2b(f.x); h[1] = f2b(f.y); h[2] = f2b(f.z); h[3] = f2b(f.w);
            *(s16x4*)&As[row][ac] = h;
        }
        #pragma unroll
        for (int p = 0; p < 2; ++p) {
            int n = br + p * 64, gn = n0 + n;
            s16x8 h = (s16x8){0,0,0,0,0,0,0,0};
            if (gn < N) {
                float4 f0 = *(const float4*)(Bv + (long)gn * K + k0 + bc);
                float4 f1 = *(const float4*)(Bv + (long)gn * K + k0 + bc + 4);
                h[0]=f2b(f0.x); h[1]=f2b(f0.y); h[2]=f2b(f0.z); h[3]=f2b(f0.w);
                h[4]=f2b(f1.x); h[5]=f2b(f1.y); h[6]=f2b(f1.z); h[7]=f2b(f1.w);
            }
            *(s16x8*)&Bs[n][bc] = h;
        }
        __syncthreads();
        s16x8 af[4], bf[4];
        #pragma unroll
        for (int i = 0; i < 4; ++i) af[i] = *(const s16x8*)&As[wr*64 + i*16 + lr][kg*8];
        #pragma unroll
        for (int j = 0; j < 4; ++j) bf[j] = *(const s16x8*)&Bs[wc*64 + j*16 + lr][kg*8];
        #pragma unroll
        for (int i = 0; i < 4; ++i)
            #pragma unroll
            for (int j = 0; j < 4; ++j)
                acc[i][j] = __builtin_amdgcn_mfma_f32_16x16x32_bf16(af[i], bf[j], acc[i][j], 0, 0, 0);
        __syncthreads();
    }
    #pragma unroll
    for (int j = 0; j < 4; ++j) {
        int gcol = n0 + wc * 64 + j * 16 + lr;
        if (gcol >= N) continue;
        float bv = bias ? bias[gcol] : 0.f;
        #pragma unroll
        for (int i = 0; i < 4; ++i) {
            int grow0 = m0 + wr * 64 + i * 16 + kg * 4;
            #pragma unroll
            for (int qq = 0; qq < 4; ++qq) {
                int gr = grow0 + qq;
                if (gr >= M) continue;
                Cm[(long)gr * ldc + gcol] = acc[i][j][qq] + bv;
            }
        }
    }
}

// ---------------------------------------------------------------------------
// MFMA flash attention (bf16 in / bf16 out). grid (16, H, B), 4 waves.
// T14 async-split: K/V prefetched to REGISTERS one tile ahead; raw s_barrier
// (not __syncthreads) so the reg-prefetch loads are NOT drained at barriers.
// qkvb: [M,3072] bf16 (q|k|v, head h at col h*64). outb: [M,C] bf16.
// scale = 1/sqrt(C) = 1/32 (reference quirk).
// ---------------------------------------------------------------------------
template<bool CAUSAL>
__global__ __launch_bounds__(256) void fattn_kernel(
    const __hip_bfloat16* __restrict__ qkvb, __hip_bfloat16* __restrict__ outb)
{
    __shared__ short Ks[64][72];
    __shared__ short Vt[64][72];
    __shared__ short Ps[4][16][72];

    const int q0 = blockIdx.x * 64;
    const int h = blockIdx.y, b = blockIdx.z;
    const int tid = threadIdx.x;
    const int lane = tid & 63, w = tid >> 6;
    const int lr = lane & 15, lg = lane >> 4;

    const float scale = 1.0f / 32.0f;
    const long base = (long)b * TT * 3072;
    const __hip_bfloat16* Kg = qkvb + base + 1024 + h * 64;
    const __hip_bfloat16* Vg = qkvb + base + 2048 + h * 64;

    s16x8 qf[2];
    {
        int qr = q0 + w * 16 + lr;
        #pragma unroll
        for (int kc = 0; kc < 2; ++kc) {
            s16x8 hv = (s16x8){0,0,0,0,0,0,0,0};
            if (qr < TT)
                hv = *(const s16x8*)(qkvb + base + (long)qr * 3072 + h * 64 + kc * 32 + lg * 8);
            qf[kc] = hv;
        }
    }

    f32x4 acc[4];
    #pragma unroll
    for (int jd = 0; jd < 4; ++jd) acc[jd] = (f32x4){0.f, 0.f, 0.f, 0.f};
    float mrun[4] = {-3.0e38f, -3.0e38f, -3.0e38f, -3.0e38f};
    float lrun[4] = {0.f, 0.f, 0.f, 0.f};

    const int send = CAUSAL ? min(TT, q0 + 64) : TT;
    const int nt = (send + 63) >> 6;
    const int sr2 = (tid >> 3) * 2;        // rows sr2, sr2+1
    const int dcc = (tid & 7) * 8;         // col chunk

    s16x8 kreg[2], vreg[2];
    auto loadkv = [&](int t) {
        int sbase = t * 64;
        #pragma unroll
        for (int rr = 0; rr < 2; ++rr) {
            int sg = sbase + sr2 + rr;
            if (sg < TT) {
                kreg[rr] = *(const s16x8*)(Kg + (long)sg * 3072 + dcc);
                vreg[rr] = *(const s16x8*)(Vg + (long)sg * 3072 + dcc);
            } else {
                kreg[rr] = (s16x8){0,0,0,0,0,0,0,0};
                vreg[rr] = (s16x8){0,0,0,0,0,0,0,0};
            }
        }
    };

    loadkv(0);
    for (int ti = 0; ti < nt; ++ti) {
        const int s0 = ti * 64;
        SCHED0; SBAR; SCHED0;          // prev tile's LDS reads done (all waves)
        // write prefetched regs -> LDS (compiler waits vmcnt only on these regs)
        *(s16x8*)&Ks[sr2][dcc]     = kreg[0];
        *(s16x8*)&Ks[sr2 + 1][dcc] = kreg[1];
        #pragma unroll
        for (int e = 0; e < 8; ++e) {
            unsigned pack = (unsigned)(unsigned short)vreg[0][e]
                          | ((unsigned)(unsigned short)vreg[1][e] << 16);
            *(unsigned*)&Vt[dcc + e][sr2] = pack;
        }
        if (ti + 1 < nt) loadkv(ti + 1);   // issue next tile's loads early
        SCHED0; LGKMCNT0; SCHED0; SBAR; SCHED0;   // LDS writes visible

        f32x4 sf[4];
        __builtin_amdgcn_s_setprio(1);
        #pragma unroll
        for (int j = 0; j < 4; ++j) {
            f32x4 z = (f32x4){0.f, 0.f, 0.f, 0.f};
            #pragma unroll
            for (int kc = 0; kc < 2; ++kc) {
                s16x8 kf = *(const s16x8*)&Ks[j * 16 + lr][kc * 32 + lg * 8];
                z = __builtin_amdgcn_mfma_f32_16x16x32_bf16(qf[kc], kf, z, 0, 0, 0);
            }
            sf[j] = z;
        }
        __builtin_amdgcn_s_setprio(0);

        float mloc[4] = {-3.0e38f, -3.0e38f, -3.0e38f, -3.0e38f};
        #pragma unroll
        for (int j = 0; j < 4; ++j) {
            int sg = s0 + j * 16 + lr;
            #pragma unroll
            for (int r = 0; r < 4; ++r) {
                float sc = sf[j][r] * scale;
                int qg = q0 + w * 16 + lg * 4 + r;
                if ((CAUSAL && sg > qg) || sg >= TT) sc = -3.0e38f;
                sf[j][r] = sc;
                mloc[r] = fmaxf(mloc[r], sc);
            }
        }
        #pragma unroll
        for (int r = 0; r < 4; ++r)
            #pragma unroll
            for (int off = 1; off < 16; off <<= 1)
                mloc[r] = fmaxf(mloc[r], __shfl_xor(mloc[r], off));

        float corr[4], psum[4];
        #pragma unroll
        for (int r = 0; r < 4; ++r) {
            float mn = fmaxf(mrun[r], mloc[r]);
            corr[r] = __expf(mrun[r] - mn);
            mrun[r] = mn;
            psum[r] = 0.f;
        }

        #pragma unroll
        for (int j = 0; j < 4; ++j) {
            #pragma unroll
            for (int r = 0; r < 4; ++r) {
                float p = __expf(sf[j][r] - mrun[r]);
                psum[r] += p;
                Ps[w][lg * 4 + r][j * 16 + lr] = f2b(p);
            }
        }
        #pragma unroll
        for (int r = 0; r < 4; ++r) {
            #pragma unroll
            for (int off = 1; off < 16; off <<= 1)
                psum[r] += __shfl_xor(psum[r], off);
            lrun[r] = lrun[r] * corr[r] + psum[r];
            #pragma unroll
            for (int jd = 0; jd < 4; ++jd) acc[jd][r] *= corr[r];
        }

        __builtin_amdgcn_s_setprio(1);
        #pragma unroll
        for (int kc = 0; kc < 2; ++kc) {
            s16x8 pa = *(const s16x8*)&Ps[w][lr][kc * 32 + lg * 8];
            #pragma unroll
            for (int jd = 0; jd < 4; ++jd) {
                s16x8 bv = *(const s16x8*)&Vt[jd * 16 + lr][kc * 32 + lg * 8];
                acc[jd] = __builtin_amdgcn_mfma_f32_16x16x32_bf16(pa, bv, acc[jd], 0, 0, 0);
            }
        }
        __builtin_amdgcn_s_setprio(0);
        SCHED0; LGKMCNT0; SCHED0;      // my LDS reads complete before next write
    }

    #pragma unroll
    for (int r = 0; r < 4; ++r) {
        int qg = q0 + w * 16 + lg * 4 + r;
        if (qg >= TT) continue;
        float inv = 1.0f / lrun[r];
        #pragma unroll
        for (int jd = 0; jd < 4; ++jd)
            outb[((long)b * TT + qg) * CC + h * 64 + jd * 16 + lr] =
                __float2bfloat16(acc[jd][r] * inv);
    }
}

// ---------------------------------------------------------------------------
// LayerNorm (+optional residual), fp32 out + optional bf16 mirror.
// ---------------------------------------------------------------------------
__global__ __launch_bounds__(256) void ln_kernel(
    const float* __restrict__ in, const float* __restrict__ res,
    const float* __restrict__ g, const float* __restrict__ b,
    float* __restrict__ out, __hip_bfloat16* __restrict__ outb)
{
    const int r = blockIdx.x, tid = threadIdx.x;
    __shared__ float sm[4];

    float4 xv = *(const float4*)(in + (long)r * CC + tid * 4);
    float s = xv.x + xv.y + xv.z + xv.w;
    #pragma unroll
    for (int o = 32; o > 0; o >>= 1) s += __shfl_xor(s, o);
    if ((tid & 63) == 0) sm[tid >> 6] = s;
    __syncthreads();
    const float mean = (sm[0] + sm[1] + sm[2] + sm[3]) * (1.0f / CC);
    __syncthreads();

    float4 d; d.x = xv.x - mean; d.y = xv.y - mean; d.z = xv.z - mean; d.w = xv.w - mean;
    float s2 = d.x * d.x + d.y * d.y + d.z * d.z + d.w * d.w;
    #pragma unroll
    for (int o = 32; o > 0; o >>= 1) s2 += __shfl_xor(s2, o);
    if ((tid & 63) == 0) sm[tid >> 6] = s2;
    __syncthreads();
    const float rstd = rsqrtf((sm[0] + sm[1] + sm[2] + sm[3]) * (1.0f / CC) + 1e-5f);

    float4 gv = *(const float4*)(g + tid * 4);
    float4 bv = *(const float4*)(b + tid * 4);
    float4 o;
    o.x = gv.x * d.x * rstd + bv.x; o.y = gv.y * d.y * rstd + bv.y;
    o.z = gv.z * d.z * rstd + bv.z; o.w = gv.w * d.w * rstd + bv.w;
    if (res) {
        float4 rv = *(const float4*)(res + (long)r * CC + tid * 4);
        o.x += rv.x; o.y += rv.y; o.z += rv.z; o.w += rv.w;
    }
    *(float4*)(out + (long)r * CC + tid * 4) = o;
    if (outb) {
        s16x4 h; h[0] = f2b(o.x); h[1] = f2b(o.y); h[2] = f2b(o.z); h[3] = f2b(o.w);
        *(s16x4*)(outb + (long)r * CC + tid * 4) = h;
    }
}

// ---------------------------------------------------------------------------
extern "C" void kernel_launch(void* const* d_in, const int* in_sizes, int n_in,
                              void* d_out, int out_size, void* d_ws, size_t ws_size,
                              hipStream_t stream)
{
    const int*   x      = (const int*)  d_in[0];
    const int*   y      = (const int*)  d_in[1];
    const float* wte    = (const float*)d_in[2];
    const float* wpe_x  = (const float*)d_in[3];
    const float* wpe_y  = (const float*)d_in[4];
    const float* eWq    = (const float*)d_in[5];
    const float* eWk    = (const float*)d_in[6];
    const float* eWv    = (const float*)d_in[7];
    const float* epw    = (const float*)d_in[8];
    const float* epb    = (const float*)d_in[9];
    const float* eln1g  = (const float*)d_in[10];
    const float* eln1b  = (const float*)d_in[11];
    const float* eln2g  = (const float*)d_in[12];
    const float* eln2b  = (const float*)d_in[13];
    const float* ew1    = (const float*)d_in[14];
    const float* eb1    = (const float*)d_in[15];
    const float* ew2    = (const float*)d_in[16];
    const float* eb2    = (const float*)d_in[17];
    const float* dsWq   = (const float*)d_in[18];
    const float* dsWk   = (const float*)d_in[19];
    const float* dsWv   = (const float*)d_in[20];
    const float* dspw   = (const float*)d_in[21];
    const float* dspb   = (const float*)d_in[22];
    const float* dcWq   = (const float*)d_in[23];
    const float* dcWk   = (const float*)d_in[24];
    const float* dcWv   = (const float*)d_in[25];
    const float* dcpw   = (const float*)d_in[26];
    const float* dcpb   = (const float*)d_in[27];
    const float* dln1g  = (const float*)d_in[28];
    const float* dln1b  = (const float*)d_in[29];
    const float* dln2g  = (const float*)d_in[30];
    const float* dln2b  = (const float*)d_in[31];
    const float* dln3g  = (const float*)d_in[32];
    const float* dln3b  = (const float*)d_in[33];
    const float* dw1    = (const float*)d_in[34];
    const float* db1    = (const float*)d_in[35];
    const float* dw2    = (const float*)d_in[36];
    const float* db2    = (const float*)d_in[37];
    const float* lnfg   = (const float*)d_in[38];
    const float* lnfb   = (const float*)d_in[39];
    const float* lm_b   = (const float*)d_in[40];

    float* out = (float*)d_out;

    // ---- workspace carve-up ----
    const size_t MCp = (size_t)MP * CC;
    float* enc = (float*)d_ws;
    float* dec = enc + MCp;
    float* t0  = dec + MCp;
    __hip_bfloat16* encb = (__hip_bfloat16*)(t0 + MCp);
    __hip_bfloat16* decb = encb + MCp;
    __hip_bfloat16* t0b  = decb + MCp;
    __hip_bfloat16* a0b  = t0b + MCp;
    __hip_bfloat16* qkvb = a0b + MCp;                    // [MP][3072]
    __hip_bfloat16* ffb  = qkvb + (size_t)MP * 3072;     // [MP][FFD]
    __hip_bfloat16* wteb = ffb + (size_t)MP * FFD;       // [VP][C]
    // big-mode weight blocks
    __hip_bfloat16* eQKVw = wteb + (size_t)VP * CC;      // [L][3072][C]
    __hip_bfloat16* ePWw  = eQKVw + (size_t)LL * 3072 * CC;
    __hip_bfloat16* eW1w  = ePWw  + (size_t)LL * CC * CC;     // [L][FFD][C]
    __hip_bfloat16* eW2w  = eW1w  + (size_t)LL * FFD * CC;    // [L][C][FFD]
    __hip_bfloat16* sQKVw = eW2w  + (size_t)LL * CC * FFD;
    __hip_bfloat16* sPWw  = sQKVw + (size_t)LL * 3072 * CC;
    __hip_bfloat16* cQKVw = sPWw  + (size_t)LL * CC * CC;
    __hip_bfloat16* cPWw  = cQKVw + (size_t)LL * 3072 * CC;
    __hip_bfloat16* dW1w  = cPWw  + (size_t)LL * CC * CC;
    __hip_bfloat16* dW2w  = dW1w  + (size_t)LL * FFD * CC;
    __hip_bfloat16* bigEnd = dW2w + (size_t)LL * CC * FFD;
    // small-mode: per-use conversion buffer where eQKVw starts
    __hip_bfloat16* wb = eQKVw;
    const size_t needBig   = (size_t)((char*)bigEnd - (char*)d_ws);
    const size_t needSmall = (size_t)((char*)(wb + (size_t)FFD * CC) - (char*)d_ws);
    const size_t needWteb  = (size_t)((char*)eQKVw - (char*)d_ws);
    const bool big     = (ws_size >= needBig);
    const bool useWteb = (ws_size >= needWteb) &&
                         (big || ws_size >= needSmall);

    const int GM = MP / 128;           // 16 m-tiles
    const int QT = (TT + 63) / 64;     // 16 q-tiles
    const dim3 tblk(32, 8);

    auto gemm = [&](const __hip_bfloat16* A, const __hip_bfloat16* B,
                    const float* bias, float* Cm, __hip_bfloat16* Cb,
                    int N_, int K_, int ldc, int wmode, bool relu) {
        int nwg = GM * ((N_ + 127) / 128);
        if (wmode == 0) {
            if (relu) mgemm2_kernel<0, true ><<<nwg, 256, 0, stream>>>(A, B, bias, Cm, Cb, MM, N_, K_, ldc, GM);
            else      mgemm2_kernel<0, false><<<nwg, 256, 0, stream>>>(A, B, bias, Cm, Cb, MM, N_, K_, ldc, GM);
        } else {
            if (relu) mgemm2_kernel<2, true ><<<nwg, 256, 0, stream>>>(A, B, bias, Cm, Cb, MM, N_, K_, ldc, GM);
            else      mgemm2_kernel<2, false><<<nwg, 256, 0, stream>>>(A, B, bias, Cm, Cb, MM, N_, K_, ldc, GM);
        }
    };

    if (useWteb) {
        long n = (long)VV * CC;
        cvtb_kernel<<<(int)((n / 8 + 255) / 256), 256, 0, stream>>>(wte, wteb, n);
    }

    if (big) {
        // ---- all weight conversions up-front ----
        const long sWH = (long)CC * HSZ;            // per-(l,h) input stride
        const long oA = (long)3072 * CC;            // per-layer qkv out stride
        const long oB = (long)HSZ * CC;             // per-head out stride
        dim3 gq(HSZ / 32, CC / 32, LL * HH);
        tcvt_kernel<<<gq, tblk, 0, stream>>>(eWq, eQKVw,             CC, HSZ, sWH, oA, oB, HH);
        tcvt_kernel<<<gq, tblk, 0, stream>>>(eWk, eQKVw + CC * CC,   CC, HSZ, sWH, oA, oB, HH);
        tcvt_kernel<<<gq, tblk, 0, stream>>>(eWv, eQKVw + 2*CC*CC,   CC, HSZ, sWH, oA, oB, HH);
        tcvt_kernel<<<gq, tblk, 0, stream>>>(dsWq, sQKVw,            CC, HSZ, sWH, oA, oB, HH);
        tcvt_kernel<<<gq, tblk, 0, stream>>>(dsWk, sQKVw + CC * CC,  CC, HSZ, sWH, oA, oB, HH);
        tcvt_kernel<<<gq, tblk, 0, stream>>>(dsWv, sQKVw + 2*CC*CC,  CC, HSZ, sWH, oA, oB, HH);
        tcvt_kernel<<<gq, tblk, 0, stream>>>(dcWq, cQKVw,            CC, HSZ, sWH, oA, oB, HH);
        tcvt_kernel<<<gq, tblk, 0, stream>>>(dcWk, cQKVw + CC * CC,  CC, HSZ, sWH, oA, oB, HH);
        tcvt_kernel<<<gq, tblk, 0, stream>>>(dcWv, cQKVw + 2*CC*CC,  CC, HSZ, sWH, oA, oB, HH);
        dim3 gp(CC / 32, CC / 32, LL);
        tcvt_kernel<<<gp, tblk, 0, stream>>>(epw,  ePWw, CC, CC, (long)CC*CC, (long)CC*CC, 0, 1);
        tcvt_kernel<<<gp, tblk, 0, stream>>>(dspw, sPWw, CC, CC, (long)CC*CC, (long)CC*CC, 0, 1);
        tcvt_kernel<<<gp, tblk, 0, stream>>>(dcpw, cPWw, CC, CC, (long)CC*CC, (long)CC*CC, 0, 1);
        dim3 g1(FFD / 32, CC / 32, LL);
        tcvt_kernel<<<g1, tblk, 0, stream>>>(ew1, eW1w, CC, FFD, (long)CC*FFD, (long)FFD*CC, 0, 1);
        tcvt_kernel<<<g1, tblk, 0, stream>>>(dw1, dW1w, CC, FFD, (long)CC*FFD, (long)FFD*CC, 0, 1);
        dim3 g2(CC / 32, FFD / 32, LL);
        tcvt_kernel<<<g2, tblk, 0, stream>>>(ew2, eW2w, FFD, CC, (long)FFD*CC, (long)CC*FFD, 0, 1);
        tcvt_kernel<<<g2, tblk, 0, stream>>>(dw2, dW2w, FFD, CC, (long)FFD*CC, (long)CC*FFD, 0, 1);
    }

    // small-mode per-use converters
    auto cvt_qkv = [&](const float* Wq, const float* Wk, const float* Wv) {
        dim3 g(HSZ / 32, CC / 32, HH);
        tcvt_kernel<<<g, tblk, 0, stream>>>(Wq, wb,             CC, HSZ, (long)CC*HSZ, (long)HSZ*CC, 0, 1);
        tcvt_kernel<<<g, tblk, 0, stream>>>(Wk, wb + CC*CC,     CC, HSZ, (long)CC*HSZ, (long)HSZ*CC, 0, 1);
        tcvt_kernel<<<g, tblk, 0, stream>>>(Wv, wb + 2*CC*CC,   CC, HSZ, (long)CC*HSZ, (long)HSZ*CC, 0, 1);
    };
    auto cvt_nt = [&](const float* W, int R, int S) {
        dim3 g(S / 32, R / 32, 1);
        tcvt_kernel<<<g, tblk, 0, stream>>>(W, wb, R, S, 0, 0, 0, 1);
    };

    // ---- encoder ----
    embed_kernel<<<MM, 256, 0, stream>>>(x, wte, wpe_x, enc, encb);
    for (int i = 0; i < LL; ++i) {
        const long cOff = (long)i * CC;
        const __hip_bfloat16 *Wqkv, *Wp, *W1, *W2;
        if (big) {
            Wqkv = eQKVw + (size_t)i * 3072 * CC;
            Wp   = ePWw  + (size_t)i * CC * CC;
            W1   = eW1w  + (size_t)i * FFD * CC;
            W2   = eW2w  + (size_t)i * CC * FFD;
        }
        if (!big) cvt_qkv(eWq + (long)i*HH*CC*HSZ, eWk + (long)i*HH*CC*HSZ, eWv + (long)i*HH*CC*HSZ), Wqkv = wb;
        gemm(encb, Wqkv, nullptr, nullptr, qkvb, 3072, CC, 3072, 2, false);
        fattn_kernel<false><<<dim3(QT, HH, BB), 256, 0, stream>>>(qkvb, a0b);
        if (!big) cvt_nt(epw + (long)i*CC*CC, CC, CC), Wp = wb;
        gemm(a0b, Wp, epb + cOff, t0, nullptr, CC, CC, CC, 0, false);
        ln_kernel<<<MM, 256, 0, stream>>>(t0, enc, eln1g + cOff, eln1b + cOff, enc, encb);
        if (!big) cvt_nt(ew1 + (long)i*CC*FFD, CC, FFD), W1 = wb;
        gemm(encb, W1, eb1 + (long)i*FFD, nullptr, ffb, FFD, CC, FFD, 2, true);
        if (!big) cvt_nt(ew2 + (long)i*FFD*CC, FFD, CC), W2 = wb;
        gemm(ffb, W2, eb2 + cOff, t0, nullptr, CC, FFD, CC, 0, false);
        ln_kernel<<<MM, 256, 0, stream>>>(t0, enc, eln2g + cOff, eln2b + cOff, enc, encb);
    }

    // ---- decoder ----
    embed_kernel<<<MM, 256, 0, stream>>>(y, wte, wpe_y, dec, decb);
    for (int i = 0; i < LL; ++i) {
        const long cOff = (long)i * CC;
        const __hip_bfloat16 *Ws, *Wsp, *Wc, *Wcp, *W1, *W2;
        if (big) {
            Ws  = sQKVw + (size_t)i * 3072 * CC;
            Wsp = sPWw  + (size_t)i * CC * CC;
            Wc  = cQKVw + (size_t)i * 3072 * CC;
            Wcp = cPWw  + (size_t)i * CC * CC;
            W1  = dW1w  + (size_t)i * FFD * CC;
            W2  = dW2w  + (size_t)i * CC * FFD;
        }
        // masked self-attn
        if (!big) cvt_qkv(dsWq + (long)i*HH*CC*HSZ, dsWk + (long)i*HH*CC*HSZ, dsWv + (long)i*HH*CC*HSZ), Ws = wb;
        gemm(decb, Ws, nullptr, nullptr, qkvb, 3072, CC, 3072, 2, false);
        fattn_kernel<true><<<dim3(QT, HH, BB), 256, 0, stream>>>(qkvb, a0b);
        if (!big) cvt_nt(dspw + (long)i*CC*CC, CC, CC), Wsp = wb;
        gemm(a0b, Wsp, dspb + cOff, t0, nullptr, CC, CC, CC, 0, false);
        ln_kernel<<<MM, 256, 0, stream>>>(t0, dec, dln1g + cOff, dln1b + cOff, dec, decb);
        // cross-attn: q from dec, k/v from enc
        if (!big) cvt_qkv(dcWq + (long)i*HH*CC*HSZ, dcWk + (long)i*HH*CC*HSZ, dcWv + (long)i*HH*CC*HSZ), Wc = wb;
        gemm(decb, Wc, nullptr, nullptr, qkvb, CC, CC, 3072, 2, false);
        gemm(encb, Wc + (size_t)CC * CC, nullptr, nullptr, qkvb + CC, 2048, CC, 3072, 2, false);
        fattn_kernel<false><<<dim3(QT, HH, BB), 256, 0, stream>>>(qkvb, a0b);
        if (!big) cvt_nt(dcpw + (long)i*CC*CC, CC, CC), Wcp = wb;
        gemm(a0b, Wcp, dcpb + cOff, t0, nullptr, CC, CC, CC, 0, false);
        ln_kernel<<<MM, 256, 0, stream>>>(t0, dec, dln2g + cOff, dln2b + cOff, dec, decb);
        // ffn
        if (!big) cvt_nt(dw1 + (long)i*CC*FFD, CC, FFD), W1 = wb;
        gemm(decb, W1, db1 + (long)i*FFD, nullptr, ffb, FFD, CC, FFD, 2, true);
        if (!big) cvt_nt(dw2 + (long)i*FFD*CC, FFD, CC), W2 = wb;
        gemm(ffb, W2, db2 + cOff, t0, nullptr, CC, FFD, CC, 0, false);
        ln_kernel<<<MM, 256, 0, stream>>>(t0, dec, dln3g + cOff, dln3b + cOff, dec, decb);
    }

    // ---- final LN + logits ----
    ln_kernel<<<MM, 256, 0, stream>>>(dec, nullptr, lnfg, lnfb, t0, t0b);
    if (useWteb) {
        gemm(t0b, wteb, lm_b, out, nullptr, VV, CC, VV, 0, false);
    } else {
        dim3 grid((VV + 127) / 128, GM);
        mgemm_f32b_kernel<<<grid, 256, 0, stream>>>(t0, wte, lm_b, out, MM, VV, CC, VV);
    }
}

// Round 9
// 3442.104 us; speedup vs baseline: 16.8695x; 1.0206x over previous
//
#include <hip/hip_runtime.h>
#include <hip/hip_bf16.h>

#define BB 2
#define TT 1023
#define CC 1024
#define HH 16
#define HSZ 64
#define LL 6
#define FFD 4096
#define VV 50258
#define MM (BB*TT)   // 2046
#define MP 2048      // padded row count
#define VP 50304     // padded vocab (multiple of 128)

typedef __attribute__((ext_vector_type(4))) float  f32x4;
typedef __attribute__((ext_vector_type(8))) short  s16x8;
typedef __attribute__((ext_vector_type(4))) short  s16x4;

#define SCHED0   __builtin_amdgcn_sched_barrier(0)
#define SBAR     __builtin_amdgcn_s_barrier()
#define VMCNT8   asm volatile("s_waitcnt vmcnt(8)" ::: "memory")
#define VMCNT4   asm volatile("s_waitcnt vmcnt(4)" ::: "memory")
#define VMCNT0   asm volatile("s_waitcnt vmcnt(0)" ::: "memory")
#define LGKMCNT0 asm volatile("s_waitcnt lgkmcnt(0)" ::: "memory")

__device__ __forceinline__ short f2b(float x) {
    __hip_bfloat16 h = __float2bfloat16(x);
    short s;
    __builtin_memcpy(&s, &h, 2);
    return s;
}

__device__ __forceinline__ void gld16(const void* g, void* l) {
    __builtin_amdgcn_global_load_lds(
        (__attribute__((address_space(1))) const void*)g,
        (__attribute__((address_space(3))) void*)l, 16, 0, 0);
}

// ---------------------------------------------------------------------------
// Embedding: fp32 + bf16 mirror
// ---------------------------------------------------------------------------
__global__ __launch_bounds__(256) void embed_kernel(
    const int* __restrict__ ids, const float* __restrict__ wte,
    const float* __restrict__ wpe, float* __restrict__ out,
    __hip_bfloat16* __restrict__ outb)
{
    int r = blockIdx.x;
    int t = r % TT;
    long id = ids[r];
    int c = threadIdx.x * 4;
    float4 a = *(const float4*)(wte + id * (long)CC + c);
    float4 p = *(const float4*)(wpe + (long)t * CC + c);
    float4 o; o.x = a.x + p.x; o.y = a.y + p.y; o.z = a.z + p.z; o.w = a.w + p.w;
    *(float4*)(out + (long)r * CC + c) = o;
    s16x4 h; h[0] = f2b(o.x); h[1] = f2b(o.y); h[2] = f2b(o.z); h[3] = f2b(o.w);
    *(s16x4*)(outb + (long)r * CC + c) = h;
}

// ---------------------------------------------------------------------------
// Elementwise fp32 -> bf16
// ---------------------------------------------------------------------------
__global__ __launch_bounds__(256) void cvtb_kernel(
    const float* __restrict__ in, __hip_bfloat16* __restrict__ out, long n)
{
    long i = ((long)blockIdx.x * 256 + threadIdx.x) * 8;
    if (i >= n) return;
    float4 f0 = *(const float4*)(in + i);
    float4 f1 = *(const float4*)(in + i + 4);
    s16x8 h;
    h[0]=f2b(f0.x); h[1]=f2b(f0.y); h[2]=f2b(f0.z); h[3]=f2b(f0.w);
    h[4]=f2b(f1.x); h[5]=f2b(f1.y); h[6]=f2b(f1.z); h[7]=f2b(f1.w);
    *(s16x8*)(out + i) = h;
}

// ---------------------------------------------------------------------------
// Transpose + fp32->bf16: in [R][S] fp32 -> out [S][R] bf16, batched over z.
// out offset = (z/zdiv)*outZa + (z%zdiv)*outZb ; in offset = z*inZ.
// ---------------------------------------------------------------------------
__global__ __launch_bounds__(256) void tcvt_kernel(
    const float* __restrict__ in, __hip_bfloat16* __restrict__ out,
    int R, int S, long inZ, long outZa, long outZb, int zdiv)
{
    int z = blockIdx.z;
    in  += (long)z * inZ;
    out += (long)(z / zdiv) * outZa + (long)(z % zdiv) * outZb;
    __shared__ float tile[32][33];
    int s0 = blockIdx.x * 32, r0 = blockIdx.y * 32;
    int tx = threadIdx.x, ty = threadIdx.y;
    #pragma unroll
    for (int i = 0; i < 4; ++i)
        tile[ty + i * 8][tx] = in[(long)(r0 + ty + i * 8) * S + s0 + tx];
    __syncthreads();
    #pragma unroll
    for (int i = 0; i < 4; ++i)
        out[(long)(s0 + ty + i * 8) * R + r0 + tx] =
            __float2bfloat16(tile[tx][ty + i * 8]);
}

// ---------------------------------------------------------------------------
// bf16 MFMA GEMM, T3+T4 pipelined: BK=32, THREE LDS buffers (48 KB),
// 2-deep prefetch with counted s_waitcnt vmcnt(8) (never 0 in loop) + raw
// s_barrier. T5 setprio around MFMA.
// T2 XOR-swizzle (global_load_lds-compatible, rule #21): LDS stays linear,
// the GLOBAL source address carries the permutation. LDS[row][slot] holds
// global col-chunk (slot ^ ((row>>1)&3)); fragment reads use
// slot = kg ^ ((lr>>1)&3). Both XOR terms are per-lane constants.
// C = act(A @ B^T + bias). A [pad(M,128)][K] bf16, B [pad(N,128)][K] bf16,
// K % 32 == 0. 128x128 tile, 4 waves (2x2).
// WMODE: 0 = fp32 out (float2-coalesced), 2 = bf16 out (b128-coalesced).
// ---------------------------------------------------------------------------
template<int WMODE, bool RELU>
__global__ __launch_bounds__(256) void mgemm2_kernel(
    const __hip_bfloat16* __restrict__ A, const __hip_bfloat16* __restrict__ B,
    const float* __restrict__ bias, float* __restrict__ Cm,
    __hip_bfloat16* __restrict__ Cb,
    int M, int N, int K, int ldc, int GM)
{
    __shared__ short LDS[3][2][4096];   // [3buf][A/B][128*32] = 48 KB

    // bijective XCD swizzle + m-fastest decode
    const int nwg = gridDim.x;
    const int bid = blockIdx.x;
    const int q = nwg >> 3, r = nwg & 7;
    const int xcd = bid & 7, lid = bid >> 3;
    const int swz = (xcd < r) ? xcd * (q + 1) + lid
                              : r * (q + 1) + (xcd - r) * q + lid;
    const int m0 = (swz % GM) * 128;
    const int n0 = (swz / GM) * 128;

    const int tid  = threadIdx.x;
    const int lane = tid & 63, w = tid >> 6;
    const int wr = w >> 1, wc = w & 1;
    const int lr = lane & 15, kg = lane >> 4;

    const __hip_bfloat16* Abase = A + (long)m0 * K;
    const __hip_bfloat16* Bbase = B + (long)n0 * K;

    f32x4 acc[4][4];
    #pragma unroll
    for (int i = 0; i < 4; ++i)
        #pragma unroll
        for (int j = 0; j < 4; ++j)
            acc[i][j] = (f32x4){0.f, 0.f, 0.f, 0.f};

    // staging geometry: tile 128x32 bf16 = 8 chunks of 512 elems (1 KB).
    // chunk cc covers rows cc*16..+15. LDS[row][slot] (slot = lane&3, 16B)
    // receives GLOBAL col-chunk slot ^ ((row>>1)&3); with row = cc*16 +
    // (lane>>2), the XOR term is (lane>>3)&3 — per-lane constant.
    const int srow = lane >> 2;
    const int scol = (((lane & 3) ^ ((lane >> 3) & 3))) * 8;   // swizzled src

    auto stage = [&](int db, long kofs) {
        short* Ad = &LDS[db][0][0];
        short* Bd = &LDS[db][1][0];
        #pragma unroll
        for (int p = 0; p < 2; ++p) {
            int cc = p * 4 + w;
            long ro = (long)(cc * 16 + srow) * K + kofs + scol;
            gld16(Abase + ro, Ad + cc * 512);
            gld16(Bbase + ro, Bd + cc * 512);
        }
    };
    // fragment read: want global chunk kg of row; stored at slot kg ^ xv,
    // xv = ((row>>1)&3) = ((lr>>1)&3) for our rows (i*16 keeps bits clear).
    const int xv = (lr >> 1) & 3;
    const int rslot = (kg ^ xv) * 8;

    auto compute = [&](int db) {
        const short* Ar = &LDS[db][0][0];
        const short* Br = &LDS[db][1][0];
        s16x8 af[4], bf[4];
        #pragma unroll
        for (int i = 0; i < 4; ++i)
            af[i] = *(const s16x8*)&Ar[(wr * 64 + i * 16 + lr) * 32 + rslot];
        #pragma unroll
        for (int j = 0; j < 4; ++j)
            bf[j] = *(const s16x8*)&Br[(wc * 64 + j * 16 + lr) * 32 + rslot];
        __builtin_amdgcn_s_setprio(1);
        #pragma unroll
        for (int i = 0; i < 4; ++i)
            #pragma unroll
            for (int j = 0; j < 4; ++j)
                acc[i][j] = __builtin_amdgcn_mfma_f32_16x16x32_bf16(
                    af[i], bf[j], acc[i][j], 0, 0, 0);
        __builtin_amdgcn_s_setprio(0);
    };

    const int nt = K >> 5;
    stage(0, 0);
    if (nt > 1) stage(1, 32);
    int db = 0;
    for (int t = 0; t < nt; ++t) {
        if (t + 2 < nt) {
            stage((db + 2) % 3, (long)(t + 2) << 5);   // keep 2 stages ahead
            SCHED0; VMCNT8; SCHED0;                    // wait stage t only
        } else if (t + 1 < nt) {
            SCHED0; VMCNT4; SCHED0;                    // drain: 1 stage left
        } else {
            SCHED0; VMCNT0; SCHED0;                    // drain: last stage
        }
        SBAR; SCHED0;                                  // stage t visible to all
        compute(db);
        SCHED0; LGKMCNT0; SCHED0; SBAR; SCHED0;        // reads done pre-overwrite
        db = (db + 1) % 3;
    }

    // ---- epilogue: stage C tile through LDS for coalesced stores ----
    if (WMODE == 0) {
        float* LF = (float*)&LDS[0][0][0];     // [128][64] fp32 = 32 KB
        #pragma unroll
        for (int h = 0; h < 2; ++h) {
            if (wc == h) {
                #pragma unroll
                for (int j = 0; j < 4; ++j) {
                    int gcol = n0 + h * 64 + j * 16 + lr;
                    float bv = (bias && gcol < N) ? bias[gcol] : 0.f;
                    #pragma unroll
                    for (int i = 0; i < 4; ++i) {
                        int row0 = wr * 64 + i * 16 + kg * 4;
                        #pragma unroll
                        for (int qq = 0; qq < 4; ++qq) {
                            float v = acc[i][j][qq] + bv;
                            if (RELU) v = fmaxf(v, 0.f);
                            LF[(row0 + qq) * 64 + j * 16 + lr] = v;
                        }
                    }
                }
            }
            __syncthreads();
            #pragma unroll
            for (int i = 0; i < 16; ++i) {
                int F = i * 256 + tid;               // float2 index
                int row = F >> 5, col = (F & 31) * 2;
                int gr = m0 + row, gc = n0 + h * 64 + col;
                if (gr < M && gc < N)
                    *(float2*)(Cm + (long)gr * ldc + gc) = *(const float2*)&LF[row * 64 + col];
            }
            __syncthreads();
        }
    } else {
        short* LS = (short*)&LDS[0][0][0];     // [128][128] bf16 = 32 KB
        #pragma unroll
        for (int j = 0; j < 4; ++j) {
            int gcol = n0 + wc * 64 + j * 16 + lr;
            float bv = (bias && gcol < N) ? bias[gcol] : 0.f;
            #pragma unroll
            for (int i = 0; i < 4; ++i) {
                int row0 = wr * 64 + i * 16 + kg * 4;
                #pragma unroll
                for (int qq = 0; qq < 4; ++qq) {
                    float v = acc[i][j][qq] + bv;
                    if (RELU) v = fmaxf(v, 0.f);
                    LS[(row0 + qq) * 128 + wc * 64 + j * 16 + lr] = f2b(v);
                }
            }
        }
        __syncthreads();
        #pragma unroll
        for (int i = 0; i < 8; ++i) {
            int F = i * 256 + tid;                   // s16x8 index
            int row = F >> 4, col = (F & 15) * 8;
            int gr = m0 + row, gc = n0 + col;
            if (gr < M && gc < N)
                *(s16x8*)((short*)Cb + (long)gr * ldc + gc) = *(const s16x8*)&LS[row * 128 + col];
        }
    }
}

// ---------------------------------------------------------------------------
// Fallback fp32-B GEMM (logits only, if ws too small for bf16 wte mirror).
// ---------------------------------------------------------------------------
__global__ __launch_bounds__(256) void mgemm_f32b_kernel(
    const float* __restrict__ A, const float* __restrict__ Bv,
    const float* __restrict__ bias, float* __restrict__ Cm,
    int M, int N, int K, int ldc)
{
    __shared__ short As[128][40];
    __shared__ short Bs[128][40];
    const int tid  = threadIdx.x;
    const int lane = tid & 63, w = tid >> 6;
    const int wr = w >> 1, wc = w & 1;
    const int lr = lane & 15, kg = lane >> 4;
    const int m0 = blockIdx.y * 128, n0 = blockIdx.x * 128;
    const int ar = tid >> 3, ac = (tid & 7) * 4;
    const int br = tid >> 2, bc = (tid & 3) * 8;

    f32x4 acc[4][4];
    #pragma unroll
    for (int i = 0; i < 4; ++i)
        #pragma unroll
        for (int j = 0; j < 4; ++j)
            acc[i][j] = (f32x4){0.f, 0.f, 0.f, 0.f};

    for (int k0 = 0; k0 < K; k0 += 32) {
        #pragma unroll
        for (int p = 0; p < 4; ++p) {
            int row = ar + p * 32, gm = m0 + row;
            float4 f = {0.f, 0.f, 0.f, 0.f};
            if (gm < M) f = *(const float4*)(A + (long)gm * K + k0 + ac);
            s16x4 h; h[0] = f2b(f.x); h[1] = f2b(f.y); h[2] = f2b(f.z); h[3] = f2b(f.w);
            *(s16x4*)&As[row][ac] = h;
        }
        #pragma unroll
        for (int p = 0; p < 2; ++p) {
            int n = br + p * 64, gn = n0 + n;
            s16x8 h = (s16x8){0,0,0,0,0,0,0,0};
            if (gn < N) {
                float4 f0 = *(const float4*)(Bv + (long)gn * K + k0 + bc);
                float4 f1 = *(const float4*)(Bv + (long)gn * K + k0 + bc + 4);
                h[0]=f2b(f0.x); h[1]=f2b(f0.y); h[2]=f2b(f0.z); h[3]=f2b(f0.w);
                h[4]=f2b(f1.x); h[5]=f2b(f1.y); h[6]=f2b(f1.z); h[7]=f2b(f1.w);
            }
            *(s16x8*)&Bs[n][bc] = h;
        }
        __syncthreads();
        s16x8 af[4], bf[4];
        #pragma unroll
        for (int i = 0; i < 4; ++i) af[i] = *(const s16x8*)&As[wr*64 + i*16 + lr][kg*8];
        #pragma unroll
        for (int j = 0; j < 4; ++j) bf[j] = *(const s16x8*)&Bs[wc*64 + j*16 + lr][kg*8];
        #pragma unroll
        for (int i = 0; i < 4; ++i)
            #pragma unroll
            for (int j = 0; j < 4; ++j)
                acc[i][j] = __builtin_amdgcn_mfma_f32_16x16x32_bf16(af[i], bf[j], acc[i][j], 0, 0, 0);
        __syncthreads();
    }
    #pragma unroll
    for (int j = 0; j < 4; ++j) {
        int gcol = n0 + wc * 64 + j * 16 + lr;
        if (gcol >= N) continue;
        float bv = bias ? bias[gcol] : 0.f;
        #pragma unroll
        for (int i = 0; i < 4; ++i) {
            int grow0 = m0 + wr * 64 + i * 16 + kg * 4;
            #pragma unroll
            for (int qq = 0; qq < 4; ++qq) {
                int gr = grow0 + qq;
                if (gr >= M) continue;
                Cm[(long)gr * ldc + gcol] = acc[i][j][qq] + bv;
            }
        }
    }
}

// ---------------------------------------------------------------------------
// MFMA flash attention (bf16 in / bf16 out). grid (16, H, B), 4 waves.
// T14 async-split: K/V prefetched to REGISTERS one tile ahead; raw s_barrier
// (not __syncthreads) so the reg-prefetch loads are NOT drained at barriers.
// qkvb: [M,3072] bf16 (q|k|v, head h at col h*64). outb: [M,C] bf16.
// scale = 1/sqrt(C) = 1/32 (reference quirk).
// ---------------------------------------------------------------------------
template<bool CAUSAL>
__global__ __launch_bounds__(256) void fattn_kernel(
    const __hip_bfloat16* __restrict__ qkvb, __hip_bfloat16* __restrict__ outb)
{
    __shared__ short Ks[64][72];
    __shared__ short Vt[64][72];
    __shared__ short Ps[4][16][72];

    const int q0 = blockIdx.x * 64;
    const int h = blockIdx.y, b = blockIdx.z;
    const int tid = threadIdx.x;
    const int lane = tid & 63, w = tid >> 6;
    const int lr = lane & 15, lg = lane >> 4;

    const float scale = 1.0f / 32.0f;
    const long base = (long)b * TT * 3072;
    const __hip_bfloat16* Kg = qkvb + base + 1024 + h * 64;
    const __hip_bfloat16* Vg = qkvb + base + 2048 + h * 64;

    s16x8 qf[2];
    {
        int qr = q0 + w * 16 + lr;
        #pragma unroll
        for (int kc = 0; kc < 2; ++kc) {
            s16x8 hv = (s16x8){0,0,0,0,0,0,0,0};
            if (qr < TT)
                hv = *(const s16x8*)(qkvb + base + (long)qr * 3072 + h * 64 + kc * 32 + lg * 8);
            qf[kc] = hv;
        }
    }

    f32x4 acc[4];
    #pragma unroll
    for (int jd = 0; jd < 4; ++jd) acc[jd] = (f32x4){0.f, 0.f, 0.f, 0.f};
    float mrun[4] = {-3.0e38f, -3.0e38f, -3.0e38f, -3.0e38f};
    float lrun[4] = {0.f, 0.f, 0.f, 0.f};

    const int send = CAUSAL ? min(TT, q0 + 64) : TT;
    const int nt = (send + 63) >> 6;
    const int sr2 = (tid >> 3) * 2;        // rows sr2, sr2+1
    const int dcc = (tid & 7) * 8;         // col chunk

    s16x8 kreg[2], vreg[2];
    auto loadkv = [&](int t) {
        int sbase = t * 64;
        #pragma unroll
        for (int rr = 0; rr < 2; ++rr) {
            int sg = sbase + sr2 + rr;
            if (sg < TT) {
                kreg[rr] = *(const s16x8*)(Kg + (long)sg * 3072 + dcc);
                vreg[rr] = *(const s16x8*)(Vg + (long)sg * 3072 + dcc);
            } else {
                kreg[rr] = (s16x8){0,0,0,0,0,0,0,0};
                vreg[rr] = (s16x8){0,0,0,0,0,0,0,0};
            }
        }
    };

    loadkv(0);
    for (int ti = 0; ti < nt; ++ti) {
        const int s0 = ti * 64;
        SCHED0; SBAR; SCHED0;          // prev tile's LDS reads done (all waves)
        // write prefetched regs -> LDS (compiler waits vmcnt only on these regs)
        *(s16x8*)&Ks[sr2][dcc]     = kreg[0];
        *(s16x8*)&Ks[sr2 + 1][dcc] = kreg[1];
        #pragma unroll
        for (int e = 0; e < 8; ++e) {
            unsigned pack = (unsigned)(unsigned short)vreg[0][e]
                          | ((unsigned)(unsigned short)vreg[1][e] << 16);
            *(unsigned*)&Vt[dcc + e][sr2] = pack;
        }
        if (ti + 1 < nt) loadkv(ti + 1);   // issue next tile's loads early
        SCHED0; LGKMCNT0; SCHED0; SBAR; SCHED0;   // LDS writes visible

        f32x4 sf[4];
        __builtin_amdgcn_s_setprio(1);
        #pragma unroll
        for (int j = 0; j < 4; ++j) {
            f32x4 z = (f32x4){0.f, 0.f, 0.f, 0.f};
            #pragma unroll
            for (int kc = 0; kc < 2; ++kc) {
                s16x8 kf = *(const s16x8*)&Ks[j * 16 + lr][kc * 32 + lg * 8];
                z = __builtin_amdgcn_mfma_f32_16x16x32_bf16(qf[kc], kf, z, 0, 0, 0);
            }
            sf[j] = z;
        }
        __builtin_amdgcn_s_setprio(0);

        float mloc[4] = {-3.0e38f, -3.0e38f, -3.0e38f, -3.0e38f};
        #pragma unroll
        for (int j = 0; j < 4; ++j) {
            int sg = s0 + j * 16 + lr;
            #pragma unroll
            for (int r = 0; r < 4; ++r) {
                float sc = sf[j][r] * scale;
                int qg = q0 + w * 16 + lg * 4 + r;
                if ((CAUSAL && sg > qg) || sg >= TT) sc = -3.0e38f;
                sf[j][r] = sc;
                mloc[r] = fmaxf(mloc[r], sc);
            }
        }
        #pragma unroll
        for (int r = 0; r < 4; ++r)
            #pragma unroll
            for (int off = 1; off < 16; off <<= 1)
                mloc[r] = fmaxf(mloc[r], __shfl_xor(mloc[r], off));

        float corr[4], psum[4];
        #pragma unroll
        for (int r = 0; r < 4; ++r) {
            float mn = fmaxf(mrun[r], mloc[r]);
            corr[r] = __expf(mrun[r] - mn);
            mrun[r] = mn;
            psum[r] = 0.f;
        }

        #pragma unroll
        for (int j = 0; j < 4; ++j) {
            #pragma unroll
            for (int r = 0; r < 4; ++r) {
                float p = __expf(sf[j][r] - mrun[r]);
                psum[r] += p;
                Ps[w][lg * 4 + r][j * 16 + lr] = f2b(p);
            }
        }
        #pragma unroll
        for (int r = 0; r < 4; ++r) {
            #pragma unroll
            for (int off = 1; off < 16; off <<= 1)
                psum[r] += __shfl_xor(psum[r], off);
            lrun[r] = lrun[r] * corr[r] + psum[r];
            #pragma unroll
            for (int jd = 0; jd < 4; ++jd) acc[jd][r] *= corr[r];
        }

        __builtin_amdgcn_s_setprio(1);
        #pragma unroll
        for (int kc = 0; kc < 2; ++kc) {
            s16x8 pa = *(const s16x8*)&Ps[w][lr][kc * 32 + lg * 8];
            #pragma unroll
            for (int jd = 0; jd < 4; ++jd) {
                s16x8 bv = *(const s16x8*)&Vt[jd * 16 + lr][kc * 32 + lg * 8];
                acc[jd] = __builtin_amdgcn_mfma_f32_16x16x32_bf16(pa, bv, acc[jd], 0, 0, 0);
            }
        }
        __builtin_amdgcn_s_setprio(0);
        SCHED0; LGKMCNT0; SCHED0;      // my LDS reads complete before next write
    }

    #pragma unroll
    for (int r = 0; r < 4; ++r) {
        int qg = q0 + w * 16 + lg * 4 + r;
        if (qg >= TT) continue;
        float inv = 1.0f / lrun[r];
        #pragma unroll
        for (int jd = 0; jd < 4; ++jd)
            outb[((long)b * TT + qg) * CC + h * 64 + jd * 16 + lr] =
                __float2bfloat16(acc[jd][r] * inv);
    }
}

// ---------------------------------------------------------------------------
// LayerNorm (+optional residual), fp32 out + optional bf16 mirror.
// ---------------------------------------------------------------------------
__global__ __launch_bounds__(256) void ln_kernel(
    const float* __restrict__ in, const float* __restrict__ res,
    const float* __restrict__ g, const float* __restrict__ b,
    float* __restrict__ out, __hip_bfloat16* __restrict__ outb)
{
    const int r = blockIdx.x, tid = threadIdx.x;
    __shared__ float sm[4];

    float4 xv = *(const float4*)(in + (long)r * CC + tid * 4);
    float s = xv.x + xv.y + xv.z + xv.w;
    #pragma unroll
    for (int o = 32; o > 0; o >>= 1) s += __shfl_xor(s, o);
    if ((tid & 63) == 0) sm[tid >> 6] = s;
    __syncthreads();
    const float mean = (sm[0] + sm[1] + sm[2] + sm[3]) * (1.0f / CC);
    __syncthreads();

    float4 d; d.x = xv.x - mean; d.y = xv.y - mean; d.z = xv.z - mean; d.w = xv.w - mean;
    float s2 = d.x * d.x + d.y * d.y + d.z * d.z + d.w * d.w;
    #pragma unroll
    for (int o = 32; o > 0; o >>= 1) s2 += __shfl_xor(s2, o);
    if ((tid & 63) == 0) sm[tid >> 6] = s2;
    __syncthreads();
    const float rstd = rsqrtf((sm[0] + sm[1] + sm[2] + sm[3]) * (1.0f / CC) + 1e-5f);

    float4 gv = *(const float4*)(g + tid * 4);
    float4 bv = *(const float4*)(b + tid * 4);
    float4 o;
    o.x = gv.x * d.x * rstd + bv.x; o.y = gv.y * d.y * rstd + bv.y;
    o.z = gv.z * d.z * rstd + bv.z; o.w = gv.w * d.w * rstd + bv.w;
    if (res) {
        float4 rv = *(const float4*)(res + (long)r * CC + tid * 4);
        o.x += rv.x; o.y += rv.y; o.z += rv.z; o.w += rv.w;
    }
    *(float4*)(out + (long)r * CC + tid * 4) = o;
    if (outb) {
        s16x4 h; h[0] = f2b(o.x); h[1] = f2b(o.y); h[2] = f2b(o.z); h[3] = f2b(o.w);
        *(s16x4*)(outb + (long)r * CC + tid * 4) = h;
    }
}

// ---------------------------------------------------------------------------
extern "C" void kernel_launch(void* const* d_in, const int* in_sizes, int n_in,
                              void* d_out, int out_size, void* d_ws, size_t ws_size,
                              hipStream_t stream)
{
    const int*   x      = (const int*)  d_in[0];
    const int*   y      = (const int*)  d_in[1];
    const float* wte    = (const float*)d_in[2];
    const float* wpe_x  = (const float*)d_in[3];
    const float* wpe_y  = (const float*)d_in[4];
    const float* eWq    = (const float*)d_in[5];
    const float* eWk    = (const float*)d_in[6];
    const float* eWv    = (const float*)d_in[7];
    const float* epw    = (const float*)d_in[8];
    const float* epb    = (const float*)d_in[9];
    const float* eln1g  = (const float*)d_in[10];
    const float* eln1b  = (const float*)d_in[11];
    const float* eln2g  = (const float*)d_in[12];
    const float* eln2b  = (const float*)d_in[13];
    const float* ew1    = (const float*)d_in[14];
    const float* eb1    = (const float*)d_in[15];
    const float* ew2    = (const float*)d_in[16];
    const float* eb2    = (const float*)d_in[17];
    const float* dsWq   = (const float*)d_in[18];
    const float* dsWk   = (const float*)d_in[19];
    const float* dsWv   = (const float*)d_in[20];
    const float* dspw   = (const float*)d_in[21];
    const float* dspb   = (const float*)d_in[22];
    const float* dcWq   = (const float*)d_in[23];
    const float* dcWk   = (const float*)d_in[24];
    const float* dcWv   = (const float*)d_in[25];
    const float* dcpw   = (const float*)d_in[26];
    const float* dcpb   = (const float*)d_in[27];
    const float* dln1g  = (const float*)d_in[28];
    const float* dln1b  = (const float*)d_in[29];
    const float* dln2g  = (const float*)d_in[30];
    const float* dln2b  = (const float*)d_in[31];
    const float* dln3g  = (const float*)d_in[32];
    const float* dln3b  = (const float*)d_in[33];
    const float* dw1    = (const float*)d_in[34];
    const float* db1    = (const float*)d_in[35];
    const float* dw2    = (const float*)d_in[36];
    const float* db2    = (const float*)d_in[37];
    const float* lnfg   = (const float*)d_in[38];
    const float* lnfb   = (const float*)d_in[39];
    const float* lm_b   = (const float*)d_in[40];

    float* out = (float*)d_out;

    // ---- workspace carve-up ----
    const size_t MCp = (size_t)MP * CC;
    float* enc = (float*)d_ws;
    float* dec = enc + MCp;
    float* t0  = dec + MCp;
    __hip_bfloat16* encb = (__hip_bfloat16*)(t0 + MCp);
    __hip_bfloat16* decb = encb + MCp;
    __hip_bfloat16* t0b  = decb + MCp;
    __hip_bfloat16* a0b  = t0b + MCp;
    __hip_bfloat16* qkvb = a0b + MCp;                    // [MP][3072]
    __hip_bfloat16* ffb  = qkvb + (size_t)MP * 3072;     // [MP][FFD]
    __hip_bfloat16* wteb = ffb + (size_t)MP * FFD;       // [VP][C]
    // big-mode weight blocks
    __hip_bfloat16* eQKVw = wteb + (size_t)VP * CC;      // [L][3072][C]
    __hip_bfloat16* ePWw  = eQKVw + (size_t)LL * 3072 * CC;
    __hip_bfloat16* eW1w  = ePWw  + (size_t)LL * CC * CC;     // [L][FFD][C]
    __hip_bfloat16* eW2w  = eW1w  + (size_t)LL * FFD * CC;    // [L][C][FFD]
    __hip_bfloat16* sQKVw = eW2w  + (size_t)LL * CC * FFD;
    __hip_bfloat16* sPWw  = sQKVw + (size_t)LL * 3072 * CC;
    __hip_bfloat16* cQKVw = sPWw  + (size_t)LL * CC * CC;
    __hip_bfloat16* cPWw  = cQKVw + (size_t)LL * 3072 * CC;
    __hip_bfloat16* dW1w  = cPWw  + (size_t)LL * CC * CC;
    __hip_bfloat16* dW2w  = dW1w  + (size_t)LL * FFD * CC;
    __hip_bfloat16* bigEnd = dW2w + (size_t)LL * CC * FFD;
    // small-mode: per-use conversion buffer where eQKVw starts
    __hip_bfloat16* wb = eQKVw;
    const size_t needBig   = (size_t)((char*)bigEnd - (char*)d_ws);
    const size_t needSmall = (size_t)((char*)(wb + (size_t)FFD * CC) - (char*)d_ws);
    const size_t needWteb  = (size_t)((char*)eQKVw - (char*)d_ws);
    const bool big     = (ws_size >= needBig);
    const bool useWteb = (ws_size >= needWteb) &&
                         (big || ws_size >= needSmall);

    const int GM = MP / 128;           // 16 m-tiles
    const int QT = (TT + 63) / 64;     // 16 q-tiles
    const dim3 tblk(32, 8);

    auto gemm = [&](const __hip_bfloat16* A, const __hip_bfloat16* B,
                    const float* bias, float* Cm, __hip_bfloat16* Cb,
                    int N_, int K_, int ldc, int wmode, bool relu) {
        int nwg = GM * ((N_ + 127) / 128);
        if (wmode == 0) {
            if (relu) mgemm2_kernel<0, true ><<<nwg, 256, 0, stream>>>(A, B, bias, Cm, Cb, MM, N_, K_, ldc, GM);
            else      mgemm2_kernel<0, false><<<nwg, 256, 0, stream>>>(A, B, bias, Cm, Cb, MM, N_, K_, ldc, GM);
        } else {
            if (relu) mgemm2_kernel<2, true ><<<nwg, 256, 0, stream>>>(A, B, bias, Cm, Cb, MM, N_, K_, ldc, GM);
            else      mgemm2_kernel<2, false><<<nwg, 256, 0, stream>>>(A, B, bias, Cm, Cb, MM, N_, K_, ldc, GM);
        }
    };

    if (useWteb) {
        long n = (long)VV * CC;
        cvtb_kernel<<<(int)((n / 8 + 255) / 256), 256, 0, stream>>>(wte, wteb, n);
    }

    if (big) {
        // ---- all weight conversions up-front ----
        const long sWH = (long)CC * HSZ;            // per-(l,h) input stride
        const long oA = (long)3072 * CC;            // per-layer qkv out stride
        const long oB = (long)HSZ * CC;             // per-head out stride
        dim3 gq(HSZ / 32, CC / 32, LL * HH);
        tcvt_kernel<<<gq, tblk, 0, stream>>>(eWq, eQKVw,             CC, HSZ, sWH, oA, oB, HH);
        tcvt_kernel<<<gq, tblk, 0, stream>>>(eWk, eQKVw + CC * CC,   CC, HSZ, sWH, oA, oB, HH);
        tcvt_kernel<<<gq, tblk, 0, stream>>>(eWv, eQKVw + 2*CC*CC,   CC, HSZ, sWH, oA, oB, HH);
        tcvt_kernel<<<gq, tblk, 0, stream>>>(dsWq, sQKVw,            CC, HSZ, sWH, oA, oB, HH);
        tcvt_kernel<<<gq, tblk, 0, stream>>>(dsWk, sQKVw + CC * CC,  CC, HSZ, sWH, oA, oB, HH);
        tcvt_kernel<<<gq, tblk, 0, stream>>>(dsWv, sQKVw + 2*CC*CC,  CC, HSZ, sWH, oA, oB, HH);
        tcvt_kernel<<<gq, tblk, 0, stream>>>(dcWq, cQKVw,            CC, HSZ, sWH, oA, oB, HH);
        tcvt_kernel<<<gq, tblk, 0, stream>>>(dcWk, cQKVw + CC * CC,  CC, HSZ, sWH, oA, oB, HH);
        tcvt_kernel<<<gq, tblk, 0, stream>>>(dcWv, cQKVw + 2*CC*CC,  CC, HSZ, sWH, oA, oB, HH);
        dim3 gp(CC / 32, CC / 32, LL);
        tcvt_kernel<<<gp, tblk, 0, stream>>>(epw,  ePWw, CC, CC, (long)CC*CC, (long)CC*CC, 0, 1);
        tcvt_kernel<<<gp, tblk, 0, stream>>>(dspw, sPWw, CC, CC, (long)CC*CC, (long)CC*CC, 0, 1);
        tcvt_kernel<<<gp, tblk, 0, stream>>>(dcpw, cPWw, CC, CC, (long)CC*CC, (long)CC*CC, 0, 1);
        dim3 g1(FFD / 32, CC / 32, LL);
        tcvt_kernel<<<g1, tblk, 0, stream>>>(ew1, eW1w, CC, FFD, (long)CC*FFD, (long)FFD*CC, 0, 1);
        tcvt_kernel<<<g1, tblk, 0, stream>>>(dw1, dW1w, CC, FFD, (long)CC*FFD, (long)FFD*CC, 0, 1);
        dim3 g2(CC / 32, FFD / 32, LL);
        tcvt_kernel<<<g2, tblk, 0, stream>>>(ew2, eW2w, FFD, CC, (long)FFD*CC, (long)CC*FFD, 0, 1);
        tcvt_kernel<<<g2, tblk, 0, stream>>>(dw2, dW2w, FFD, CC, (long)FFD*CC, (long)CC*FFD, 0, 1);
    }

    // small-mode per-use converters
    auto cvt_qkv = [&](const float* Wq, const float* Wk, const float* Wv) {
        dim3 g(HSZ / 32, CC / 32, HH);
        tcvt_kernel<<<g, tblk, 0, stream>>>(Wq, wb,             CC, HSZ, (long)CC*HSZ, (long)HSZ*CC, 0, 1);
        tcvt_kernel<<<g, tblk, 0, stream>>>(Wk, wb + CC*CC,     CC, HSZ, (long)CC*HSZ, (long)HSZ*CC, 0, 1);
        tcvt_kernel<<<g, tblk, 0, stream>>>(Wv, wb + 2*CC*CC,   CC, HSZ, (long)CC*HSZ, (long)HSZ*CC, 0, 1);
    };
    auto cvt_nt = [&](const float* W, int R, int S) {
        dim3 g(S / 32, R / 32, 1);
        tcvt_kernel<<<g, tblk, 0, stream>>>(W, wb, R, S, 0, 0, 0, 1);
    };

    // ---- encoder ----
    embed_kernel<<<MM, 256, 0, stream>>>(x, wte, wpe_x, enc, encb);
    for (int i = 0; i < LL; ++i) {
        const long cOff = (long)i * CC;
        const __hip_bfloat16 *Wqkv, *Wp, *W1, *W2;
        if (big) {
            Wqkv = eQKVw + (size_t)i * 3072 * CC;
            Wp   = ePWw  + (size_t)i * CC * CC;
            W1   = eW1w  + (size_t)i * FFD * CC;
            W2   = eW2w  + (size_t)i * CC * FFD;
        }
        if (!big) cvt_qkv(eWq + (long)i*HH*CC*HSZ, eWk + (long)i*HH*CC*HSZ, eWv + (long)i*HH*CC*HSZ), Wqkv = wb;
        gemm(encb, Wqkv, nullptr, nullptr, qkvb, 3072, CC, 3072, 2, false);
        fattn_kernel<false><<<dim3(QT, HH, BB), 256, 0, stream>>>(qkvb, a0b);
        if (!big) cvt_nt(epw + (long)i*CC*CC, CC, CC), Wp = wb;
        gemm(a0b, Wp, epb + cOff, t0, nullptr, CC, CC, CC, 0, false);
        ln_kernel<<<MM, 256, 0, stream>>>(t0, enc, eln1g + cOff, eln1b + cOff, enc, encb);
        if (!big) cvt_nt(ew1 + (long)i*CC*FFD, CC, FFD), W1 = wb;
        gemm(encb, W1, eb1 + (long)i*FFD, nullptr, ffb, FFD, CC, FFD, 2, true);
        if (!big) cvt_nt(ew2 + (long)i*FFD*CC, FFD, CC), W2 = wb;
        gemm(ffb, W2, eb2 + cOff, t0, nullptr, CC, FFD, CC, 0, false);
        ln_kernel<<<MM, 256, 0, stream>>>(t0, enc, eln2g + cOff, eln2b + cOff, enc, encb);
    }

    // ---- decoder ----
    embed_kernel<<<MM, 256, 0, stream>>>(y, wte, wpe_y, dec, decb);
    for (int i = 0; i < LL; ++i) {
        const long cOff = (long)i * CC;
        const __hip_bfloat16 *Ws, *Wsp, *Wc, *Wcp, *W1, *W2;
        if (big) {
            Ws  = sQKVw + (size_t)i * 3072 * CC;
            Wsp = sPWw  + (size_t)i * CC * CC;
            Wc  = cQKVw + (size_t)i * 3072 * CC;
            Wcp = cPWw  + (size_t)i * CC * CC;
            W1  = dW1w  + (size_t)i * FFD * CC;
            W2  = dW2w  + (size_t)i * CC * FFD;
        }
        // masked self-attn
        if (!big) cvt_qkv(dsWq + (long)i*HH*CC*HSZ, dsWk + (long)i*HH*CC*HSZ, dsWv + (long)i*HH*CC*HSZ), Ws = wb;
        gemm(decb, Ws, nullptr, nullptr, qkvb, 3072, CC, 3072, 2, false);
        fattn_kernel<true><<<dim3(QT, HH, BB), 256, 0, stream>>>(qkvb, a0b);
        if (!big) cvt_nt(dspw + (long)i*CC*CC, CC, CC), Wsp = wb;
        gemm(a0b, Wsp, dspb + cOff, t0, nullptr, CC, CC, CC, 0, false);
        ln_kernel<<<MM, 256, 0, stream>>>(t0, dec, dln1g + cOff, dln1b + cOff, dec, decb);
        // cross-attn: q from dec, k/v from enc
        if (!big) cvt_qkv(dcWq + (long)i*HH*CC*HSZ, dcWk + (long)i*HH*CC*HSZ, dcWv + (long)i*HH*CC*HSZ), Wc = wb;
        gemm(decb, Wc, nullptr, nullptr, qkvb, CC, CC, 3072, 2, false);
        gemm(encb, Wc + (size_t)CC * CC, nullptr, nullptr, qkvb + CC, 2048, CC, 3072, 2, false);
        fattn_kernel<false><<<dim3(QT, HH, BB), 256, 0, stream>>>(qkvb, a0b);
        if (!big) cvt_nt(dcpw + (long)i*CC*CC, CC, CC), Wcp = wb;
        gemm(a0b, Wcp, dcpb + cOff, t0, nullptr, CC, CC, CC, 0, false);
        ln_kernel<<<MM, 256, 0, stream>>>(t0, dec, dln2g + cOff, dln2b + cOff, dec, decb);
        // ffn
        if (!big) cvt_nt(dw1 + (long)i*CC*FFD, CC, FFD), W1 = wb;
        gemm(decb, W1, db1 + (long)i*FFD, nullptr, ffb, FFD, CC, FFD, 2, true);
        if (!big) cvt_nt(dw2 + (long)i*FFD*CC, FFD, CC), W2 = wb;
        gemm(ffb, W2, db2 + cOff, t0, nullptr, CC, FFD, CC, 0, false);
        ln_kernel<<<MM, 256, 0, stream>>>(t0, dec, dln3g + cOff, dln3b + cOff, dec, decb);
    }

    // ---- final LN + logits ----
    ln_kernel<<<MM, 256, 0, stream>>>(dec, nullptr, lnfg, lnfb, t0, t0b);
    if (useWteb) {
        gemm(t0b, wteb, lm_b, out, nullptr, VV, CC, VV, 0, false);
    } else {
        dim3 grid((VV + 127) / 128, GM);
        mgemm_f32b_kernel<<<grid, 256, 0, stream>>>(t0, wte, lm_b, out, MM, VV, CC, VV);
    }
}

// Round 10
// 3217.918 us; speedup vs baseline: 18.0448x; 1.0697x over previous
//
#include <hip/hip_runtime.h>
#include <hip/hip_bf16.h>

#define BB 2
#define TT 1023
#define CC 1024
#define HH 16
#define HSZ 64
#define LL 6
#define FFD 4096
#define VV 50258
#define MM (BB*TT)   // 2046
#define MP 2048      // padded row count
#define VP 50304     // padded vocab (multiple of 128)

typedef __attribute__((ext_vector_type(4))) float  f32x4;
typedef __attribute__((ext_vector_type(8))) short  s16x8;
typedef __attribute__((ext_vector_type(4))) short  s16x4;

#define SCHED0   __builtin_amdgcn_sched_barrier(0)
#define SBAR     __builtin_amdgcn_s_barrier()
#define LGKMCNT0 asm volatile("s_waitcnt lgkmcnt(0)" ::: "memory")

__device__ __forceinline__ short f2b(float x) {
    __hip_bfloat16 h = __float2bfloat16(x);
    short s;
    __builtin_memcpy(&s, &h, 2);
    return s;
}

__device__ __forceinline__ void gld16(const void* g, void* l) {
    __builtin_amdgcn_global_load_lds(
        (__attribute__((address_space(1))) const void*)g,
        (__attribute__((address_space(3))) void*)l, 16, 0, 0);
}

// ---------------------------------------------------------------------------
// Embedding: fp32 + bf16 mirror
// ---------------------------------------------------------------------------
__global__ __launch_bounds__(256) void embed_kernel(
    const int* __restrict__ ids, const float* __restrict__ wte,
    const float* __restrict__ wpe, float* __restrict__ out,
    __hip_bfloat16* __restrict__ outb)
{
    int r = blockIdx.x;
    int t = r % TT;
    long id = ids[r];
    int c = threadIdx.x * 4;
    float4 a = *(const float4*)(wte + id * (long)CC + c);
    float4 p = *(const float4*)(wpe + (long)t * CC + c);
    float4 o; o.x = a.x + p.x; o.y = a.y + p.y; o.z = a.z + p.z; o.w = a.w + p.w;
    *(float4*)(out + (long)r * CC + c) = o;
    s16x4 h; h[0] = f2b(o.x); h[1] = f2b(o.y); h[2] = f2b(o.z); h[3] = f2b(o.w);
    *(s16x4*)(outb + (long)r * CC + c) = h;
}

// ---------------------------------------------------------------------------
// Elementwise fp32 -> bf16
// ---------------------------------------------------------------------------
__global__ __launch_bounds__(256) void cvtb_kernel(
    const float* __restrict__ in, __hip_bfloat16* __restrict__ out, long n)
{
    long i = ((long)blockIdx.x * 256 + threadIdx.x) * 8;
    if (i >= n) return;
    float4 f0 = *(const float4*)(in + i);
    float4 f1 = *(const float4*)(in + i + 4);
    s16x8 h;
    h[0]=f2b(f0.x); h[1]=f2b(f0.y); h[2]=f2b(f0.z); h[3]=f2b(f0.w);
    h[4]=f2b(f1.x); h[5]=f2b(f1.y); h[6]=f2b(f1.z); h[7]=f2b(f1.w);
    *(s16x8*)(out + i) = h;
}

// ---------------------------------------------------------------------------
// Transpose + fp32->bf16: in [R][S] fp32 -> out [S][R] bf16, batched over z.
// ---------------------------------------------------------------------------
__global__ __launch_bounds__(256) void tcvt_kernel(
    const float* __restrict__ in, __hip_bfloat16* __restrict__ out,
    int R, int S, long inZ, long outZa, long outZb, int zdiv)
{
    int z = blockIdx.z;
    in  += (long)z * inZ;
    out += (long)(z / zdiv) * outZa + (long)(z % zdiv) * outZb;
    __shared__ float tile[32][33];
    int s0 = blockIdx.x * 32, r0 = blockIdx.y * 32;
    int tx = threadIdx.x, ty = threadIdx.y;
    #pragma unroll
    for (int i = 0; i < 4; ++i)
        tile[ty + i * 8][tx] = in[(long)(r0 + ty + i * 8) * S + s0 + tx];
    __syncthreads();
    #pragma unroll
    for (int i = 0; i < 4; ++i)
        out[(long)(s0 + ty + i * 8) * R + r0 + tx] =
            __float2bfloat16(tile[tx][ty + i * 8]);
}

// ---------------------------------------------------------------------------
// bf16 MFMA GEMM, T3+T4 pipelined, T2-swizzled, XCD-swizzled.
// BM template: B64=false -> 128x128 tile (4 waves 2x2, 16 MFMA/K-step/wave);
//              B64=true  ->  64x128 tile (4 waves 2x2, 8 MFMA/K-step/wave)
// -- used for N<=2048 GEMMs so grid covers all 256 CUs.
// 3 LDS buffers, 2-deep prefetch, counted vmcnt (8/4/0 or 6/3/0), raw
// s_barrier, setprio around MFMA.
// C = act(A @ B^T + bias). A [pad(M,BM)][K] bf16, B [pad(N,128)][K] bf16.
// WMODE: 0 = fp32 out (float2-coalesced), 2 = bf16 out (b128-coalesced).
// ---------------------------------------------------------------------------
template<int WMODE, bool RELU, bool B64>
__global__ __launch_bounds__(256) void mgemm2_kernel(
    const __hip_bfloat16* __restrict__ A, const __hip_bfloat16* __restrict__ B,
    const float* __restrict__ bias, float* __restrict__ Cm,
    __hip_bfloat16* __restrict__ Cb,
    int M, int N, int K, int ldc, int GM)
{
    constexpr int BM   = B64 ? 64 : 128;
    constexpr int ASZ  = BM * 32;          // shorts per A buffer
    constexpr int BSZ  = 128 * 32;         // shorts per B buffer
    constexpr int BUF  = ASZ + BSZ;
    constexpr int WROW = BM / 2;           // rows per wave-row group
    constexpr int NI   = WROW / 16;        // A frags per wave (4 or 2)
    constexpr int NAC  = BM / 64;          // A chunks per wave (2 or 1)
    __shared__ short LDS[3 * BUF];

    // bijective XCD swizzle + m-fastest decode
    const int nwg = gridDim.x;
    const int bid = blockIdx.x;
    const int q = nwg >> 3, r = nwg & 7;
    const int xcd = bid & 7, lid = bid >> 3;
    const int swz = (xcd < r) ? xcd * (q + 1) + lid
                              : r * (q + 1) + (xcd - r) * q + lid;
    const int m0 = (swz % GM) * BM;
    const int n0 = (swz / GM) * 128;

    const int tid  = threadIdx.x;
    const int lane = tid & 63, w = tid >> 6;
    const int wr = w >> 1, wc = w & 1;
    const int lr = lane & 15, kg = lane >> 4;

    const __hip_bfloat16* Abase = A + (long)m0 * K;
    const __hip_bfloat16* Bbase = B + (long)n0 * K;

    f32x4 acc[NI][4];
    #pragma unroll
    for (int i = 0; i < NI; ++i)
        #pragma unroll
        for (int j = 0; j < 4; ++j)
            acc[i][j] = (f32x4){0.f, 0.f, 0.f, 0.f};

    // staging: chunk cc covers rows cc*16..+15; LDS[row][slot] receives
    // global col-chunk slot ^ ((row>>1)&3); per-lane constants only.
    const int srow = lane >> 2;
    const int scol = (((lane & 3) ^ ((lane >> 3) & 3))) * 8;   // swizzled src

    auto stage = [&](int db, long kofs) {
        short* Ad = &LDS[db * BUF];
        short* Bd = Ad + ASZ;
        #pragma unroll
        for (int p = 0; p < NAC; ++p) {
            int cc = p * 4 + w;
            long ro = (long)(cc * 16 + srow) * K + kofs + scol;
            gld16(Abase + ro, Ad + cc * 512);
        }
        #pragma unroll
        for (int p = 0; p < 2; ++p) {
            int cc = p * 4 + w;
            long ro = (long)(cc * 16 + srow) * K + kofs + scol;
            gld16(Bbase + ro, Bd + cc * 512);
        }
    };
    // fragment read: global chunk kg of row is stored at slot kg ^ ((lr>>1)&3)
    const int rslot = (kg ^ ((lr >> 1) & 3)) * 8;

    auto compute = [&](int db) {
        const short* Ar = &LDS[db * BUF];
        const short* Br = Ar + ASZ;
        s16x8 af[NI], bf[4];
        #pragma unroll
        for (int i = 0; i < NI; ++i)
            af[i] = *(const s16x8*)&Ar[(wr * WROW + i * 16 + lr) * 32 + rslot];
        #pragma unroll
        for (int j = 0; j < 4; ++j)
            bf[j] = *(const s16x8*)&Br[(wc * 64 + j * 16 + lr) * 32 + rslot];
        __builtin_amdgcn_s_setprio(1);
        #pragma unroll
        for (int i = 0; i < NI; ++i)
            #pragma unroll
            for (int j = 0; j < 4; ++j)
                acc[i][j] = __builtin_amdgcn_mfma_f32_16x16x32_bf16(
                    af[i], bf[j], acc[i][j], 0, 0, 0);
        __builtin_amdgcn_s_setprio(0);
    };

    const int nt = K >> 5;
    stage(0, 0);
    if (nt > 1) stage(1, 32);
    int db = 0;
    for (int t = 0; t < nt; ++t) {
        if (t + 2 < nt) {
            stage((db + 2) % 3, (long)(t + 2) << 5);   // keep 2 stages ahead
            SCHED0;
            if (B64) asm volatile("s_waitcnt vmcnt(6)" ::: "memory");
            else     asm volatile("s_waitcnt vmcnt(8)" ::: "memory");
            SCHED0;
        } else if (t + 1 < nt) {
            SCHED0;
            if (B64) asm volatile("s_waitcnt vmcnt(3)" ::: "memory");
            else     asm volatile("s_waitcnt vmcnt(4)" ::: "memory");
            SCHED0;
        } else {
            SCHED0; asm volatile("s_waitcnt vmcnt(0)" ::: "memory"); SCHED0;
        }
        SBAR; SCHED0;                                  // stage t visible to all
        compute(db);
        SCHED0; LGKMCNT0; SCHED0; SBAR; SCHED0;        // reads done pre-overwrite
        db = (db + 1) % 3;
    }

    // ---- epilogue: stage C tile through LDS for coalesced stores ----
    if (WMODE == 0) {
        float* LF = (float*)&LDS[0];
        if (!B64) {
            // [128][64] fp32 half-tiles
            #pragma unroll
            for (int h = 0; h < 2; ++h) {
                if (wc == h) {
                    #pragma unroll
                    for (int j = 0; j < 4; ++j) {
                        int gcol = n0 + h * 64 + j * 16 + lr;
                        float bv = (bias && gcol < N) ? bias[gcol] : 0.f;
                        #pragma unroll
                        for (int i = 0; i < NI; ++i) {
                            int row0 = wr * WROW + i * 16 + kg * 4;
                            #pragma unroll
                            for (int qq = 0; qq < 4; ++qq) {
                                float v = acc[i][j][qq] + bv;
                                if (RELU) v = fmaxf(v, 0.f);
                                LF[(row0 + qq) * 64 + j * 16 + lr] = v;
                            }
                        }
                    }
                }
                __syncthreads();
                #pragma unroll
                for (int i = 0; i < 16; ++i) {
                    int F = i * 256 + tid;               // float2 index
                    int row = F >> 5, col = (F & 31) * 2;
                    int gr = m0 + row, gc = n0 + h * 64 + col;
                    if (gr < M && gc < N)
                        *(float2*)(Cm + (long)gr * ldc + gc) = *(const float2*)&LF[row * 64 + col];
                }
                __syncthreads();
            }
        } else {
            // [64][128] fp32 full tile (32 KB <= 36 KB LDS)
            #pragma unroll
            for (int j = 0; j < 4; ++j) {
                int gcol = n0 + wc * 64 + j * 16 + lr;
                float bv = (bias && gcol < N) ? bias[gcol] : 0.f;
                #pragma unroll
                for (int i = 0; i < NI; ++i) {
                    int row0 = wr * WROW + i * 16 + kg * 4;
                    #pragma unroll
                    for (int qq = 0; qq < 4; ++qq) {
                        float v = acc[i][j][qq] + bv;
                        if (RELU) v = fmaxf(v, 0.f);
                        LF[(row0 + qq) * 128 + wc * 64 + j * 16 + lr] = v;
                    }
                }
            }
            __syncthreads();
            #pragma unroll
            for (int i = 0; i < 16; ++i) {
                int F = i * 256 + tid;                   // float2 index
                int row = F >> 6, col = (F & 63) * 2;
                int gr = m0 + row, gc = n0 + col;
                if (gr < M && gc < N)
                    *(float2*)(Cm + (long)gr * ldc + gc) = *(const float2*)&LF[row * 128 + col];
            }
        }
    } else {
        short* LS = (short*)&LDS[0];       // [BM][128] bf16
        #pragma unroll
        for (int j = 0; j < 4; ++j) {
            int gcol = n0 + wc * 64 + j * 16 + lr;
            float bv = (bias && gcol < N) ? bias[gcol] : 0.f;
            #pragma unroll
            for (int i = 0; i < NI; ++i) {
                int row0 = wr * WROW + i * 16 + kg * 4;
                #pragma unroll
                for (int qq = 0; qq < 4; ++qq) {
                    float v = acc[i][j][qq] + bv;
                    if (RELU) v = fmaxf(v, 0.f);
                    LS[(row0 + qq) * 128 + wc * 64 + j * 16 + lr] = f2b(v);
                }
            }
        }
        __syncthreads();
        #pragma unroll
        for (int i = 0; i < BM / 16; ++i) {
            int F = i * 256 + tid;                   // s16x8 index
            int row = F >> 4, col = (F & 15) * 8;
            int gr = m0 + row, gc = n0 + col;
            if (gr < M && gc < N)
                *(s16x8*)((short*)Cb + (long)gr * ldc + gc) = *(const s16x8*)&LS[row * 128 + col];
        }
    }
}

// ---------------------------------------------------------------------------
// Fallback fp32-B GEMM (logits only, if ws too small for bf16 wte mirror).
// ---------------------------------------------------------------------------
__global__ __launch_bounds__(256) void mgemm_f32b_kernel(
    const float* __restrict__ A, const float* __restrict__ Bv,
    const float* __restrict__ bias, float* __restrict__ Cm,
    int M, int N, int K, int ldc)
{
    __shared__ short As[128][40];
    __shared__ short Bs[128][40];
    const int tid  = threadIdx.x;
    const int lane = tid & 63, w = tid >> 6;
    const int wr = w >> 1, wc = w & 1;
    const int lr = lane & 15, kg = lane >> 4;
    const int m0 = blockIdx.y * 128, n0 = blockIdx.x * 128;
    const int ar = tid >> 3, ac = (tid & 7) * 4;
    const int br = tid >> 2, bc = (tid & 3) * 8;

    f32x4 acc[4][4];
    #pragma unroll
    for (int i = 0; i < 4; ++i)
        #pragma unroll
        for (int j = 0; j < 4; ++j)
            acc[i][j] = (f32x4){0.f, 0.f, 0.f, 0.f};

    for (int k0 = 0; k0 < K; k0 += 32) {
        #pragma unroll
        for (int p = 0; p < 4; ++p) {
            int row = ar + p * 32, gm = m0 + row;
            float4 f = {0.f, 0.f, 0.f, 0.f};
            if (gm < M) f = *(const float4*)(A + (long)gm * K + k0 + ac);
            s16x4 h; h[0] = f2b(f.x); h[1] = f2b(f.y); h[2] = f2b(f.z); h[3] = f2b(f.w);
            *(s16x4*)&As[row][ac] = h;
        }
        #pragma unroll
        for (int p = 0; p < 2; ++p) {
            int n = br + p * 64, gn = n0 + n;
            s16x8 h = (s16x8){0,0,0,0,0,0,0,0};
            if (gn < N) {
                float4 f0 = *(const float4*)(Bv + (long)gn * K + k0 + bc);
                float4 f1 = *(const float4*)(Bv + (long)gn * K + k0 + bc + 4);
                h[0]=f2b(f0.x); h[1]=f2b(f0.y); h[2]=f2b(f0.z); h[3]=f2b(f0.w);
                h[4]=f2b(f1.x); h[5]=f2b(f1.y); h[6]=f2b(f1.z); h[7]=f2b(f1.w);
            }
            *(s16x8*)&Bs[n][bc] = h;
        }
        __syncthreads();
        s16x8 af[4], bf[4];
        #pragma unroll
        for (int i = 0; i < 4; ++i) af[i] = *(const s16x8*)&As[wr*64 + i*16 + lr][kg*8];
        #pragma unroll
        for (int j = 0; j < 4; ++j) bf[j] = *(const s16x8*)&Bs[wc*64 + j*16 + lr][kg*8];
        #pragma unroll
        for (int i = 0; i < 4; ++i)
            #pragma unroll
            for (int j = 0; j < 4; ++j)
                acc[i][j] = __builtin_amdgcn_mfma_f32_16x16x32_bf16(af[i], bf[j], acc[i][j], 0, 0, 0);
        __syncthreads();
    }
    #pragma unroll
    for (int j = 0; j < 4; ++j) {
        int gcol = n0 + wc * 64 + j * 16 + lr;
        if (gcol >= N) continue;
        float bv = bias ? bias[gcol] : 0.f;
        #pragma unroll
        for (int i = 0; i < 4; ++i) {
            int grow0 = m0 + wr * 64 + i * 16 + kg * 4;
            #pragma unroll
            for (int qq = 0; qq < 4; ++qq) {
                int gr = grow0 + qq;
                if (gr >= M) continue;
                Cm[(long)gr * ldc + gcol] = acc[i][j][qq] + bv;
            }
        }
    }
}

// ---------------------------------------------------------------------------
// MFMA flash attention (bf16 in / bf16 out). grid (16, H, B), 4 waves.
// T14 async-split: K/V prefetched to REGISTERS one tile ahead; raw s_barrier.
// qkvb: [M,3072] bf16 (q|k|v, head h at col h*64). outb: [M,C] bf16.
// scale = 1/sqrt(C) = 1/32 (reference quirk).
// ---------------------------------------------------------------------------
template<bool CAUSAL>
__global__ __launch_bounds__(256) void fattn_kernel(
    const __hip_bfloat16* __restrict__ qkvb, __hip_bfloat16* __restrict__ outb)
{
    __shared__ short Ks[64][72];
    __shared__ short Vt[64][72];
    __shared__ short Ps[4][16][72];

    const int q0 = blockIdx.x * 64;
    const int h = blockIdx.y, b = blockIdx.z;
    const int tid = threadIdx.x;
    const int lane = tid & 63, w = tid >> 6;
    const int lr = lane & 15, lg = lane >> 4;

    const float scale = 1.0f / 32.0f;
    const long base = (long)b * TT * 3072;
    const __hip_bfloat16* Kg = qkvb + base + 1024 + h * 64;
    const __hip_bfloat16* Vg = qkvb + base + 2048 + h * 64;

    s16x8 qf[2];
    {
        int qr = q0 + w * 16 + lr;
        #pragma unroll
        for (int kc = 0; kc < 2; ++kc) {
            s16x8 hv = (s16x8){0,0,0,0,0,0,0,0};
            if (qr < TT)
                hv = *(const s16x8*)(qkvb + base + (long)qr * 3072 + h * 64 + kc * 32 + lg * 8);
            qf[kc] = hv;
        }
    }

    f32x4 acc[4];
    #pragma unroll
    for (int jd = 0; jd < 4; ++jd) acc[jd] = (f32x4){0.f, 0.f, 0.f, 0.f};
    float mrun[4] = {-3.0e38f, -3.0e38f, -3.0e38f, -3.0e38f};
    float lrun[4] = {0.f, 0.f, 0.f, 0.f};

    const int send = CAUSAL ? min(TT, q0 + 64) : TT;
    const int nt = (send + 63) >> 6;
    const int sr2 = (tid >> 3) * 2;        // rows sr2, sr2+1
    const int dcc = (tid & 7) * 8;         // col chunk

    s16x8 kreg[2], vreg[2];
    auto loadkv = [&](int t) {
        int sbase = t * 64;
        #pragma unroll
        for (int rr = 0; rr < 2; ++rr) {
            int sg = sbase + sr2 + rr;
            if (sg < TT) {
                kreg[rr] = *(const s16x8*)(Kg + (long)sg * 3072 + dcc);
                vreg[rr] = *(const s16x8*)(Vg + (long)sg * 3072 + dcc);
            } else {
                kreg[rr] = (s16x8){0,0,0,0,0,0,0,0};
                vreg[rr] = (s16x8){0,0,0,0,0,0,0,0};
            }
        }
    };

    loadkv(0);
    for (int ti = 0; ti < nt; ++ti) {
        const int s0 = ti * 64;
        SCHED0; SBAR; SCHED0;          // prev tile's LDS reads done (all waves)
        *(s16x8*)&Ks[sr2][dcc]     = kreg[0];
        *(s16x8*)&Ks[sr2 + 1][dcc] = kreg[1];
        #pragma unroll
        for (int e = 0; e < 8; ++e) {
            unsigned pack = (unsigned)(unsigned short)vreg[0][e]
                          | ((unsigned)(unsigned short)vreg[1][e] << 16);
            *(unsigned*)&Vt[dcc + e][sr2] = pack;
        }
        if (ti + 1 < nt) loadkv(ti + 1);   // issue next tile's loads early
        SCHED0; LGKMCNT0; SCHED0; SBAR; SCHED0;   // LDS writes visible

        f32x4 sf[4];
        __builtin_amdgcn_s_setprio(1);
        #pragma unroll
        for (int j = 0; j < 4; ++j) {
            f32x4 z = (f32x4){0.f, 0.f, 0.f, 0.f};
            #pragma unroll
            for (int kc = 0; kc < 2; ++kc) {
                s16x8 kf = *(const s16x8*)&Ks[j * 16 + lr][kc * 32 + lg * 8];
                z = __builtin_amdgcn_mfma_f32_16x16x32_bf16(qf[kc], kf, z, 0, 0, 0);
            }
            sf[j] = z;
        }
        __builtin_amdgcn_s_setprio(0);

        float mloc[4] = {-3.0e38f, -3.0e38f, -3.0e38f, -3.0e38f};
        #pragma unroll
        for (int j = 0; j < 4; ++j) {
            int sg = s0 + j * 16 + lr;
            #pragma unroll
            for (int r = 0; r < 4; ++r) {
                float sc = sf[j][r] * scale;
                int qg = q0 + w * 16 + lg * 4 + r;
                if ((CAUSAL && sg > qg) || sg >= TT) sc = -3.0e38f;
                sf[j][r] = sc;
                mloc[r] = fmaxf(mloc[r], sc);
            }
        }
        #pragma unroll
        for (int r = 0; r < 4; ++r)
            #pragma unroll
            for (int off = 1; off < 16; off <<= 1)
                mloc[r] = fmaxf(mloc[r], __shfl_xor(mloc[r], off));

        float corr[4], psum[4];
        #pragma unroll
        for (int r = 0; r < 4; ++r) {
            float mn = fmaxf(mrun[r], mloc[r]);
            corr[r] = __expf(mrun[r] - mn);
            mrun[r] = mn;
            psum[r] = 0.f;
        }

        #pragma unroll
        for (int j = 0; j < 4; ++j) {
            #pragma unroll
            for (int r = 0; r < 4; ++r) {
                float p = __expf(sf[j][r] - mrun[r]);
                psum[r] += p;
                Ps[w][lg * 4 + r][j * 16 + lr] = f2b(p);
            }
        }
        #pragma unroll
        for (int r = 0; r < 4; ++r) {
            #pragma unroll
            for (int off = 1; off < 16; off <<= 1)
                psum[r] += __shfl_xor(psum[r], off);
            lrun[r] = lrun[r] * corr[r] + psum[r];
            #pragma unroll
            for (int jd = 0; jd < 4; ++jd) acc[jd][r] *= corr[r];
        }

        __builtin_amdgcn_s_setprio(1);
        #pragma unroll
        for (int kc = 0; kc < 2; ++kc) {
            s16x8 pa = *(const s16x8*)&Ps[w][lr][kc * 32 + lg * 8];
            #pragma unroll
            for (int jd = 0; jd < 4; ++jd) {
                s16x8 bv = *(const s16x8*)&Vt[jd * 16 + lr][kc * 32 + lg * 8];
                acc[jd] = __builtin_amdgcn_mfma_f32_16x16x32_bf16(pa, bv, acc[jd], 0, 0, 0);
            }
        }
        __builtin_amdgcn_s_setprio(0);
        SCHED0; LGKMCNT0; SCHED0;      // my LDS reads complete before next write
    }

    #pragma unroll
    for (int r = 0; r < 4; ++r) {
        int qg = q0 + w * 16 + lg * 4 + r;
        if (qg >= TT) continue;
        float inv = 1.0f / lrun[r];
        #pragma unroll
        for (int jd = 0; jd < 4; ++jd)
            outb[((long)b * TT + qg) * CC + h * 64 + jd * 16 + lr] =
                __float2bfloat16(acc[jd][r] * inv);
    }
}

// ---------------------------------------------------------------------------
// LayerNorm (+optional residual), fp32 out + optional bf16 mirror.
// ---------------------------------------------------------------------------
__global__ __launch_bounds__(256) void ln_kernel(
    const float* __restrict__ in, const float* __restrict__ res,
    const float* __restrict__ g, const float* __restrict__ b,
    float* __restrict__ out, __hip_bfloat16* __restrict__ outb)
{
    const int r = blockIdx.x, tid = threadIdx.x;
    __shared__ float sm[4];

    float4 xv = *(const float4*)(in + (long)r * CC + tid * 4);
    float s = xv.x + xv.y + xv.z + xv.w;
    #pragma unroll
    for (int o = 32; o > 0; o >>= 1) s += __shfl_xor(s, o);
    if ((tid & 63) == 0) sm[tid >> 6] = s;
    __syncthreads();
    const float mean = (sm[0] + sm[1] + sm[2] + sm[3]) * (1.0f / CC);
    __syncthreads();

    float4 d; d.x = xv.x - mean; d.y = xv.y - mean; d.z = xv.z - mean; d.w = xv.w - mean;
    float s2 = d.x * d.x + d.y * d.y + d.z * d.z + d.w * d.w;
    #pragma unroll
    for (int o = 32; o > 0; o >>= 1) s2 += __shfl_xor(s2, o);
    if ((tid & 63) == 0) sm[tid >> 6] = s2;
    __syncthreads();
    const float rstd = rsqrtf((sm[0] + sm[1] + sm[2] + sm[3]) * (1.0f / CC) + 1e-5f);

    float4 gv = *(const float4*)(g + tid * 4);
    float4 bv = *(const float4*)(b + tid * 4);
    float4 o;
    o.x = gv.x * d.x * rstd + bv.x; o.y = gv.y * d.y * rstd + bv.y;
    o.z = gv.z * d.z * rstd + bv.z; o.w = gv.w * d.w * rstd + bv.w;
    if (res) {
        float4 rv = *(const float4*)(res + (long)r * CC + tid * 4);
        o.x += rv.x; o.y += rv.y; o.z += rv.z; o.w += rv.w;
    }
    *(float4*)(out + (long)r * CC + tid * 4) = o;
    if (outb) {
        s16x4 h; h[0] = f2b(o.x); h[1] = f2b(o.y); h[2] = f2b(o.z); h[3] = f2b(o.w);
        *(s16x4*)(outb + (long)r * CC + tid * 4) = h;
    }
}

// ---------------------------------------------------------------------------
extern "C" void kernel_launch(void* const* d_in, const int* in_sizes, int n_in,
                              void* d_out, int out_size, void* d_ws, size_t ws_size,
                              hipStream_t stream)
{
    const int*   x      = (const int*)  d_in[0];
    const int*   y      = (const int*)  d_in[1];
    const float* wte    = (const float*)d_in[2];
    const float* wpe_x  = (const float*)d_in[3];
    const float* wpe_y  = (const float*)d_in[4];
    const float* eWq    = (const float*)d_in[5];
    const float* eWk    = (const float*)d_in[6];
    const float* eWv    = (const float*)d_in[7];
    const float* epw    = (const float*)d_in[8];
    const float* epb    = (const float*)d_in[9];
    const float* eln1g  = (const float*)d_in[10];
    const float* eln1b  = (const float*)d_in[11];
    const float* eln2g  = (const float*)d_in[12];
    const float* eln2b  = (const float*)d_in[13];
    const float* ew1    = (const float*)d_in[14];
    const float* eb1    = (const float*)d_in[15];
    const float* ew2    = (const float*)d_in[16];
    const float* eb2    = (const float*)d_in[17];
    const float* dsWq   = (const float*)d_in[18];
    const float* dsWk   = (const float*)d_in[19];
    const float* dsWv   = (const float*)d_in[20];
    const float* dspw   = (const float*)d_in[21];
    const float* dspb   = (const float*)d_in[22];
    const float* dcWq   = (const float*)d_in[23];
    const float* dcWk   = (const float*)d_in[24];
    const float* dcWv   = (const float*)d_in[25];
    const float* dcpw   = (const float*)d_in[26];
    const float* dcpb   = (const float*)d_in[27];
    const float* dln1g  = (const float*)d_in[28];
    const float* dln1b  = (const float*)d_in[29];
    const float* dln2g  = (const float*)d_in[30];
    const float* dln2b  = (const float*)d_in[31];
    const float* dln3g  = (const float*)d_in[32];
    const float* dln3b  = (const float*)d_in[33];
    const float* dw1    = (const float*)d_in[34];
    const float* db1    = (const float*)d_in[35];
    const float* dw2    = (const float*)d_in[36];
    const float* db2    = (const float*)d_in[37];
    const float* lnfg   = (const float*)d_in[38];
    const float* lnfb   = (const float*)d_in[39];
    const float* lm_b   = (const float*)d_in[40];

    float* out = (float*)d_out;

    // ---- workspace carve-up ----
    const size_t MCp = (size_t)MP * CC;
    float* enc = (float*)d_ws;
    float* dec = enc + MCp;
    float* t0  = dec + MCp;
    __hip_bfloat16* encb = (__hip_bfloat16*)(t0 + MCp);
    __hip_bfloat16* decb = encb + MCp;
    __hip_bfloat16* t0b  = decb + MCp;
    __hip_bfloat16* a0b  = t0b + MCp;
    __hip_bfloat16* qkvb = a0b + MCp;                    // [MP][3072]
    __hip_bfloat16* ffb  = qkvb + (size_t)MP * 3072;     // [MP][FFD]
    __hip_bfloat16* wteb = ffb + (size_t)MP * FFD;       // [VP][C]
    // big-mode weight blocks
    __hip_bfloat16* eQKVw = wteb + (size_t)VP * CC;      // [L][3072][C]
    __hip_bfloat16* ePWw  = eQKVw + (size_t)LL * 3072 * CC;
    __hip_bfloat16* eW1w  = ePWw  + (size_t)LL * CC * CC;     // [L][FFD][C]
    __hip_bfloat16* eW2w  = eW1w  + (size_t)LL * FFD * CC;    // [L][C][FFD]
    __hip_bfloat16* sQKVw = eW2w  + (size_t)LL * CC * FFD;
    __hip_bfloat16* sPWw  = sQKVw + (size_t)LL * 3072 * CC;
    __hip_bfloat16* cQKVw = sPWw  + (size_t)LL * CC * CC;
    __hip_bfloat16* cPWw  = cQKVw + (size_t)LL * 3072 * CC;
    __hip_bfloat16* dW1w  = cPWw  + (size_t)LL * CC * CC;
    __hip_bfloat16* dW2w  = dW1w  + (size_t)LL * FFD * CC;
    __hip_bfloat16* bigEnd = dW2w + (size_t)LL * CC * FFD;
    // small-mode: per-use conversion buffer where eQKVw starts
    __hip_bfloat16* wb = eQKVw;
    const size_t needBig   = (size_t)((char*)bigEnd - (char*)d_ws);
    const size_t needSmall = (size_t)((char*)(wb + (size_t)FFD * CC) - (char*)d_ws);
    const size_t needWteb  = (size_t)((char*)eQKVw - (char*)d_ws);
    const bool big     = (ws_size >= needBig);
    const bool useWteb = (ws_size >= needWteb) &&
                         (big || ws_size >= needSmall);

    const int QT = (TT + 63) / 64;     // 16 q-tiles
    const dim3 tblk(32, 8);

    auto gemm = [&](const __hip_bfloat16* A, const __hip_bfloat16* B,
                    const float* bias, float* Cm, __hip_bfloat16* Cb,
                    int N_, int K_, int ldc, int wmode, bool relu) {
        const bool b64 = (N_ <= 2048);          // small-N: double the grid
        const int GMv = b64 ? MP / 64 : MP / 128;
        int nwg = GMv * ((N_ + 127) / 128);
        if (wmode == 0) {
            if (b64) {
                if (relu) mgemm2_kernel<0, true , true ><<<nwg, 256, 0, stream>>>(A, B, bias, Cm, Cb, MM, N_, K_, ldc, GMv);
                else      mgemm2_kernel<0, false, true ><<<nwg, 256, 0, stream>>>(A, B, bias, Cm, Cb, MM, N_, K_, ldc, GMv);
            } else {
                if (relu) mgemm2_kernel<0, true , false><<<nwg, 256, 0, stream>>>(A, B, bias, Cm, Cb, MM, N_, K_, ldc, GMv);
                else      mgemm2_kernel<0, false, false><<<nwg, 256, 0, stream>>>(A, B, bias, Cm, Cb, MM, N_, K_, ldc, GMv);
            }
        } else {
            if (b64) {
                if (relu) mgemm2_kernel<2, true , true ><<<nwg, 256, 0, stream>>>(A, B, bias, Cm, Cb, MM, N_, K_, ldc, GMv);
                else      mgemm2_kernel<2, false, true ><<<nwg, 256, 0, stream>>>(A, B, bias, Cm, Cb, MM, N_, K_, ldc, GMv);
            } else {
                if (relu) mgemm2_kernel<2, true , false><<<nwg, 256, 0, stream>>>(A, B, bias, Cm, Cb, MM, N_, K_, ldc, GMv);
                else      mgemm2_kernel<2, false, false><<<nwg, 256, 0, stream>>>(A, B, bias, Cm, Cb, MM, N_, K_, ldc, GMv);
            }
        }
    };

    if (useWteb) {
        long n = (long)VV * CC;
        cvtb_kernel<<<(int)((n / 8 + 255) / 256), 256, 0, stream>>>(wte, wteb, n);
    }

    if (big) {
        // ---- all weight conversions up-front ----
        const long sWH = (long)CC * HSZ;            // per-(l,h) input stride
        const long oA = (long)3072 * CC;            // per-layer qkv out stride
        const long oB = (long)HSZ * CC;             // per-head out stride
        dim3 gq(HSZ / 32, CC / 32, LL * HH);
        tcvt_kernel<<<gq, tblk, 0, stream>>>(eWq, eQKVw,             CC, HSZ, sWH, oA, oB, HH);
        tcvt_kernel<<<gq, tblk, 0, stream>>>(eWk, eQKVw + CC * CC,   CC, HSZ, sWH, oA, oB, HH);
        tcvt_kernel<<<gq, tblk, 0, stream>>>(eWv, eQKVw + 2*CC*CC,   CC, HSZ, sWH, oA, oB, HH);
        tcvt_kernel<<<gq, tblk, 0, stream>>>(dsWq, sQKVw,            CC, HSZ, sWH, oA, oB, HH);
        tcvt_kernel<<<gq, tblk, 0, stream>>>(dsWk, sQKVw + CC * CC,  CC, HSZ, sWH, oA, oB, HH);
        tcvt_kernel<<<gq, tblk, 0, stream>>>(dsWv, sQKVw + 2*CC*CC,  CC, HSZ, sWH, oA, oB, HH);
        tcvt_kernel<<<gq, tblk, 0, stream>>>(dcWq, cQKVw,            CC, HSZ, sWH, oA, oB, HH);
        tcvt_kernel<<<gq, tblk, 0, stream>>>(dcWk, cQKVw + CC * CC,  CC, HSZ, sWH, oA, oB, HH);
        tcvt_kernel<<<gq, tblk, 0, stream>>>(dcWv, cQKVw + 2*CC*CC,  CC, HSZ, sWH, oA, oB, HH);
        dim3 gp(CC / 32, CC / 32, LL);
        tcvt_kernel<<<gp, tblk, 0, stream>>>(epw,  ePWw, CC, CC, (long)CC*CC, (long)CC*CC, 0, 1);
        tcvt_kernel<<<gp, tblk, 0, stream>>>(dspw, sPWw, CC, CC, (long)CC*CC, (long)CC*CC, 0, 1);
        tcvt_kernel<<<gp, tblk, 0, stream>>>(dcpw, cPWw, CC, CC, (long)CC*CC, (long)CC*CC, 0, 1);
        dim3 g1(FFD / 32, CC / 32, LL);
        tcvt_kernel<<<g1, tblk, 0, stream>>>(ew1, eW1w, CC, FFD, (long)CC*FFD, (long)FFD*CC, 0, 1);
        tcvt_kernel<<<g1, tblk, 0, stream>>>(dw1, dW1w, CC, FFD, (long)CC*FFD, (long)FFD*CC, 0, 1);
        dim3 g2(CC / 32, FFD / 32, LL);
        tcvt_kernel<<<g2, tblk, 0, stream>>>(ew2, eW2w, FFD, CC, (long)FFD*CC, (long)CC*FFD, 0, 1);
        tcvt_kernel<<<g2, tblk, 0, stream>>>(dw2, dW2w, FFD, CC, (long)FFD*CC, (long)CC*FFD, 0, 1);
    }

    // small-mode per-use converters
    auto cvt_qkv = [&](const float* Wq, const float* Wk, const float* Wv) {
        dim3 g(HSZ / 32, CC / 32, HH);
        tcvt_kernel<<<g, tblk, 0, stream>>>(Wq, wb,             CC, HSZ, (long)CC*HSZ, (long)HSZ*CC, 0, 1);
        tcvt_kernel<<<g, tblk, 0, stream>>>(Wk, wb + CC*CC,     CC, HSZ, (long)CC*HSZ, (long)HSZ*CC, 0, 1);
        tcvt_kernel<<<g, tblk, 0, stream>>>(Wv, wb + 2*CC*CC,   CC, HSZ, (long)CC*HSZ, (long)HSZ*CC, 0, 1);
    };
    auto cvt_nt = [&](const float* W, int R, int S) {
        dim3 g(S / 32, R / 32, 1);
        tcvt_kernel<<<g, tblk, 0, stream>>>(W, wb, R, S, 0, 0, 0, 1);
    };

    // ---- encoder ----
    embed_kernel<<<MM, 256, 0, stream>>>(x, wte, wpe_x, enc, encb);
    for (int i = 0; i < LL; ++i) {
        const long cOff = (long)i * CC;
        const __hip_bfloat16 *Wqkv, *Wp, *W1, *W2;
        if (big) {
            Wqkv = eQKVw + (size_t)i * 3072 * CC;
            Wp   = ePWw  + (size_t)i * CC * CC;
            W1   = eW1w  + (size_t)i * FFD * CC;
            W2   = eW2w  + (size_t)i * CC * FFD;
        }
        if (!big) cvt_qkv(eWq + (long)i*HH*CC*HSZ, eWk + (long)i*HH*CC*HSZ, eWv + (long)i*HH*CC*HSZ), Wqkv = wb;
        gemm(encb, Wqkv, nullptr, nullptr, qkvb, 3072, CC, 3072, 2, false);
        fattn_kernel<false><<<dim3(QT, HH, BB), 256, 0, stream>>>(qkvb, a0b);
        if (!big) cvt_nt(epw + (long)i*CC*CC, CC, CC), Wp = wb;
        gemm(a0b, Wp, epb + cOff, t0, nullptr, CC, CC, CC, 0, false);
        ln_kernel<<<MM, 256, 0, stream>>>(t0, enc, eln1g + cOff, eln1b + cOff, enc, encb);
        if (!big) cvt_nt(ew1 + (long)i*CC*FFD, CC, FFD), W1 = wb;
        gemm(encb, W1, eb1 + (long)i*FFD, nullptr, ffb, FFD, CC, FFD, 2, true);
        if (!big) cvt_nt(ew2 + (long)i*FFD*CC, FFD, CC), W2 = wb;
        gemm(ffb, W2, eb2 + cOff, t0, nullptr, CC, FFD, CC, 0, false);
        ln_kernel<<<MM, 256, 0, stream>>>(t0, enc, eln2g + cOff, eln2b + cOff, enc, encb);
    }

    // ---- decoder ----
    embed_kernel<<<MM, 256, 0, stream>>>(y, wte, wpe_y, dec, decb);
    for (int i = 0; i < LL; ++i) {
        const long cOff = (long)i * CC;
        const __hip_bfloat16 *Ws, *Wsp, *Wc, *Wcp, *W1, *W2;
        if (big) {
            Ws  = sQKVw + (size_t)i * 3072 * CC;
            Wsp = sPWw  + (size_t)i * CC * CC;
            Wc  = cQKVw + (size_t)i * 3072 * CC;
            Wcp = cPWw  + (size_t)i * CC * CC;
            W1  = dW1w  + (size_t)i * FFD * CC;
            W2  = dW2w  + (size_t)i * CC * FFD;
        }
        // masked self-attn
        if (!big) cvt_qkv(dsWq + (long)i*HH*CC*HSZ, dsWk + (long)i*HH*CC*HSZ, dsWv + (long)i*HH*CC*HSZ), Ws = wb;
        gemm(decb, Ws, nullptr, nullptr, qkvb, 3072, CC, 3072, 2, false);
        fattn_kernel<true><<<dim3(QT, HH, BB), 256, 0, stream>>>(qkvb, a0b);
        if (!big) cvt_nt(dspw + (long)i*CC*CC, CC, CC), Wsp = wb;
        gemm(a0b, Wsp, dspb + cOff, t0, nullptr, CC, CC, CC, 0, false);
        ln_kernel<<<MM, 256, 0, stream>>>(t0, dec, dln1g + cOff, dln1b + cOff, dec, decb);
        // cross-attn: q from dec, k/v from enc
        if (!big) cvt_qkv(dcWq + (long)i*HH*CC*HSZ, dcWk + (long)i*HH*CC*HSZ, dcWv + (long)i*HH*CC*HSZ), Wc = wb;
        gemm(decb, Wc, nullptr, nullptr, qkvb, CC, CC, 3072, 2, false);
        gemm(encb, Wc + (size_t)CC * CC, nullptr, nullptr, qkvb + CC, 2048, CC, 3072, 2, false);
        fattn_kernel<false><<<dim3(QT, HH, BB), 256, 0, stream>>>(qkvb, a0b);
        if (!big) cvt_nt(dcpw + (long)i*CC*CC, CC, CC), Wcp = wb;
        gemm(a0b, Wcp, dcpb + cOff, t0, nullptr, CC, CC, CC, 0, false);
        ln_kernel<<<MM, 256, 0, stream>>>(t0, dec, dln2g + cOff, dln2b + cOff, dec, decb);
        // ffn
        if (!big) cvt_nt(dw1 + (long)i*CC*FFD, CC, FFD), W1 = wb;
        gemm(decb, W1, db1 + (long)i*FFD, nullptr, ffb, FFD, CC, FFD, 2, true);
        if (!big) cvt_nt(dw2 + (long)i*FFD*CC, FFD, CC), W2 = wb;
        gemm(ffb, W2, db2 + cOff, t0, nullptr, CC, FFD, CC, 0, false);
        ln_kernel<<<MM, 256, 0, stream>>>(t0, dec, dln3g + cOff, dln3b + cOff, dec, decb);
    }

    // ---- final LN + logits ----
    ln_kernel<<<MM, 256, 0, stream>>>(dec, nullptr, lnfg, lnfb, t0, t0b);
    if (useWteb) {
        gemm(t0b, wteb, lm_b, out, nullptr, VV, CC, VV, 0, false);
    } else {
        dim3 grid((VV + 127) / 128, MP / 128);
        mgemm_f32b_kernel<<<grid, 256, 0, stream>>>(t0, wte, lm_b, out, MM, VV, CC, VV);
    }
}

// Round 11
// 3127.445 us; speedup vs baseline: 18.5668x; 1.0289x over previous
//
#include <hip/hip_runtime.h>
#include <hip/hip_bf16.h>

#define BB 2
#define TT 1023
#define CC 1024
#define HH 16
#define HSZ 64
#define LL 6
#define FFD 4096
#define VV 50258
#define MM (BB*TT)   // 2046
#define MP 2048      // padded row count
#define VP 50304     // padded vocab (multiple of 128)

typedef __attribute__((ext_vector_type(4))) float  f32x4;
typedef __attribute__((ext_vector_type(8))) short  s16x8;
typedef __attribute__((ext_vector_type(4))) short  s16x4;

#define SCHED0   __builtin_amdgcn_sched_barrier(0)
#define SBAR     __builtin_amdgcn_s_barrier()
#define LGKMCNT0 asm volatile("s_waitcnt lgkmcnt(0)" ::: "memory")

__device__ __forceinline__ short f2b(float x) {
    __hip_bfloat16 h = __float2bfloat16(x);
    short s;
    __builtin_memcpy(&s, &h, 2);
    return s;
}

__device__ __forceinline__ void gld16(const void* g, void* l) {
    __builtin_amdgcn_global_load_lds(
        (__attribute__((address_space(1))) const void*)g,
        (__attribute__((address_space(3))) void*)l, 16, 0, 0);
}

// ---------------------------------------------------------------------------
// Embedding: fp32 + bf16 mirror
// ---------------------------------------------------------------------------
__global__ __launch_bounds__(256) void embed_kernel(
    const int* __restrict__ ids, const float* __restrict__ wte,
    const float* __restrict__ wpe, float* __restrict__ out,
    __hip_bfloat16* __restrict__ outb)
{
    int r = blockIdx.x;
    int t = r % TT;
    long id = ids[r];
    int c = threadIdx.x * 4;
    float4 a = *(const float4*)(wte + id * (long)CC + c);
    float4 p = *(const float4*)(wpe + (long)t * CC + c);
    float4 o; o.x = a.x + p.x; o.y = a.y + p.y; o.z = a.z + p.z; o.w = a.w + p.w;
    *(float4*)(out + (long)r * CC + c) = o;
    s16x4 h; h[0] = f2b(o.x); h[1] = f2b(o.y); h[2] = f2b(o.z); h[3] = f2b(o.w);
    *(s16x4*)(outb + (long)r * CC + c) = h;
}

// ---------------------------------------------------------------------------
// Elementwise fp32 -> bf16
// ---------------------------------------------------------------------------
__global__ __launch_bounds__(256) void cvtb_kernel(
    const float* __restrict__ in, __hip_bfloat16* __restrict__ out, long n)
{
    long i = ((long)blockIdx.x * 256 + threadIdx.x) * 8;
    if (i >= n) return;
    float4 f0 = *(const float4*)(in + i);
    float4 f1 = *(const float4*)(in + i + 4);
    s16x8 h;
    h[0]=f2b(f0.x); h[1]=f2b(f0.y); h[2]=f2b(f0.z); h[3]=f2b(f0.w);
    h[4]=f2b(f1.x); h[5]=f2b(f1.y); h[6]=f2b(f1.z); h[7]=f2b(f1.w);
    *(s16x8*)(out + i) = h;
}

// ---------------------------------------------------------------------------
// Transpose + fp32->bf16: in [R][S] fp32 -> out [S][R] bf16, batched over z.
// ---------------------------------------------------------------------------
__global__ __launch_bounds__(256) void tcvt_kernel(
    const float* __restrict__ in, __hip_bfloat16* __restrict__ out,
    int R, int S, long inZ, long outZa, long outZb, int zdiv)
{
    int z = blockIdx.z;
    in  += (long)z * inZ;
    out += (long)(z / zdiv) * outZa + (long)(z % zdiv) * outZb;
    __shared__ float tile[32][33];
    int s0 = blockIdx.x * 32, r0 = blockIdx.y * 32;
    int tx = threadIdx.x, ty = threadIdx.y;
    #pragma unroll
    for (int i = 0; i < 4; ++i)
        tile[ty + i * 8][tx] = in[(long)(r0 + ty + i * 8) * S + s0 + tx];
    __syncthreads();
    #pragma unroll
    for (int i = 0; i < 4; ++i)
        out[(long)(s0 + ty + i * 8) * R + r0 + tx] =
            __float2bfloat16(tile[tx][ty + i * 8]);
}

// ---------------------------------------------------------------------------
// bf16 MFMA GEMM, T3+T4 pipelined, T2-swizzled, XCD-swizzled.
// BM template: B64=false -> 128x128 tile; B64=true -> 64x128 tile (N<=2048).
// 3 LDS buffers, 2-deep prefetch, counted vmcnt, raw s_barrier, setprio.
// C = act(A @ B^T + bias). A [pad(M,BM)][K] bf16, B [pad(N,128)][K] bf16.
// WMODE: 0 = fp32 out (float2-coalesced), 2 = bf16 out (b128-coalesced).
// ---------------------------------------------------------------------------
template<int WMODE, bool RELU, bool B64>
__global__ __launch_bounds__(256) void mgemm2_kernel(
    const __hip_bfloat16* __restrict__ A, const __hip_bfloat16* __restrict__ B,
    const float* __restrict__ bias, float* __restrict__ Cm,
    __hip_bfloat16* __restrict__ Cb,
    int M, int N, int K, int ldc, int GM)
{
    constexpr int BM   = B64 ? 64 : 128;
    constexpr int ASZ  = BM * 32;
    constexpr int BSZ  = 128 * 32;
    constexpr int BUF  = ASZ + BSZ;
    constexpr int WROW = BM / 2;
    constexpr int NI   = WROW / 16;
    constexpr int NAC  = BM / 64;
    __shared__ short LDS[3 * BUF];

    // bijective XCD swizzle + m-fastest decode
    const int nwg = gridDim.x;
    const int bid = blockIdx.x;
    const int q = nwg >> 3, r = nwg & 7;
    const int xcd = bid & 7, lid = bid >> 3;
    const int swz = (xcd < r) ? xcd * (q + 1) + lid
                              : r * (q + 1) + (xcd - r) * q + lid;
    const int m0 = (swz % GM) * BM;
    const int n0 = (swz / GM) * 128;

    const int tid  = threadIdx.x;
    const int lane = tid & 63, w = tid >> 6;
    const int wr = w >> 1, wc = w & 1;
    const int lr = lane & 15, kg = lane >> 4;

    const __hip_bfloat16* Abase = A + (long)m0 * K;
    const __hip_bfloat16* Bbase = B + (long)n0 * K;

    f32x4 acc[NI][4];
    #pragma unroll
    for (int i = 0; i < NI; ++i)
        #pragma unroll
        for (int j = 0; j < 4; ++j)
            acc[i][j] = (f32x4){0.f, 0.f, 0.f, 0.f};

    const int srow = lane >> 2;
    const int scol = (((lane & 3) ^ ((lane >> 3) & 3))) * 8;   // swizzled src

    auto stage = [&](int db, long kofs) {
        short* Ad = &LDS[db * BUF];
        short* Bd = Ad + ASZ;
        #pragma unroll
        for (int p = 0; p < NAC; ++p) {
            int cc = p * 4 + w;
            long ro = (long)(cc * 16 + srow) * K + kofs + scol;
            gld16(Abase + ro, Ad + cc * 512);
        }
        #pragma unroll
        for (int p = 0; p < 2; ++p) {
            int cc = p * 4 + w;
            long ro = (long)(cc * 16 + srow) * K + kofs + scol;
            gld16(Bbase + ro, Bd + cc * 512);
        }
    };
    const int rslot = (kg ^ ((lr >> 1) & 3)) * 8;

    auto compute = [&](int db) {
        const short* Ar = &LDS[db * BUF];
        const short* Br = Ar + ASZ;
        s16x8 af[NI], bf[4];
        #pragma unroll
        for (int i = 0; i < NI; ++i)
            af[i] = *(const s16x8*)&Ar[(wr * WROW + i * 16 + lr) * 32 + rslot];
        #pragma unroll
        for (int j = 0; j < 4; ++j)
            bf[j] = *(const s16x8*)&Br[(wc * 64 + j * 16 + lr) * 32 + rslot];
        __builtin_amdgcn_s_setprio(1);
        #pragma unroll
        for (int i = 0; i < NI; ++i)
            #pragma unroll
            for (int j = 0; j < 4; ++j)
                acc[i][j] = __builtin_amdgcn_mfma_f32_16x16x32_bf16(
                    af[i], bf[j], acc[i][j], 0, 0, 0);
        __builtin_amdgcn_s_setprio(0);
    };

    const int nt = K >> 5;
    stage(0, 0);
    if (nt > 1) stage(1, 32);
    int db = 0;
    for (int t = 0; t < nt; ++t) {
        if (t + 2 < nt) {
            stage((db + 2) % 3, (long)(t + 2) << 5);
            SCHED0;
            if (B64) asm volatile("s_waitcnt vmcnt(6)" ::: "memory");
            else     asm volatile("s_waitcnt vmcnt(8)" ::: "memory");
            SCHED0;
        } else if (t + 1 < nt) {
            SCHED0;
            if (B64) asm volatile("s_waitcnt vmcnt(3)" ::: "memory");
            else     asm volatile("s_waitcnt vmcnt(4)" ::: "memory");
            SCHED0;
        } else {
            SCHED0; asm volatile("s_waitcnt vmcnt(0)" ::: "memory"); SCHED0;
        }
        SBAR; SCHED0;
        compute(db);
        SCHED0; LGKMCNT0; SCHED0; SBAR; SCHED0;
        db = (db + 1) % 3;
    }

    // ---- epilogue: stage C tile through LDS for coalesced stores ----
    if (WMODE == 0) {
        float* LF = (float*)&LDS[0];
        if (!B64) {
            #pragma unroll
            for (int h = 0; h < 2; ++h) {
                if (wc == h) {
                    #pragma unroll
                    for (int j = 0; j < 4; ++j) {
                        int gcol = n0 + h * 64 + j * 16 + lr;
                        float bv = (bias && gcol < N) ? bias[gcol] : 0.f;
                        #pragma unroll
                        for (int i = 0; i < NI; ++i) {
                            int row0 = wr * WROW + i * 16 + kg * 4;
                            #pragma unroll
                            for (int qq = 0; qq < 4; ++qq) {
                                float v = acc[i][j][qq] + bv;
                                if (RELU) v = fmaxf(v, 0.f);
                                LF[(row0 + qq) * 64 + j * 16 + lr] = v;
                            }
                        }
                    }
                }
                __syncthreads();
                #pragma unroll
                for (int i = 0; i < 16; ++i) {
                    int F = i * 256 + tid;
                    int row = F >> 5, col = (F & 31) * 2;
                    int gr = m0 + row, gc = n0 + h * 64 + col;
                    if (gr < M && gc < N)
                        *(float2*)(Cm + (long)gr * ldc + gc) = *(const float2*)&LF[row * 64 + col];
                }
                __syncthreads();
            }
        } else {
            #pragma unroll
            for (int j = 0; j < 4; ++j) {
                int gcol = n0 + wc * 64 + j * 16 + lr;
                float bv = (bias && gcol < N) ? bias[gcol] : 0.f;
                #pragma unroll
                for (int i = 0; i < NI; ++i) {
                    int row0 = wr * WROW + i * 16 + kg * 4;
                    #pragma unroll
                    for (int qq = 0; qq < 4; ++qq) {
                        float v = acc[i][j][qq] + bv;
                        if (RELU) v = fmaxf(v, 0.f);
                        LF[(row0 + qq) * 128 + wc * 64 + j * 16 + lr] = v;
                    }
                }
            }
            __syncthreads();
            #pragma unroll
            for (int i = 0; i < 16; ++i) {
                int F = i * 256 + tid;
                int row = F >> 6, col = (F & 63) * 2;
                int gr = m0 + row, gc = n0 + col;
                if (gr < M && gc < N)
                    *(float2*)(Cm + (long)gr * ldc + gc) = *(const float2*)&LF[row * 128 + col];
            }
        }
    } else {
        short* LS = (short*)&LDS[0];
        #pragma unroll
        for (int j = 0; j < 4; ++j) {
            int gcol = n0 + wc * 64 + j * 16 + lr;
            float bv = (bias && gcol < N) ? bias[gcol] : 0.f;
            #pragma unroll
            for (int i = 0; i < NI; ++i) {
                int row0 = wr * WROW + i * 16 + kg * 4;
                #pragma unroll
                for (int qq = 0; qq < 4; ++qq) {
                    float v = acc[i][j][qq] + bv;
                    if (RELU) v = fmaxf(v, 0.f);
                    LS[(row0 + qq) * 128 + wc * 64 + j * 16 + lr] = f2b(v);
                }
            }
        }
        __syncthreads();
        #pragma unroll
        for (int i = 0; i < BM / 16; ++i) {
            int F = i * 256 + tid;
            int row = F >> 4, col = (F & 15) * 8;
            int gr = m0 + row, gc = n0 + col;
            if (gr < M && gc < N)
                *(s16x8*)((short*)Cb + (long)gr * ldc + gc) = *(const s16x8*)&LS[row * 128 + col];
        }
    }
}

// ---------------------------------------------------------------------------
// Fallback fp32-B GEMM (logits only, if ws too small for bf16 wte mirror).
// ---------------------------------------------------------------------------
__global__ __launch_bounds__(256) void mgemm_f32b_kernel(
    const float* __restrict__ A, const float* __restrict__ Bv,
    const float* __restrict__ bias, float* __restrict__ Cm,
    int M, int N, int K, int ldc)
{
    __shared__ short As[128][40];
    __shared__ short Bs[128][40];
    const int tid  = threadIdx.x;
    const int lane = tid & 63, w = tid >> 6;
    const int wr = w >> 1, wc = w & 1;
    const int lr = lane & 15, kg = lane >> 4;
    const int m0 = blockIdx.y * 128, n0 = blockIdx.x * 128;
    const int ar = tid >> 3, ac = (tid & 7) * 4;
    const int br = tid >> 2, bc = (tid & 3) * 8;

    f32x4 acc[4][4];
    #pragma unroll
    for (int i = 0; i < 4; ++i)
        #pragma unroll
        for (int j = 0; j < 4; ++j)
            acc[i][j] = (f32x4){0.f, 0.f, 0.f, 0.f};

    for (int k0 = 0; k0 < K; k0 += 32) {
        #pragma unroll
        for (int p = 0; p < 4; ++p) {
            int row = ar + p * 32, gm = m0 + row;
            float4 f = {0.f, 0.f, 0.f, 0.f};
            if (gm < M) f = *(const float4*)(A + (long)gm * K + k0 + ac);
            s16x4 h; h[0] = f2b(f.x); h[1] = f2b(f.y); h[2] = f2b(f.z); h[3] = f2b(f.w);
            *(s16x4*)&As[row][ac] = h;
        }
        #pragma unroll
        for (int p = 0; p < 2; ++p) {
            int n = br + p * 64, gn = n0 + n;
            s16x8 h = (s16x8){0,0,0,0,0,0,0,0};
            if (gn < N) {
                float4 f0 = *(const float4*)(Bv + (long)gn * K + k0 + bc);
                float4 f1 = *(const float4*)(Bv + (long)gn * K + k0 + bc + 4);
                h[0]=f2b(f0.x); h[1]=f2b(f0.y); h[2]=f2b(f0.z); h[3]=f2b(f0.w);
                h[4]=f2b(f1.x); h[5]=f2b(f1.y); h[6]=f2b(f1.z); h[7]=f2b(f1.w);
            }
            *(s16x8*)&Bs[n][bc] = h;
        }
        __syncthreads();
        s16x8 af[4], bf[4];
        #pragma unroll
        for (int i = 0; i < 4; ++i) af[i] = *(const s16x8*)&As[wr*64 + i*16 + lr][kg*8];
        #pragma unroll
        for (int j = 0; j < 4; ++j) bf[j] = *(const s16x8*)&Bs[wc*64 + j*16 + lr][kg*8];
        #pragma unroll
        for (int i = 0; i < 4; ++i)
            #pragma unroll
            for (int j = 0; j < 4; ++j)
                acc[i][j] = __builtin_amdgcn_mfma_f32_16x16x32_bf16(af[i], bf[j], acc[i][j], 0, 0, 0);
        __syncthreads();
    }
    #pragma unroll
    for (int j = 0; j < 4; ++j) {
        int gcol = n0 + wc * 64 + j * 16 + lr;
        if (gcol >= N) continue;
        float bv = bias ? bias[gcol] : 0.f;
        #pragma unroll
        for (int i = 0; i < 4; ++i) {
            int grow0 = m0 + wr * 64 + i * 16 + kg * 4;
            #pragma unroll
            for (int qq = 0; qq < 4; ++qq) {
                int gr = grow0 + qq;
                if (gr >= M) continue;
                Cm[(long)gr * ldc + gcol] = acc[i][j][qq] + bv;
            }
        }
    }
}

// ---------------------------------------------------------------------------
// MFMA flash attention, KVBLK=128 (half the barrier/staging iterations).
// grid (16, H, B), 4 waves, 64 q-rows per block (16/wave).
// T14 async-split: K/V prefetched to REGISTERS one tile ahead; raw s_barrier.
// qkvb: [M,3072] bf16 (q|k|v, head h at col h*64). outb: [M,C] bf16.
// scale = 1/sqrt(C) = 1/32 (reference quirk).
// ---------------------------------------------------------------------------
template<bool CAUSAL>
__global__ __launch_bounds__(256) void fattn_kernel(
    const __hip_bfloat16* __restrict__ qkvb, __hip_bfloat16* __restrict__ outb)
{
    __shared__ short Ks[128][72];        // [s][d]   144B row stride
    __shared__ short Vt[64][136];        // [d][s]   272B row stride
    __shared__ short Ps[4][16][136];     // per-wave [q][s]

    const int q0 = blockIdx.x * 64;
    const int h = blockIdx.y, b = blockIdx.z;
    const int tid = threadIdx.x;
    const int lane = tid & 63, w = tid >> 6;
    const int lr = lane & 15, lg = lane >> 4;

    const float scale = 1.0f / 32.0f;
    const long base = (long)b * TT * 3072;
    const __hip_bfloat16* Kg = qkvb + base + 1024 + h * 64;
    const __hip_bfloat16* Vg = qkvb + base + 2048 + h * 64;

    s16x8 qf[2];
    {
        int qr = q0 + w * 16 + lr;
        #pragma unroll
        for (int kc = 0; kc < 2; ++kc) {
            s16x8 hv = (s16x8){0,0,0,0,0,0,0,0};
            if (qr < TT)
                hv = *(const s16x8*)(qkvb + base + (long)qr * 3072 + h * 64 + kc * 32 + lg * 8);
            qf[kc] = hv;
        }
    }

    f32x4 acc[4];
    #pragma unroll
    for (int jd = 0; jd < 4; ++jd) acc[jd] = (f32x4){0.f, 0.f, 0.f, 0.f};
    float mrun[4] = {-3.0e38f, -3.0e38f, -3.0e38f, -3.0e38f};
    float lrun[4] = {0.f, 0.f, 0.f, 0.f};

    const int send = CAUSAL ? min(TT, q0 + 64) : TT;
    const int nt = (send + 127) >> 7;
    const int sr4 = (tid >> 3) * 4;        // rows sr4..sr4+3
    const int dcc = (tid & 7) * 8;         // col chunk

    s16x8 kreg[4], vreg[4];
    auto loadkv = [&](int t) {
        int sbase = t * 128;
        #pragma unroll
        for (int rr = 0; rr < 4; ++rr) {
            int sg = sbase + sr4 + rr;
            if (sg < TT) {
                kreg[rr] = *(const s16x8*)(Kg + (long)sg * 3072 + dcc);
                vreg[rr] = *(const s16x8*)(Vg + (long)sg * 3072 + dcc);
            } else {
                kreg[rr] = (s16x8){0,0,0,0,0,0,0,0};
                vreg[rr] = (s16x8){0,0,0,0,0,0,0,0};
            }
        }
    };

    loadkv(0);
    for (int ti = 0; ti < nt; ++ti) {
        const int s0 = ti * 128;
        SCHED0; SBAR; SCHED0;          // prev tile's LDS reads done (all waves)
        #pragma unroll
        for (int rr = 0; rr < 4; ++rr)
            *(s16x8*)&Ks[sr4 + rr][dcc] = kreg[rr];
        #pragma unroll
        for (int pr = 0; pr < 2; ++pr) {
            #pragma unroll
            for (int e = 0; e < 8; ++e) {
                unsigned pack = (unsigned)(unsigned short)vreg[2*pr][e]
                              | ((unsigned)(unsigned short)vreg[2*pr + 1][e] << 16);
                *(unsigned*)&Vt[dcc + e][sr4 + 2*pr] = pack;
            }
        }
        if (ti + 1 < nt) loadkv(ti + 1);   // issue next tile's loads early
        SCHED0; LGKMCNT0; SCHED0; SBAR; SCHED0;   // LDS writes visible

        // ---- S = Q K^T over 128 kv cols (8 col-tiles) ----
        f32x4 sf[8];
        __builtin_amdgcn_s_setprio(1);
        #pragma unroll
        for (int j = 0; j < 8; ++j) {
            f32x4 z = (f32x4){0.f, 0.f, 0.f, 0.f};
            #pragma unroll
            for (int kc = 0; kc < 2; ++kc) {
                s16x8 kf = *(const s16x8*)&Ks[j * 16 + lr][kc * 32 + lg * 8];
                z = __builtin_amdgcn_mfma_f32_16x16x32_bf16(qf[kc], kf, z, 0, 0, 0);
            }
            sf[j] = z;
        }
        __builtin_amdgcn_s_setprio(0);

        float mloc[4] = {-3.0e38f, -3.0e38f, -3.0e38f, -3.0e38f};
        #pragma unroll
        for (int j = 0; j < 8; ++j) {
            int sg = s0 + j * 16 + lr;
            #pragma unroll
            for (int r = 0; r < 4; ++r) {
                float sc = sf[j][r] * scale;
                int qg = q0 + w * 16 + lg * 4 + r;
                if ((CAUSAL && sg > qg) || sg >= TT) sc = -3.0e38f;
                sf[j][r] = sc;
                mloc[r] = fmaxf(mloc[r], sc);
            }
        }
        #pragma unroll
        for (int r = 0; r < 4; ++r)
            #pragma unroll
            for (int off = 1; off < 16; off <<= 1)
                mloc[r] = fmaxf(mloc[r], __shfl_xor(mloc[r], off));

        float corr[4], psum[4];
        #pragma unroll
        for (int r = 0; r < 4; ++r) {
            float mn = fmaxf(mrun[r], mloc[r]);
            corr[r] = __expf(mrun[r] - mn);
            mrun[r] = mn;
            psum[r] = 0.f;
        }

        #pragma unroll
        for (int j = 0; j < 8; ++j) {
            #pragma unroll
            for (int r = 0; r < 4; ++r) {
                float p = __expf(sf[j][r] - mrun[r]);
                psum[r] += p;
                Ps[w][lg * 4 + r][j * 16 + lr] = f2b(p);
            }
        }
        #pragma unroll
        for (int r = 0; r < 4; ++r) {
            #pragma unroll
            for (int off = 1; off < 16; off <<= 1)
                psum[r] += __shfl_xor(psum[r], off);
            lrun[r] = lrun[r] * corr[r] + psum[r];
            #pragma unroll
            for (int jd = 0; jd < 4; ++jd) acc[jd][r] *= corr[r];
        }

        // ---- O += P @ V over K=128 (4 k-chunks) ----
        __builtin_amdgcn_s_setprio(1);
        #pragma unroll
        for (int kc = 0; kc < 4; ++kc) {
            s16x8 pa = *(const s16x8*)&Ps[w][lr][kc * 32 + lg * 8];
            #pragma unroll
            for (int jd = 0; jd < 4; ++jd) {
                s16x8 bv = *(const s16x8*)&Vt[jd * 16 + lr][kc * 32 + lg * 8];
                acc[jd] = __builtin_amdgcn_mfma_f32_16x16x32_bf16(pa, bv, acc[jd], 0, 0, 0);
            }
        }
        __builtin_amdgcn_s_setprio(0);
        SCHED0; LGKMCNT0; SCHED0;      // my LDS reads complete before next write
    }

    #pragma unroll
    for (int r = 0; r < 4; ++r) {
        int qg = q0 + w * 16 + lg * 4 + r;
        if (qg >= TT) continue;
        float inv = 1.0f / lrun[r];
        #pragma unroll
        for (int jd = 0; jd < 4; ++jd)
            outb[((long)b * TT + qg) * CC + h * 64 + jd * 16 + lr] =
                __float2bfloat16(acc[jd][r] * inv);
    }
}

// ---------------------------------------------------------------------------
// LayerNorm (+optional residual), fp32 out + optional bf16 mirror.
// ---------------------------------------------------------------------------
__global__ __launch_bounds__(256) void ln_kernel(
    const float* __restrict__ in, const float* __restrict__ res,
    const float* __restrict__ g, const float* __restrict__ b,
    float* __restrict__ out, __hip_bfloat16* __restrict__ outb)
{
    const int r = blockIdx.x, tid = threadIdx.x;
    __shared__ float sm[4];

    float4 xv = *(const float4*)(in + (long)r * CC + tid * 4);
    float s = xv.x + xv.y + xv.z + xv.w;
    #pragma unroll
    for (int o = 32; o > 0; o >>= 1) s += __shfl_xor(s, o);
    if ((tid & 63) == 0) sm[tid >> 6] = s;
    __syncthreads();
    const float mean = (sm[0] + sm[1] + sm[2] + sm[3]) * (1.0f / CC);
    __syncthreads();

    float4 d; d.x = xv.x - mean; d.y = xv.y - mean; d.z = xv.z - mean; d.w = xv.w - mean;
    float s2 = d.x * d.x + d.y * d.y + d.z * d.z + d.w * d.w;
    #pragma unroll
    for (int o = 32; o > 0; o >>= 1) s2 += __shfl_xor(s2, o);
    if ((tid & 63) == 0) sm[tid >> 6] = s2;
    __syncthreads();
    const float rstd = rsqrtf((sm[0] + sm[1] + sm[2] + sm[3]) * (1.0f / CC) + 1e-5f);

    float4 gv = *(const float4*)(g + tid * 4);
    float4 bv = *(const float4*)(b + tid * 4);
    float4 o;
    o.x = gv.x * d.x * rstd + bv.x; o.y = gv.y * d.y * rstd + bv.y;
    o.z = gv.z * d.z * rstd + bv.z; o.w = gv.w * d.w * rstd + bv.w;
    if (res) {
        float4 rv = *(const float4*)(res + (long)r * CC + tid * 4);
        o.x += rv.x; o.y += rv.y; o.z += rv.z; o.w += rv.w;
    }
    *(float4*)(out + (long)r * CC + tid * 4) = o;
    if (outb) {
        s16x4 h; h[0] = f2b(o.x); h[1] = f2b(o.y); h[2] = f2b(o.z); h[3] = f2b(o.w);
        *(s16x4*)(outb + (long)r * CC + tid * 4) = h;
    }
}

// ---------------------------------------------------------------------------
extern "C" void kernel_launch(void* const* d_in, const int* in_sizes, int n_in,
                              void* d_out, int out_size, void* d_ws, size_t ws_size,
                              hipStream_t stream)
{
    const int*   x      = (const int*)  d_in[0];
    const int*   y      = (const int*)  d_in[1];
    const float* wte    = (const float*)d_in[2];
    const float* wpe_x  = (const float*)d_in[3];
    const float* wpe_y  = (const float*)d_in[4];
    const float* eWq    = (const float*)d_in[5];
    const float* eWk    = (const float*)d_in[6];
    const float* eWv    = (const float*)d_in[7];
    const float* epw    = (const float*)d_in[8];
    const float* epb    = (const float*)d_in[9];
    const float* eln1g  = (const float*)d_in[10];
    const float* eln1b  = (const float*)d_in[11];
    const float* eln2g  = (const float*)d_in[12];
    const float* eln2b  = (const float*)d_in[13];
    const float* ew1    = (const float*)d_in[14];
    const float* eb1    = (const float*)d_in[15];
    const float* ew2    = (const float*)d_in[16];
    const float* eb2    = (const float*)d_in[17];
    const float* dsWq   = (const float*)d_in[18];
    const float* dsWk   = (const float*)d_in[19];
    const float* dsWv   = (const float*)d_in[20];
    const float* dspw   = (const float*)d_in[21];
    const float* dspb   = (const float*)d_in[22];
    const float* dcWq   = (const float*)d_in[23];
    const float* dcWk   = (const float*)d_in[24];
    const float* dcWv   = (const float*)d_in[25];
    const float* dcpw   = (const float*)d_in[26];
    const float* dcpb   = (const float*)d_in[27];
    const float* dln1g  = (const float*)d_in[28];
    const float* dln1b  = (const float*)d_in[29];
    const float* dln2g  = (const float*)d_in[30];
    const float* dln2b  = (const float*)d_in[31];
    const float* dln3g  = (const float*)d_in[32];
    const float* dln3b  = (const float*)d_in[33];
    const float* dw1    = (const float*)d_in[34];
    const float* db1    = (const float*)d_in[35];
    const float* dw2    = (const float*)d_in[36];
    const float* db2    = (const float*)d_in[37];
    const float* lnfg   = (const float*)d_in[38];
    const float* lnfb   = (const float*)d_in[39];
    const float* lm_b   = (const float*)d_in[40];

    float* out = (float*)d_out;

    // ---- workspace carve-up ----
    const size_t MCp = (size_t)MP * CC;
    float* enc = (float*)d_ws;
    float* dec = enc + MCp;
    float* t0  = dec + MCp;
    __hip_bfloat16* encb = (__hip_bfloat16*)(t0 + MCp);
    __hip_bfloat16* decb = encb + MCp;
    __hip_bfloat16* t0b  = decb + MCp;
    __hip_bfloat16* a0b  = t0b + MCp;
    __hip_bfloat16* qkvb = a0b + MCp;                    // [MP][3072]
    __hip_bfloat16* ffb  = qkvb + (size_t)MP * 3072;     // [MP][FFD]
    __hip_bfloat16* wteb = ffb + (size_t)MP * FFD;       // [VP][C]
    // big-mode weight blocks
    __hip_bfloat16* eQKVw = wteb + (size_t)VP * CC;      // [L][3072][C]
    __hip_bfloat16* ePWw  = eQKVw + (size_t)LL * 3072 * CC;
    __hip_bfloat16* eW1w  = ePWw  + (size_t)LL * CC * CC;     // [L][FFD][C]
    __hip_bfloat16* eW2w  = eW1w  + (size_t)LL * FFD * CC;    // [L][C][FFD]
    __hip_bfloat16* sQKVw = eW2w  + (size_t)LL * CC * FFD;
    __hip_bfloat16* sPWw  = sQKVw + (size_t)LL * 3072 * CC;
    __hip_bfloat16* cQKVw = sPWw  + (size_t)LL * CC * CC;
    __hip_bfloat16* cPWw  = cQKVw + (size_t)LL * 3072 * CC;
    __hip_bfloat16* dW1w  = cPWw  + (size_t)LL * CC * CC;
    __hip_bfloat16* dW2w  = dW1w  + (size_t)LL * FFD * CC;
    __hip_bfloat16* bigEnd = dW2w + (size_t)LL * CC * FFD;
    // small-mode: per-use conversion buffer where eQKVw starts
    __hip_bfloat16* wb = eQKVw;
    const size_t needBig   = (size_t)((char*)bigEnd - (char*)d_ws);
    const size_t needSmall = (size_t)((char*)(wb + (size_t)FFD * CC) - (char*)d_ws);
    const size_t needWteb  = (size_t)((char*)eQKVw - (char*)d_ws);
    const bool big     = (ws_size >= needBig);
    const bool useWteb = (ws_size >= needWteb) &&
                         (big || ws_size >= needSmall);

    const int QT = (TT + 63) / 64;     // 16 q-tiles
    const dim3 tblk(32, 8);

    auto gemm = [&](const __hip_bfloat16* A, const __hip_bfloat16* B,
                    const float* bias, float* Cm, __hip_bfloat16* Cb,
                    int N_, int K_, int ldc, int wmode, bool relu) {
        const bool b64 = (N_ <= 2048);          // small-N: double the grid
        const int GMv = b64 ? MP / 64 : MP / 128;
        int nwg = GMv * ((N_ + 127) / 128);
        if (wmode == 0) {
            if (b64) {
                if (relu) mgemm2_kernel<0, true , true ><<<nwg, 256, 0, stream>>>(A, B, bias, Cm, Cb, MM, N_, K_, ldc, GMv);
                else      mgemm2_kernel<0, false, true ><<<nwg, 256, 0, stream>>>(A, B, bias, Cm, Cb, MM, N_, K_, ldc, GMv);
            } else {
                if (relu) mgemm2_kernel<0, true , false><<<nwg, 256, 0, stream>>>(A, B, bias, Cm, Cb, MM, N_, K_, ldc, GMv);
                else      mgemm2_kernel<0, false, false><<<nwg, 256, 0, stream>>>(A, B, bias, Cm, Cb, MM, N_, K_, ldc, GMv);
            }
        } else {
            if (b64) {
                if (relu) mgemm2_kernel<2, true , true ><<<nwg, 256, 0, stream>>>(A, B, bias, Cm, Cb, MM, N_, K_, ldc, GMv);
                else      mgemm2_kernel<2, false, true ><<<nwg, 256, 0, stream>>>(A, B, bias, Cm, Cb, MM, N_, K_, ldc, GMv);
            } else {
                if (relu) mgemm2_kernel<2, true , false><<<nwg, 256, 0, stream>>>(A, B, bias, Cm, Cb, MM, N_, K_, ldc, GMv);
                else      mgemm2_kernel<2, false, false><<<nwg, 256, 0, stream>>>(A, B, bias, Cm, Cb, MM, N_, K_, ldc, GMv);
            }
        }
    };

    if (useWteb) {
        long n = (long)VV * CC;
        cvtb_kernel<<<(int)((n / 8 + 255) / 256), 256, 0, stream>>>(wte, wteb, n);
    }

    if (big) {
        // ---- all weight conversions up-front ----
        const long sWH = (long)CC * HSZ;            // per-(l,h) input stride
        const long oA = (long)3072 * CC;            // per-layer qkv out stride
        const long oB = (long)HSZ * CC;             // per-head out stride
        dim3 gq(HSZ / 32, CC / 32, LL * HH);
        tcvt_kernel<<<gq, tblk, 0, stream>>>(eWq, eQKVw,             CC, HSZ, sWH, oA, oB, HH);
        tcvt_kernel<<<gq, tblk, 0, stream>>>(eWk, eQKVw + CC * CC,   CC, HSZ, sWH, oA, oB, HH);
        tcvt_kernel<<<gq, tblk, 0, stream>>>(eWv, eQKVw + 2*CC*CC,   CC, HSZ, sWH, oA, oB, HH);
        tcvt_kernel<<<gq, tblk, 0, stream>>>(dsWq, sQKVw,            CC, HSZ, sWH, oA, oB, HH);
        tcvt_kernel<<<gq, tblk, 0, stream>>>(dsWk, sQKVw + CC * CC,  CC, HSZ, sWH, oA, oB, HH);
        tcvt_kernel<<<gq, tblk, 0, stream>>>(dsWv, sQKVw + 2*CC*CC,  CC, HSZ, sWH, oA, oB, HH);
        tcvt_kernel<<<gq, tblk, 0, stream>>>(dcWq, cQKVw,            CC, HSZ, sWH, oA, oB, HH);
        tcvt_kernel<<<gq, tblk, 0, stream>>>(dcWk, cQKVw + CC * CC,  CC, HSZ, sWH, oA, oB, HH);
        tcvt_kernel<<<gq, tblk, 0, stream>>>(dcWv, cQKVw + 2*CC*CC,  CC, HSZ, sWH, oA, oB, HH);
        dim3 gp(CC / 32, CC / 32, LL);
        tcvt_kernel<<<gp, tblk, 0, stream>>>(epw,  ePWw, CC, CC, (long)CC*CC, (long)CC*CC, 0, 1);
        tcvt_kernel<<<gp, tblk, 0, stream>>>(dspw, sPWw, CC, CC, (long)CC*CC, (long)CC*CC, 0, 1);
        tcvt_kernel<<<gp, tblk, 0, stream>>>(dcpw, cPWw, CC, CC, (long)CC*CC, (long)CC*CC, 0, 1);
        dim3 g1(FFD / 32, CC / 32, LL);
        tcvt_kernel<<<g1, tblk, 0, stream>>>(ew1, eW1w, CC, FFD, (long)CC*FFD, (long)FFD*CC, 0, 1);
        tcvt_kernel<<<g1, tblk, 0, stream>>>(dw1, dW1w, CC, FFD, (long)CC*FFD, (long)FFD*CC, 0, 1);
        dim3 g2(CC / 32, FFD / 32, LL);
        tcvt_kernel<<<g2, tblk, 0, stream>>>(ew2, eW2w, FFD, CC, (long)FFD*CC, (long)CC*FFD, 0, 1);
        tcvt_kernel<<<g2, tblk, 0, stream>>>(dw2, dW2w, FFD, CC, (long)FFD*CC, (long)CC*FFD, 0, 1);
    }

    // small-mode per-use converters
    auto cvt_qkv = [&](const float* Wq, const float* Wk, const float* Wv) {
        dim3 g(HSZ / 32, CC / 32, HH);
        tcvt_kernel<<<g, tblk, 0, stream>>>(Wq, wb,             CC, HSZ, (long)CC*HSZ, (long)HSZ*CC, 0, 1);
        tcvt_kernel<<<g, tblk, 0, stream>>>(Wk, wb + CC*CC,     CC, HSZ, (long)CC*HSZ, (long)HSZ*CC, 0, 1);
        tcvt_kernel<<<g, tblk, 0, stream>>>(Wv, wb + 2*CC*CC,   CC, HSZ, (long)CC*HSZ, (long)HSZ*CC, 0, 1);
    };
    auto cvt_nt = [&](const float* W, int R, int S) {
        dim3 g(S / 32, R / 32, 1);
        tcvt_kernel<<<g, tblk, 0, stream>>>(W, wb, R, S, 0, 0, 0, 1);
    };

    // ---- encoder ----
    embed_kernel<<<MM, 256, 0, stream>>>(x, wte, wpe_x, enc, encb);
    for (int i = 0; i < LL; ++i) {
        const long cOff = (long)i * CC;
        const __hip_bfloat16 *Wqkv, *Wp, *W1, *W2;
        if (big) {
            Wqkv = eQKVw + (size_t)i * 3072 * CC;
            Wp   = ePWw  + (size_t)i * CC * CC;
            W1   = eW1w  + (size_t)i * FFD * CC;
            W2   = eW2w  + (size_t)i * CC * FFD;
        }
        if (!big) cvt_qkv(eWq + (long)i*HH*CC*HSZ, eWk + (long)i*HH*CC*HSZ, eWv + (long)i*HH*CC*HSZ), Wqkv = wb;
        gemm(encb, Wqkv, nullptr, nullptr, qkvb, 3072, CC, 3072, 2, false);
        fattn_kernel<false><<<dim3(QT, HH, BB), 256, 0, stream>>>(qkvb, a0b);
        if (!big) cvt_nt(epw + (long)i*CC*CC, CC, CC), Wp = wb;
        gemm(a0b, Wp, epb + cOff, t0, nullptr, CC, CC, CC, 0, false);
        ln_kernel<<<MM, 256, 0, stream>>>(t0, enc, eln1g + cOff, eln1b + cOff, enc, encb);
        if (!big) cvt_nt(ew1 + (long)i*CC*FFD, CC, FFD), W1 = wb;
        gemm(encb, W1, eb1 + (long)i*FFD, nullptr, ffb, FFD, CC, FFD, 2, true);
        if (!big) cvt_nt(ew2 + (long)i*FFD*CC, FFD, CC), W2 = wb;
        gemm(ffb, W2, eb2 + cOff, t0, nullptr, CC, FFD, CC, 0, false);
        ln_kernel<<<MM, 256, 0, stream>>>(t0, enc, eln2g + cOff, eln2b + cOff, enc, encb);
    }

    // ---- decoder ----
    embed_kernel<<<MM, 256, 0, stream>>>(y, wte, wpe_y, dec, decb);
    for (int i = 0; i < LL; ++i) {
        const long cOff = (long)i * CC;
        const __hip_bfloat16 *Ws, *Wsp, *Wc, *Wcp, *W1, *W2;
        if (big) {
            Ws  = sQKVw + (size_t)i * 3072 * CC;
            Wsp = sPWw  + (size_t)i * CC * CC;
            Wc  = cQKVw + (size_t)i * 3072 * CC;
            Wcp = cPWw  + (size_t)i * CC * CC;
            W1  = dW1w  + (size_t)i * FFD * CC;
            W2  = dW2w  + (size_t)i * CC * FFD;
        }
        // masked self-attn
        if (!big) cvt_qkv(dsWq + (long)i*HH*CC*HSZ, dsWk + (long)i*HH*CC*HSZ, dsWv + (long)i*HH*CC*HSZ), Ws = wb;
        gemm(decb, Ws, nullptr, nullptr, qkvb, 3072, CC, 3072, 2, false);
        fattn_kernel<true><<<dim3(QT, HH, BB), 256, 0, stream>>>(qkvb, a0b);
        if (!big) cvt_nt(dspw + (long)i*CC*CC, CC, CC), Wsp = wb;
        gemm(a0b, Wsp, dspb + cOff, t0, nullptr, CC, CC, CC, 0, false);
        ln_kernel<<<MM, 256, 0, stream>>>(t0, dec, dln1g + cOff, dln1b + cOff, dec, decb);
        // cross-attn: q from dec, k/v from enc
        if (!big) cvt_qkv(dcWq + (long)i*HH*CC*HSZ, dcWk + (long)i*HH*CC*HSZ, dcWv + (long)i*HH*CC*HSZ), Wc = wb;
        gemm(decb, Wc, nullptr, nullptr, qkvb, CC, CC, 3072, 2, false);
        gemm(encb, Wc + (size_t)CC * CC, nullptr, nullptr, qkvb + CC, 2048, CC, 3072, 2, false);
        fattn_kernel<false><<<dim3(QT, HH, BB), 256, 0, stream>>>(qkvb, a0b);
        if (!big) cvt_nt(dcpw + (long)i*CC*CC, CC, CC), Wcp = wb;
        gemm(a0b, Wcp, dcpb + cOff, t0, nullptr, CC, CC, CC, 0, false);
        ln_kernel<<<MM, 256, 0, stream>>>(t0, dec, dln2g + cOff, dln2b + cOff, dec, decb);
        // ffn
        if (!big) cvt_nt(dw1 + (long)i*CC*FFD, CC, FFD), W1 = wb;
        gemm(decb, W1, db1 + (long)i*FFD, nullptr, ffb, FFD, CC, FFD, 2, true);
        if (!big) cvt_nt(dw2 + (long)i*FFD*CC, FFD, CC), W2 = wb;
        gemm(ffb, W2, db2 + cOff, t0, nullptr, CC, FFD, CC, 0, false);
        ln_kernel<<<MM, 256, 0, stream>>>(t0, dec, dln3g + cOff, dln3b + cOff, dec, decb);
    }

    // ---- final LN + logits (M-split: keep the 2 MB A half-panel L2-resident) ----
    ln_kernel<<<MM, 256, 0, stream>>>(dec, nullptr, lnfg, lnfb, t0, t0b);
    if (useWteb) {
        const int GMv = 1024 / 128;                 // 8 m-tiles per half
        const int nwg = GMv * ((VV + 127) / 128);
        mgemm2_kernel<0, false, false><<<nwg, 256, 0, stream>>>(
            t0b, wteb, lm_b, out, nullptr, 1024, VV, CC, VV, GMv);
        mgemm2_kernel<0, false, false><<<nwg, 256, 0, stream>>>(
            t0b + (size_t)1024 * CC, wteb, lm_b, out + (size_t)1024 * VV, nullptr,
            MM - 1024, VV, CC, VV, GMv);
    } else {
        dim3 grid((VV + 127) / 128, MP / 128);
        mgemm_f32b_kernel<<<grid, 256, 0, stream>>>(t0, wte, lm_b, out, MM, VV, CC, VV);
    }
}

// Round 12
// 3093.316 us; speedup vs baseline: 18.7716x; 1.0110x over previous
//
#include <hip/hip_runtime.h>
#include <hip/hip_bf16.h>

#define BB 2
#define TT 1023
#define CC 1024
#define HH 16
#define HSZ 64
#define LL 6
#define FFD 4096
#define VV 50258
#define MM (BB*TT)   // 2046
#define MP 2048      // padded row count
#define VP 50304     // padded vocab (multiple of 128)

typedef __attribute__((ext_vector_type(4))) float  f32x4;
typedef __attribute__((ext_vector_type(8))) short  s16x8;
typedef __attribute__((ext_vector_type(4))) short  s16x4;

#define SCHED0   __builtin_amdgcn_sched_barrier(0)
#define SBAR     __builtin_amdgcn_s_barrier()
#define LGKMCNT0 asm volatile("s_waitcnt lgkmcnt(0)" ::: "memory")

__device__ __forceinline__ short f2b(float x) {
    __hip_bfloat16 h = __float2bfloat16(x);
    short s;
    __builtin_memcpy(&s, &h, 2);
    return s;
}
__device__ __forceinline__ float b2f(short s) {
    unsigned u = ((unsigned)(unsigned short)s) << 16;
    float f;
    __builtin_memcpy(&f, &u, 4);
    return f;
}

__device__ __forceinline__ void gld16(const void* g, void* l) {
    __builtin_amdgcn_global_load_lds(
        (__attribute__((address_space(1))) const void*)g,
        (__attribute__((address_space(3))) void*)l, 16, 0, 0);
}

// ---------------------------------------------------------------------------
// Embedding: fp32 + bf16 mirror
// ---------------------------------------------------------------------------
__global__ __launch_bounds__(256) void embed_kernel(
    const int* __restrict__ ids, const float* __restrict__ wte,
    const float* __restrict__ wpe, float* __restrict__ out,
    __hip_bfloat16* __restrict__ outb)
{
    int r = blockIdx.x;
    int t = r % TT;
    long id = ids[r];
    int c = threadIdx.x * 4;
    float4 a = *(const float4*)(wte + id * (long)CC + c);
    float4 p = *(const float4*)(wpe + (long)t * CC + c);
    float4 o; o.x = a.x + p.x; o.y = a.y + p.y; o.z = a.z + p.z; o.w = a.w + p.w;
    *(float4*)(out + (long)r * CC + c) = o;
    s16x4 h; h[0] = f2b(o.x); h[1] = f2b(o.y); h[2] = f2b(o.z); h[3] = f2b(o.w);
    *(s16x4*)(outb + (long)r * CC + c) = h;
}

// ---------------------------------------------------------------------------
// Elementwise fp32 -> bf16
// ---------------------------------------------------------------------------
__global__ __launch_bounds__(256) void cvtb_kernel(
    const float* __restrict__ in, __hip_bfloat16* __restrict__ out, long n)
{
    long i = ((long)blockIdx.x * 256 + threadIdx.x) * 8;
    if (i >= n) return;
    float4 f0 = *(const float4*)(in + i);
    float4 f1 = *(const float4*)(in + i + 4);
    s16x8 h;
    h[0]=f2b(f0.x); h[1]=f2b(f0.y); h[2]=f2b(f0.z); h[3]=f2b(f0.w);
    h[4]=f2b(f1.x); h[5]=f2b(f1.y); h[6]=f2b(f1.z); h[7]=f2b(f1.w);
    *(s16x8*)(out + i) = h;
}

// ---------------------------------------------------------------------------
// Transpose + fp32->bf16: in [R][S] fp32 -> out [S][R] bf16, batched over z.
// ---------------------------------------------------------------------------
__global__ __launch_bounds__(256) void tcvt_kernel(
    const float* __restrict__ in, __hip_bfloat16* __restrict__ out,
    int R, int S, long inZ, long outZa, long outZb, int zdiv)
{
    int z = blockIdx.z;
    in  += (long)z * inZ;
    out += (long)(z / zdiv) * outZa + (long)(z % zdiv) * outZb;
    __shared__ float tile[32][33];
    int s0 = blockIdx.x * 32, r0 = blockIdx.y * 32;
    int tx = threadIdx.x, ty = threadIdx.y;
    #pragma unroll
    for (int i = 0; i < 4; ++i)
        tile[ty + i * 8][tx] = in[(long)(r0 + ty + i * 8) * S + s0 + tx];
    __syncthreads();
    #pragma unroll
    for (int i = 0; i < 4; ++i)
        out[(long)(s0 + ty + i * 8) * R + r0 + tx] =
            __float2bfloat16(tile[tx][ty + i * 8]);
}

// ---------------------------------------------------------------------------
// bf16 MFMA GEMM, T3+T4 pipelined, T2-swizzled, XCD-swizzled.
// BM template: B64=false -> 128x128 tile; B64=true -> 64x128 tile (N<=2048).
// 3 LDS buffers, 2-deep prefetch, counted vmcnt, raw s_barrier, setprio.
// C = act(A @ B^T + bias). A [pad(M,BM)][K] bf16, B [pad(N,128)][K] bf16.
// WMODE: 0 = fp32 out (float2-coalesced), 2 = bf16 out (b128-coalesced).
// ---------------------------------------------------------------------------
template<int WMODE, bool RELU, bool B64>
__global__ __launch_bounds__(256) void mgemm2_kernel(
    const __hip_bfloat16* __restrict__ A, const __hip_bfloat16* __restrict__ B,
    const float* __restrict__ bias, float* __restrict__ Cm,
    __hip_bfloat16* __restrict__ Cb,
    int M, int N, int K, int ldc, int GM)
{
    constexpr int BM   = B64 ? 64 : 128;
    constexpr int ASZ  = BM * 32;
    constexpr int BSZ  = 128 * 32;
    constexpr int BUF  = ASZ + BSZ;
    constexpr int WROW = BM / 2;
    constexpr int NI   = WROW / 16;
    constexpr int NAC  = BM / 64;
    __shared__ short LDS[3 * BUF];

    // bijective XCD swizzle + m-fastest decode
    const int nwg = gridDim.x;
    const int bid = blockIdx.x;
    const int q = nwg >> 3, r = nwg & 7;
    const int xcd = bid & 7, lid = bid >> 3;
    const int swz = (xcd < r) ? xcd * (q + 1) + lid
                              : r * (q + 1) + (xcd - r) * q + lid;
    const int m0 = (swz % GM) * BM;
    const int n0 = (swz / GM) * 128;

    const int tid  = threadIdx.x;
    const int lane = tid & 63, w = tid >> 6;
    const int wr = w >> 1, wc = w & 1;
    const int lr = lane & 15, kg = lane >> 4;

    const __hip_bfloat16* Abase = A + (long)m0 * K;
    const __hip_bfloat16* Bbase = B + (long)n0 * K;

    f32x4 acc[NI][4];
    #pragma unroll
    for (int i = 0; i < NI; ++i)
        #pragma unroll
        for (int j = 0; j < 4; ++j)
            acc[i][j] = (f32x4){0.f, 0.f, 0.f, 0.f};

    const int srow = lane >> 2;
    const int scol = (((lane & 3) ^ ((lane >> 3) & 3))) * 8;   // swizzled src

    auto stage = [&](int db, long kofs) {
        short* Ad = &LDS[db * BUF];
        short* Bd = Ad + ASZ;
        #pragma unroll
        for (int p = 0; p < NAC; ++p) {
            int cc = p * 4 + w;
            long ro = (long)(cc * 16 + srow) * K + kofs + scol;
            gld16(Abase + ro, Ad + cc * 512);
        }
        #pragma unroll
        for (int p = 0; p < 2; ++p) {
            int cc = p * 4 + w;
            long ro = (long)(cc * 16 + srow) * K + kofs + scol;
            gld16(Bbase + ro, Bd + cc * 512);
        }
    };
    const int rslot = (kg ^ ((lr >> 1) & 3)) * 8;

    auto compute = [&](int db) {
        const short* Ar = &LDS[db * BUF];
        const short* Br = Ar + ASZ;
        s16x8 af[NI], bf[4];
        #pragma unroll
        for (int i = 0; i < NI; ++i)
            af[i] = *(const s16x8*)&Ar[(wr * WROW + i * 16 + lr) * 32 + rslot];
        #pragma unroll
        for (int j = 0; j < 4; ++j)
            bf[j] = *(const s16x8*)&Br[(wc * 64 + j * 16 + lr) * 32 + rslot];
        __builtin_amdgcn_s_setprio(1);
        #pragma unroll
        for (int i = 0; i < NI; ++i)
            #pragma unroll
            for (int j = 0; j < 4; ++j)
                acc[i][j] = __builtin_amdgcn_mfma_f32_16x16x32_bf16(
                    af[i], bf[j], acc[i][j], 0, 0, 0);
        __builtin_amdgcn_s_setprio(0);
    };

    const int nt = K >> 5;
    stage(0, 0);
    if (nt > 1) stage(1, 32);
    int db = 0;
    for (int t = 0; t < nt; ++t) {
        if (t + 2 < nt) {
            stage((db + 2) % 3, (long)(t + 2) << 5);
            SCHED0;
            if (B64) asm volatile("s_waitcnt vmcnt(6)" ::: "memory");
            else     asm volatile("s_waitcnt vmcnt(8)" ::: "memory");
            SCHED0;
        } else if (t + 1 < nt) {
            SCHED0;
            if (B64) asm volatile("s_waitcnt vmcnt(3)" ::: "memory");
            else     asm volatile("s_waitcnt vmcnt(4)" ::: "memory");
            SCHED0;
        } else {
            SCHED0; asm volatile("s_waitcnt vmcnt(0)" ::: "memory"); SCHED0;
        }
        SBAR; SCHED0;
        compute(db);
        SCHED0; LGKMCNT0; SCHED0; SBAR; SCHED0;
        db = (db + 1) % 3;
    }

    // ---- epilogue: stage C tile through LDS for coalesced stores ----
    if (WMODE == 0) {
        float* LF = (float*)&LDS[0];
        if (!B64) {
            #pragma unroll
            for (int h = 0; h < 2; ++h) {
                if (wc == h) {
                    #pragma unroll
                    for (int j = 0; j < 4; ++j) {
                        int gcol = n0 + h * 64 + j * 16 + lr;
                        float bv = (bias && gcol < N) ? bias[gcol] : 0.f;
                        #pragma unroll
                        for (int i = 0; i < NI; ++i) {
                            int row0 = wr * WROW + i * 16 + kg * 4;
                            #pragma unroll
                            for (int qq = 0; qq < 4; ++qq) {
                                float v = acc[i][j][qq] + bv;
                                if (RELU) v = fmaxf(v, 0.f);
                                LF[(row0 + qq) * 64 + j * 16 + lr] = v;
                            }
                        }
                    }
                }
                __syncthreads();
                #pragma unroll
                for (int i = 0; i < 16; ++i) {
                    int F = i * 256 + tid;
                    int row = F >> 5, col = (F & 31) * 2;
                    int gr = m0 + row, gc = n0 + h * 64 + col;
                    if (gr < M && gc < N)
                        *(float2*)(Cm + (long)gr * ldc + gc) = *(const float2*)&LF[row * 64 + col];
                }
                __syncthreads();
            }
        } else {
            #pragma unroll
            for (int j = 0; j < 4; ++j) {
                int gcol = n0 + wc * 64 + j * 16 + lr;
                float bv = (bias && gcol < N) ? bias[gcol] : 0.f;
                #pragma unroll
                for (int i = 0; i < NI; ++i) {
                    int row0 = wr * WROW + i * 16 + kg * 4;
                    #pragma unroll
                    for (int qq = 0; qq < 4; ++qq) {
                        float v = acc[i][j][qq] + bv;
                        if (RELU) v = fmaxf(v, 0.f);
                        LF[(row0 + qq) * 128 + wc * 64 + j * 16 + lr] = v;
                    }
                }
            }
            __syncthreads();
            #pragma unroll
            for (int i = 0; i < 16; ++i) {
                int F = i * 256 + tid;
                int row = F >> 6, col = (F & 63) * 2;
                int gr = m0 + row, gc = n0 + col;
                if (gr < M && gc < N)
                    *(float2*)(Cm + (long)gr * ldc + gc) = *(const float2*)&LF[row * 128 + col];
            }
        }
    } else {
        short* LS = (short*)&LDS[0];
        #pragma unroll
        for (int j = 0; j < 4; ++j) {
            int gcol = n0 + wc * 64 + j * 16 + lr;
            float bv = (bias && gcol < N) ? bias[gcol] : 0.f;
            #pragma unroll
            for (int i = 0; i < NI; ++i) {
                int row0 = wr * WROW + i * 16 + kg * 4;
                #pragma unroll
                for (int qq = 0; qq < 4; ++qq) {
                    float v = acc[i][j][qq] + bv;
                    if (RELU) v = fmaxf(v, 0.f);
                    LS[(row0 + qq) * 128 + wc * 64 + j * 16 + lr] = f2b(v);
                }
            }
        }
        __syncthreads();
        #pragma unroll
        for (int i = 0; i < BM / 16; ++i) {
            int F = i * 256 + tid;
            int row = F >> 4, col = (F & 15) * 8;
            int gr = m0 + row, gc = n0 + col;
            if (gr < M && gc < N)
                *(s16x8*)((short*)Cb + (long)gr * ldc + gc) = *(const s16x8*)&LS[row * 128 + col];
        }
    }
}

// ---------------------------------------------------------------------------
// Fallback fp32-B GEMM (logits only, if ws too small for bf16 wte mirror).
// ---------------------------------------------------------------------------
__global__ __launch_bounds__(256) void mgemm_f32b_kernel(
    const float* __restrict__ A, const float* __restrict__ Bv,
    const float* __restrict__ bias, float* __restrict__ Cm,
    int M, int N, int K, int ldc)
{
    __shared__ short As[128][40];
    __shared__ short Bs[128][40];
    const int tid  = threadIdx.x;
    const int lane = tid & 63, w = tid >> 6;
    const int wr = w >> 1, wc = w & 1;
    const int lr = lane & 15, kg = lane >> 4;
    const int m0 = blockIdx.y * 128, n0 = blockIdx.x * 128;
    const int ar = tid >> 3, ac = (tid & 7) * 4;
    const int br = tid >> 2, bc = (tid & 3) * 8;

    f32x4 acc[4][4];
    #pragma unroll
    for (int i = 0; i < 4; ++i)
        #pragma unroll
        for (int j = 0; j < 4; ++j)
            acc[i][j] = (f32x4){0.f, 0.f, 0.f, 0.f};

    for (int k0 = 0; k0 < K; k0 += 32) {
        #pragma unroll
        for (int p = 0; p < 4; ++p) {
            int row = ar + p * 32, gm = m0 + row;
            float4 f = {0.f, 0.f, 0.f, 0.f};
            if (gm < M) f = *(const float4*)(A + (long)gm * K + k0 + ac);
            s16x4 h; h[0] = f2b(f.x); h[1] = f2b(f.y); h[2] = f2b(f.z); h[3] = f2b(f.w);
            *(s16x4*)&As[row][ac] = h;
        }
        #pragma unroll
        for (int p = 0; p < 2; ++p) {
            int n = br + p * 64, gn = n0 + n;
            s16x8 h = (s16x8){0,0,0,0,0,0,0,0};
            if (gn < N) {
                float4 f0 = *(const float4*)(Bv + (long)gn * K + k0 + bc);
                float4 f1 = *(const float4*)(Bv + (long)gn * K + k0 + bc + 4);
                h[0]=f2b(f0.x); h[1]=f2b(f0.y); h[2]=f2b(f0.z); h[3]=f2b(f0.w);
                h[4]=f2b(f1.x); h[5]=f2b(f1.y); h[6]=f2b(f1.z); h[7]=f2b(f1.w);
            }
            *(s16x8*)&Bs[n][bc] = h;
        }
        __syncthreads();
        s16x8 af[4], bf[4];
        #pragma unroll
        for (int i = 0; i < 4; ++i) af[i] = *(const s16x8*)&As[wr*64 + i*16 + lr][kg*8];
        #pragma unroll
        for (int j = 0; j < 4; ++j) bf[j] = *(const s16x8*)&Bs[wc*64 + j*16 + lr][kg*8];
        #pragma unroll
        for (int i = 0; i < 4; ++i)
            #pragma unroll
            for (int j = 0; j < 4; ++j)
                acc[i][j] = __builtin_amdgcn_mfma_f32_16x16x32_bf16(af[i], bf[j], acc[i][j], 0, 0, 0);
        __syncthreads();
    }
    #pragma unroll
    for (int j = 0; j < 4; ++j) {
        int gcol = n0 + wc * 64 + j * 16 + lr;
        if (gcol >= N) continue;
        float bv = bias ? bias[gcol] : 0.f;
        #pragma unroll
        for (int i = 0; i < 4; ++i) {
            int grow0 = m0 + wr * 64 + i * 16 + kg * 4;
            #pragma unroll
            for (int qq = 0; qq < 4; ++qq) {
                int gr = grow0 + qq;
                if (gr >= M) continue;
                Cm[(long)gr * ldc + gcol] = acc[i][j][qq] + bv;
            }
        }
    }
}

// ---------------------------------------------------------------------------
// MFMA flash attention, KVBLK=128. grid (16, H, B), 4 waves, 64 q-rows/block.
// T14 async reg-prefetch; T13 defer-max (skip rescale when max growth <= 8);
// Q pre-scaled by 1/32 (power of two -> exact in bf16).
// qkvb: [M,3072] bf16 (q|k|v, head h at col h*64). outb: [M,C] bf16.
// ---------------------------------------------------------------------------
template<bool CAUSAL>
__global__ __launch_bounds__(256) void fattn_kernel(
    const __hip_bfloat16* __restrict__ qkvb, __hip_bfloat16* __restrict__ outb)
{
    __shared__ short Ks[128][72];        // [s][d]
    __shared__ short Vt[64][136];        // [d][s]
    __shared__ short Ps[4][16][136];     // per-wave [q][s]

    const int q0 = blockIdx.x * 64;
    const int h = blockIdx.y, b = blockIdx.z;
    const int tid = threadIdx.x;
    const int lane = tid & 63, w = tid >> 6;
    const int lr = lane & 15, lg = lane >> 4;

    const long base = (long)b * TT * 3072;
    const __hip_bfloat16* Kg = qkvb + base + 1024 + h * 64;
    const __hip_bfloat16* Vg = qkvb + base + 2048 + h * 64;

    // Q fragments, pre-scaled by 1/32 (exact: exponent shift only)
    s16x8 qf[2];
    {
        int qr = q0 + w * 16 + lr;
        #pragma unroll
        for (int kc = 0; kc < 2; ++kc) {
            s16x8 hv = (s16x8){0,0,0,0,0,0,0,0};
            if (qr < TT) {
                hv = *(const s16x8*)(qkvb + base + (long)qr * 3072 + h * 64 + kc * 32 + lg * 8);
                #pragma unroll
                for (int e = 0; e < 8; ++e)
                    hv[e] = f2b(b2f(hv[e]) * 0.03125f);
            }
            qf[kc] = hv;
        }
    }

    f32x4 acc[4];
    #pragma unroll
    for (int jd = 0; jd < 4; ++jd) acc[jd] = (f32x4){0.f, 0.f, 0.f, 0.f};
    float mrun[4] = {-3.0e38f, -3.0e38f, -3.0e38f, -3.0e38f};
    float lrun[4] = {0.f, 0.f, 0.f, 0.f};

    const int send = CAUSAL ? min(TT, q0 + 64) : TT;
    const int nt = (send + 127) >> 7;
    const int sr4 = (tid >> 3) * 4;        // rows sr4..sr4+3
    const int dcc = (tid & 7) * 8;         // col chunk

    s16x8 kreg[4], vreg[4];
    auto loadkv = [&](int t) {
        int sbase = t * 128;
        #pragma unroll
        for (int rr = 0; rr < 4; ++rr) {
            int sg = sbase + sr4 + rr;
            if (sg < TT) {
                kreg[rr] = *(const s16x8*)(Kg + (long)sg * 3072 + dcc);
                vreg[rr] = *(const s16x8*)(Vg + (long)sg * 3072 + dcc);
            } else {
                kreg[rr] = (s16x8){0,0,0,0,0,0,0,0};
                vreg[rr] = (s16x8){0,0,0,0,0,0,0,0};
            }
        }
    };

    loadkv(0);
    for (int ti = 0; ti < nt; ++ti) {
        const int s0 = ti * 128;
        SCHED0; SBAR; SCHED0;          // prev tile's LDS reads done (all waves)
        #pragma unroll
        for (int rr = 0; rr < 4; ++rr)
            *(s16x8*)&Ks[sr4 + rr][dcc] = kreg[rr];
        #pragma unroll
        for (int pr = 0; pr < 2; ++pr) {
            #pragma unroll
            for (int e = 0; e < 8; ++e) {
                unsigned pack = (unsigned)(unsigned short)vreg[2*pr][e]
                              | ((unsigned)(unsigned short)vreg[2*pr + 1][e] << 16);
                *(unsigned*)&Vt[dcc + e][sr4 + 2*pr] = pack;
            }
        }
        if (ti + 1 < nt) loadkv(ti + 1);   // issue next tile's loads early
        SCHED0; LGKMCNT0; SCHED0; SBAR; SCHED0;   // LDS writes visible

        // ---- S = (Q/32) K^T over 128 kv cols ----
        f32x4 sf[8];
        __builtin_amdgcn_s_setprio(1);
        #pragma unroll
        for (int j = 0; j < 8; ++j) {
            f32x4 z = (f32x4){0.f, 0.f, 0.f, 0.f};
            #pragma unroll
            for (int kc = 0; kc < 2; ++kc) {
                s16x8 kf = *(const s16x8*)&Ks[j * 16 + lr][kc * 32 + lg * 8];
                z = __builtin_amdgcn_mfma_f32_16x16x32_bf16(qf[kc], kf, z, 0, 0, 0);
            }
            sf[j] = z;
        }
        __builtin_amdgcn_s_setprio(0);

        float mloc[4] = {-3.0e38f, -3.0e38f, -3.0e38f, -3.0e38f};
        #pragma unroll
        for (int j = 0; j < 8; ++j) {
            int sg = s0 + j * 16 + lr;
            #pragma unroll
            for (int r = 0; r < 4; ++r) {
                float sc = sf[j][r];
                int qg = q0 + w * 16 + lg * 4 + r;
                if ((CAUSAL && sg > qg) || sg >= TT) sc = -3.0e38f;
                sf[j][r] = sc;
                mloc[r] = fmaxf(mloc[r], sc);
            }
        }
        #pragma unroll
        for (int r = 0; r < 4; ++r)
            #pragma unroll
            for (int off = 1; off < 16; off <<= 1)
                mloc[r] = fmaxf(mloc[r], __shfl_xor(mloc[r], off));

        // ---- T13 defer-max: rescale only if some row's max grew > 8 ----
        bool grow = false;
        #pragma unroll
        for (int r = 0; r < 4; ++r)
            grow = grow || (mloc[r] > mrun[r] + 8.0f);
        if (__any((int)grow)) {
            #pragma unroll
            for (int r = 0; r < 4; ++r) {
                float mn = fmaxf(mrun[r], mloc[r]);
                float corr = __expf(mrun[r] - mn);
                mrun[r] = mn;
                lrun[r] *= corr;
                #pragma unroll
                for (int jd = 0; jd < 4; ++jd) acc[jd][r] *= corr;
            }
        }

        float psum[4] = {0.f, 0.f, 0.f, 0.f};
        #pragma unroll
        for (int j = 0; j < 8; ++j) {
            #pragma unroll
            for (int r = 0; r < 4; ++r) {
                float p = __expf(sf[j][r] - mrun[r]);
                psum[r] += p;
                Ps[w][lg * 4 + r][j * 16 + lr] = f2b(p);
            }
        }
        #pragma unroll
        for (int r = 0; r < 4; ++r) {
            #pragma unroll
            for (int off = 1; off < 16; off <<= 1)
                psum[r] += __shfl_xor(psum[r], off);
            lrun[r] += psum[r];
        }

        // ---- O += P @ V over K=128 ----
        __builtin_amdgcn_s_setprio(1);
        #pragma unroll
        for (int kc = 0; kc < 4; ++kc) {
            s16x8 pa = *(const s16x8*)&Ps[w][lr][kc * 32 + lg * 8];
            #pragma unroll
            for (int jd = 0; jd < 4; ++jd) {
                s16x8 bv = *(const s16x8*)&Vt[jd * 16 + lr][kc * 32 + lg * 8];
                acc[jd] = __builtin_amdgcn_mfma_f32_16x16x32_bf16(pa, bv, acc[jd], 0, 0, 0);
            }
        }
        __builtin_amdgcn_s_setprio(0);
        SCHED0; LGKMCNT0; SCHED0;      // my LDS reads complete before next write
    }

    #pragma unroll
    for (int r = 0; r < 4; ++r) {
        int qg = q0 + w * 16 + lg * 4 + r;
        if (qg >= TT) continue;
        float inv = 1.0f / lrun[r];
        #pragma unroll
        for (int jd = 0; jd < 4; ++jd)
            outb[((long)b * TT + qg) * CC + h * 64 + jd * 16 + lr] =
                __float2bfloat16(acc[jd][r] * inv);
    }
}

// ---------------------------------------------------------------------------
// LayerNorm from fp32 input (+optional residual), fp32 out + bf16 mirror.
// ---------------------------------------------------------------------------
__global__ __launch_bounds__(256) void ln_kernel(
    const float* __restrict__ in, const float* __restrict__ res,
    const float* __restrict__ g, const float* __restrict__ b,
    float* __restrict__ out, __hip_bfloat16* __restrict__ outb)
{
    const int r = blockIdx.x, tid = threadIdx.x;
    __shared__ float sm[4];

    float4 xv = *(const float4*)(in + (long)r * CC + tid * 4);
    float s = xv.x + xv.y + xv.z + xv.w;
    #pragma unroll
    for (int o = 32; o > 0; o >>= 1) s += __shfl_xor(s, o);
    if ((tid & 63) == 0) sm[tid >> 6] = s;
    __syncthreads();
    const float mean = (sm[0] + sm[1] + sm[2] + sm[3]) * (1.0f / CC);
    __syncthreads();

    float4 d; d.x = xv.x - mean; d.y = xv.y - mean; d.z = xv.z - mean; d.w = xv.w - mean;
    float s2 = d.x * d.x + d.y * d.y + d.z * d.z + d.w * d.w;
    #pragma unroll
    for (int o = 32; o > 0; o >>= 1) s2 += __shfl_xor(s2, o);
    if ((tid & 63) == 0) sm[tid >> 6] = s2;
    __syncthreads();
    const float rstd = rsqrtf((sm[0] + sm[1] + sm[2] + sm[3]) * (1.0f / CC) + 1e-5f);

    float4 gv = *(const float4*)(g + tid * 4);
    float4 bv = *(const float4*)(b + tid * 4);
    float4 o;
    o.x = gv.x * d.x * rstd + bv.x; o.y = gv.y * d.y * rstd + bv.y;
    o.z = gv.z * d.z * rstd + bv.z; o.w = gv.w * d.w * rstd + bv.w;
    if (res) {
        float4 rv = *(const float4*)(res + (long)r * CC + tid * 4);
        o.x += rv.x; o.y += rv.y; o.z += rv.z; o.w += rv.w;
    }
    *(float4*)(out + (long)r * CC + tid * 4) = o;
    if (outb) {
        s16x4 h; h[0] = f2b(o.x); h[1] = f2b(o.y); h[2] = f2b(o.z); h[3] = f2b(o.w);
        *(s16x4*)(outb + (long)r * CC + tid * 4) = h;
    }
}

// ---------------------------------------------------------------------------
// LayerNorm from bf16 input (+fp32 residual), fp32 out + bf16 mirror.
// ---------------------------------------------------------------------------
__global__ __launch_bounds__(256) void lnb_kernel(
    const __hip_bfloat16* __restrict__ in, const float* __restrict__ res,
    const float* __restrict__ g, const float* __restrict__ b,
    float* __restrict__ out, __hip_bfloat16* __restrict__ outb)
{
    const int r = blockIdx.x, tid = threadIdx.x;
    __shared__ float sm[4];

    s16x4 hv = *(const s16x4*)((const short*)in + (long)r * CC + tid * 4);
    float4 xv;
    xv.x = b2f(hv[0]); xv.y = b2f(hv[1]); xv.z = b2f(hv[2]); xv.w = b2f(hv[3]);
    float s = xv.x + xv.y + xv.z + xv.w;
    #pragma unroll
    for (int o = 32; o > 0; o >>= 1) s += __shfl_xor(s, o);
    if ((tid & 63) == 0) sm[tid >> 6] = s;
    __syncthreads();
    const float mean = (sm[0] + sm[1] + sm[2] + sm[3]) * (1.0f / CC);
    __syncthreads();

    float4 d; d.x = xv.x - mean; d.y = xv.y - mean; d.z = xv.z - mean; d.w = xv.w - mean;
    float s2 = d.x * d.x + d.y * d.y + d.z * d.z + d.w * d.w;
    #pragma unroll
    for (int o = 32; o > 0; o >>= 1) s2 += __shfl_xor(s2, o);
    if ((tid & 63) == 0) sm[tid >> 6] = s2;
    __syncthreads();
    const float rstd = rsqrtf((sm[0] + sm[1] + sm[2] + sm[3]) * (1.0f / CC) + 1e-5f);

    float4 gv = *(const float4*)(g + tid * 4);
    float4 bv = *(const float4*)(b + tid * 4);
    float4 o;
    o.x = gv.x * d.x * rstd + bv.x; o.y = gv.y * d.y * rstd + bv.y;
    o.z = gv.z * d.z * rstd + bv.z; o.w = gv.w * d.w * rstd + bv.w;
    if (res) {
        float4 rv = *(const float4*)(res + (long)r * CC + tid * 4);
        o.x += rv.x; o.y += rv.y; o.z += rv.z; o.w += rv.w;
    }
    *(float4*)(out + (long)r * CC + tid * 4) = o;
    s16x4 hh; hh[0] = f2b(o.x); hh[1] = f2b(o.y); hh[2] = f2b(o.z); hh[3] = f2b(o.w);
    *(s16x4*)((short*)outb + (long)r * CC + tid * 4) = hh;
}

// ---------------------------------------------------------------------------
extern "C" void kernel_launch(void* const* d_in, const int* in_sizes, int n_in,
                              void* d_out, int out_size, void* d_ws, size_t ws_size,
                              hipStream_t stream)
{
    const int*   x      = (const int*)  d_in[0];
    const int*   y      = (const int*)  d_in[1];
    const float* wte    = (const float*)d_in[2];
    const float* wpe_x  = (const float*)d_in[3];
    const float* wpe_y  = (const float*)d_in[4];
    const float* eWq    = (const float*)d_in[5];
    const float* eWk    = (const float*)d_in[6];
    const float* eWv    = (const float*)d_in[7];
    const float* epw    = (const float*)d_in[8];
    const float* epb    = (const float*)d_in[9];
    const float* eln1g  = (const float*)d_in[10];
    const float* eln1b  = (const float*)d_in[11];
    const float* eln2g  = (const float*)d_in[12];
    const float* eln2b  = (const float*)d_in[13];
    const float* ew1    = (const float*)d_in[14];
    const float* eb1    = (const float*)d_in[15];
    const float* ew2    = (const float*)d_in[16];
    const float* eb2    = (const float*)d_in[17];
    const float* dsWq   = (const float*)d_in[18];
    const float* dsWk   = (const float*)d_in[19];
    const float* dsWv   = (const float*)d_in[20];
    const float* dspw   = (const float*)d_in[21];
    const float* dspb   = (const float*)d_in[22];
    const float* dcWq   = (const float*)d_in[23];
    const float* dcWk   = (const float*)d_in[24];
    const float* dcWv   = (const float*)d_in[25];
    const float* dcpw   = (const float*)d_in[26];
    const float* dcpb   = (const float*)d_in[27];
    const float* dln1g  = (const float*)d_in[28];
    const float* dln1b  = (const float*)d_in[29];
    const float* dln2g  = (const float*)d_in[30];
    const float* dln2b  = (const float*)d_in[31];
    const float* dln3g  = (const float*)d_in[32];
    const float* dln3b  = (const float*)d_in[33];
    const float* dw1    = (const float*)d_in[34];
    const float* db1    = (const float*)d_in[35];
    const float* dw2    = (const float*)d_in[36];
    const float* db2    = (const float*)d_in[37];
    const float* lnfg   = (const float*)d_in[38];
    const float* lnfb   = (const float*)d_in[39];
    const float* lm_b   = (const float*)d_in[40];

    float* out = (float*)d_out;

    // ---- workspace carve-up ----
    const size_t MCp = (size_t)MP * CC;
    float* enc = (float*)d_ws;
    float* dec = enc + MCp;
    float* t0  = dec + MCp;
    __hip_bfloat16* encb = (__hip_bfloat16*)(t0 + MCp);
    __hip_bfloat16* decb = encb + MCp;
    __hip_bfloat16* t0b  = decb + MCp;
    __hip_bfloat16* a0b  = t0b + MCp;
    __hip_bfloat16* qkvb = a0b + MCp;                    // [MP][3072]
    __hip_bfloat16* ffb  = qkvb + (size_t)MP * 3072;     // [MP][FFD]
    __hip_bfloat16* wteb = ffb + (size_t)MP * FFD;       // [VP][C]
    // big-mode weight blocks
    __hip_bfloat16* eQKVw = wteb + (size_t)VP * CC;      // [L][3072][C]
    __hip_bfloat16* ePWw  = eQKVw + (size_t)LL * 3072 * CC;
    __hip_bfloat16* eW1w  = ePWw  + (size_t)LL * CC * CC;     // [L][FFD][C]
    __hip_bfloat16* eW2w  = eW1w  + (size_t)LL * FFD * CC;    // [L][C][FFD]
    __hip_bfloat16* sQKVw = eW2w  + (size_t)LL * CC * FFD;
    __hip_bfloat16* sPWw  = sQKVw + (size_t)LL * 3072 * CC;
    __hip_bfloat16* cQKVw = sPWw  + (size_t)LL * CC * CC;
    __hip_bfloat16* cPWw  = cQKVw + (size_t)LL * 3072 * CC;
    __hip_bfloat16* dW1w  = cPWw  + (size_t)LL * CC * CC;
    __hip_bfloat16* dW2w  = dW1w  + (size_t)LL * FFD * CC;
    __hip_bfloat16* bigEnd = dW2w + (size_t)LL * CC * FFD;
    // small-mode: per-use conversion buffer where eQKVw starts
    __hip_bfloat16* wb = eQKVw;
    const size_t needBig   = (size_t)((char*)bigEnd - (char*)d_ws);
    const size_t needSmall = (size_t)((char*)(wb + (size_t)FFD * CC) - (char*)d_ws);
    const size_t needWteb  = (size_t)((char*)eQKVw - (char*)d_ws);
    const bool big     = (ws_size >= needBig);
    const bool useWteb = (ws_size >= needWteb) &&
                         (big || ws_size >= needSmall);

    const int QT = (TT + 63) / 64;     // 16 q-tiles
    const dim3 tblk(32, 8);

    auto gemm = [&](const __hip_bfloat16* A, const __hip_bfloat16* B,
                    const float* bias, float* Cm, __hip_bfloat16* Cb,
                    int N_, int K_, int ldc, int wmode, bool relu) {
        const bool b64 = (N_ <= 2048);          // small-N: double the grid
        const int GMv = b64 ? MP / 64 : MP / 128;
        int nwg = GMv * ((N_ + 127) / 128);
        if (wmode == 0) {
            if (b64) {
                if (relu) mgemm2_kernel<0, true , true ><<<nwg, 256, 0, stream>>>(A, B, bias, Cm, Cb, MM, N_, K_, ldc, GMv);
                else      mgemm2_kernel<0, false, true ><<<nwg, 256, 0, stream>>>(A, B, bias, Cm, Cb, MM, N_, K_, ldc, GMv);
            } else {
                if (relu) mgemm2_kernel<0, true , false><<<nwg, 256, 0, stream>>>(A, B, bias, Cm, Cb, MM, N_, K_, ldc, GMv);
                else      mgemm2_kernel<0, false, false><<<nwg, 256, 0, stream>>>(A, B, bias, Cm, Cb, MM, N_, K_, ldc, GMv);
            }
        } else {
            if (b64) {
                if (relu) mgemm2_kernel<2, true , true ><<<nwg, 256, 0, stream>>>(A, B, bias, Cm, Cb, MM, N_, K_, ldc, GMv);
                else      mgemm2_kernel<2, false, true ><<<nwg, 256, 0, stream>>>(A, B, bias, Cm, Cb, MM, N_, K_, ldc, GMv);
            } else {
                if (relu) mgemm2_kernel<2, true , false><<<nwg, 256, 0, stream>>>(A, B, bias, Cm, Cb, MM, N_, K_, ldc, GMv);
                else      mgemm2_kernel<2, false, false><<<nwg, 256, 0, stream>>>(A, B, bias, Cm, Cb, MM, N_, K_, ldc, GMv);
            }
        }
    };

    if (useWteb) {
        long n = (long)VV * CC;
        cvtb_kernel<<<(int)((n / 8 + 255) / 256), 256, 0, stream>>>(wte, wteb, n);
    }

    if (big) {
        // ---- all weight conversions up-front ----
        const long sWH = (long)CC * HSZ;            // per-(l,h) input stride
        const long oA = (long)3072 * CC;            // per-layer qkv out stride
        const long oB = (long)HSZ * CC;             // per-head out stride
        dim3 gq(HSZ / 32, CC / 32, LL * HH);
        tcvt_kernel<<<gq, tblk, 0, stream>>>(eWq, eQKVw,             CC, HSZ, sWH, oA, oB, HH);
        tcvt_kernel<<<gq, tblk, 0, stream>>>(eWk, eQKVw + CC * CC,   CC, HSZ, sWH, oA, oB, HH);
        tcvt_kernel<<<gq, tblk, 0, stream>>>(eWv, eQKVw + 2*CC*CC,   CC, HSZ, sWH, oA, oB, HH);
        tcvt_kernel<<<gq, tblk, 0, stream>>>(dsWq, sQKVw,            CC, HSZ, sWH, oA, oB, HH);
        tcvt_kernel<<<gq, tblk, 0, stream>>>(dsWk, sQKVw + CC * CC,  CC, HSZ, sWH, oA, oB, HH);
        tcvt_kernel<<<gq, tblk, 0, stream>>>(dsWv, sQKVw + 2*CC*CC,  CC, HSZ, sWH, oA, oB, HH);
        tcvt_kernel<<<gq, tblk, 0, stream>>>(dcWq, cQKVw,            CC, HSZ, sWH, oA, oB, HH);
        tcvt_kernel<<<gq, tblk, 0, stream>>>(dcWk, cQKVw + CC * CC,  CC, HSZ, sWH, oA, oB, HH);
        tcvt_kernel<<<gq, tblk, 0, stream>>>(dcWv, cQKVw + 2*CC*CC,  CC, HSZ, sWH, oA, oB, HH);
        dim3 gp(CC / 32, CC / 32, LL);
        tcvt_kernel<<<gp, tblk, 0, stream>>>(epw,  ePWw, CC, CC, (long)CC*CC, (long)CC*CC, 0, 1);
        tcvt_kernel<<<gp, tblk, 0, stream>>>(dspw, sPWw, CC, CC, (long)CC*CC, (long)CC*CC, 0, 1);
        tcvt_kernel<<<gp, tblk, 0, stream>>>(dcpw, cPWw, CC, CC, (long)CC*CC, (long)CC*CC, 0, 1);
        dim3 g1(FFD / 32, CC / 32, LL);
        tcvt_kernel<<<g1, tblk, 0, stream>>>(ew1, eW1w, CC, FFD, (long)CC*FFD, (long)FFD*CC, 0, 1);
        tcvt_kernel<<<g1, tblk, 0, stream>>>(dw1, dW1w, CC, FFD, (long)CC*FFD, (long)FFD*CC, 0, 1);
        dim3 g2(CC / 32, FFD / 32, LL);
        tcvt_kernel<<<g2, tblk, 0, stream>>>(ew2, eW2w, FFD, CC, (long)FFD*CC, (long)CC*FFD, 0, 1);
        tcvt_kernel<<<g2, tblk, 0, stream>>>(dw2, dW2w, FFD, CC, (long)FFD*CC, (long)CC*FFD, 0, 1);
    }

    // small-mode per-use converters
    auto cvt_qkv = [&](const float* Wq, const float* Wk, const float* Wv) {
        dim3 g(HSZ / 32, CC / 32, HH);
        tcvt_kernel<<<g, tblk, 0, stream>>>(Wq, wb,             CC, HSZ, (long)CC*HSZ, (long)HSZ*CC, 0, 1);
        tcvt_kernel<<<g, tblk, 0, stream>>>(Wk, wb + CC*CC,     CC, HSZ, (long)CC*HSZ, (long)HSZ*CC, 0, 1);
        tcvt_kernel<<<g, tblk, 0, stream>>>(Wv, wb + 2*CC*CC,   CC, HSZ, (long)CC*HSZ, (long)HSZ*CC, 0, 1);
    };
    auto cvt_nt = [&](const float* W, int R, int S) {
        dim3 g(S / 32, R / 32, 1);
        tcvt_kernel<<<g, tblk, 0, stream>>>(W, wb, R, S, 0, 0, 0, 1);
    };

    // ---- encoder ----
    embed_kernel<<<MM, 256, 0, stream>>>(x, wte, wpe_x, enc, encb);
    for (int i = 0; i < LL; ++i) {
        const long cOff = (long)i * CC;
        const __hip_bfloat16 *Wqkv, *Wp, *W1, *W2;
        if (big) {
            Wqkv = eQKVw + (size_t)i * 3072 * CC;
            Wp   = ePWw  + (size_t)i * CC * CC;
            W1   = eW1w  + (size_t)i * FFD * CC;
            W2   = eW2w  + (size_t)i * CC * FFD;
        }
        if (!big) cvt_qkv(eWq + (long)i*HH*CC*HSZ, eWk + (long)i*HH*CC*HSZ, eWv + (long)i*HH*CC*HSZ), Wqkv = wb;
        gemm(encb, Wqkv, nullptr, nullptr, qkvb, 3072, CC, 3072, 2, false);
        fattn_kernel<false><<<dim3(QT, HH, BB), 256, 0, stream>>>(qkvb, a0b);
        if (!big) cvt_nt(epw + (long)i*CC*CC, CC, CC), Wp = wb;
        gemm(a0b, Wp, epb + cOff, nullptr, t0b, CC, CC, CC, 2, false);
        lnb_kernel<<<MM, 256, 0, stream>>>(t0b, enc, eln1g + cOff, eln1b + cOff, enc, encb);
        if (!big) cvt_nt(ew1 + (long)i*CC*FFD, CC, FFD), W1 = wb;
        gemm(encb, W1, eb1 + (long)i*FFD, nullptr, ffb, FFD, CC, FFD, 2, true);
        if (!big) cvt_nt(ew2 + (long)i*FFD*CC, FFD, CC), W2 = wb;
        gemm(ffb, W2, eb2 + cOff, nullptr, t0b, CC, FFD, CC, 2, false);
        lnb_kernel<<<MM, 256, 0, stream>>>(t0b, enc, eln2g + cOff, eln2b + cOff, enc, encb);
    }

    // ---- decoder ----
    embed_kernel<<<MM, 256, 0, stream>>>(y, wte, wpe_y, dec, decb);
    for (int i = 0; i < LL; ++i) {
        const long cOff = (long)i * CC;
        const __hip_bfloat16 *Ws, *Wsp, *Wc, *Wcp, *W1, *W2;
        if (big) {
            Ws  = sQKVw + (size_t)i * 3072 * CC;
            Wsp = sPWw  + (size_t)i * CC * CC;
            Wc  = cQKVw + (size_t)i * 3072 * CC;
            Wcp = cPWw  + (size_t)i * CC * CC;
            W1  = dW1w  + (size_t)i * FFD * CC;
            W2  = dW2w  + (size_t)i * CC * FFD;
        }
        // masked self-attn
        if (!big) cvt_qkv(dsWq + (long)i*HH*CC*HSZ, dsWk + (long)i*HH*CC*HSZ, dsWv + (long)i*HH*CC*HSZ), Ws = wb;
        gemm(decb, Ws, nullptr, nullptr, qkvb, 3072, CC, 3072, 2, false);
        fattn_kernel<true><<<dim3(QT, HH, BB), 256, 0, stream>>>(qkvb, a0b);
        if (!big) cvt_nt(dspw + (long)i*CC*CC, CC, CC), Wsp = wb;
        gemm(a0b, Wsp, dspb + cOff, nullptr, t0b, CC, CC, CC, 2, false);
        lnb_kernel<<<MM, 256, 0, stream>>>(t0b, dec, dln1g + cOff, dln1b + cOff, dec, decb);
        // cross-attn: q from dec, k/v from enc
        if (!big) cvt_qkv(dcWq + (long)i*HH*CC*HSZ, dcWk + (long)i*HH*CC*HSZ, dcWv + (long)i*HH*CC*HSZ), Wc = wb;
        gemm(decb, Wc, nullptr, nullptr, qkvb, CC, CC, 3072, 2, false);
        gemm(encb, Wc + (size_t)CC * CC, nullptr, nullptr, qkvb + CC, 2048, CC, 3072, 2, false);
        fattn_kernel<false><<<dim3(QT, HH, BB), 256, 0, stream>>>(qkvb, a0b);
        if (!big) cvt_nt(dcpw + (long)i*CC*CC, CC, CC), Wcp = wb;
        gemm(a0b, Wcp, dcpb + cOff, nullptr, t0b, CC, CC, CC, 2, false);
        lnb_kernel<<<MM, 256, 0, stream>>>(t0b, dec, dln2g + cOff, dln2b + cOff, dec, decb);
        // ffn
        if (!big) cvt_nt(dw1 + (long)i*CC*FFD, CC, FFD), W1 = wb;
        gemm(decb, W1, db1 + (long)i*FFD, nullptr, ffb, FFD, CC, FFD, 2, true);
        if (!big) cvt_nt(dw2 + (long)i*FFD*CC, FFD, CC), W2 = wb;
        gemm(ffb, W2, db2 + cOff, nullptr, t0b, CC, FFD, CC, 2, false);
        lnb_kernel<<<MM, 256, 0, stream>>>(t0b, dec, dln3g + cOff, dln3b + cOff, dec, decb);
    }

    // ---- final LN + logits (M-split: keep the 2 MB A half-panel L2-resident) ----
    ln_kernel<<<MM, 256, 0, stream>>>(dec, nullptr, lnfg, lnfb, t0, t0b);
    if (useWteb) {
        const int GMv = 1024 / 128;                 // 8 m-tiles per half
        const int nwg = GMv * ((VV + 127) / 128);
        mgemm2_kernel<0, false, false><<<nwg, 256, 0, stream>>>(
            t0b, wteb, lm_b, out, nullptr, 1024, VV, CC, VV, GMv);
        mgemm2_kernel<0, false, false><<<nwg, 256, 0, stream>>>(
            t0b + (size_t)1024 * CC, wteb, lm_b, out + (size_t)1024 * VV, nullptr,
            MM - 1024, VV, CC, VV, GMv);
    } else {
        dim3 grid((VV + 127) / 128, MP / 128);
        mgemm_f32b_kernel<<<grid, 256, 0, stream>>>(t0, wte, lm_b, out, MM, VV, CC, VV);
    }
}